// Round 1
// 2691.101 us; speedup vs baseline: 1.1886x; 1.1886x over previous
//
#include <hip/hip_runtime.h>
#include <hip/hip_bf16.h>

using bf16 = __hip_bfloat16;
typedef __attribute__((ext_vector_type(8))) short short8;     // 8 bf16 (4 VGPRs)
typedef __attribute__((ext_vector_type(4))) float floatx4;    // MFMA acc

// Problem constants
constexpr int kB = 8, kT = 512, kE = 1024, kH = 16, kA = 64, kNF = 64, kHS = 64;
constexpr int kMLP = 4096, kT2 = 1024, kNFREQ = 255, kKTOP = 5;

constexpr int TAG_F32 = 0, TAG_BF16 = 1, TAG_AUTO = 2;

// ---------------- workspace arena (BYTE offsets) ----------------------------
// XC 16.78M | SMALL 4.36M | FLAG 64 | WREG 20.97M (phase-reused weight xposes)
// | ACT 67.11M (phase-reused activations).  Total 109.2 MB < 117.6 MB proven.
constexpr long BOFF_XC    = 0;                          // fp32 (B,T,E)
constexpr long BOFF_SMALL = 16777216;                   // 4,360,192 B
constexpr long BOFF_FLAG  = 21137408;                   // 64 B
constexpr long BOFF_WREG  = 21137472;                   // 20,971,520 B
constexpr long BOFF_ACT   = 42108992;                   // 67,108,864 B
constexpr long WS_NEED    = BOFF_ACT + 67108864;        // 109,217,856 B

// WREG slots (bytes from BOFF_WREG)
constexpr long WR_Q   = 0;          // fp32 1024x1024 (4,194,304)
constexpr long WR_KV  = 4194304;    // fp32 2048x1024 (8,388,608)
constexpr long WR_AGO = 12582912;   // fp32 1024x1024
constexpr long WR_PRJ = 16777216;   // fp32 1024x1024
constexpr long WR_W1  = 0;          // bf16 4096x1024 (8,388,608)  [phase 4]
constexpr long WR_W2  = 8388608;    // bf16 1024x4096 (8,388,608)  [phase 4]

// ACT slots (bytes from BOFF_ACT)
constexpr long AC_N1   = 0;         // fp32 (B,T,E) 16.78M   (also ENCF / P lo-half / N1b+HID)
constexpr long AC_QBUF = 16777216;  // fp32 (B,T,E) 16.78M
constexpr long AC_KV   = 33554432;  // fp32 (B,T,2E) 33.55M
constexpr long AC_KA   = 0;         // bf16 (H,B,T,HS) 8.39M  (over N1, after N1 dead)
constexpr long AC_VA   = 8388608;   // bf16 (H,B,T,HS) 8.39M
constexpr long AC_ATT  = 33554432;  // fp32 (B,T,E) 16.78M    (over KV, after KV dead)
constexpr long AC_Y2   = 50331648;  // fp32 (B,T,E) 16.78M
constexpr long AC_P    = 0;         // fp32 (B,2T,E) 33.55M   [phase 3]
constexpr long AC_RE   = 33554432;  // fp32 (B,255,E) 8,355,840
constexpr long AC_IM   = 41910272;  // fp32 (B,255,E) 8,355,840
constexpr long AC_N1B  = 0;         // bf16 (B,T,E) 8.39M     [phase 4]
constexpr long AC_HID  = 8388608;   // bf16 (B,T,MLP) 33.55M  [phase 4]

// small-region float offsets (relative to BOFF_SMALL)
constexpr long F_TS = 0, F_AD1 = 8192, F_AD11 = 32768, F_AD2 = 57344, F_QA = 81920,
               F_C1 = 147456, F_H2 = 671744, F_G1 = 673280, F_MB = 697856,
               F_TRE = 706048, F_TIM = 747008, F_TIX = 787968, F_TRIG = 828928;

// output regions (element offsets)
constexpr long O0 = 0, O1 = 4194304, O2 = 4194816, O3 = 4456960;

// ---------------- helpers ---------------------------------------------------
__device__ inline float bf2f(bf16 h) {
    unsigned short u = *(unsigned short*)&h;
    return __uint_as_float((unsigned)u << 16);
}
__device__ inline unsigned short bfbits(bf16 b) { return *(unsigned short*)&b; }
__device__ inline float gelu_f(float x) {
    return 0.5f * x * (1.0f + erff(x * 0.7071067811865476f));
}
__device__ inline float4 load4f(const float* p) { return *(const float4*)p; }
__device__ inline float4 load4bf(const bf16* p) {
    ushort4 u = *(const ushort4*)p;
    float4 r;
    r.x = __uint_as_float((unsigned)u.x << 16);
    r.y = __uint_as_float((unsigned)u.y << 16);
    r.z = __uint_as_float((unsigned)u.z << 16);
    r.w = __uint_as_float((unsigned)u.w << 16);
    return r;
}
__device__ inline float4 load4auto(const void* p, long idx, bool isF32) {
    if (isF32) return load4f((const float*)p + idx);
    return load4bf((const bf16*)p + idx);
}
__device__ inline float ld1auto(const void* p, long idx, bool isF32) {
    if (isF32) return ((const float*)p)[idx];
    return bf2f(((const bf16*)p)[idx]);
}
__device__ inline void st1auto(void* p, long idx, bool isF32, float v) {
    if (isF32) ((float*)p)[idx] = v;
    else       ((bf16*)p)[idx] = __float2bfloat16(v);
}
__device__ inline float ldc1(const float* p) { return *p; }
__device__ inline float ldc1(const bf16* p) { return bf2f(*p); }
__device__ inline void stc1(float* p, float v) { *p = v; }
__device__ inline void stc1(bf16* p, float v) { *p = __float2bfloat16(v); }

__device__ inline void blockReduce2(float& a, float& b, float* sm) {
    #pragma unroll
    for (int m = 32; m > 0; m >>= 1) { a += __shfl_down(a, m); b += __shfl_down(b, m); }
    int w = threadIdx.x >> 6;
    if ((threadIdx.x & 63) == 0) { sm[w] = a; sm[4 + w] = b; }
    __syncthreads();
    a = sm[0] + sm[1] + sm[2] + sm[3];
    b = sm[4] + sm[5] + sm[6] + sm[7];
    __syncthreads();
}

// ---------------- dtype detector --------------------------------------------
__global__ void k_detect(const unsigned short* __restrict__ xraw, int* __restrict__ flag) {
    int tid = threadIdx.x;
    unsigned short h = xraw[2 * tid];
    float v = __uint_as_float((unsigned)h << 16);
    float av = fabsf(v);
    if (!(av == av)) av = 1e30f;
    __shared__ float red[4];
    for (int m = 32; m > 0; m >>= 1) av = fmaxf(av, __shfl_down(av, m));
    if ((tid & 63) == 0) red[tid >> 6] = av;
    __syncthreads();
    if (tid == 0) {
        float mx = fmaxf(fmaxf(red[0], red[1]), fmaxf(red[2], red[3]));
        flag[0] = (mx < 1e3f) ? 0 : 1;             // 0 = bf16, 1 = fp32
    }
}

// ---------------- small kernels ---------------------------------------------
__global__ void k_temb(const int* __restrict__ ts, float* __restrict__ out) {
    int b = blockIdx.x, i = threadIdx.x;           // 512 threads
    float t = (float)ts[b];
    const float rate = (float)(-9.210340371976184 / 511.0);
    float f = expf(rate * (float)i);
    float arg = t * f;
    float sv = sinf(arg), cv = cosf(arg);
    out[(long)b * kE + i]        = sv / (1.f + expf(-sv));
    out[(long)b * kE + 512 + i]  = cv / (1.f + expf(-cv));
}

__global__ void k_castin(const void* __restrict__ in, float* __restrict__ out,
                         const int* __restrict__ DF) {
    bool f = DF[0] != 0;
    long i = ((long)blockIdx.x * 256 + threadIdx.x) * 4;
    float4 v = load4auto(in, i, f);
    *(float4*)(out + i) = v;
}

// fp32 weight transpose: W[K][Ntot] (auto dtype), cols [c0, c0+Nout) -> WT[Nout][K] fp32
__global__ __launch_bounds__(256) void k_wtf(const void* __restrict__ W, float* __restrict__ WT,
                                             int K, int Ntot, int c0,
                                             const int* __restrict__ DF) {
    bool f = DF[0] != 0;
    __shared__ float tile[32][33];
    int n0 = blockIdx.x * 32, k0 = blockIdx.y * 32;
    int tx = threadIdx.x & 31, ty = threadIdx.x >> 5;
    #pragma unroll
    for (int i = 0; i < 4; i++) {
        int k = ty + i * 8;
        tile[k][tx] = ld1auto(W, (long)(k0 + k) * Ntot + c0 + n0 + tx, f);
    }
    __syncthreads();
    #pragma unroll
    for (int i = 0; i < 4; i++) {
        int n = ty + i * 8;
        WT[(long)(n0 + n) * K + k0 + tx] = tile[tx][n];
    }
}

// bf16 weight transpose (for MLP): W[K][N] -> WT[N][K] bf16
__global__ __launch_bounds__(256) void k_wt(const void* __restrict__ W, bf16* __restrict__ WT,
                                            int K, int N, const int* __restrict__ DF) {
    bool f = DF[0] != 0;
    __shared__ float tile[32][33];
    int n0 = blockIdx.x * 32, k0 = blockIdx.y * 32;
    int tx = threadIdx.x & 31, ty = threadIdx.x >> 5;
    #pragma unroll
    for (int i = 0; i < 4; i++) {
        int k = ty + i * 8;
        tile[k][tx] = ld1auto(W, (long)(k0 + k) * N + n0 + tx, f);
    }
    __syncthreads();
    #pragma unroll
    for (int i = 0; i < 4; i++) {
        int n = ty + i * 8;
        WT[(long)(n0 + n) * K + k0 + tx] = __float2bfloat16(tile[tx][n]);
    }
}

// adaLN -> fp32 out (phases 1,2)
__global__ __launch_bounds__(256) void k_adalnf(const float* __restrict__ X,
                                                const float* __restrict__ AD,
                                                float* __restrict__ N) {
    int row = blockIdx.x;
    int b = row / kT;
    const float* xr = X + (long)row * kE;
    int tid = threadIdx.x;
    float4 xv = *(const float4*)(xr + tid * 4);
    float s  = xv.x + xv.y + xv.z + xv.w;
    float sq = xv.x * xv.x + xv.y * xv.y + xv.z * xv.z + xv.w * xv.w;
    __shared__ float sm[8];
    blockReduce2(s, sq, sm);
    float mu  = s * (1.f / kE);
    float var = sq * (1.f / kE) - mu * mu;
    float rstd = rsqrtf(fmaxf(var, 0.f) + 1e-5f);
    const float* ad = AD + (long)b * 3 * kE;
    float* nr = N + (long)row * kE;
    float xs[4] = {xv.x, xv.y, xv.z, xv.w};
    #pragma unroll
    for (int j = 0; j < 4; j++) {
        int e = tid * 4 + j;
        float xn = (xs[j] - mu) * rstd;
        nr[e] = xn * (1.f + ad[kE + e]) + ad[e];
    }
}

// adaLN -> bf16 out (phase 4 / MLP)
__global__ __launch_bounds__(256) void k_adaln(const float* __restrict__ X,
                                               const float* __restrict__ AD,
                                               bf16* __restrict__ N) {
    int row = blockIdx.x;
    int b = row / kT;
    const float* xr = X + (long)row * kE;
    int tid = threadIdx.x;
    float4 xv = *(const float4*)(xr + tid * 4);
    float s  = xv.x + xv.y + xv.z + xv.w;
    float sq = xv.x * xv.x + xv.y * xv.y + xv.z * xv.z + xv.w * xv.w;
    __shared__ float sm[8];
    blockReduce2(s, sq, sm);
    float mu  = s * (1.f / kE);
    float var = sq * (1.f / kE) - mu * mu;
    float rstd = rsqrtf(fmaxf(var, 0.f) + 1e-5f);
    const float* ad = AD + (long)b * 3 * kE;
    bf16* nr = N + (long)row * kE;
    float xs[4] = {xv.x, xv.y, xv.z, xv.w};
    #pragma unroll
    for (int j = 0; j < 4; j++) {
        int e = tid * 4 + j;
        float xn = (xs[j] - mu) * rstd;
        nr[e] = __float2bfloat16(xn * (1.f + ad[kE + e]) + ad[e]);
    }
}

// ---------------- split-precision MFMA GEMM (fp32-accurate) -----------------
// C = A(fp32 MxK) @ WT(fp32 NxK)^T via hi/lo bf16 split: Ah*Bh + Ah*Bl + Al*Bh.
// Relative error ~8e-6 (vs 2e-3 plain bf16). M,N mult of 128, K mult of 32.
template <typename TC>
__global__ __launch_bounds__(256) void k_mfma32(
    const float* __restrict__ A, int lda,
    const float* __restrict__ WT,
    TC* __restrict__ C, int ldc,
    int M, int N, int K,
    const void* __restrict__ bias, int bTag, long biasOff,
    const float* __restrict__ alpha, int alphaStride, int rowsPerB,
    const int* __restrict__ DF) {
    constexpr int BK = 32, PAD = 8;                 // 40 elem (80 B) row stride
    __shared__ bf16 Ah[128][BK + PAD], Al[128][BK + PAD];
    __shared__ bf16 Bh[128][BK + PAD], Bl[128][BK + PAD];
    int tid = threadIdx.x;
    int wave = tid >> 6, lane = tid & 63;
    int bm = blockIdx.y * 128, bn = blockIdx.x * 128;
    int wm = (wave >> 1) * 64, wn = (wave & 1) * 64;
    int lm = lane & 15, quad = lane >> 4;
    floatx4 acc[4][4] = {};
    int sRow = tid >> 1, sCol = (tid & 1) * 16;      // 16 fp32 per thread per tile
    const float* ag = A  + (long)(bm + sRow) * lda + sCol;
    const float* bg = WT + (long)(bn + sRow) * K   + sCol;
    for (int k0 = 0; k0 < K; k0 += BK) {
        #pragma unroll
        for (int i = 0; i < 4; i++) {
            float4 v = *(const float4*)(ag + k0 + i * 4);
            bf16 h0 = __float2bfloat16(v.x), h1 = __float2bfloat16(v.y);
            bf16 h2 = __float2bfloat16(v.z), h3 = __float2bfloat16(v.w);
            bf16 l0 = __float2bfloat16(v.x - bf2f(h0));
            bf16 l1 = __float2bfloat16(v.y - bf2f(h1));
            bf16 l2 = __float2bfloat16(v.z - bf2f(h2));
            bf16 l3 = __float2bfloat16(v.w - bf2f(h3));
            ushort4 hv = {bfbits(h0), bfbits(h1), bfbits(h2), bfbits(h3)};
            ushort4 lv = {bfbits(l0), bfbits(l1), bfbits(l2), bfbits(l3)};
            *(ushort4*)&Ah[sRow][sCol + i * 4] = hv;
            *(ushort4*)&Al[sRow][sCol + i * 4] = lv;
        }
        #pragma unroll
        for (int i = 0; i < 4; i++) {
            float4 v = *(const float4*)(bg + k0 + i * 4);
            bf16 h0 = __float2bfloat16(v.x), h1 = __float2bfloat16(v.y);
            bf16 h2 = __float2bfloat16(v.z), h3 = __float2bfloat16(v.w);
            bf16 l0 = __float2bfloat16(v.x - bf2f(h0));
            bf16 l1 = __float2bfloat16(v.y - bf2f(h1));
            bf16 l2 = __float2bfloat16(v.z - bf2f(h2));
            bf16 l3 = __float2bfloat16(v.w - bf2f(h3));
            ushort4 hv = {bfbits(h0), bfbits(h1), bfbits(h2), bfbits(h3)};
            ushort4 lv = {bfbits(l0), bfbits(l1), bfbits(l2), bfbits(l3)};
            *(ushort4*)&Bh[sRow][sCol + i * 4] = hv;
            *(ushort4*)&Bl[sRow][sCol + i * 4] = lv;
        }
        __syncthreads();
        short8 ahf[4], alf[4], bhf[4], blf[4];
        #pragma unroll
        for (int mi = 0; mi < 4; mi++) {
            ahf[mi] = *(const short8*)&Ah[wm + mi * 16 + lm][quad * 8];
            alf[mi] = *(const short8*)&Al[wm + mi * 16 + lm][quad * 8];
        }
        #pragma unroll
        for (int ni = 0; ni < 4; ni++) {
            bhf[ni] = *(const short8*)&Bh[wn + ni * 16 + lm][quad * 8];
            blf[ni] = *(const short8*)&Bl[wn + ni * 16 + lm][quad * 8];
        }
        #pragma unroll
        for (int mi = 0; mi < 4; mi++)
            #pragma unroll
            for (int ni = 0; ni < 4; ni++) {
                acc[mi][ni] = __builtin_amdgcn_mfma_f32_16x16x32_bf16(ahf[mi], bhf[ni], acc[mi][ni], 0, 0, 0);
                acc[mi][ni] = __builtin_amdgcn_mfma_f32_16x16x32_bf16(ahf[mi], blf[ni], acc[mi][ni], 0, 0, 0);
                acc[mi][ni] = __builtin_amdgcn_mfma_f32_16x16x32_bf16(alf[mi], bhf[ni], acc[mi][ni], 0, 0, 0);
            }
        __syncthreads();
    }
    bool f32f = DF[0] != 0;
    bool bF = (bTag == TAG_F32) || (bTag == TAG_AUTO && f32f);
    #pragma unroll
    for (int ni = 0; ni < 4; ni++) {
        int col = bn + wn + ni * 16 + lm;
        float cb = bias ? ld1auto(bias, biasOff + col, bF) : 0.f;
        #pragma unroll
        for (int mi = 0; mi < 4; mi++) {
            #pragma unroll
            for (int reg = 0; reg < 4; reg++) {
                int row = bm + wm + mi * 16 + quad * 4 + reg;
                float v = acc[mi][ni][reg] + cb;
                TC* cp = C + (long)row * ldc + col;
                if (alpha) {
                    const float* al = alpha + (long)(row / rowsPerB) * alphaStride + col;
                    v = ldc1(cp) + al[0] * v;
                }
                stc1(cp, v);
            }
        }
    }
}

template <typename TC>
static void mgemm32(hipStream_t s, const float* A, int lda, const float* WT,
                    TC* C, int ldc, int M, int N, int K,
                    const void* bias, int bTag, long biasOff,
                    const float* alpha, int alphaStride, int rowsPerB, const int* DF) {
    dim3 g(N / 128, M / 128);
    k_mfma32<TC><<<g, 256, 0, s>>>(A, lda, WT, C, ldc, M, N, K,
                                   bias, bTag, biasOff, alpha, alphaStride, rowsPerB, DF);
}

// ---------------- plain bf16 MFMA GEMM (MLP only; post-season-critical) -----
template <typename TC>
__global__ __launch_bounds__(256) void k_mfma(
    const bf16* __restrict__ A, int lda,
    const bf16* __restrict__ WT,
    TC* __restrict__ C, int ldc,
    int M, int N, int K,
    const void* __restrict__ bias, int bTag, int act,
    const float* __restrict__ alpha, int alphaStride, int rowsPerB,
    const int* __restrict__ DF) {
    constexpr int BK = 64, PAD = 8;
    __shared__ bf16 As[128][BK + PAD];
    __shared__ bf16 Bs[128][BK + PAD];
    int tid = threadIdx.x;
    int wave = tid >> 6, lane = tid & 63;
    int bm = blockIdx.y * 128, bn = blockIdx.x * 128;
    int wm = (wave >> 1) * 64, wn = (wave & 1) * 64;
    int lm = lane & 15, quad = lane >> 4;
    floatx4 acc[4][4] = {};
    int sRow = tid >> 1, sCol = (tid & 1) * 32;
    const bf16* ag = A  + (long)(bm + sRow) * lda + sCol;
    const bf16* bg = WT + (long)(bn + sRow) * K   + sCol;
    for (int k0 = 0; k0 < K; k0 += BK) {
        #pragma unroll
        for (int i = 0; i < 4; i++)
            *(float4*)&As[sRow][sCol + i * 8] = *(const float4*)(ag + k0 + i * 8);
        #pragma unroll
        for (int i = 0; i < 4; i++)
            *(float4*)&Bs[sRow][sCol + i * 8] = *(const float4*)(bg + k0 + i * 8);
        __syncthreads();
        #pragma unroll
        for (int kk = 0; kk < BK; kk += 32) {
            short8 af[4], bf[4];
            #pragma unroll
            for (int mi = 0; mi < 4; mi++)
                af[mi] = *(const short8*)&As[wm + mi * 16 + lm][kk + quad * 8];
            #pragma unroll
            for (int ni = 0; ni < 4; ni++)
                bf[ni] = *(const short8*)&Bs[wn + ni * 16 + lm][kk + quad * 8];
            #pragma unroll
            for (int mi = 0; mi < 4; mi++)
                #pragma unroll
                for (int ni = 0; ni < 4; ni++)
                    acc[mi][ni] = __builtin_amdgcn_mfma_f32_16x16x32_bf16(
                        af[mi], bf[ni], acc[mi][ni], 0, 0, 0);
        }
        __syncthreads();
    }
    bool f32f = DF[0] != 0;
    bool bF = (bTag == TAG_F32) || (bTag == TAG_AUTO && f32f);
    #pragma unroll
    for (int ni = 0; ni < 4; ni++) {
        int col = bn + wn + ni * 16 + lm;
        float cb = bias ? ld1auto(bias, col, bF) : 0.f;
        #pragma unroll
        for (int mi = 0; mi < 4; mi++) {
            #pragma unroll
            for (int reg = 0; reg < 4; reg++) {
                int row = bm + wm + mi * 16 + quad * 4 + reg;
                float v = acc[mi][ni][reg] + cb;
                TC* cp = C + (long)row * ldc + col;
                if (alpha) {
                    const float* al = alpha + (long)(row / rowsPerB) * alphaStride + col;
                    v = ldc1(cp) + al[0] * v;
                } else if (act == 1) {
                    v = gelu_f(v);
                }
                stc1(cp, v);
            }
        }
    }
}

template <typename TC>
static void mgemm(hipStream_t s, const bf16* A, int lda, const bf16* WT,
                  TC* C, int ldc, int M, int N, int K,
                  const void* bias, int bTag, int act,
                  const float* alpha, int alphaStride, int rowsPerB, const int* DF) {
    dim3 g(N / 128, M / 128);
    k_mfma<TC><<<g, 256, 0, s>>>(A, lda, WT, C, ldc, M, N, K,
                                 bias, bTag, act, alpha, alphaStride, rowsPerB, DF);
}

// ---------------- generic tiled fp32-VALU GEMM ------------------------------
template <typename TC>
__global__ __launch_bounds__(256) void k_gemm(
    const void* __restrict__ Ab, int aTag, int lda, long bsA,
    const void* __restrict__ Wb, int wTag, int ldw, long bsW,
    TC* __restrict__ Cb, int ldc, long bsC,
    int M, int N, int K,
    const void* __restrict__ bias, int bTag, int biasRow, int act,
    const float* __restrict__ alpha, int alphaStride, int rowsPerB,
    const int* __restrict__ DF) {
    __shared__ float As[16][68];
    __shared__ float Bs[16][68];
    bool f32f = DF[0] != 0;
    bool aF = (aTag == TAG_F32) || (aTag == TAG_AUTO && f32f);
    bool wF = (wTag == TAG_F32) || (wTag == TAG_AUTO && f32f);
    bool bF = (bTag == TAG_F32) || (bTag == TAG_AUTO && f32f);
    TC* Cbase = Cb + (long)blockIdx.z * bsC;
    long aBase = (long)blockIdx.z * bsA;
    long wBase = (long)blockIdx.z * bsW;
    int tid = threadIdx.x;
    int bm = blockIdx.y, bn = blockIdx.x;
    int tx = tid & 15, ty = tid >> 4;
    int arow = tid >> 2, acol = (tid & 3) * 4;
    int wrow = tid >> 4, wcol = (tid & 15) * 4;
    int gArow = bm * 64 + arow;
    bool aValid = gArow < M;
    float acc[4][4] = {};
    for (int kk = 0; kk < K; kk += 16) {
        float4 av = {0.f, 0.f, 0.f, 0.f};
        if (aValid) av = load4auto(Ab, aBase + (long)gArow * lda + kk + acol, aF);
        As[acol + 0][arow] = av.x;
        As[acol + 1][arow] = av.y;
        As[acol + 2][arow] = av.z;
        As[acol + 3][arow] = av.w;
        float4 wv = load4auto(Wb, wBase + (long)(kk + wrow) * ldw + bn * 64 + wcol, wF);
        *(float4*)&Bs[wrow][wcol] = wv;
        __syncthreads();
        #pragma unroll
        for (int k = 0; k < 16; k++) {
            float4 a4 = *(const float4*)&As[k][ty * 4];
            float4 b4 = *(const float4*)&Bs[k][tx * 4];
            acc[0][0] += a4.x * b4.x; acc[0][1] += a4.x * b4.y; acc[0][2] += a4.x * b4.z; acc[0][3] += a4.x * b4.w;
            acc[1][0] += a4.y * b4.x; acc[1][1] += a4.y * b4.y; acc[1][2] += a4.y * b4.z; acc[1][3] += a4.y * b4.w;
            acc[2][0] += a4.z * b4.x; acc[2][1] += a4.z * b4.y; acc[2][2] += a4.z * b4.z; acc[2][3] += a4.z * b4.w;
            acc[3][0] += a4.w * b4.x; acc[3][1] += a4.w * b4.y; acc[3][2] += a4.w * b4.z; acc[3][3] += a4.w * b4.w;
        }
        __syncthreads();
    }
    int gcol = bn * 64 + tx * 4;
    float cb[4] = {0.f, 0.f, 0.f, 0.f};
    if (bias && !biasRow) {
        #pragma unroll
        for (int j = 0; j < 4; j++) cb[j] = ld1auto(bias, gcol + j, bF);
    }
    #pragma unroll
    for (int i = 0; i < 4; i++) {
        int grow = bm * 64 + ty * 4 + i;
        if (grow >= M) continue;
        float rb = (bias && biasRow) ? ld1auto(bias, grow, bF) : 0.f;
        TC* crow = Cbase + (long)grow * ldc + gcol;
        const float* al = nullptr;
        if (alpha) al = alpha + (long)(grow / rowsPerB) * alphaStride + gcol;
        #pragma unroll
        for (int j = 0; j < 4; j++) {
            float v = acc[i][j] + cb[j] + rb;
            if (alpha)         v = ldc1(crow + j) + al[j] * v;
            else if (act == 1) v = gelu_f(v);
            stc1(crow + j, v);
        }
    }
}

template <typename TC>
static void gemm(hipStream_t s, const void* A, int aTag, int lda, long bsA,
                 const void* W, int wTag, int ldw, long bsW,
                 TC* C, int ldc, long bsC, int M, int N, int K,
                 const void* bias, int bTag, int biasRow, int act,
                 const float* alpha, int alphaStride, int rowsPerB, int batch,
                 const int* DF) {
    dim3 g(N / 64, (M + 63) / 64, batch);
    k_gemm<TC><<<g, 256, 0, s>>>(A, aTag, lda, bsA, W, wTag, ldw, bsW, C, ldc, bsC,
                                 M, N, K, bias, bTag, biasRow, act,
                                 alpha, alphaStride, rowsPerB, DF);
}

// ---------------- agent attention stage 1 (ka/va bf16 -- as passing round 3)
__global__ __launch_bounds__(256) void k_agatt1(const float* __restrict__ qa,
                                                const bf16* __restrict__ ka,
                                                const bf16* __restrict__ va,
                                                float* __restrict__ c1) {
    int blk = blockIdx.x;
    int a = blk % kA;
    int h = (blk / kA) % kH;
    int b = blk / (kA * kH);
    __shared__ float qrow[kHS];
    __shared__ float probs[kT];
    __shared__ float sm[8];
    __shared__ float part[4][64];
    int tid = threadIdx.x;
    if (tid < kHS) qrow[tid] = qa[((long)h * kA + a) * kHS + tid];
    __syncthreads();
    const bf16* kab = ka + ((long)h * kB + b) * kT * kHS;
    float sc[2];
    #pragma unroll
    for (int rep = 0; rep < 2; rep++) {
        const bf16* kr = kab + (long)(tid + rep * 256) * kHS;
        float acc = 0.f;
        #pragma unroll
        for (int d = 0; d < kHS; d += 4) {
            float4 k4 = load4bf(kr + d);
            acc += k4.x * qrow[d] + k4.y * qrow[d + 1] + k4.z * qrow[d + 2] + k4.w * qrow[d + 3];
        }
        sc[rep] = acc * 0.125f;
    }
    float mx = fmaxf(sc[0], sc[1]);
    for (int m = 32; m > 0; m >>= 1) mx = fmaxf(mx, __shfl_down(mx, m));
    if ((tid & 63) == 0) sm[tid >> 6] = mx;
    __syncthreads();
    mx = fmaxf(fmaxf(sm[0], sm[1]), fmaxf(sm[2], sm[3]));
    float e0 = expf(sc[0] - mx), e1 = expf(sc[1] - mx);
    float ss = e0 + e1;
    for (int m = 32; m > 0; m >>= 1) ss += __shfl_down(ss, m);
    if ((tid & 63) == 0) sm[4 + (tid >> 6)] = ss;
    __syncthreads();
    ss = sm[4] + sm[5] + sm[6] + sm[7];
    float rs = 1.f / ss;
    probs[tid] = e0 * rs;
    probs[tid + 256] = e1 * rs;
    __syncthreads();
    int d = tid & 63, ch = tid >> 6;
    const bf16* vab = va + ((long)h * kB + b) * kT * kHS;
    float acc = 0.f;
    for (int n = ch * 128; n < (ch + 1) * 128; n++)
        acc += probs[n] * bf2f(vab[(long)n * kHS + d]);
    part[ch][d] = acc;
    __syncthreads();
    if (tid < 64)
        c1[(((long)b * kH + h) * kA + a) * kHS + tid] =
            part[0][tid] + part[1][tid] + part[2][tid] + part[3][tid];
}

// ---------------- agent attention stage 2 (fp32 in/out) ----------------------
__global__ __launch_bounds__(256) void k_agatt2f(const float* __restrict__ qsrc, int ldq,
                                                 const float* __restrict__ c1,
                                                 float* __restrict__ out) {
    int blk = blockIdx.x;
    int nt = blk % (kT / 16);
    int h = (blk / (kT / 16)) % kH;
    int b = blk / ((kT / 16) * kH);
    __shared__ float c1s[kA][kHS + 1];
    __shared__ float qs[16][kHS + 1];
    __shared__ float ps[16][kA + 1];
    int tid = threadIdx.x;
    const float* c1b = c1 + ((long)b * kH + h) * kA * kHS;
    for (int i = tid; i < kA * kHS; i += 256) c1s[i >> 6][i & 63] = c1b[i];
    int n0 = nt * 16;
    {
        int r = tid >> 4, d = (tid & 15) * 4;
        float4 q4 = load4f(qsrc + (long)(b * kT + n0 + r) * ldq + h * kHS + d);
        qs[r][d] = q4.x; qs[r][d + 1] = q4.y; qs[r][d + 2] = q4.z; qs[r][d + 3] = q4.w;
    }
    __syncthreads();
    int r = tid >> 4, c = tid & 15;
    float sc[4];
    #pragma unroll
    for (int j = 0; j < 4; j++) {
        int a = c * 4 + j;
        float acc = 0.f;
        for (int d = 0; d < kHS; d++) acc += qs[r][d] * c1s[a][d];
        sc[j] = acc * 0.125f;
    }
    float mx = fmaxf(fmaxf(sc[0], sc[1]), fmaxf(sc[2], sc[3]));
    for (int m = 1; m < 16; m <<= 1) mx = fmaxf(mx, __shfl_xor(mx, m));
    float e[4], ss = 0.f;
    #pragma unroll
    for (int j = 0; j < 4; j++) { e[j] = expf(sc[j] - mx); ss += e[j]; }
    for (int m = 1; m < 16; m <<= 1) ss += __shfl_xor(ss, m);
    float rs = 1.f / ss;
    #pragma unroll
    for (int j = 0; j < 4; j++) ps[r][c * 4 + j] = e[j] * rs;
    __syncthreads();
    float o0 = 0.f, o1 = 0.f, o2 = 0.f, o3 = 0.f;
    int d0 = c * 4;
    for (int a = 0; a < kA; a++) {
        float p = ps[r][a];
        o0 += p * c1s[a][d0 + 0];
        o1 += p * c1s[a][d0 + 1];
        o2 += p * c1s[a][d0 + 2];
        o3 += p * c1s[a][d0 + 3];
    }
    float* orow = out + (long)(b * kT + n0 + r) * kE + h * kHS + d0;
    orow[0] = o0; orow[1] = o1; orow[2] = o2; orow[3] = o3;
}

// ---------------- DFT tables --------------------------------------------------
__global__ void k_trig(float* __restrict__ trig) {
    int id = blockIdx.x * 256 + threadIdx.x;
    if (id >= kNFREQ * kT) return;
    int t = id & 511;
    int f = (id >> 9) + 1;
    int m = (f * t) & 511;
    double ang = (double)m * (2.0 * 3.14159265358979323846 / 512.0);
    trig[id] = (float)cos(ang);
    trig[kNFREQ * kT + id] = (float)(-sin(ang));
}

// ---------------- top-5 |X_f|^2 per (b,e) column ------------------------------
__global__ void k_topk(const float* __restrict__ RE, const float* __restrict__ IM,
                       float* __restrict__ tre, float* __restrict__ tim,
                       int* __restrict__ tix) {
    int id = blockIdx.x * 256 + threadIdx.x;
    int b = id >> 10, e = id & 1023;
    const float* rp = RE + (long)b * kNFREQ * kE + e;
    const float* ip = IM + (long)b * kNFREQ * kE + e;
    float bv[kKTOP] = {-1e30f, -1e30f, -1e30f, -1e30f, -1e30f};
    int bi[kKTOP] = {0, 0, 0, 0, 0};
    for (int f = 0; f < kNFREQ; f++) {
        float re = rp[(long)f * kE], im = ip[(long)f * kE];
        float m2 = re * re + im * im;
        if (m2 > bv[kKTOP - 1]) {
            int p = kKTOP - 1;
            while (p > 0 && m2 > bv[p - 1]) { bv[p] = bv[p - 1]; bi[p] = bi[p - 1]; p--; }
            bv[p] = m2; bi[p] = f;
        }
    }
    #pragma unroll
    for (int j = 0; j < kKTOP; j++) {
        int f = bi[j];
        tre[(long)id * kKTOP + j] = rp[(long)f * kE];
        tim[(long)id * kKTOP + j] = ip[(long)f * kE];
        tix[(long)id * kKTOP + j] = f;
    }
}

__global__ void k_season(const float* __restrict__ tre, const float* __restrict__ tim,
                         const int* __restrict__ tix, const float* __restrict__ trig,
                         void* __restrict__ out, long obase, const int* __restrict__ DF) {
    bool f32o = DF[0] != 0;
    long id = (long)blockIdx.x * 256 + threadIdx.x;
    int e = id & 1023;
    long bt = id >> 10;
    int t = (int)(bt & 511);
    int b = (int)(bt >> 9);
    long be = (long)b * kE + e;
    float acc = 0.f;
    #pragma unroll
    for (int j = 0; j < kKTOP; j++) {
        int f = tix[be * kKTOP + j];
        acc += tre[be * kKTOP + j] * trig[(long)f * kT + t]
             + tim[be * kKTOP + j] * trig[(long)kNFREQ * kT + (long)f * kT + t];
    }
    st1auto(out, obase + id, f32o, 2.f * acc);
}

// ---------------- trend branch ------------------------------------------------
__global__ void k_conv1(const float* __restrict__ P, const void* __restrict__ w,
                        const void* __restrict__ bias, float* __restrict__ G,
                        const int* __restrict__ DF) {
    bool f = DF[0] != 0;
    int id = blockIdx.x * 256 + threadIdx.x;
    int l = id & 1023;
    int o = (id >> 10) % 3;
    int b = id / (3 * 1024);
    const float* xb = P + (long)b * kT2 * kE;
    float acc = ld1auto(bias, o, f);
    for (int i = 0; i < 512; i++) {
        const float* xr = xb + (long)i * kE;
        long wo = ((long)o * 512 + i) * 3;
        float w0 = ld1auto(w, wo + 0, f), w1 = ld1auto(w, wo + 1, f), w2 = ld1auto(w, wo + 2, f);
        if (l > 0)    acc += xr[l - 1] * w0;
        acc += xr[l] * w1;
        if (l < 1023) acc += xr[l + 1] * w2;
    }
    G[id] = gelu_f(acc);
}

// conv2 re-parallelized: one workgroup per (b,n) output pair (512 blocks),
// 256 threads stride over i, 3 pp-partials in registers, block-reduce.
// Old version: 6 blocks, serial 3072-iter scalar loop -> 489 us @ 0.3% occupancy.
__global__ __launch_bounds__(256) void k_conv2(const float* __restrict__ G,
                                               const void* __restrict__ w,
                                               const void* __restrict__ bias,
                                               float* __restrict__ H2,
                                               const int* __restrict__ DF) {
    bool f = DF[0] != 0;
    int n = blockIdx.x % kNF;
    int b = blockIdx.x / kNF;
    int tid = threadIdx.x;
    const float* Gb = G + (long)b * 3 * 1024;
    // valid (pp, k -> l = pp + k - 1) combos:
    // pp=0: g[0]*w[1] + g[1]*w[2]
    // pp=1: g[0]*w[0] + g[1]*w[1] + g[2]*w[2]
    // pp=2: g[1]*w[0] + g[2]*w[1]
    float a0 = 0.f, a1 = 0.f, a2 = 0.f;
    for (int i = tid; i < 1024; i += 256) {
        float g0 = Gb[i], g1 = Gb[1024 + i], g2 = Gb[2048 + i];
        long wo = ((long)n * 1024 + i) * 3;
        float w0 = ld1auto(w, wo + 0, f);
        float w1 = ld1auto(w, wo + 1, f);
        float w2 = ld1auto(w, wo + 2, f);
        a0 += g0 * w1 + g1 * w2;
        a1 += g0 * w0 + g1 * w1 + g2 * w2;
        a2 += g1 * w0 + g2 * w1;
    }
    __shared__ float sm[12];
    #pragma unroll
    for (int m = 32; m > 0; m >>= 1) {
        a0 += __shfl_down(a0, m);
        a1 += __shfl_down(a1, m);
        a2 += __shfl_down(a2, m);
    }
    int wv = tid >> 6;
    if ((tid & 63) == 0) { sm[wv] = a0; sm[4 + wv] = a1; sm[8 + wv] = a2; }
    __syncthreads();
    if (tid == 0) {
        float cb = ld1auto(bias, n, f);
        float* hp = H2 + ((long)b * kNF + n) * 3;
        hp[0] = cb + sm[0] + sm[1] + sm[2] + sm[3];
        hp[1] = cb + sm[4] + sm[5] + sm[6] + sm[7];
        hp[2] = cb + sm[8] + sm[9] + sm[10] + sm[11];
    }
}

__global__ void k_trend(const float* __restrict__ H2, void* __restrict__ out, long obase,
                        const int* __restrict__ DF) {
    bool f32o = DF[0] != 0;
    int id = blockIdx.x * 256 + threadIdx.x;
    int n = id % kNF;
    int t = (id / kNF) % kT;
    int b = id / (kNF * kT);
    float lin = (float)(t + 1) / 513.0f;
    const float* h = H2 + ((long)b * kNF + n) * 3;
    float l2 = lin * lin;
    st1auto(out, obase + id, f32o, h[0] * lin + h[1] * l2 + h[2] * l2 * lin);
}

// ---------------- finals -------------------------------------------------------
__global__ void k_mean(const float* __restrict__ X, float* __restrict__ m) {
    int id = blockIdx.x * 256 + threadIdx.x;
    int b = id >> 10, e = id & 1023;
    const float* p = X + (long)b * kT * kE + e;
    float s = 0.f;
    for (int t = 0; t < kT; t++) s += p[(long)t * kE];
    m[id] = s * (1.f / kT);
}

__global__ void k_out0(const float* __restrict__ X, const float* __restrict__ m,
                       void* __restrict__ out, long obase, const int* __restrict__ DF) {
    bool f32o = DF[0] != 0;
    long id = (long)blockIdx.x * 256 + threadIdx.x;
    int e = id & 1023;
    int b = (int)(id >> 19);
    st1auto(out, obase + id, f32o, X[id] - m[b * kE + e]);
}

__global__ void k_out1(const float* __restrict__ m, const void* __restrict__ w,
                       const void* __restrict__ bias, void* __restrict__ out, long obase,
                       const int* __restrict__ DF) {
    bool f = DF[0] != 0;
    int id = blockIdx.x * 256 + threadIdx.x;
    if (id >= kB * kNF) return;
    int b = id / kNF, n = id % kNF;
    float acc = ld1auto(bias, n, f);
    for (int e = 0; e < kE; e++) acc += m[b * kE + e] * ld1auto(w, (long)e * kNF + n, f);
    st1auto(out, obase + id, f, acc);
}

// ---------------- launch -------------------------------------------------------
extern "C" void kernel_launch(void* const* d_in, const int* in_sizes, int n_in,
                              void* d_out, int out_size, void* d_ws, size_t ws_size,
                              hipStream_t stream) {
    (void)in_sizes; (void)n_in; (void)out_size; (void)ws_size;
    const void* x_in = d_in[0];
    const void* enc  = d_in[1];
    const int* tstep = (const int*)d_in[2];
    const void *ln1_w = d_in[3],  *ln1_b = d_in[4],  *ln11_w = d_in[5], *ln11_b = d_in[6];
    const void *ln2_w = d_in[7],  *ln2_b = d_in[8];
    const void *a1_qkv_w = d_in[9], *a1_qkv_b = d_in[10];
    const void *a1_agq_w = d_in[11], *a1_agq_b = d_in[12];
    const void *a1_agk_w = d_in[13], *a1_agk_b = d_in[14];
    const void *a1_agv_w = d_in[15], *a1_agv_b = d_in[16];
    const void *a1_ago_w = d_in[17], *a1_ago_b = d_in[18];
    const void *a1_agents = d_in[19];
    const void *a1_proj_w = d_in[20], *a1_proj_b = d_in[21];
    const void *a2_q_w = d_in[22], *a2_q_b = d_in[23];
    const void *a2_kv_w = d_in[24], *a2_kv_b = d_in[25];
    const void *a2_agq_w = d_in[26], *a2_agq_b = d_in[27];
    const void *a2_agk_w = d_in[28], *a2_agk_b = d_in[29];
    const void *a2_agv_w = d_in[30], *a2_agv_b = d_in[31];
    const void *a2_ago_w = d_in[32], *a2_ago_b = d_in[33];
    const void *a2_agents = d_in[34];
    const void *a2_proj_w = d_in[35], *a2_proj_b = d_in[36];
    const void *tr_c1_w = d_in[37], *tr_c1_b = d_in[38];
    const void *tr_c2_w = d_in[39], *tr_c2_b = d_in[40];
    const void *mlp_w1 = d_in[41], *mlp_b1 = d_in[42];
    const void *mlp_w2 = d_in[43], *mlp_b2 = d_in[44];
    const void *pr_w = d_in[45], *pr_b = d_in[46];
    const void *lin_w = d_in[47], *lin_b = d_in[48];

    char* wsb = (char*)d_ws;
    float* XC = (float*)(wsb + BOFF_XC);
    float* SM = (float*)(wsb + BOFF_SMALL);
    float* TS = SM + F_TS;
    float* AD1 = SM + F_AD1;
    float* AD11 = SM + F_AD11;
    float* AD2 = SM + F_AD2;
    float* QA = SM + F_QA;
    float* C1 = SM + F_C1;
    float* H2 = SM + F_H2;
    float* G1 = SM + F_G1;
    float* MB = SM + F_MB;
    float* TRE = SM + F_TRE;
    float* TIM = SM + F_TIM;
    int*   TIX = (int*)(SM + F_TIX);
    float* TRIG = SM + F_TRIG;
    int* DF = (int*)(wsb + BOFF_FLAG);
    char* WR = wsb + BOFF_WREG;
    float* WTQ  = (float*)(WR + WR_Q);
    float* WTKV = (float*)(WR + WR_KV);
    float* WAGO = (float*)(WR + WR_AGO);
    float* WPRJ = (float*)(WR + WR_PRJ);
    bf16*  W1B  = (bf16*)(WR + WR_W1);
    bf16*  W2B  = (bf16*)(WR + WR_W2);
    char* AC = wsb + BOFF_ACT;
    float* N1F  = (float*)(AC + AC_N1);     // also ENCF
    float* QBUF = (float*)(AC + AC_QBUF);
    float* KVB  = (float*)(AC + AC_KV);
    bf16*  KA   = (bf16*)(AC + AC_KA);
    bf16*  VA   = (bf16*)(AC + AC_VA);
    float* ATTF = (float*)(AC + AC_ATT);
    float* Y2F  = (float*)(AC + AC_Y2);
    float* P    = (float*)(AC + AC_P);
    float* RE   = (float*)(AC + AC_RE);
    float* IM   = (float*)(AC + AC_IM);
    bf16*  N1B  = (bf16*)(AC + AC_N1B);
    bf16*  HID  = (bf16*)(AC + AC_HID);

    const int M_BT = kB * kT;                      // 4096
    const long bsKA = (long)kB * kT * kHS;

    // 0) dtype detection (precedes all d_in consumers)
    k_detect<<<1, 256, 0, stream>>>((const unsigned short*)x_in, DF);

    // phase-1 weight transposes (fp32)
    k_wtf<<<dim3(1024/32, 1024/32), 256, 0, stream>>>(a1_qkv_w, WTQ, 1024, 3072, 0, DF);
    k_wtf<<<dim3(2048/32, 1024/32), 256, 0, stream>>>(a1_qkv_w, WTKV, 1024, 3072, 1024, DF);
    k_wtf<<<dim3(1024/32, 1024/32), 256, 0, stream>>>(a1_ago_w, WAGO, 1024, 1024, 0, DF);
    k_wtf<<<dim3(1024/32, 1024/32), 256, 0, stream>>>(a1_proj_w, WPRJ, 1024, 1024, 0, DF);

    // prologue
    k_temb<<<kB, 512, 0, stream>>>(tstep, TS);
    gemm(stream, TS, TAG_F32, kE, 0L, ln1_w, TAG_AUTO, 3 * kE, 0L, AD1, 3 * kE, 0L,
         kB, 3 * kE, kE, ln1_b, TAG_AUTO, 0, 0, nullptr, 0, 1, 1, DF);
    gemm(stream, TS, TAG_F32, kE, 0L, ln11_w, TAG_AUTO, 3 * kE, 0L, AD11, 3 * kE, 0L,
         kB, 3 * kE, kE, ln11_b, TAG_AUTO, 0, 0, nullptr, 0, 1, 1, DF);
    gemm(stream, TS, TAG_F32, kE, 0L, ln2_w, TAG_AUTO, 3 * kE, 0L, AD2, 3 * kE, 0L,
         kB, 3 * kE, kE, ln2_b, TAG_AUTO, 0, 0, nullptr, 0, 1, 1, DF);
    k_castin<<<(kB * kT * kE) / 1024, 256, 0, stream>>>(x_in, XC, DF);
    k_trig<<<(kNFREQ * kT + 255) / 256, 256, 0, stream>>>(TRIG);

    // ---- attention block 1 (self), fp32 end-to-end via split MFMA ----
    k_adalnf<<<M_BT, 256, 0, stream>>>(XC, AD1, N1F);
    mgemm32(stream, N1F, kE, WTQ, QBUF, kE, M_BT, kE, kE,
            a1_qkv_b, TAG_AUTO, 0L, nullptr, 0, 1, DF);
    mgemm32(stream, N1F, kE, WTKV, KVB, 2 * kE, M_BT, 2 * kE, kE,
            a1_qkv_b, TAG_AUTO, (long)kE, nullptr, 0, 1, DF);
    gemm(stream, a1_agents, TAG_AUTO, kHS, 0L, a1_agq_w, TAG_AUTO, kHS, 0L, QA, kHS, 0L,
         kH * kA, kHS, kHS, a1_agq_b, TAG_AUTO, 0, 0, nullptr, 0, 1, 1, DF);
    gemm(stream, KVB, TAG_F32, 2 * kE, 64L, a1_agk_w, TAG_AUTO, kHS, 0L, KA, kHS, bsKA,
         M_BT, kHS, kHS, a1_agk_b, TAG_AUTO, 0, 0, nullptr, 0, 1, kH, DF);
    gemm(stream, KVB + kE, TAG_F32, 2 * kE, 64L, a1_agv_w, TAG_AUTO, kHS, 0L, VA, kHS, bsKA,
         M_BT, kHS, kHS, a1_agv_b, TAG_AUTO, 0, 0, nullptr, 0, 1, kH, DF);
    k_agatt1<<<kB * kH * kA, 256, 0, stream>>>(QA, KA, VA, C1);
    k_agatt2f<<<kB * kH * (kT / 16), 256, 0, stream>>>(QBUF, kE, C1, ATTF);
    mgemm32(stream, ATTF, kE, WAGO, Y2F, kE, M_BT, kE, kE,
            a1_ago_b, TAG_AUTO, 0L, nullptr, 0, 1, DF);
    mgemm32(stream, Y2F, kE, WPRJ, XC, kE, M_BT, kE, kE,
            a1_proj_b, TAG_AUTO, 0L, AD1 + 2 * kE, 3 * kE, kT, DF);

    // phase-2 weight transposes (WREG safely reusable after prj1)
    k_wtf<<<dim3(1024/32, 1024/32), 256, 0, stream>>>(a2_q_w, WTQ, 1024, 1024, 0, DF);
    k_wtf<<<dim3(2048/32, 1024/32), 256, 0, stream>>>(a2_kv_w, WTKV, 1024, 2048, 0, DF);
    k_wtf<<<dim3(1024/32, 1024/32), 256, 0, stream>>>(a2_ago_w, WAGO, 1024, 1024, 0, DF);
    k_wtf<<<dim3(1024/32, 1024/32), 256, 0, stream>>>(a2_proj_w, WPRJ, 1024, 1024, 0, DF);

    // ---- attention block 2 (cross) ----
    k_castin<<<(kB * kT * kE) / 1024, 256, 0, stream>>>(enc, N1F, DF);   // ENCF in N1F slot
    mgemm32(stream, N1F, kE, WTKV, KVB, 2 * kE, M_BT, 2 * kE, kE,
            a2_kv_b, TAG_AUTO, 0L, nullptr, 0, 1, DF);
    k_adalnf<<<M_BT, 256, 0, stream>>>(XC, AD11, N1F);                    // overwrites ENCF (dead)
    mgemm32(stream, N1F, kE, WTQ, QBUF, kE, M_BT, kE, kE,
            a2_q_b, TAG_AUTO, 0L, nullptr, 0, 1, DF);
    gemm(stream, a2_agents, TAG_AUTO, kHS, 0L, a2_agq_w, TAG_AUTO, kHS, 0L, QA, kHS, 0L,
         kH * kA, kHS, kHS, a2_agq_b, TAG_AUTO, 0, 0, nullptr, 0, 1, 1, DF);
    gemm(stream, KVB, TAG_F32, 2 * kE, 64L, a2_agk_w, TAG_AUTO, kHS, 0L, KA, kHS, bsKA,
         M_BT, kHS, kHS, a2_agk_b, TAG_AUTO, 0, 0, nullptr, 0, 1, kH, DF);
    gemm(stream, KVB + kE, TAG_F32, 2 * kE, 64L, a2_agv_w, TAG_AUTO, kHS, 0L, VA, kHS, bsKA,
         M_BT, kHS, kHS, a2_agv_b, TAG_AUTO, 0, 0, nullptr, 0, 1, kH, DF);
    k_agatt1<<<kB * kH * kA, 256, 0, stream>>>(QA, KA, VA, C1);
    k_agatt2f<<<kB * kH * (kT / 16), 256, 0, stream>>>(QBUF, kE, C1, ATTF);
    mgemm32(stream, ATTF, kE, WAGO, Y2F, kE, M_BT, kE, kE,
            a2_ago_b, TAG_AUTO, 0L, nullptr, 0, 1, DF);
    mgemm32(stream, Y2F, kE, WPRJ, XC, kE, M_BT, kE, kE,
            a2_proj_b, TAG_AUTO, 0L, AD11 + 2 * kE, 3 * kE, kT, DF);

    // ---- phase 3: p = einsum('bce,oc->boe') + DFT + trend (all fp32 VALU) ----
    gemm(stream, pr_w, TAG_AUTO, kT, 0L, XC, TAG_F32, kE, (long)kT * kE,
         P, kE, (long)kT2 * kE, kT2, kE, kT,
         pr_b, TAG_AUTO, 1, 0, nullptr, 0, 1, kB, DF);
    gemm(stream, TRIG, TAG_F32, kT, 0L, P + (long)kT * kE, TAG_F32, kE, (long)kT2 * kE,
         RE, kE, (long)kNFREQ * kE, kNFREQ, kE, kT,
         nullptr, 0, 0, 0, nullptr, 0, 1, kB, DF);
    gemm(stream, TRIG + (long)kNFREQ * kT, TAG_F32, kT, 0L, P + (long)kT * kE, TAG_F32, kE, (long)kT2 * kE,
         IM, kE, (long)kNFREQ * kE, kNFREQ, kE, kT,
         nullptr, 0, 0, 0, nullptr, 0, 1, kB, DF);
    k_topk<<<(kB * kE) / 256, 256, 0, stream>>>(RE, IM, TRE, TIM, TIX);
    k_season<<<(kB * kT * kE) / 256, 256, 0, stream>>>(TRE, TIM, TIX, TRIG, d_out, O3, DF);
    k_conv1<<<(kB * 3 * kE) / 256, 256, 0, stream>>>(P, tr_c1_w, tr_c1_b, G1, DF);
    k_conv2<<<kB * kNF, 256, 0, stream>>>(G1, tr_c2_w, tr_c2_b, H2, DF);
    k_trend<<<(kB * kT * kNF) / 256, 256, 0, stream>>>(H2, d_out, O2, DF);

    // ---- phase 4: MLP (post-P; plain bf16 MFMA -- proven on outputs 0/1) ----
    k_wt<<<dim3(4096/32, 1024/32), 256, 0, stream>>>(mlp_w1, W1B, 1024, 4096, DF);
    k_wt<<<dim3(1024/32, 4096/32), 256, 0, stream>>>(mlp_w2, W2B, 4096, 1024, DF);
    k_adaln<<<M_BT, 256, 0, stream>>>(XC, AD2, N1B);
    mgemm(stream, N1B, kE, W1B, HID, kMLP, M_BT, kMLP, kE,
          mlp_b1, TAG_AUTO, 1 /*gelu*/, nullptr, 0, 1, DF);
    mgemm(stream, HID, kMLP, W2B, XC, kE, M_BT, kE, kMLP,
          mlp_b2, TAG_AUTO, 0, AD2 + 2 * kE, 3 * kE, kT, DF);

    // ---- finals ----
    k_mean<<<(kB * kE) / 256, 256, 0, stream>>>(XC, MB);
    k_out0<<<(kB * kT * kE) / 256, 256, 0, stream>>>(XC, MB, d_out, O0, DF);
    k_out1<<<(kB * kNF + 255) / 256, 256, 0, stream>>>(MB, lin_w, lin_b, d_out, O1, DF);
}

// Round 3
// 2518.903 us; speedup vs baseline: 1.2699x; 1.0684x over previous
//
#include <hip/hip_runtime.h>
#include <hip/hip_bf16.h>

using bf16 = __hip_bfloat16;
typedef __attribute__((ext_vector_type(8))) short short8;     // 8 bf16 (4 VGPRs)
typedef __attribute__((ext_vector_type(4))) float floatx4;    // MFMA acc

// Problem constants
constexpr int kB = 8, kT = 512, kE = 1024, kH = 16, kA = 64, kNF = 64, kHS = 64;
constexpr int kMLP = 4096, kT2 = 1024, kNFREQ = 255, kKTOP = 5;

constexpr int TAG_F32 = 0, TAG_BF16 = 1, TAG_AUTO = 2;

// ---------------- workspace arena (BYTE offsets) ----------------------------
// XC 16.78M | SMALL 4.36M | FLAG 64 | WREG 20.97M (phase-reused weight xposes)
// | ACT 67.11M (phase-reused activations).  Total 109.2 MB < 117.6 MB proven.
constexpr long BOFF_XC    = 0;                          // fp32 (B,T,E)
constexpr long BOFF_SMALL = 16777216;                   // 4,360,192 B
constexpr long BOFF_FLAG  = 21137408;                   // 64 B
constexpr long BOFF_WREG  = 21137472;                   // 20,971,520 B
constexpr long BOFF_ACT   = 42108992;                   // 67,108,864 B
constexpr long WS_NEED    = BOFF_ACT + 67108864;        // 109,217,856 B

// WREG slots (bytes from BOFF_WREG)
constexpr long WR_Q   = 0;          // fp32 1024x1024 (4,194,304)
constexpr long WR_KV  = 4194304;    // fp32 2048x1024 (8,388,608)
constexpr long WR_AGO = 12582912;   // fp32 1024x1024
constexpr long WR_PRJ = 16777216;   // fp32 1024x1024
constexpr long WR_W1  = 0;          // bf16 4096x1024 (8,388,608)  [phase 4]
constexpr long WR_W2  = 8388608;    // bf16 1024x4096 (8,388,608)  [phase 4]

// ACT slots (bytes from BOFF_ACT)
constexpr long AC_N1   = 0;         // fp32 (B,T,E) 16.78M   (also ENCF / P lo-half / N1b+HID)
constexpr long AC_QBUF = 16777216;  // fp32 (B,T,E) 16.78M
constexpr long AC_KV   = 33554432;  // fp32 (B,T,2E) 33.55M
constexpr long AC_KA   = 0;         // bf16 (H,B,T,HS) 8.39M  (over N1, after N1 dead)
constexpr long AC_VA   = 8388608;   // bf16 (H,B,T,HS) 8.39M
constexpr long AC_ATT  = 33554432;  // fp32 (B,T,E) 16.78M    (over KV, after KV dead)
constexpr long AC_Y2   = 50331648;  // fp32 (B,T,E) 16.78M
constexpr long AC_P    = 0;         // fp32 (B,2T,E) 33.55M   [phase 3]
constexpr long AC_RE   = 33554432;  // fp32 (B,255,E) 8,355,840
constexpr long AC_IM   = 41910272;  // fp32 (B,255,E) 8,355,840
constexpr long AC_N1B  = 0;         // bf16 (B,T,E) 8.39M     [phase 4]
constexpr long AC_HID  = 8388608;   // bf16 (B,T,MLP) 33.55M  [phase 4]

// small-region float offsets (relative to BOFF_SMALL)
constexpr long F_TS = 0, F_AD1 = 8192, F_AD11 = 32768, F_AD2 = 57344, F_QA = 81920,
               F_C1 = 147456, F_H2 = 671744, F_G1 = 673280, F_MB = 697856,
               F_TRE = 706048, F_TIM = 747008, F_TIX = 787968, F_TRIG = 828928;

// output regions (element offsets)
constexpr long O0 = 0, O1 = 4194304, O2 = 4194816, O3 = 4456960;

// ---------------- helpers ---------------------------------------------------
__device__ inline float bf2f(bf16 h) {
    unsigned short u = *(unsigned short*)&h;
    return __uint_as_float((unsigned)u << 16);
}
__device__ inline unsigned short bfbits(bf16 b) { return *(unsigned short*)&b; }
__device__ inline float gelu_f(float x) {
    return 0.5f * x * (1.0f + erff(x * 0.7071067811865476f));
}
__device__ inline float4 load4f(const float* p) { return *(const float4*)p; }
__device__ inline float4 load4bf(const bf16* p) {
    ushort4 u = *(const ushort4*)p;
    float4 r;
    r.x = __uint_as_float((unsigned)u.x << 16);
    r.y = __uint_as_float((unsigned)u.y << 16);
    r.z = __uint_as_float((unsigned)u.z << 16);
    r.w = __uint_as_float((unsigned)u.w << 16);
    return r;
}
__device__ inline float4 load4auto(const void* p, long idx, bool isF32) {
    if (isF32) return load4f((const float*)p + idx);
    return load4bf((const bf16*)p + idx);
}
__device__ inline float ld1auto(const void* p, long idx, bool isF32) {
    if (isF32) return ((const float*)p)[idx];
    return bf2f(((const bf16*)p)[idx]);
}
__device__ inline void st1auto(void* p, long idx, bool isF32, float v) {
    if (isF32) ((float*)p)[idx] = v;
    else       ((bf16*)p)[idx] = __float2bfloat16(v);
}
__device__ inline float ldc1(const float* p) { return *p; }
__device__ inline float ldc1(const bf16* p) { return bf2f(*p); }
__device__ inline void stc1(float* p, float v) { *p = v; }
__device__ inline void stc1(bf16* p, float v) { *p = __float2bfloat16(v); }

__device__ inline void blockReduce2(float& a, float& b, float* sm) {
    #pragma unroll
    for (int m = 32; m > 0; m >>= 1) { a += __shfl_down(a, m); b += __shfl_down(b, m); }
    int w = threadIdx.x >> 6;
    if ((threadIdx.x & 63) == 0) { sm[w] = a; sm[4 + w] = b; }
    __syncthreads();
    a = sm[0] + sm[1] + sm[2] + sm[3];
    b = sm[4] + sm[5] + sm[6] + sm[7];
    __syncthreads();
}

// ---------------- dtype detector --------------------------------------------
__global__ void k_detect(const unsigned short* __restrict__ xraw, int* __restrict__ flag) {
    int tid = threadIdx.x;
    unsigned short h = xraw[2 * tid];
    float v = __uint_as_float((unsigned)h << 16);
    float av = fabsf(v);
    if (!(av == av)) av = 1e30f;
    __shared__ float red[4];
    for (int m = 32; m > 0; m >>= 1) av = fmaxf(av, __shfl_down(av, m));
    if ((tid & 63) == 0) red[tid >> 6] = av;
    __syncthreads();
    if (tid == 0) {
        float mx = fmaxf(fmaxf(red[0], red[1]), fmaxf(red[2], red[3]));
        flag[0] = (mx < 1e3f) ? 0 : 1;             // 0 = bf16, 1 = fp32
    }
}

// ---------------- small kernels ---------------------------------------------
__global__ void k_temb(const int* __restrict__ ts, float* __restrict__ out) {
    int b = blockIdx.x, i = threadIdx.x;           // 512 threads
    float t = (float)ts[b];
    const float rate = (float)(-9.210340371976184 / 511.0);
    float f = expf(rate * (float)i);
    float arg = t * f;
    float sv = sinf(arg), cv = cosf(arg);
    out[(long)b * kE + i]        = sv / (1.f + expf(-sv));
    out[(long)b * kE + 512 + i]  = cv / (1.f + expf(-cv));
}

__global__ void k_castin(const void* __restrict__ in, float* __restrict__ out,
                         const int* __restrict__ DF) {
    bool f = DF[0] != 0;
    long i = ((long)blockIdx.x * 256 + threadIdx.x) * 4;
    float4 v = load4auto(in, i, f);
    *(float4*)(out + i) = v;
}

// fp32 weight transpose: W[K][Ntot] (auto dtype), cols [c0, c0+Nout) -> WT[Nout][K] fp32
__global__ __launch_bounds__(256) void k_wtf(const void* __restrict__ W, float* __restrict__ WT,
                                             int K, int Ntot, int c0,
                                             const int* __restrict__ DF) {
    bool f = DF[0] != 0;
    __shared__ float tile[32][33];
    int n0 = blockIdx.x * 32, k0 = blockIdx.y * 32;
    int tx = threadIdx.x & 31, ty = threadIdx.x >> 5;
    #pragma unroll
    for (int i = 0; i < 4; i++) {
        int k = ty + i * 8;
        tile[k][tx] = ld1auto(W, (long)(k0 + k) * Ntot + c0 + n0 + tx, f);
    }
    __syncthreads();
    #pragma unroll
    for (int i = 0; i < 4; i++) {
        int n = ty + i * 8;
        WT[(long)(n0 + n) * K + k0 + tx] = tile[tx][n];
    }
}

// bf16 weight transpose (for MLP): W[K][N] -> WT[N][K] bf16
__global__ __launch_bounds__(256) void k_wt(const void* __restrict__ W, bf16* __restrict__ WT,
                                            int K, int N, const int* __restrict__ DF) {
    bool f = DF[0] != 0;
    __shared__ float tile[32][33];
    int n0 = blockIdx.x * 32, k0 = blockIdx.y * 32;
    int tx = threadIdx.x & 31, ty = threadIdx.x >> 5;
    #pragma unroll
    for (int i = 0; i < 4; i++) {
        int k = ty + i * 8;
        tile[k][tx] = ld1auto(W, (long)(k0 + k) * N + n0 + tx, f);
    }
    __syncthreads();
    #pragma unroll
    for (int i = 0; i < 4; i++) {
        int n = ty + i * 8;
        WT[(long)(n0 + n) * K + k0 + tx] = __float2bfloat16(tile[tx][n]);
    }
}

// adaLN -> fp32 out (phases 1,2)
__global__ __launch_bounds__(256) void k_adalnf(const float* __restrict__ X,
                                                const float* __restrict__ AD,
                                                float* __restrict__ N) {
    int row = blockIdx.x;
    int b = row / kT;
    const float* xr = X + (long)row * kE;
    int tid = threadIdx.x;
    float4 xv = *(const float4*)(xr + tid * 4);
    float s  = xv.x + xv.y + xv.z + xv.w;
    float sq = xv.x * xv.x + xv.y * xv.y + xv.z * xv.z + xv.w * xv.w;
    __shared__ float sm[8];
    blockReduce2(s, sq, sm);
    float mu  = s * (1.f / kE);
    float var = sq * (1.f / kE) - mu * mu;
    float rstd = rsqrtf(fmaxf(var, 0.f) + 1e-5f);
    const float* ad = AD + (long)b * 3 * kE;
    float* nr = N + (long)row * kE;
    float xs[4] = {xv.x, xv.y, xv.z, xv.w};
    #pragma unroll
    for (int j = 0; j < 4; j++) {
        int e = tid * 4 + j;
        float xn = (xs[j] - mu) * rstd;
        nr[e] = xn * (1.f + ad[kE + e]) + ad[e];
    }
}

// adaLN -> bf16 out (phase 4 / MLP)
__global__ __launch_bounds__(256) void k_adaln(const float* __restrict__ X,
                                               const float* __restrict__ AD,
                                               bf16* __restrict__ N) {
    int row = blockIdx.x;
    int b = row / kT;
    const float* xr = X + (long)row * kE;
    int tid = threadIdx.x;
    float4 xv = *(const float4*)(xr + tid * 4);
    float s  = xv.x + xv.y + xv.z + xv.w;
    float sq = xv.x * xv.x + xv.y * xv.y + xv.z * xv.z + xv.w * xv.w;
    __shared__ float sm[8];
    blockReduce2(s, sq, sm);
    float mu  = s * (1.f / kE);
    float var = sq * (1.f / kE) - mu * mu;
    float rstd = rsqrtf(fmaxf(var, 0.f) + 1e-5f);
    const float* ad = AD + (long)b * 3 * kE;
    bf16* nr = N + (long)row * kE;
    float xs[4] = {xv.x, xv.y, xv.z, xv.w};
    #pragma unroll
    for (int j = 0; j < 4; j++) {
        int e = tid * 4 + j;
        float xn = (xs[j] - mu) * rstd;
        nr[e] = __float2bfloat16(xn * (1.f + ad[kE + e]) + ad[e]);
    }
}

// ---------------- split-precision MFMA GEMM (fp32-accurate) -----------------
// C = A(fp32 MxK) @ WT(fp32 NxK)^T via hi/lo bf16 split: Ah*Bh + Ah*Bl + Al*Bh.
// Relative error ~8e-6 (vs 2e-3 plain bf16). M,N mult of 128, K mult of 32.
template <typename TC>
__global__ __launch_bounds__(256) void k_mfma32(
    const float* __restrict__ A, int lda,
    const float* __restrict__ WT,
    TC* __restrict__ C, int ldc,
    int M, int N, int K,
    const void* __restrict__ bias, int bTag, long biasOff,
    const float* __restrict__ alpha, int alphaStride, int rowsPerB,
    const int* __restrict__ DF) {
    constexpr int BK = 32, PAD = 8;                 // 40 elem (80 B) row stride
    __shared__ bf16 Ah[128][BK + PAD], Al[128][BK + PAD];
    __shared__ bf16 Bh[128][BK + PAD], Bl[128][BK + PAD];
    int tid = threadIdx.x;
    int wave = tid >> 6, lane = tid & 63;
    int bm = blockIdx.y * 128, bn = blockIdx.x * 128;
    int wm = (wave >> 1) * 64, wn = (wave & 1) * 64;
    int lm = lane & 15, quad = lane >> 4;
    floatx4 acc[4][4] = {};
    int sRow = tid >> 1, sCol = (tid & 1) * 16;      // 16 fp32 per thread per tile
    const float* ag = A  + (long)(bm + sRow) * lda + sCol;
    const float* bg = WT + (long)(bn + sRow) * K   + sCol;
    for (int k0 = 0; k0 < K; k0 += BK) {
        #pragma unroll
        for (int i = 0; i < 4; i++) {
            float4 v = *(const float4*)(ag + k0 + i * 4);
            bf16 h0 = __float2bfloat16(v.x), h1 = __float2bfloat16(v.y);
            bf16 h2 = __float2bfloat16(v.z), h3 = __float2bfloat16(v.w);
            bf16 l0 = __float2bfloat16(v.x - bf2f(h0));
            bf16 l1 = __float2bfloat16(v.y - bf2f(h1));
            bf16 l2 = __float2bfloat16(v.z - bf2f(h2));
            bf16 l3 = __float2bfloat16(v.w - bf2f(h3));
            ushort4 hv = {bfbits(h0), bfbits(h1), bfbits(h2), bfbits(h3)};
            ushort4 lv = {bfbits(l0), bfbits(l1), bfbits(l2), bfbits(l3)};
            *(ushort4*)&Ah[sRow][sCol + i * 4] = hv;
            *(ushort4*)&Al[sRow][sCol + i * 4] = lv;
        }
        #pragma unroll
        for (int i = 0; i < 4; i++) {
            float4 v = *(const float4*)(bg + k0 + i * 4);
            bf16 h0 = __float2bfloat16(v.x), h1 = __float2bfloat16(v.y);
            bf16 h2 = __float2bfloat16(v.z), h3 = __float2bfloat16(v.w);
            bf16 l0 = __float2bfloat16(v.x - bf2f(h0));
            bf16 l1 = __float2bfloat16(v.y - bf2f(h1));
            bf16 l2 = __float2bfloat16(v.z - bf2f(h2));
            bf16 l3 = __float2bfloat16(v.w - bf2f(h3));
            ushort4 hv = {bfbits(h0), bfbits(h1), bfbits(h2), bfbits(h3)};
            ushort4 lv = {bfbits(l0), bfbits(l1), bfbits(l2), bfbits(l3)};
            *(ushort4*)&Bh[sRow][sCol + i * 4] = hv;
            *(ushort4*)&Bl[sRow][sCol + i * 4] = lv;
        }
        __syncthreads();
        short8 ahf[4], alf[4], bhf[4], blf[4];
        #pragma unroll
        for (int mi = 0; mi < 4; mi++) {
            ahf[mi] = *(const short8*)&Ah[wm + mi * 16 + lm][quad * 8];
            alf[mi] = *(const short8*)&Al[wm + mi * 16 + lm][quad * 8];
        }
        #pragma unroll
        for (int ni = 0; ni < 4; ni++) {
            bhf[ni] = *(const short8*)&Bh[wn + ni * 16 + lm][quad * 8];
            blf[ni] = *(const short8*)&Bl[wn + ni * 16 + lm][quad * 8];
        }
        #pragma unroll
        for (int mi = 0; mi < 4; mi++)
            #pragma unroll
            for (int ni = 0; ni < 4; ni++) {
                acc[mi][ni] = __builtin_amdgcn_mfma_f32_16x16x32_bf16(ahf[mi], bhf[ni], acc[mi][ni], 0, 0, 0);
                acc[mi][ni] = __builtin_amdgcn_mfma_f32_16x16x32_bf16(ahf[mi], blf[ni], acc[mi][ni], 0, 0, 0);
                acc[mi][ni] = __builtin_amdgcn_mfma_f32_16x16x32_bf16(alf[mi], bhf[ni], acc[mi][ni], 0, 0, 0);
            }
        __syncthreads();
    }
    bool f32f = DF[0] != 0;
    bool bF = (bTag == TAG_F32) || (bTag == TAG_AUTO && f32f);
    #pragma unroll
    for (int ni = 0; ni < 4; ni++) {
        int col = bn + wn + ni * 16 + lm;
        float cb = bias ? ld1auto(bias, biasOff + col, bF) : 0.f;
        #pragma unroll
        for (int mi = 0; mi < 4; mi++) {
            #pragma unroll
            for (int reg = 0; reg < 4; reg++) {
                int row = bm + wm + mi * 16 + quad * 4 + reg;
                float v = acc[mi][ni][reg] + cb;
                TC* cp = C + (long)row * ldc + col;
                if (alpha) {
                    const float* al = alpha + (long)(row / rowsPerB) * alphaStride + col;
                    v = ldc1(cp) + al[0] * v;
                }
                stc1(cp, v);
            }
        }
    }
}

template <typename TC>
static void mgemm32(hipStream_t s, const float* A, int lda, const float* WT,
                    TC* C, int ldc, int M, int N, int K,
                    const void* bias, int bTag, long biasOff,
                    const float* alpha, int alphaStride, int rowsPerB, const int* DF) {
    dim3 g(N / 128, M / 128);
    k_mfma32<TC><<<g, 256, 0, s>>>(A, lda, WT, C, ldc, M, N, K,
                                   bias, bTag, biasOff, alpha, alphaStride, rowsPerB, DF);
}

// ---------------- plain bf16 MFMA GEMM (MLP only; post-season-critical) -----
template <typename TC>
__global__ __launch_bounds__(256) void k_mfma(
    const bf16* __restrict__ A, int lda,
    const bf16* __restrict__ WT,
    TC* __restrict__ C, int ldc,
    int M, int N, int K,
    const void* __restrict__ bias, int bTag, int act,
    const float* __restrict__ alpha, int alphaStride, int rowsPerB,
    const int* __restrict__ DF) {
    constexpr int BK = 64, PAD = 8;
    __shared__ bf16 As[128][BK + PAD];
    __shared__ bf16 Bs[128][BK + PAD];
    int tid = threadIdx.x;
    int wave = tid >> 6, lane = tid & 63;
    int bm = blockIdx.y * 128, bn = blockIdx.x * 128;
    int wm = (wave >> 1) * 64, wn = (wave & 1) * 64;
    int lm = lane & 15, quad = lane >> 4;
    floatx4 acc[4][4] = {};
    int sRow = tid >> 1, sCol = (tid & 1) * 32;
    const bf16* ag = A  + (long)(bm + sRow) * lda + sCol;
    const bf16* bg = WT + (long)(bn + sRow) * K   + sCol;
    for (int k0 = 0; k0 < K; k0 += BK) {
        #pragma unroll
        for (int i = 0; i < 4; i++)
            *(float4*)&As[sRow][sCol + i * 8] = *(const float4*)(ag + k0 + i * 8);
        #pragma unroll
        for (int i = 0; i < 4; i++)
            *(float4*)&Bs[sRow][sCol + i * 8] = *(const float4*)(bg + k0 + i * 8);
        __syncthreads();
        #pragma unroll
        for (int kk = 0; kk < BK; kk += 32) {
            short8 af[4], bf[4];
            #pragma unroll
            for (int mi = 0; mi < 4; mi++)
                af[mi] = *(const short8*)&As[wm + mi * 16 + lm][kk + quad * 8];
            #pragma unroll
            for (int ni = 0; ni < 4; ni++)
                bf[ni] = *(const short8*)&Bs[wn + ni * 16 + lm][kk + quad * 8];
            #pragma unroll
            for (int mi = 0; mi < 4; mi++)
                #pragma unroll
                for (int ni = 0; ni < 4; ni++)
                    acc[mi][ni] = __builtin_amdgcn_mfma_f32_16x16x32_bf16(
                        af[mi], bf[ni], acc[mi][ni], 0, 0, 0);
        }
        __syncthreads();
    }
    bool f32f = DF[0] != 0;
    bool bF = (bTag == TAG_F32) || (bTag == TAG_AUTO && f32f);
    #pragma unroll
    for (int ni = 0; ni < 4; ni++) {
        int col = bn + wn + ni * 16 + lm;
        float cb = bias ? ld1auto(bias, col, bF) : 0.f;
        #pragma unroll
        for (int mi = 0; mi < 4; mi++) {
            #pragma unroll
            for (int reg = 0; reg < 4; reg++) {
                int row = bm + wm + mi * 16 + quad * 4 + reg;
                float v = acc[mi][ni][reg] + cb;
                TC* cp = C + (long)row * ldc + col;
                if (alpha) {
                    const float* al = alpha + (long)(row / rowsPerB) * alphaStride + col;
                    v = ldc1(cp) + al[0] * v;
                } else if (act == 1) {
                    v = gelu_f(v);
                }
                stc1(cp, v);
            }
        }
    }
}

template <typename TC>
static void mgemm(hipStream_t s, const bf16* A, int lda, const bf16* WT,
                  TC* C, int ldc, int M, int N, int K,
                  const void* bias, int bTag, int act,
                  const float* alpha, int alphaStride, int rowsPerB, const int* DF) {
    dim3 g(N / 128, M / 128);
    k_mfma<TC><<<g, 256, 0, s>>>(A, lda, WT, C, ldc, M, N, K,
                                 bias, bTag, act, alpha, alphaStride, rowsPerB, DF);
}

// ---------------- generic tiled fp32-VALU GEMM ------------------------------
template <typename TC>
__global__ __launch_bounds__(256) void k_gemm(
    const void* __restrict__ Ab, int aTag, int lda, long bsA,
    const void* __restrict__ Wb, int wTag, int ldw, long bsW,
    TC* __restrict__ Cb, int ldc, long bsC,
    int M, int N, int K,
    const void* __restrict__ bias, int bTag, int biasRow, int act,
    const float* __restrict__ alpha, int alphaStride, int rowsPerB,
    const int* __restrict__ DF) {
    __shared__ float As[16][68];
    __shared__ float Bs[16][68];
    bool f32f = DF[0] != 0;
    bool aF = (aTag == TAG_F32) || (aTag == TAG_AUTO && f32f);
    bool wF = (wTag == TAG_F32) || (wTag == TAG_AUTO && f32f);
    bool bF = (bTag == TAG_F32) || (bTag == TAG_AUTO && f32f);
    TC* Cbase = Cb + (long)blockIdx.z * bsC;
    long aBase = (long)blockIdx.z * bsA;
    long wBase = (long)blockIdx.z * bsW;
    int tid = threadIdx.x;
    int bm = blockIdx.y, bn = blockIdx.x;
    int tx = tid & 15, ty = tid >> 4;
    int arow = tid >> 2, acol = (tid & 3) * 4;
    int wrow = tid >> 4, wcol = (tid & 15) * 4;
    int gArow = bm * 64 + arow;
    bool aValid = gArow < M;
    float acc[4][4] = {};
    for (int kk = 0; kk < K; kk += 16) {
        float4 av = {0.f, 0.f, 0.f, 0.f};
        if (aValid) av = load4auto(Ab, aBase + (long)gArow * lda + kk + acol, aF);
        As[acol + 0][arow] = av.x;
        As[acol + 1][arow] = av.y;
        As[acol + 2][arow] = av.z;
        As[acol + 3][arow] = av.w;
        float4 wv = load4auto(Wb, wBase + (long)(kk + wrow) * ldw + bn * 64 + wcol, wF);
        *(float4*)&Bs[wrow][wcol] = wv;
        __syncthreads();
        #pragma unroll
        for (int k = 0; k < 16; k++) {
            float4 a4 = *(const float4*)&As[k][ty * 4];
            float4 b4 = *(const float4*)&Bs[k][tx * 4];
            acc[0][0] += a4.x * b4.x; acc[0][1] += a4.x * b4.y; acc[0][2] += a4.x * b4.z; acc[0][3] += a4.x * b4.w;
            acc[1][0] += a4.y * b4.x; acc[1][1] += a4.y * b4.y; acc[1][2] += a4.y * b4.z; acc[1][3] += a4.y * b4.w;
            acc[2][0] += a4.z * b4.x; acc[2][1] += a4.z * b4.y; acc[2][2] += a4.z * b4.z; acc[2][3] += a4.z * b4.w;
            acc[3][0] += a4.w * b4.x; acc[3][1] += a4.w * b4.y; acc[3][2] += a4.w * b4.z; acc[3][3] += a4.w * b4.w;
        }
        __syncthreads();
    }
    int gcol = bn * 64 + tx * 4;
    float cb[4] = {0.f, 0.f, 0.f, 0.f};
    if (bias && !biasRow) {
        #pragma unroll
        for (int j = 0; j < 4; j++) cb[j] = ld1auto(bias, gcol + j, bF);
    }
    #pragma unroll
    for (int i = 0; i < 4; i++) {
        int grow = bm * 64 + ty * 4 + i;
        if (grow >= M) continue;
        float rb = (bias && biasRow) ? ld1auto(bias, grow, bF) : 0.f;
        TC* crow = Cbase + (long)grow * ldc + gcol;
        const float* al = nullptr;
        if (alpha) al = alpha + (long)(grow / rowsPerB) * alphaStride + gcol;
        #pragma unroll
        for (int j = 0; j < 4; j++) {
            float v = acc[i][j] + cb[j] + rb;
            if (alpha)         v = ldc1(crow + j) + al[j] * v;
            else if (act == 1) v = gelu_f(v);
            stc1(crow + j, v);
        }
    }
}

template <typename TC>
static void gemm(hipStream_t s, const void* A, int aTag, int lda, long bsA,
                 const void* W, int wTag, int ldw, long bsW,
                 TC* C, int ldc, long bsC, int M, int N, int K,
                 const void* bias, int bTag, int biasRow, int act,
                 const float* alpha, int alphaStride, int rowsPerB, int batch,
                 const int* DF) {
    dim3 g(N / 64, (M + 63) / 64, batch);
    k_gemm<TC><<<g, 256, 0, s>>>(A, aTag, lda, bsA, W, wTag, ldw, bsW, C, ldc, bsC,
                                 M, N, K, bias, bTag, biasRow, act,
                                 alpha, alphaStride, rowsPerB, DF);
}

// ---------------- agent attention stage 1 (ka/va bf16 -- as passing round 3)
__global__ __launch_bounds__(256) void k_agatt1(const float* __restrict__ qa,
                                                const bf16* __restrict__ ka,
                                                const bf16* __restrict__ va,
                                                float* __restrict__ c1) {
    int blk = blockIdx.x;
    int a = blk % kA;
    int h = (blk / kA) % kH;
    int b = blk / (kA * kH);
    __shared__ float qrow[kHS];
    __shared__ float probs[kT];
    __shared__ float sm[8];
    __shared__ float part[4][64];
    int tid = threadIdx.x;
    if (tid < kHS) qrow[tid] = qa[((long)h * kA + a) * kHS + tid];
    __syncthreads();
    const bf16* kab = ka + ((long)h * kB + b) * kT * kHS;
    float sc[2];
    #pragma unroll
    for (int rep = 0; rep < 2; rep++) {
        const bf16* kr = kab + (long)(tid + rep * 256) * kHS;
        float acc = 0.f;
        #pragma unroll
        for (int d = 0; d < kHS; d += 4) {
            float4 k4 = load4bf(kr + d);
            acc += k4.x * qrow[d] + k4.y * qrow[d + 1] + k4.z * qrow[d + 2] + k4.w * qrow[d + 3];
        }
        sc[rep] = acc * 0.125f;
    }
    float mx = fmaxf(sc[0], sc[1]);
    for (int m = 32; m > 0; m >>= 1) mx = fmaxf(mx, __shfl_down(mx, m));
    if ((tid & 63) == 0) sm[tid >> 6] = mx;
    __syncthreads();
    mx = fmaxf(fmaxf(sm[0], sm[1]), fmaxf(sm[2], sm[3]));
    float e0 = expf(sc[0] - mx), e1 = expf(sc[1] - mx);
    float ss = e0 + e1;
    for (int m = 32; m > 0; m >>= 1) ss += __shfl_down(ss, m);
    if ((tid & 63) == 0) sm[4 + (tid >> 6)] = ss;
    __syncthreads();
    ss = sm[4] + sm[5] + sm[6] + sm[7];
    float rs = 1.f / ss;
    probs[tid] = e0 * rs;
    probs[tid + 256] = e1 * rs;
    __syncthreads();
    int d = tid & 63, ch = tid >> 6;
    const bf16* vab = va + ((long)h * kB + b) * kT * kHS;
    float acc = 0.f;
    for (int n = ch * 128; n < (ch + 1) * 128; n++)
        acc += probs[n] * bf2f(vab[(long)n * kHS + d]);
    part[ch][d] = acc;
    __syncthreads();
    if (tid < 64)
        c1[(((long)b * kH + h) * kA + a) * kHS + tid] =
            part[0][tid] + part[1][tid] + part[2][tid] + part[3][tid];
}

// ---------------- agent attention stage 2 (fp32 in/out) ----------------------
__global__ __launch_bounds__(256) void k_agatt2f(const float* __restrict__ qsrc, int ldq,
                                                 const float* __restrict__ c1,
                                                 float* __restrict__ out) {
    int blk = blockIdx.x;
    int nt = blk % (kT / 16);
    int h = (blk / (kT / 16)) % kH;
    int b = blk / ((kT / 16) * kH);
    __shared__ float c1s[kA][kHS + 1];
    __shared__ float qs[16][kHS + 1];
    __shared__ float ps[16][kA + 1];
    int tid = threadIdx.x;
    const float* c1b = c1 + ((long)b * kH + h) * kA * kHS;
    for (int i = tid; i < kA * kHS; i += 256) c1s[i >> 6][i & 63] = c1b[i];
    int n0 = nt * 16;
    {
        int r = tid >> 4, d = (tid & 15) * 4;
        float4 q4 = load4f(qsrc + (long)(b * kT + n0 + r) * ldq + h * kHS + d);
        qs[r][d] = q4.x; qs[r][d + 1] = q4.y; qs[r][d + 2] = q4.z; qs[r][d + 3] = q4.w;
    }
    __syncthreads();
    int r = tid >> 4, c = tid & 15;
    float sc[4];
    #pragma unroll
    for (int j = 0; j < 4; j++) {
        int a = c * 4 + j;
        float acc = 0.f;
        for (int d = 0; d < kHS; d++) acc += qs[r][d] * c1s[a][d];
        sc[j] = acc * 0.125f;
    }
    float mx = fmaxf(fmaxf(sc[0], sc[1]), fmaxf(sc[2], sc[3]));
    for (int m = 1; m < 16; m <<= 1) mx = fmaxf(mx, __shfl_xor(mx, m));
    float e[4], ss = 0.f;
    #pragma unroll
    for (int j = 0; j < 4; j++) { e[j] = expf(sc[j] - mx); ss += e[j]; }
    for (int m = 1; m < 16; m <<= 1) ss += __shfl_xor(ss, m);
    float rs = 1.f / ss;
    #pragma unroll
    for (int j = 0; j < 4; j++) ps[r][c * 4 + j] = e[j] * rs;
    __syncthreads();
    float o0 = 0.f, o1 = 0.f, o2 = 0.f, o3 = 0.f;
    int d0 = c * 4;
    for (int a = 0; a < kA; a++) {
        float p = ps[r][a];
        o0 += p * c1s[a][d0 + 0];
        o1 += p * c1s[a][d0 + 1];
        o2 += p * c1s[a][d0 + 2];
        o3 += p * c1s[a][d0 + 3];
    }
    float* orow = out + (long)(b * kT + n0 + r) * kE + h * kHS + d0;
    orow[0] = o0; orow[1] = o1; orow[2] = o2; orow[3] = o3;
}

// ---------------- DFT tables --------------------------------------------------
__global__ void k_trig(float* __restrict__ trig) {
    int id = blockIdx.x * 256 + threadIdx.x;
    if (id >= kNFREQ * kT) return;
    int t = id & 511;
    int f = (id >> 9) + 1;
    int m = (f * t) & 511;
    double ang = (double)m * (2.0 * 3.14159265358979323846 / 512.0);
    trig[id] = (float)cos(ang);
    trig[kNFREQ * kT + id] = (float)(-sin(ang));
}

// ---------------- top-5 |X_f|^2 per (b,e) column ------------------------------
__global__ void k_topk(const float* __restrict__ RE, const float* __restrict__ IM,
                       float* __restrict__ tre, float* __restrict__ tim,
                       int* __restrict__ tix) {
    int id = blockIdx.x * 256 + threadIdx.x;
    int b = id >> 10, e = id & 1023;
    const float* rp = RE + (long)b * kNFREQ * kE + e;
    const float* ip = IM + (long)b * kNFREQ * kE + e;
    float bv[kKTOP] = {-1e30f, -1e30f, -1e30f, -1e30f, -1e30f};
    int bi[kKTOP] = {0, 0, 0, 0, 0};
    for (int f = 0; f < kNFREQ; f++) {
        float re = rp[(long)f * kE], im = ip[(long)f * kE];
        float m2 = re * re + im * im;
        if (m2 > bv[kKTOP - 1]) {
            int p = kKTOP - 1;
            while (p > 0 && m2 > bv[p - 1]) { bv[p] = bv[p - 1]; bi[p] = bi[p - 1]; p--; }
            bv[p] = m2; bi[p] = f;
        }
    }
    #pragma unroll
    for (int j = 0; j < kKTOP; j++) {
        int f = bi[j];
        tre[(long)id * kKTOP + j] = rp[(long)f * kE];
        tim[(long)id * kKTOP + j] = ip[(long)f * kE];
        tix[(long)id * kKTOP + j] = f;
    }
}

__global__ void k_season(const float* __restrict__ tre, const float* __restrict__ tim,
                         const int* __restrict__ tix, const float* __restrict__ trig,
                         void* __restrict__ out, long obase, const int* __restrict__ DF) {
    bool f32o = DF[0] != 0;
    long id = (long)blockIdx.x * 256 + threadIdx.x;
    int e = id & 1023;
    long bt = id >> 10;
    int t = (int)(bt & 511);
    int b = (int)(bt >> 9);
    long be = (long)b * kE + e;
    float acc = 0.f;
    #pragma unroll
    for (int j = 0; j < kKTOP; j++) {
        int f = tix[be * kKTOP + j];
        acc += tre[be * kKTOP + j] * trig[(long)f * kT + t]
             + tim[be * kKTOP + j] * trig[(long)kNFREQ * kT + (long)f * kT + t];
    }
    st1auto(out, obase + id, f32o, 2.f * acc);
}

// ---------------- trend branch ------------------------------------------------
// conv1 re-parallelized: grid = (b,o) x 8 l-tiles = 192 blocks.  Weight slab
// w[o,:,:] (6 KB) staged in LDS once; each thread owns one l of a 128-wide
// tile and half the i-range; 2-way LDS reduce.  Old: 96 blocks, 512-iter
// serial loop with per-iter scalar weight loads -> 224 us @ 4.2% occupancy.
__global__ __launch_bounds__(256) void k_conv1(const float* __restrict__ P,
                                               const void* __restrict__ w,
                                               const void* __restrict__ bias,
                                               float* __restrict__ G,
                                               const int* __restrict__ DF) {
    bool f = DF[0] != 0;
    int bo = blockIdx.x;                 // 0..23 -> (b,o)
    int lt = blockIdx.y;                 // 0..7  -> 128-l tile
    int o = bo % 3, b = bo / 3;
    int tid = threadIdx.x;
    __shared__ float ws[512][3];         // 6 KB weight slab for this o
    for (int idx = tid; idx < 512 * 3; idx += 256)
        ws[idx / 3][idx % 3] = ld1auto(w, (long)o * 512 * 3 + idx, f);
    __syncthreads();
    int l = lt * 128 + (tid & 127);
    int ih = (tid >> 7) * 256;           // 0 or 256
    const float* xb = P + (long)b * kT2 * kE;
    float acc = 0.f;
    for (int ii = 0; ii < 256; ii++) {
        int i = ih + ii;
        const float* xr = xb + (long)i * kE + l;
        float xm = (l > 0)    ? xr[-1] : 0.f;
        float xc = xr[0];
        float xp = (l < 1023) ? xr[1]  : 0.f;
        acc += xm * ws[i][0] + xc * ws[i][1] + xp * ws[i][2];
    }
    __shared__ float red[128];
    if (tid >= 128) red[tid - 128] = acc;
    __syncthreads();
    if (tid < 128) {
        float tot = acc + red[tid] + ld1auto(bias, o, f);
        G[((long)b * 3 + o) * 1024 + l] = gelu_f(tot);
    }
}

// conv2 re-parallelized: one workgroup per (b,n) output pair (512 blocks),
// 256 threads stride over i, 3 pp-partials in registers, block-reduce.
// Old version: 6 blocks, serial 3072-iter scalar loop -> 489 us @ 0.3% occupancy.
__global__ __launch_bounds__(256) void k_conv2(const float* __restrict__ G,
                                               const void* __restrict__ w,
                                               const void* __restrict__ bias,
                                               float* __restrict__ H2,
                                               const int* __restrict__ DF) {
    bool f = DF[0] != 0;
    int n = blockIdx.x % kNF;
    int b = blockIdx.x / kNF;
    int tid = threadIdx.x;
    const float* Gb = G + (long)b * 3 * 1024;
    // valid (pp, k -> l = pp + k - 1) combos:
    // pp=0: g[0]*w[1] + g[1]*w[2]
    // pp=1: g[0]*w[0] + g[1]*w[1] + g[2]*w[2]
    // pp=2: g[1]*w[0] + g[2]*w[1]
    float a0 = 0.f, a1 = 0.f, a2 = 0.f;
    for (int i = tid; i < 1024; i += 256) {
        float g0 = Gb[i], g1 = Gb[1024 + i], g2 = Gb[2048 + i];
        long wo = ((long)n * 1024 + i) * 3;
        float w0 = ld1auto(w, wo + 0, f);
        float w1 = ld1auto(w, wo + 1, f);
        float w2 = ld1auto(w, wo + 2, f);
        a0 += g0 * w1 + g1 * w2;
        a1 += g0 * w0 + g1 * w1 + g2 * w2;
        a2 += g1 * w0 + g2 * w1;
    }
    __shared__ float sm[12];
    #pragma unroll
    for (int m = 32; m > 0; m >>= 1) {
        a0 += __shfl_down(a0, m);
        a1 += __shfl_down(a1, m);
        a2 += __shfl_down(a2, m);
    }
    int wv = tid >> 6;
    if ((tid & 63) == 0) { sm[wv] = a0; sm[4 + wv] = a1; sm[8 + wv] = a2; }
    __syncthreads();
    if (tid == 0) {
        float cb = ld1auto(bias, n, f);
        float* hp = H2 + ((long)b * kNF + n) * 3;
        hp[0] = cb + sm[0] + sm[1] + sm[2] + sm[3];
        hp[1] = cb + sm[4] + sm[5] + sm[6] + sm[7];
        hp[2] = cb + sm[8] + sm[9] + sm[10] + sm[11];
    }
}

__global__ void k_trend(const float* __restrict__ H2, void* __restrict__ out, long obase,
                        const int* __restrict__ DF) {
    bool f32o = DF[0] != 0;
    int id = blockIdx.x * 256 + threadIdx.x;
    int n = id % kNF;
    int t = (id / kNF) % kT;
    int b = id / (kNF * kT);
    float lin = (float)(t + 1) / 513.0f;
    const float* h = H2 + ((long)b * kNF + n) * 3;
    float l2 = lin * lin;
    st1auto(out, obase + id, f32o, h[0] * lin + h[1] * l2 + h[2] * l2 * lin);
}

// ---------------- finals -------------------------------------------------------
__global__ void k_mean(const float* __restrict__ X, float* __restrict__ m) {
    int id = blockIdx.x * 256 + threadIdx.x;
    int b = id >> 10, e = id & 1023;
    const float* p = X + (long)b * kT * kE + e;
    float s = 0.f;
    for (int t = 0; t < kT; t++) s += p[(long)t * kE];
    m[id] = s * (1.f / kT);
}

__global__ void k_out0(const float* __restrict__ X, const float* __restrict__ m,
                       void* __restrict__ out, long obase, const int* __restrict__ DF) {
    bool f32o = DF[0] != 0;
    long id = (long)blockIdx.x * 256 + threadIdx.x;
    int e = id & 1023;
    int b = (int)(id >> 19);
    st1auto(out, obase + id, f32o, X[id] - m[b * kE + e]);
}

__global__ void k_out1(const float* __restrict__ m, const void* __restrict__ w,
                       const void* __restrict__ bias, void* __restrict__ out, long obase,
                       const int* __restrict__ DF) {
    bool f = DF[0] != 0;
    int id = blockIdx.x * 256 + threadIdx.x;
    if (id >= kB * kNF) return;
    int b = id / kNF, n = id % kNF;
    float acc = ld1auto(bias, n, f);
    for (int e = 0; e < kE; e++) acc += m[b * kE + e] * ld1auto(w, (long)e * kNF + n, f);
    st1auto(out, obase + id, f, acc);
}

// ---------------- launch -------------------------------------------------------
extern "C" void kernel_launch(void* const* d_in, const int* in_sizes, int n_in,
                              void* d_out, int out_size, void* d_ws, size_t ws_size,
                              hipStream_t stream) {
    (void)in_sizes; (void)n_in; (void)out_size; (void)ws_size;
    const void* x_in = d_in[0];
    const void* enc  = d_in[1];
    const int* tstep = (const int*)d_in[2];
    const void *ln1_w = d_in[3],  *ln1_b = d_in[4],  *ln11_w = d_in[5], *ln11_b = d_in[6];
    const void *ln2_w = d_in[7],  *ln2_b = d_in[8];
    const void *a1_qkv_w = d_in[9], *a1_qkv_b = d_in[10];
    const void *a1_agq_w = d_in[11], *a1_agq_b = d_in[12];
    const void *a1_agk_w = d_in[13], *a1_agk_b = d_in[14];
    const void *a1_agv_w = d_in[15], *a1_agv_b = d_in[16];
    const void *a1_ago_w = d_in[17], *a1_ago_b = d_in[18];
    const void *a1_agents = d_in[19];
    const void *a1_proj_w = d_in[20], *a1_proj_b = d_in[21];
    const void *a2_q_w = d_in[22], *a2_q_b = d_in[23];
    const void *a2_kv_w = d_in[24], *a2_kv_b = d_in[25];
    const void *a2_agq_w = d_in[26], *a2_agq_b = d_in[27];
    const void *a2_agk_w = d_in[28], *a2_agk_b = d_in[29];
    const void *a2_agv_w = d_in[30], *a2_agv_b = d_in[31];
    const void *a2_ago_w = d_in[32], *a2_ago_b = d_in[33];
    const void *a2_agents = d_in[34];
    const void *a2_proj_w = d_in[35], *a2_proj_b = d_in[36];
    const void *tr_c1_w = d_in[37], *tr_c1_b = d_in[38];
    const void *tr_c2_w = d_in[39], *tr_c2_b = d_in[40];
    const void *mlp_w1 = d_in[41], *mlp_b1 = d_in[42];
    const void *mlp_w2 = d_in[43], *mlp_b2 = d_in[44];
    const void *pr_w = d_in[45], *pr_b = d_in[46];
    const void *lin_w = d_in[47], *lin_b = d_in[48];

    char* wsb = (char*)d_ws;
    float* XC = (float*)(wsb + BOFF_XC);
    float* SM = (float*)(wsb + BOFF_SMALL);
    float* TS = SM + F_TS;
    float* AD1 = SM + F_AD1;
    float* AD11 = SM + F_AD11;
    float* AD2 = SM + F_AD2;
    float* QA = SM + F_QA;
    float* C1 = SM + F_C1;
    float* H2 = SM + F_H2;
    float* G1 = SM + F_G1;
    float* MB = SM + F_MB;
    float* TRE = SM + F_TRE;
    float* TIM = SM + F_TIM;
    int*   TIX = (int*)(SM + F_TIX);
    float* TRIG = SM + F_TRIG;
    int* DF = (int*)(wsb + BOFF_FLAG);
    char* WR = wsb + BOFF_WREG;
    float* WTQ  = (float*)(WR + WR_Q);
    float* WTKV = (float*)(WR + WR_KV);
    float* WAGO = (float*)(WR + WR_AGO);
    float* WPRJ = (float*)(WR + WR_PRJ);
    bf16*  W1B  = (bf16*)(WR + WR_W1);
    bf16*  W2B  = (bf16*)(WR + WR_W2);
    char* AC = wsb + BOFF_ACT;
    float* N1F  = (float*)(AC + AC_N1);     // also ENCF
    float* QBUF = (float*)(AC + AC_QBUF);
    float* KVB  = (float*)(AC + AC_KV);
    bf16*  KA   = (bf16*)(AC + AC_KA);
    bf16*  VA   = (bf16*)(AC + AC_VA);
    float* ATTF = (float*)(AC + AC_ATT);
    float* Y2F  = (float*)(AC + AC_Y2);
    float* P    = (float*)(AC + AC_P);
    float* RE   = (float*)(AC + AC_RE);
    float* IM   = (float*)(AC + AC_IM);
    bf16*  N1B  = (bf16*)(AC + AC_N1B);
    bf16*  HID  = (bf16*)(AC + AC_HID);

    const int M_BT = kB * kT;                      // 4096
    const long bsKA = (long)kB * kT * kHS;

    // 0) dtype detection (precedes all d_in consumers)
    k_detect<<<1, 256, 0, stream>>>((const unsigned short*)x_in, DF);

    // phase-1 weight transposes (fp32)
    k_wtf<<<dim3(1024/32, 1024/32), 256, 0, stream>>>(a1_qkv_w, WTQ, 1024, 3072, 0, DF);
    k_wtf<<<dim3(2048/32, 1024/32), 256, 0, stream>>>(a1_qkv_w, WTKV, 1024, 3072, 1024, DF);
    k_wtf<<<dim3(1024/32, 1024/32), 256, 0, stream>>>(a1_ago_w, WAGO, 1024, 1024, 0, DF);
    k_wtf<<<dim3(1024/32, 1024/32), 256, 0, stream>>>(a1_proj_w, WPRJ, 1024, 1024, 0, DF);

    // prologue
    k_temb<<<kB, 512, 0, stream>>>(tstep, TS);
    gemm(stream, TS, TAG_F32, kE, 0L, ln1_w, TAG_AUTO, 3 * kE, 0L, AD1, 3 * kE, 0L,
         kB, 3 * kE, kE, ln1_b, TAG_AUTO, 0, 0, nullptr, 0, 1, 1, DF);
    gemm(stream, TS, TAG_F32, kE, 0L, ln11_w, TAG_AUTO, 3 * kE, 0L, AD11, 3 * kE, 0L,
         kB, 3 * kE, kE, ln11_b, TAG_AUTO, 0, 0, nullptr, 0, 1, 1, DF);
    gemm(stream, TS, TAG_F32, kE, 0L, ln2_w, TAG_AUTO, 3 * kE, 0L, AD2, 3 * kE, 0L,
         kB, 3 * kE, kE, ln2_b, TAG_AUTO, 0, 0, nullptr, 0, 1, 1, DF);
    k_castin<<<(kB * kT * kE) / 1024, 256, 0, stream>>>(x_in, XC, DF);
    k_trig<<<(kNFREQ * kT + 255) / 256, 256, 0, stream>>>(TRIG);

    // ---- attention block 1 (self), fp32 end-to-end via split MFMA ----
    k_adalnf<<<M_BT, 256, 0, stream>>>(XC, AD1, N1F);
    mgemm32(stream, N1F, kE, WTQ, QBUF, kE, M_BT, kE, kE,
            a1_qkv_b, TAG_AUTO, 0L, nullptr, 0, 1, DF);
    mgemm32(stream, N1F, kE, WTKV, KVB, 2 * kE, M_BT, 2 * kE, kE,
            a1_qkv_b, TAG_AUTO, (long)kE, nullptr, 0, 1, DF);
    gemm(stream, a1_agents, TAG_AUTO, kHS, 0L, a1_agq_w, TAG_AUTO, kHS, 0L, QA, kHS, 0L,
         kH * kA, kHS, kHS, a1_agq_b, TAG_AUTO, 0, 0, nullptr, 0, 1, 1, DF);
    gemm(stream, KVB, TAG_F32, 2 * kE, 64L, a1_agk_w, TAG_AUTO, kHS, 0L, KA, kHS, bsKA,
         M_BT, kHS, kHS, a1_agk_b, TAG_AUTO, 0, 0, nullptr, 0, 1, kH, DF);
    gemm(stream, KVB + kE, TAG_F32, 2 * kE, 64L, a1_agv_w, TAG_AUTO, kHS, 0L, VA, kHS, bsKA,
         M_BT, kHS, kHS, a1_agv_b, TAG_AUTO, 0, 0, nullptr, 0, 1, kH, DF);
    k_agatt1<<<kB * kH * kA, 256, 0, stream>>>(QA, KA, VA, C1);
    k_agatt2f<<<kB * kH * (kT / 16), 256, 0, stream>>>(QBUF, kE, C1, ATTF);
    mgemm32(stream, ATTF, kE, WAGO, Y2F, kE, M_BT, kE, kE,
            a1_ago_b, TAG_AUTO, 0L, nullptr, 0, 1, DF);
    mgemm32(stream, Y2F, kE, WPRJ, XC, kE, M_BT, kE, kE,
            a1_proj_b, TAG_AUTO, 0L, AD1 + 2 * kE, 3 * kE, kT, DF);

    // phase-2 weight transposes (WREG safely reusable after prj1)
    k_wtf<<<dim3(1024/32, 1024/32), 256, 0, stream>>>(a2_q_w, WTQ, 1024, 1024, 0, DF);
    k_wtf<<<dim3(2048/32, 1024/32), 256, 0, stream>>>(a2_kv_w, WTKV, 1024, 2048, 0, DF);
    k_wtf<<<dim3(1024/32, 1024/32), 256, 0, stream>>>(a2_ago_w, WAGO, 1024, 1024, 0, DF);
    k_wtf<<<dim3(1024/32, 1024/32), 256, 0, stream>>>(a2_proj_w, WPRJ, 1024, 1024, 0, DF);

    // ---- attention block 2 (cross) ----
    k_castin<<<(kB * kT * kE) / 1024, 256, 0, stream>>>(enc, N1F, DF);   // ENCF in N1F slot
    mgemm32(stream, N1F, kE, WTKV, KVB, 2 * kE, M_BT, 2 * kE, kE,
            a2_kv_b, TAG_AUTO, 0L, nullptr, 0, 1, DF);
    k_adalnf<<<M_BT, 256, 0, stream>>>(XC, AD11, N1F);                    // overwrites ENCF (dead)
    mgemm32(stream, N1F, kE, WTQ, QBUF, kE, M_BT, kE, kE,
            a2_q_b, TAG_AUTO, 0L, nullptr, 0, 1, DF);
    gemm(stream, a2_agents, TAG_AUTO, kHS, 0L, a2_agq_w, TAG_AUTO, kHS, 0L, QA, kHS, 0L,
         kH * kA, kHS, kHS, a2_agq_b, TAG_AUTO, 0, 0, nullptr, 0, 1, 1, DF);
    gemm(stream, KVB, TAG_F32, 2 * kE, 64L, a2_agk_w, TAG_AUTO, kHS, 0L, KA, kHS, bsKA,
         M_BT, kHS, kHS, a2_agk_b, TAG_AUTO, 0, 0, nullptr, 0, 1, kH, DF);
    gemm(stream, KVB + kE, TAG_F32, 2 * kE, 64L, a2_agv_w, TAG_AUTO, kHS, 0L, VA, kHS, bsKA,
         M_BT, kHS, kHS, a2_agv_b, TAG_AUTO, 0, 0, nullptr, 0, 1, kH, DF);
    k_agatt1<<<kB * kH * kA, 256, 0, stream>>>(QA, KA, VA, C1);
    k_agatt2f<<<kB * kH * (kT / 16), 256, 0, stream>>>(QBUF, kE, C1, ATTF);
    mgemm32(stream, ATTF, kE, WAGO, Y2F, kE, M_BT, kE, kE,
            a2_ago_b, TAG_AUTO, 0L, nullptr, 0, 1, DF);
    mgemm32(stream, Y2F, kE, WPRJ, XC, kE, M_BT, kE, kE,
            a2_proj_b, TAG_AUTO, 0L, AD11 + 2 * kE, 3 * kE, kT, DF);

    // ---- phase 3: p = einsum('bce,oc->boe') + DFT + trend (all fp32 VALU) ----
    gemm(stream, pr_w, TAG_AUTO, kT, 0L, XC, TAG_F32, kE, (long)kT * kE,
         P, kE, (long)kT2 * kE, kT2, kE, kT,
         pr_b, TAG_AUTO, 1, 0, nullptr, 0, 1, kB, DF);
    gemm(stream, TRIG, TAG_F32, kT, 0L, P + (long)kT * kE, TAG_F32, kE, (long)kT2 * kE,
         RE, kE, (long)kNFREQ * kE, kNFREQ, kE, kT,
         nullptr, 0, 0, 0, nullptr, 0, 1, kB, DF);
    gemm(stream, TRIG + (long)kNFREQ * kT, TAG_F32, kT, 0L, P + (long)kT * kE, TAG_F32, kE, (long)kT2 * kE,
         IM, kE, (long)kNFREQ * kE, kNFREQ, kE, kT,
         nullptr, 0, 0, 0, nullptr, 0, 1, kB, DF);
    k_topk<<<(kB * kE) / 256, 256, 0, stream>>>(RE, IM, TRE, TIM, TIX);
    k_season<<<(kB * kT * kE) / 256, 256, 0, stream>>>(TRE, TIM, TIX, TRIG, d_out, O3, DF);
    k_conv1<<<dim3(kB * 3, 8), 256, 0, stream>>>(P, tr_c1_w, tr_c1_b, G1, DF);
    k_conv2<<<kB * kNF, 256, 0, stream>>>(G1, tr_c2_w, tr_c2_b, H2, DF);
    k_trend<<<(kB * kT * kNF) / 256, 256, 0, stream>>>(H2, d_out, O2, DF);

    // ---- phase 4: MLP (post-P; plain bf16 MFMA -- proven on outputs 0/1) ----
    k_wt<<<dim3(4096/32, 1024/32), 256, 0, stream>>>(mlp_w1, W1B, 1024, 4096, DF);
    k_wt<<<dim3(1024/32, 4096/32), 256, 0, stream>>>(mlp_w2, W2B, 4096, 1024, DF);
    k_adaln<<<M_BT, 256, 0, stream>>>(XC, AD2, N1B);
    mgemm(stream, N1B, kE, W1B, HID, kMLP, M_BT, kMLP, kE,
          mlp_b1, TAG_AUTO, 1 /*gelu*/, nullptr, 0, 1, DF);
    mgemm(stream, HID, kMLP, W2B, XC, kE, M_BT, kE, kMLP,
          mlp_b2, TAG_AUTO, 0, AD2 + 2 * kE, 3 * kE, kT, DF);

    // ---- finals ----
    k_mean<<<(kB * kE) / 256, 256, 0, stream>>>(XC, MB);
    k_out0<<<(kB * kT * kE) / 256, 256, 0, stream>>>(XC, MB, d_out, O0, DF);
    k_out1<<<(kB * kNF + 255) / 256, 256, 0, stream>>>(MB, lin_w, lin_b, d_out, O1, DF);
}

// Round 4
// 2378.132 us; speedup vs baseline: 1.3451x; 1.0592x over previous
//
#include <hip/hip_runtime.h>
#include <hip/hip_bf16.h>

using bf16 = __hip_bfloat16;
typedef __attribute__((ext_vector_type(8))) short short8;     // 8 bf16 (4 VGPRs)
typedef __attribute__((ext_vector_type(4))) float floatx4;    // MFMA acc

// Problem constants
constexpr int kB = 8, kT = 512, kE = 1024, kH = 16, kA = 64, kNF = 64, kHS = 64;
constexpr int kMLP = 4096, kT2 = 1024, kNFREQ = 255, kKTOP = 5;

constexpr int TAG_F32 = 0, TAG_BF16 = 1, TAG_AUTO = 2;

// ---------------- workspace arena (BYTE offsets) ----------------------------
// XC 16.78M | SMALL 4.36M | FLAG 64 | WREG 20.97M (phase-reused weight xposes)
// | ACT 67.11M (phase-reused activations).  Total 109.2 MB < 117.6 MB proven.
constexpr long BOFF_XC    = 0;                          // fp32 (B,T,E)
constexpr long BOFF_SMALL = 16777216;                   // 4,360,192 B
constexpr long BOFF_FLAG  = 21137408;                   // 64 B
constexpr long BOFF_WREG  = 21137472;                   // 20,971,520 B
constexpr long BOFF_ACT   = 42108992;                   // 67,108,864 B
constexpr long WS_NEED    = BOFF_ACT + 67108864;        // 109,217,856 B

// WREG slots (bytes from BOFF_WREG)
constexpr long WR_Q   = 0;          // fp32 1024x1024 (4,194,304)
constexpr long WR_KV  = 4194304;    // fp32 2048x1024 (8,388,608)
constexpr long WR_AGO = 12582912;   // fp32 1024x1024
constexpr long WR_PRJ = 16777216;   // fp32 1024x1024
constexpr long WR_W1  = 0;          // bf16 4096x1024 (8,388,608)  [phase 4]
constexpr long WR_W2  = 8388608;    // bf16 1024x4096 (8,388,608)  [phase 4]

// ACT slots (bytes from BOFF_ACT)
constexpr long AC_N1   = 0;         // fp32 (B,T,E) 16.78M   (also ENCF / P lo-half / N1b+HID)
constexpr long AC_QBUF = 16777216;  // fp32 (B,T,E) 16.78M
constexpr long AC_KV   = 33554432;  // fp32 (B,T,2E) 33.55M
constexpr long AC_KA   = 0;         // bf16 (H,B,T,HS) 8.39M  (over N1, after N1 dead)
constexpr long AC_VA   = 8388608;   // bf16 (H,B,T,HS) 8.39M
constexpr long AC_ATT  = 33554432;  // fp32 (B,T,E) 16.78M    (over KV, after KV dead)
constexpr long AC_Y2   = 50331648;  // fp32 (B,T,E) 16.78M
constexpr long AC_P    = 0;         // fp32 (B,2T,E) 33.55M   [phase 3]
constexpr long AC_RE   = 33554432;  // fp32 (B,255,E) 8,355,840
constexpr long AC_IM   = 41910272;  // fp32 (B,255,E) 8,355,840
constexpr long AC_N1B  = 0;         // bf16 (B,T,E) 8.39M     [phase 4]
constexpr long AC_HID  = 8388608;   // bf16 (B,T,MLP) 33.55M  [phase 4]

// small-region float offsets (relative to BOFF_SMALL)
constexpr long F_TS = 0, F_AD1 = 8192, F_AD11 = 32768, F_AD2 = 57344, F_QA = 81920,
               F_C1 = 147456, F_H2 = 671744, F_G1 = 673280, F_MB = 697856,
               F_TRE = 706048, F_TIM = 747008, F_TIX = 787968, F_TRIG = 828928;

// output regions (element offsets)
constexpr long O0 = 0, O1 = 4194304, O2 = 4194816, O3 = 4456960;

// ---------------- helpers ---------------------------------------------------
__device__ inline float bf2f(bf16 h) {
    unsigned short u = *(unsigned short*)&h;
    return __uint_as_float((unsigned)u << 16);
}
__device__ inline unsigned short bfbits(bf16 b) { return *(unsigned short*)&b; }
__device__ inline float gelu_f(float x) {
    return 0.5f * x * (1.0f + erff(x * 0.7071067811865476f));
}
__device__ inline float4 load4f(const float* p) { return *(const float4*)p; }
__device__ inline float4 load4bf(const bf16* p) {
    ushort4 u = *(const ushort4*)p;
    float4 r;
    r.x = __uint_as_float((unsigned)u.x << 16);
    r.y = __uint_as_float((unsigned)u.y << 16);
    r.z = __uint_as_float((unsigned)u.z << 16);
    r.w = __uint_as_float((unsigned)u.w << 16);
    return r;
}
__device__ inline float4 load4auto(const void* p, long idx, bool isF32) {
    if (isF32) return load4f((const float*)p + idx);
    return load4bf((const bf16*)p + idx);
}
__device__ inline float ld1auto(const void* p, long idx, bool isF32) {
    if (isF32) return ((const float*)p)[idx];
    return bf2f(((const bf16*)p)[idx]);
}
__device__ inline void st1auto(void* p, long idx, bool isF32, float v) {
    if (isF32) ((float*)p)[idx] = v;
    else       ((bf16*)p)[idx] = __float2bfloat16(v);
}
__device__ inline float ldc1(const float* p) { return *p; }
__device__ inline float ldc1(const bf16* p) { return bf2f(*p); }
__device__ inline void stc1(float* p, float v) { *p = v; }
__device__ inline void stc1(bf16* p, float v) { *p = __float2bfloat16(v); }

__device__ inline void blockReduce2(float& a, float& b, float* sm) {
    #pragma unroll
    for (int m = 32; m > 0; m >>= 1) { a += __shfl_down(a, m); b += __shfl_down(b, m); }
    int w = threadIdx.x >> 6;
    if ((threadIdx.x & 63) == 0) { sm[w] = a; sm[4 + w] = b; }
    __syncthreads();
    a = sm[0] + sm[1] + sm[2] + sm[3];
    b = sm[4] + sm[5] + sm[6] + sm[7];
    __syncthreads();
}

// ---------------- dtype detector --------------------------------------------
__global__ void k_detect(const unsigned short* __restrict__ xraw, int* __restrict__ flag) {
    int tid = threadIdx.x;
    unsigned short h = xraw[2 * tid];
    float v = __uint_as_float((unsigned)h << 16);
    float av = fabsf(v);
    if (!(av == av)) av = 1e30f;
    __shared__ float red[4];
    for (int m = 32; m > 0; m >>= 1) av = fmaxf(av, __shfl_down(av, m));
    if ((tid & 63) == 0) red[tid >> 6] = av;
    __syncthreads();
    if (tid == 0) {
        float mx = fmaxf(fmaxf(red[0], red[1]), fmaxf(red[2], red[3]));
        flag[0] = (mx < 1e3f) ? 0 : 1;             // 0 = bf16, 1 = fp32
    }
}

// ---------------- small kernels ---------------------------------------------
__global__ void k_temb(const int* __restrict__ ts, float* __restrict__ out) {
    int b = blockIdx.x, i = threadIdx.x;           // 512 threads
    float t = (float)ts[b];
    const float rate = (float)(-9.210340371976184 / 511.0);
    float f = expf(rate * (float)i);
    float arg = t * f;
    float sv = sinf(arg), cv = cosf(arg);
    out[(long)b * kE + i]        = sv / (1.f + expf(-sv));
    out[(long)b * kE + 512 + i]  = cv / (1.f + expf(-cv));
}

__global__ void k_castin(const void* __restrict__ in, float* __restrict__ out,
                         const int* __restrict__ DF) {
    bool f = DF[0] != 0;
    long i = ((long)blockIdx.x * 256 + threadIdx.x) * 4;
    float4 v = load4auto(in, i, f);
    *(float4*)(out + i) = v;
}

// fp32 weight transpose: W[K][Ntot] (auto dtype), cols [c0, c0+Nout) -> WT[Nout][K] fp32
__global__ __launch_bounds__(256) void k_wtf(const void* __restrict__ W, float* __restrict__ WT,
                                             int K, int Ntot, int c0,
                                             const int* __restrict__ DF) {
    bool f = DF[0] != 0;
    __shared__ float tile[32][33];
    int n0 = blockIdx.x * 32, k0 = blockIdx.y * 32;
    int tx = threadIdx.x & 31, ty = threadIdx.x >> 5;
    #pragma unroll
    for (int i = 0; i < 4; i++) {
        int k = ty + i * 8;
        tile[k][tx] = ld1auto(W, (long)(k0 + k) * Ntot + c0 + n0 + tx, f);
    }
    __syncthreads();
    #pragma unroll
    for (int i = 0; i < 4; i++) {
        int n = ty + i * 8;
        WT[(long)(n0 + n) * K + k0 + tx] = tile[tx][n];
    }
}

// bf16 weight transpose (for MLP): W[K][N] -> WT[N][K] bf16
__global__ __launch_bounds__(256) void k_wt(const void* __restrict__ W, bf16* __restrict__ WT,
                                            int K, int N, const int* __restrict__ DF) {
    bool f = DF[0] != 0;
    __shared__ float tile[32][33];
    int n0 = blockIdx.x * 32, k0 = blockIdx.y * 32;
    int tx = threadIdx.x & 31, ty = threadIdx.x >> 5;
    #pragma unroll
    for (int i = 0; i < 4; i++) {
        int k = ty + i * 8;
        tile[k][tx] = ld1auto(W, (long)(k0 + k) * N + n0 + tx, f);
    }
    __syncthreads();
    #pragma unroll
    for (int i = 0; i < 4; i++) {
        int n = ty + i * 8;
        WT[(long)(n0 + n) * K + k0 + tx] = __float2bfloat16(tile[tx][n]);
    }
}

// adaLN -> fp32 out (phases 1,2)
__global__ __launch_bounds__(256) void k_adalnf(const float* __restrict__ X,
                                                const float* __restrict__ AD,
                                                float* __restrict__ N) {
    int row = blockIdx.x;
    int b = row / kT;
    const float* xr = X + (long)row * kE;
    int tid = threadIdx.x;
    float4 xv = *(const float4*)(xr + tid * 4);
    float s  = xv.x + xv.y + xv.z + xv.w;
    float sq = xv.x * xv.x + xv.y * xv.y + xv.z * xv.z + xv.w * xv.w;
    __shared__ float sm[8];
    blockReduce2(s, sq, sm);
    float mu  = s * (1.f / kE);
    float var = sq * (1.f / kE) - mu * mu;
    float rstd = rsqrtf(fmaxf(var, 0.f) + 1e-5f);
    const float* ad = AD + (long)b * 3 * kE;
    float* nr = N + (long)row * kE;
    float xs[4] = {xv.x, xv.y, xv.z, xv.w};
    #pragma unroll
    for (int j = 0; j < 4; j++) {
        int e = tid * 4 + j;
        float xn = (xs[j] - mu) * rstd;
        nr[e] = xn * (1.f + ad[kE + e]) + ad[e];
    }
}

// adaLN -> bf16 out (phase 4 / MLP)
__global__ __launch_bounds__(256) void k_adaln(const float* __restrict__ X,
                                               const float* __restrict__ AD,
                                               bf16* __restrict__ N) {
    int row = blockIdx.x;
    int b = row / kT;
    const float* xr = X + (long)row * kE;
    int tid = threadIdx.x;
    float4 xv = *(const float4*)(xr + tid * 4);
    float s  = xv.x + xv.y + xv.z + xv.w;
    float sq = xv.x * xv.x + xv.y * xv.y + xv.z * xv.z + xv.w * xv.w;
    __shared__ float sm[8];
    blockReduce2(s, sq, sm);
    float mu  = s * (1.f / kE);
    float var = sq * (1.f / kE) - mu * mu;
    float rstd = rsqrtf(fmaxf(var, 0.f) + 1e-5f);
    const float* ad = AD + (long)b * 3 * kE;
    bf16* nr = N + (long)row * kE;
    float xs[4] = {xv.x, xv.y, xv.z, xv.w};
    #pragma unroll
    for (int j = 0; j < 4; j++) {
        int e = tid * 4 + j;
        float xn = (xs[j] - mu) * rstd;
        nr[e] = __float2bfloat16(xn * (1.f + ad[kE + e]) + ad[e]);
    }
}

// ---------------- split-precision MFMA GEMM (fp32-accurate) -----------------
// C = A(fp32 MxK) @ WT(fp32 NxK)^T via hi/lo bf16 split: Ah*Bh + Ah*Bl + Al*Bh.
// Relative error ~8e-6 (vs 2e-3 plain bf16). M,N mult of 128, K mult of 32.
template <typename TC>
__global__ __launch_bounds__(256) void k_mfma32(
    const float* __restrict__ A, int lda,
    const float* __restrict__ WT,
    TC* __restrict__ C, int ldc,
    int M, int N, int K,
    const void* __restrict__ bias, int bTag, long biasOff,
    const float* __restrict__ alpha, int alphaStride, int rowsPerB,
    const int* __restrict__ DF) {
    constexpr int BK = 32, PAD = 8;                 // 40 elem (80 B) row stride
    __shared__ bf16 Ah[128][BK + PAD], Al[128][BK + PAD];
    __shared__ bf16 Bh[128][BK + PAD], Bl[128][BK + PAD];
    int tid = threadIdx.x;
    int wave = tid >> 6, lane = tid & 63;
    int bm = blockIdx.y * 128, bn = blockIdx.x * 128;
    int wm = (wave >> 1) * 64, wn = (wave & 1) * 64;
    int lm = lane & 15, quad = lane >> 4;
    floatx4 acc[4][4] = {};
    int sRow = tid >> 1, sCol = (tid & 1) * 16;      // 16 fp32 per thread per tile
    const float* ag = A  + (long)(bm + sRow) * lda + sCol;
    const float* bg = WT + (long)(bn + sRow) * K   + sCol;
    for (int k0 = 0; k0 < K; k0 += BK) {
        #pragma unroll
        for (int i = 0; i < 4; i++) {
            float4 v = *(const float4*)(ag + k0 + i * 4);
            bf16 h0 = __float2bfloat16(v.x), h1 = __float2bfloat16(v.y);
            bf16 h2 = __float2bfloat16(v.z), h3 = __float2bfloat16(v.w);
            bf16 l0 = __float2bfloat16(v.x - bf2f(h0));
            bf16 l1 = __float2bfloat16(v.y - bf2f(h1));
            bf16 l2 = __float2bfloat16(v.z - bf2f(h2));
            bf16 l3 = __float2bfloat16(v.w - bf2f(h3));
            ushort4 hv = {bfbits(h0), bfbits(h1), bfbits(h2), bfbits(h3)};
            ushort4 lv = {bfbits(l0), bfbits(l1), bfbits(l2), bfbits(l3)};
            *(ushort4*)&Ah[sRow][sCol + i * 4] = hv;
            *(ushort4*)&Al[sRow][sCol + i * 4] = lv;
        }
        #pragma unroll
        for (int i = 0; i < 4; i++) {
            float4 v = *(const float4*)(bg + k0 + i * 4);
            bf16 h0 = __float2bfloat16(v.x), h1 = __float2bfloat16(v.y);
            bf16 h2 = __float2bfloat16(v.z), h3 = __float2bfloat16(v.w);
            bf16 l0 = __float2bfloat16(v.x - bf2f(h0));
            bf16 l1 = __float2bfloat16(v.y - bf2f(h1));
            bf16 l2 = __float2bfloat16(v.z - bf2f(h2));
            bf16 l3 = __float2bfloat16(v.w - bf2f(h3));
            ushort4 hv = {bfbits(h0), bfbits(h1), bfbits(h2), bfbits(h3)};
            ushort4 lv = {bfbits(l0), bfbits(l1), bfbits(l2), bfbits(l3)};
            *(ushort4*)&Bh[sRow][sCol + i * 4] = hv;
            *(ushort4*)&Bl[sRow][sCol + i * 4] = lv;
        }
        __syncthreads();
        short8 ahf[4], alf[4], bhf[4], blf[4];
        #pragma unroll
        for (int mi = 0; mi < 4; mi++) {
            ahf[mi] = *(const short8*)&Ah[wm + mi * 16 + lm][quad * 8];
            alf[mi] = *(const short8*)&Al[wm + mi * 16 + lm][quad * 8];
        }
        #pragma unroll
        for (int ni = 0; ni < 4; ni++) {
            bhf[ni] = *(const short8*)&Bh[wn + ni * 16 + lm][quad * 8];
            blf[ni] = *(const short8*)&Bl[wn + ni * 16 + lm][quad * 8];
        }
        #pragma unroll
        for (int mi = 0; mi < 4; mi++)
            #pragma unroll
            for (int ni = 0; ni < 4; ni++) {
                acc[mi][ni] = __builtin_amdgcn_mfma_f32_16x16x32_bf16(ahf[mi], bhf[ni], acc[mi][ni], 0, 0, 0);
                acc[mi][ni] = __builtin_amdgcn_mfma_f32_16x16x32_bf16(ahf[mi], blf[ni], acc[mi][ni], 0, 0, 0);
                acc[mi][ni] = __builtin_amdgcn_mfma_f32_16x16x32_bf16(alf[mi], bhf[ni], acc[mi][ni], 0, 0, 0);
            }
        __syncthreads();
    }
    bool f32f = DF[0] != 0;
    bool bF = (bTag == TAG_F32) || (bTag == TAG_AUTO && f32f);
    #pragma unroll
    for (int ni = 0; ni < 4; ni++) {
        int col = bn + wn + ni * 16 + lm;
        float cb = bias ? ld1auto(bias, biasOff + col, bF) : 0.f;
        #pragma unroll
        for (int mi = 0; mi < 4; mi++) {
            #pragma unroll
            for (int reg = 0; reg < 4; reg++) {
                int row = bm + wm + mi * 16 + quad * 4 + reg;
                float v = acc[mi][ni][reg] + cb;
                TC* cp = C + (long)row * ldc + col;
                if (alpha) {
                    const float* al = alpha + (long)(row / rowsPerB) * alphaStride + col;
                    v = ldc1(cp) + al[0] * v;
                }
                stc1(cp, v);
            }
        }
    }
}

template <typename TC>
static void mgemm32(hipStream_t s, const float* A, int lda, const float* WT,
                    TC* C, int ldc, int M, int N, int K,
                    const void* bias, int bTag, long biasOff,
                    const float* alpha, int alphaStride, int rowsPerB, const int* DF) {
    dim3 g(N / 128, M / 128);
    k_mfma32<TC><<<g, 256, 0, s>>>(A, lda, WT, C, ldc, M, N, K,
                                   bias, bTag, biasOff, alpha, alphaStride, rowsPerB, DF);
}

// ---------------- plain bf16 MFMA GEMM (MLP only; post-season-critical) -----
template <typename TC>
__global__ __launch_bounds__(256) void k_mfma(
    const bf16* __restrict__ A, int lda,
    const bf16* __restrict__ WT,
    TC* __restrict__ C, int ldc,
    int M, int N, int K,
    const void* __restrict__ bias, int bTag, int act,
    const float* __restrict__ alpha, int alphaStride, int rowsPerB,
    const int* __restrict__ DF) {
    constexpr int BK = 64, PAD = 8;
    __shared__ bf16 As[128][BK + PAD];
    __shared__ bf16 Bs[128][BK + PAD];
    int tid = threadIdx.x;
    int wave = tid >> 6, lane = tid & 63;
    int bm = blockIdx.y * 128, bn = blockIdx.x * 128;
    int wm = (wave >> 1) * 64, wn = (wave & 1) * 64;
    int lm = lane & 15, quad = lane >> 4;
    floatx4 acc[4][4] = {};
    int sRow = tid >> 1, sCol = (tid & 1) * 32;
    const bf16* ag = A  + (long)(bm + sRow) * lda + sCol;
    const bf16* bg = WT + (long)(bn + sRow) * K   + sCol;
    for (int k0 = 0; k0 < K; k0 += BK) {
        #pragma unroll
        for (int i = 0; i < 4; i++)
            *(float4*)&As[sRow][sCol + i * 8] = *(const float4*)(ag + k0 + i * 8);
        #pragma unroll
        for (int i = 0; i < 4; i++)
            *(float4*)&Bs[sRow][sCol + i * 8] = *(const float4*)(bg + k0 + i * 8);
        __syncthreads();
        #pragma unroll
        for (int kk = 0; kk < BK; kk += 32) {
            short8 af[4], bf[4];
            #pragma unroll
            for (int mi = 0; mi < 4; mi++)
                af[mi] = *(const short8*)&As[wm + mi * 16 + lm][kk + quad * 8];
            #pragma unroll
            for (int ni = 0; ni < 4; ni++)
                bf[ni] = *(const short8*)&Bs[wn + ni * 16 + lm][kk + quad * 8];
            #pragma unroll
            for (int mi = 0; mi < 4; mi++)
                #pragma unroll
                for (int ni = 0; ni < 4; ni++)
                    acc[mi][ni] = __builtin_amdgcn_mfma_f32_16x16x32_bf16(
                        af[mi], bf[ni], acc[mi][ni], 0, 0, 0);
        }
        __syncthreads();
    }
    bool f32f = DF[0] != 0;
    bool bF = (bTag == TAG_F32) || (bTag == TAG_AUTO && f32f);
    #pragma unroll
    for (int ni = 0; ni < 4; ni++) {
        int col = bn + wn + ni * 16 + lm;
        float cb = bias ? ld1auto(bias, col, bF) : 0.f;
        #pragma unroll
        for (int mi = 0; mi < 4; mi++) {
            #pragma unroll
            for (int reg = 0; reg < 4; reg++) {
                int row = bm + wm + mi * 16 + quad * 4 + reg;
                float v = acc[mi][ni][reg] + cb;
                TC* cp = C + (long)row * ldc + col;
                if (alpha) {
                    const float* al = alpha + (long)(row / rowsPerB) * alphaStride + col;
                    v = ldc1(cp) + al[0] * v;
                } else if (act == 1) {
                    v = gelu_f(v);
                }
                stc1(cp, v);
            }
        }
    }
}

template <typename TC>
static void mgemm(hipStream_t s, const bf16* A, int lda, const bf16* WT,
                  TC* C, int ldc, int M, int N, int K,
                  const void* bias, int bTag, int act,
                  const float* alpha, int alphaStride, int rowsPerB, const int* DF) {
    dim3 g(N / 128, M / 128);
    k_mfma<TC><<<g, 256, 0, s>>>(A, lda, WT, C, ldc, M, N, K,
                                 bias, bTag, act, alpha, alphaStride, rowsPerB, DF);
}

// ---------------- generic tiled fp32-VALU GEMM ------------------------------
template <typename TC>
__global__ __launch_bounds__(256) void k_gemm(
    const void* __restrict__ Ab, int aTag, int lda, long bsA,
    const void* __restrict__ Wb, int wTag, int ldw, long bsW,
    TC* __restrict__ Cb, int ldc, long bsC,
    int M, int N, int K,
    const void* __restrict__ bias, int bTag, int biasRow, int act,
    const float* __restrict__ alpha, int alphaStride, int rowsPerB,
    const int* __restrict__ DF) {
    __shared__ float As[16][68];
    __shared__ float Bs[16][68];
    bool f32f = DF[0] != 0;
    bool aF = (aTag == TAG_F32) || (aTag == TAG_AUTO && f32f);
    bool wF = (wTag == TAG_F32) || (wTag == TAG_AUTO && f32f);
    bool bF = (bTag == TAG_F32) || (bTag == TAG_AUTO && f32f);
    TC* Cbase = Cb + (long)blockIdx.z * bsC;
    long aBase = (long)blockIdx.z * bsA;
    long wBase = (long)blockIdx.z * bsW;
    int tid = threadIdx.x;
    int bm = blockIdx.y, bn = blockIdx.x;
    int tx = tid & 15, ty = tid >> 4;
    int arow = tid >> 2, acol = (tid & 3) * 4;
    int wrow = tid >> 4, wcol = (tid & 15) * 4;
    int gArow = bm * 64 + arow;
    bool aValid = gArow < M;
    float acc[4][4] = {};
    for (int kk = 0; kk < K; kk += 16) {
        float4 av = {0.f, 0.f, 0.f, 0.f};
        if (aValid) av = load4auto(Ab, aBase + (long)gArow * lda + kk + acol, aF);
        As[acol + 0][arow] = av.x;
        As[acol + 1][arow] = av.y;
        As[acol + 2][arow] = av.z;
        As[acol + 3][arow] = av.w;
        float4 wv = load4auto(Wb, wBase + (long)(kk + wrow) * ldw + bn * 64 + wcol, wF);
        *(float4*)&Bs[wrow][wcol] = wv;
        __syncthreads();
        #pragma unroll
        for (int k = 0; k < 16; k++) {
            float4 a4 = *(const float4*)&As[k][ty * 4];
            float4 b4 = *(const float4*)&Bs[k][tx * 4];
            acc[0][0] += a4.x * b4.x; acc[0][1] += a4.x * b4.y; acc[0][2] += a4.x * b4.z; acc[0][3] += a4.x * b4.w;
            acc[1][0] += a4.y * b4.x; acc[1][1] += a4.y * b4.y; acc[1][2] += a4.y * b4.z; acc[1][3] += a4.y * b4.w;
            acc[2][0] += a4.z * b4.x; acc[2][1] += a4.z * b4.y; acc[2][2] += a4.z * b4.z; acc[2][3] += a4.z * b4.w;
            acc[3][0] += a4.w * b4.x; acc[3][1] += a4.w * b4.y; acc[3][2] += a4.w * b4.z; acc[3][3] += a4.w * b4.w;
        }
        __syncthreads();
    }
    int gcol = bn * 64 + tx * 4;
    float cb[4] = {0.f, 0.f, 0.f, 0.f};
    if (bias && !biasRow) {
        #pragma unroll
        for (int j = 0; j < 4; j++) cb[j] = ld1auto(bias, gcol + j, bF);
    }
    #pragma unroll
    for (int i = 0; i < 4; i++) {
        int grow = bm * 64 + ty * 4 + i;
        if (grow >= M) continue;
        float rb = (bias && biasRow) ? ld1auto(bias, grow, bF) : 0.f;
        TC* crow = Cbase + (long)grow * ldc + gcol;
        const float* al = nullptr;
        if (alpha) al = alpha + (long)(grow / rowsPerB) * alphaStride + gcol;
        #pragma unroll
        for (int j = 0; j < 4; j++) {
            float v = acc[i][j] + cb[j] + rb;
            if (alpha)         v = ldc1(crow + j) + al[j] * v;
            else if (act == 1) v = gelu_f(v);
            stc1(crow + j, v);
        }
    }
}

template <typename TC>
static void gemm(hipStream_t s, const void* A, int aTag, int lda, long bsA,
                 const void* W, int wTag, int ldw, long bsW,
                 TC* C, int ldc, long bsC, int M, int N, int K,
                 const void* bias, int bTag, int biasRow, int act,
                 const float* alpha, int alphaStride, int rowsPerB, int batch,
                 const int* DF) {
    dim3 g(N / 64, (M + 63) / 64, batch);
    k_gemm<TC><<<g, 256, 0, s>>>(A, aTag, lda, bsA, W, wTag, ldw, bsW, C, ldc, bsC,
                                 M, N, K, bias, bTag, biasRow, act,
                                 alpha, alphaStride, rowsPerB, DF);
}

// ---------------- agent attention stage 1 (ka/va bf16 -- as passing round 3)
__global__ __launch_bounds__(256) void k_agatt1(const float* __restrict__ qa,
                                                const bf16* __restrict__ ka,
                                                const bf16* __restrict__ va,
                                                float* __restrict__ c1) {
    int blk = blockIdx.x;
    int a = blk % kA;
    int h = (blk / kA) % kH;
    int b = blk / (kA * kH);
    __shared__ float qrow[kHS];
    __shared__ float probs[kT];
    __shared__ float sm[8];
    __shared__ float part[4][64];
    int tid = threadIdx.x;
    if (tid < kHS) qrow[tid] = qa[((long)h * kA + a) * kHS + tid];
    __syncthreads();
    const bf16* kab = ka + ((long)h * kB + b) * kT * kHS;
    float sc[2];
    #pragma unroll
    for (int rep = 0; rep < 2; rep++) {
        const bf16* kr = kab + (long)(tid + rep * 256) * kHS;
        float acc = 0.f;
        #pragma unroll
        for (int d = 0; d < kHS; d += 4) {
            float4 k4 = load4bf(kr + d);
            acc += k4.x * qrow[d] + k4.y * qrow[d + 1] + k4.z * qrow[d + 2] + k4.w * qrow[d + 3];
        }
        sc[rep] = acc * 0.125f;
    }
    float mx = fmaxf(sc[0], sc[1]);
    for (int m = 32; m > 0; m >>= 1) mx = fmaxf(mx, __shfl_down(mx, m));
    if ((tid & 63) == 0) sm[tid >> 6] = mx;
    __syncthreads();
    mx = fmaxf(fmaxf(sm[0], sm[1]), fmaxf(sm[2], sm[3]));
    float e0 = expf(sc[0] - mx), e1 = expf(sc[1] - mx);
    float ss = e0 + e1;
    for (int m = 32; m > 0; m >>= 1) ss += __shfl_down(ss, m);
    if ((tid & 63) == 0) sm[4 + (tid >> 6)] = ss;
    __syncthreads();
    ss = sm[4] + sm[5] + sm[6] + sm[7];
    float rs = 1.f / ss;
    probs[tid] = e0 * rs;
    probs[tid + 256] = e1 * rs;
    __syncthreads();
    int d = tid & 63, ch = tid >> 6;
    const bf16* vab = va + ((long)h * kB + b) * kT * kHS;
    float acc = 0.f;
    for (int n = ch * 128; n < (ch + 1) * 128; n++)
        acc += probs[n] * bf2f(vab[(long)n * kHS + d]);
    part[ch][d] = acc;
    __syncthreads();
    if (tid < 64)
        c1[(((long)b * kH + h) * kA + a) * kHS + tid] =
            part[0][tid] + part[1][tid] + part[2][tid] + part[3][tid];
}

// ---------------- agent attention stage 2 (fp32 in/out) ----------------------
__global__ __launch_bounds__(256) void k_agatt2f(const float* __restrict__ qsrc, int ldq,
                                                 const float* __restrict__ c1,
                                                 float* __restrict__ out) {
    int blk = blockIdx.x;
    int nt = blk % (kT / 16);
    int h = (blk / (kT / 16)) % kH;
    int b = blk / ((kT / 16) * kH);
    __shared__ float c1s[kA][kHS + 1];
    __shared__ float qs[16][kHS + 1];
    __shared__ float ps[16][kA + 1];
    int tid = threadIdx.x;
    const float* c1b = c1 + ((long)b * kH + h) * kA * kHS;
    for (int i = tid; i < kA * kHS; i += 256) c1s[i >> 6][i & 63] = c1b[i];
    int n0 = nt * 16;
    {
        int r = tid >> 4, d = (tid & 15) * 4;
        float4 q4 = load4f(qsrc + (long)(b * kT + n0 + r) * ldq + h * kHS + d);
        qs[r][d] = q4.x; qs[r][d + 1] = q4.y; qs[r][d + 2] = q4.z; qs[r][d + 3] = q4.w;
    }
    __syncthreads();
    int r = tid >> 4, c = tid & 15;
    float sc[4];
    #pragma unroll
    for (int j = 0; j < 4; j++) {
        int a = c * 4 + j;
        float acc = 0.f;
        for (int d = 0; d < kHS; d++) acc += qs[r][d] * c1s[a][d];
        sc[j] = acc * 0.125f;
    }
    float mx = fmaxf(fmaxf(sc[0], sc[1]), fmaxf(sc[2], sc[3]));
    for (int m = 1; m < 16; m <<= 1) mx = fmaxf(mx, __shfl_xor(mx, m));
    float e[4], ss = 0.f;
    #pragma unroll
    for (int j = 0; j < 4; j++) { e[j] = expf(sc[j] - mx); ss += e[j]; }
    for (int m = 1; m < 16; m <<= 1) ss += __shfl_xor(ss, m);
    float rs = 1.f / ss;
    #pragma unroll
    for (int j = 0; j < 4; j++) ps[r][c * 4 + j] = e[j] * rs;
    __syncthreads();
    float o0 = 0.f, o1 = 0.f, o2 = 0.f, o3 = 0.f;
    int d0 = c * 4;
    for (int a = 0; a < kA; a++) {
        float p = ps[r][a];
        o0 += p * c1s[a][d0 + 0];
        o1 += p * c1s[a][d0 + 1];
        o2 += p * c1s[a][d0 + 2];
        o3 += p * c1s[a][d0 + 3];
    }
    float* orow = out + (long)(b * kT + n0 + r) * kE + h * kHS + d0;
    orow[0] = o0; orow[1] = o1; orow[2] = o2; orow[3] = o3;
}

// ---------------- DFT tables --------------------------------------------------
__global__ void k_trig(float* __restrict__ trig) {
    int id = blockIdx.x * 256 + threadIdx.x;
    if (id >= kNFREQ * kT) return;
    int t = id & 511;
    int f = (id >> 9) + 1;
    int m = (f * t) & 511;
    double ang = (double)m * (2.0 * 3.14159265358979323846 / 512.0);
    trig[id] = (float)cos(ang);
    trig[kNFREQ * kT + id] = (float)(-sin(ang));
}

// ---------------- top-5 |X_f|^2 per (b,e) column ------------------------------
// f-parallel rewrite: 16 threads per column each scan a 16-frequency chunk
// keeping a private top-5; partials merge via LDS.  Tie-break (v==, lower f
// wins) reproduces jax.lax.top_k stable semantics independent of merge order.
// Old: 32 blocks, serial 255-iter scan -> 207 us @ 1.4% occupancy.
__global__ __launch_bounds__(256) void k_topk(const float* __restrict__ RE, const float* __restrict__ IM,
                                              float* __restrict__ tre, float* __restrict__ tim,
                                              int* __restrict__ tix) {
    int tid = threadIdx.x;
    int c = tid & 15;                       // column within block
    int j = tid >> 4;                       // f-group 0..15
    int colId = blockIdx.x * 16 + c;        // 0..8191
    int b = colId >> 10, e = colId & 1023;
    const float* rp = RE + (long)b * kNFREQ * kE + e;
    const float* ip = IM + (long)b * kNFREQ * kE + e;
    float bv[kKTOP] = {-1e30f, -1e30f, -1e30f, -1e30f, -1e30f};
    int bi[kKTOP] = {1 << 30, 1 << 30, 1 << 30, 1 << 30, 1 << 30};
    #pragma unroll
    for (int s = 0; s < 16; s++) {
        int fq = j * 16 + s;
        if (fq >= kNFREQ) break;
        float re = rp[(long)fq * kE], im = ip[(long)fq * kE];
        float m2 = re * re + im * im;
        if (m2 > bv[kKTOP - 1] || (m2 == bv[kKTOP - 1] && fq < bi[kKTOP - 1])) {
            int p = kKTOP - 1;
            while (p > 0 && (m2 > bv[p - 1] || (m2 == bv[p - 1] && fq < bi[p - 1]))) {
                bv[p] = bv[p - 1]; bi[p] = bi[p - 1]; p--;
            }
            bv[p] = m2; bi[p] = fq;
        }
    }
    __shared__ float sv[16][16][kKTOP];
    __shared__ int   si[16][16][kKTOP];
    #pragma unroll
    for (int q = 0; q < kKTOP; q++) { sv[c][j][q] = bv[q]; si[c][j][q] = bi[q]; }
    __syncthreads();
    if (j == 0) {
        for (int jj = 1; jj < 16; jj++) {
            #pragma unroll
            for (int q = 0; q < kKTOP; q++) {
                float v = sv[c][jj][q];
                int fq = si[c][jj][q];
                if (v > bv[kKTOP - 1] || (v == bv[kKTOP - 1] && fq < bi[kKTOP - 1])) {
                    int p = kKTOP - 1;
                    while (p > 0 && (v > bv[p - 1] || (v == bv[p - 1] && fq < bi[p - 1]))) {
                        bv[p] = bv[p - 1]; bi[p] = bi[p - 1]; p--;
                    }
                    bv[p] = v; bi[p] = fq;
                }
            }
        }
        #pragma unroll
        for (int q = 0; q < kKTOP; q++) {
            int fq = bi[q];
            tre[(long)colId * kKTOP + q] = rp[(long)fq * kE];
            tim[(long)colId * kKTOP + q] = ip[(long)fq * kE];
            tix[(long)colId * kKTOP + q] = fq;
        }
    }
}

__global__ void k_season(const float* __restrict__ tre, const float* __restrict__ tim,
                         const int* __restrict__ tix, const float* __restrict__ trig,
                         void* __restrict__ out, long obase, const int* __restrict__ DF) {
    bool f32o = DF[0] != 0;
    long id = (long)blockIdx.x * 256 + threadIdx.x;
    int e = id & 1023;
    long bt = id >> 10;
    int t = (int)(bt & 511);
    int b = (int)(bt >> 9);
    long be = (long)b * kE + e;
    float acc = 0.f;
    #pragma unroll
    for (int j = 0; j < kKTOP; j++) {
        int f = tix[be * kKTOP + j];
        acc += tre[be * kKTOP + j] * trig[(long)f * kT + t]
             + tim[be * kKTOP + j] * trig[(long)kNFREQ * kT + (long)f * kT + t];
    }
    st1auto(out, obase + id, f32o, 2.f * acc);
}

// ---------------- trend branch ------------------------------------------------
// conv1 re-parallelized: grid = (b,o) x 8 l-tiles = 192 blocks.  Weight slab
// w[o,:,:] (6 KB) staged in LDS once; each thread owns one l of a 128-wide
// tile and half the i-range; 2-way LDS reduce.  Old: 96 blocks, 512-iter
// serial loop with per-iter scalar weight loads -> 224 us @ 4.2% occupancy.
__global__ __launch_bounds__(256) void k_conv1(const float* __restrict__ P,
                                               const void* __restrict__ w,
                                               const void* __restrict__ bias,
                                               float* __restrict__ G,
                                               const int* __restrict__ DF) {
    bool f = DF[0] != 0;
    int bo = blockIdx.x;                 // 0..23 -> (b,o)
    int lt = blockIdx.y;                 // 0..7  -> 128-l tile
    int o = bo % 3, b = bo / 3;
    int tid = threadIdx.x;
    __shared__ float ws[512][3];         // 6 KB weight slab for this o
    for (int idx = tid; idx < 512 * 3; idx += 256)
        ws[idx / 3][idx % 3] = ld1auto(w, (long)o * 512 * 3 + idx, f);
    __syncthreads();
    int l = lt * 128 + (tid & 127);
    int ih = (tid >> 7) * 256;           // 0 or 256
    const float* xb = P + (long)b * kT2 * kE;
    float acc = 0.f;
    for (int ii = 0; ii < 256; ii++) {
        int i = ih + ii;
        const float* xr = xb + (long)i * kE + l;
        float xm = (l > 0)    ? xr[-1] : 0.f;
        float xc = xr[0];
        float xp = (l < 1023) ? xr[1]  : 0.f;
        acc += xm * ws[i][0] + xc * ws[i][1] + xp * ws[i][2];
    }
    __shared__ float red[128];
    if (tid >= 128) red[tid - 128] = acc;
    __syncthreads();
    if (tid < 128) {
        float tot = acc + red[tid] + ld1auto(bias, o, f);
        G[((long)b * 3 + o) * 1024 + l] = gelu_f(tot);
    }
}

// conv2 re-parallelized: one workgroup per (b,n) output pair (512 blocks),
// 256 threads stride over i, 3 pp-partials in registers, block-reduce.
// Old version: 6 blocks, serial 3072-iter scalar loop -> 489 us @ 0.3% occupancy.
__global__ __launch_bounds__(256) void k_conv2(const float* __restrict__ G,
                                               const void* __restrict__ w,
                                               const void* __restrict__ bias,
                                               float* __restrict__ H2,
                                               const int* __restrict__ DF) {
    bool f = DF[0] != 0;
    int n = blockIdx.x % kNF;
    int b = blockIdx.x / kNF;
    int tid = threadIdx.x;
    const float* Gb = G + (long)b * 3 * 1024;
    // valid (pp, k -> l = pp + k - 1) combos:
    // pp=0: g[0]*w[1] + g[1]*w[2]
    // pp=1: g[0]*w[0] + g[1]*w[1] + g[2]*w[2]
    // pp=2: g[1]*w[0] + g[2]*w[1]
    float a0 = 0.f, a1 = 0.f, a2 = 0.f;
    for (int i = tid; i < 1024; i += 256) {
        float g0 = Gb[i], g1 = Gb[1024 + i], g2 = Gb[2048 + i];
        long wo = ((long)n * 1024 + i) * 3;
        float w0 = ld1auto(w, wo + 0, f);
        float w1 = ld1auto(w, wo + 1, f);
        float w2 = ld1auto(w, wo + 2, f);
        a0 += g0 * w1 + g1 * w2;
        a1 += g0 * w0 + g1 * w1 + g2 * w2;
        a2 += g1 * w0 + g2 * w1;
    }
    __shared__ float sm[12];
    #pragma unroll
    for (int m = 32; m > 0; m >>= 1) {
        a0 += __shfl_down(a0, m);
        a1 += __shfl_down(a1, m);
        a2 += __shfl_down(a2, m);
    }
    int wv = tid >> 6;
    if ((tid & 63) == 0) { sm[wv] = a0; sm[4 + wv] = a1; sm[8 + wv] = a2; }
    __syncthreads();
    if (tid == 0) {
        float cb = ld1auto(bias, n, f);
        float* hp = H2 + ((long)b * kNF + n) * 3;
        hp[0] = cb + sm[0] + sm[1] + sm[2] + sm[3];
        hp[1] = cb + sm[4] + sm[5] + sm[6] + sm[7];
        hp[2] = cb + sm[8] + sm[9] + sm[10] + sm[11];
    }
}

__global__ void k_trend(const float* __restrict__ H2, void* __restrict__ out, long obase,
                        const int* __restrict__ DF) {
    bool f32o = DF[0] != 0;
    int id = blockIdx.x * 256 + threadIdx.x;
    int n = id % kNF;
    int t = (id / kNF) % kT;
    int b = id / (kNF * kT);
    float lin = (float)(t + 1) / 513.0f;
    const float* h = H2 + ((long)b * kNF + n) * 3;
    float l2 = lin * lin;
    st1auto(out, obase + id, f32o, h[0] * lin + h[1] * l2 + h[2] * l2 * lin);
}

// ---------------- finals -------------------------------------------------------
__global__ void k_mean(const float* __restrict__ X, float* __restrict__ m) {
    int id = blockIdx.x * 256 + threadIdx.x;
    int b = id >> 10, e = id & 1023;
    const float* p = X + (long)b * kT * kE + e;
    float s = 0.f;
    for (int t = 0; t < kT; t++) s += p[(long)t * kE];
    m[id] = s * (1.f / kT);
}

__global__ void k_out0(const float* __restrict__ X, const float* __restrict__ m,
                       void* __restrict__ out, long obase, const int* __restrict__ DF) {
    bool f32o = DF[0] != 0;
    long id = (long)blockIdx.x * 256 + threadIdx.x;
    int e = id & 1023;
    int b = (int)(id >> 19);
    st1auto(out, obase + id, f32o, X[id] - m[b * kE + e]);
}

__global__ void k_out1(const float* __restrict__ m, const void* __restrict__ w,
                       const void* __restrict__ bias, void* __restrict__ out, long obase,
                       const int* __restrict__ DF) {
    bool f = DF[0] != 0;
    int id = blockIdx.x * 256 + threadIdx.x;
    if (id >= kB * kNF) return;
    int b = id / kNF, n = id % kNF;
    float acc = ld1auto(bias, n, f);
    for (int e = 0; e < kE; e++) acc += m[b * kE + e] * ld1auto(w, (long)e * kNF + n, f);
    st1auto(out, obase + id, f, acc);
}

// ---------------- launch -------------------------------------------------------
extern "C" void kernel_launch(void* const* d_in, const int* in_sizes, int n_in,
                              void* d_out, int out_size, void* d_ws, size_t ws_size,
                              hipStream_t stream) {
    (void)in_sizes; (void)n_in; (void)out_size; (void)ws_size;
    const void* x_in = d_in[0];
    const void* enc  = d_in[1];
    const int* tstep = (const int*)d_in[2];
    const void *ln1_w = d_in[3],  *ln1_b = d_in[4],  *ln11_w = d_in[5], *ln11_b = d_in[6];
    const void *ln2_w = d_in[7],  *ln2_b = d_in[8];
    const void *a1_qkv_w = d_in[9], *a1_qkv_b = d_in[10];
    const void *a1_agq_w = d_in[11], *a1_agq_b = d_in[12];
    const void *a1_agk_w = d_in[13], *a1_agk_b = d_in[14];
    const void *a1_agv_w = d_in[15], *a1_agv_b = d_in[16];
    const void *a1_ago_w = d_in[17], *a1_ago_b = d_in[18];
    const void *a1_agents = d_in[19];
    const void *a1_proj_w = d_in[20], *a1_proj_b = d_in[21];
    const void *a2_q_w = d_in[22], *a2_q_b = d_in[23];
    const void *a2_kv_w = d_in[24], *a2_kv_b = d_in[25];
    const void *a2_agq_w = d_in[26], *a2_agq_b = d_in[27];
    const void *a2_agk_w = d_in[28], *a2_agk_b = d_in[29];
    const void *a2_agv_w = d_in[30], *a2_agv_b = d_in[31];
    const void *a2_ago_w = d_in[32], *a2_ago_b = d_in[33];
    const void *a2_agents = d_in[34];
    const void *a2_proj_w = d_in[35], *a2_proj_b = d_in[36];
    const void *tr_c1_w = d_in[37], *tr_c1_b = d_in[38];
    const void *tr_c2_w = d_in[39], *tr_c2_b = d_in[40];
    const void *mlp_w1 = d_in[41], *mlp_b1 = d_in[42];
    const void *mlp_w2 = d_in[43], *mlp_b2 = d_in[44];
    const void *pr_w = d_in[45], *pr_b = d_in[46];
    const void *lin_w = d_in[47], *lin_b = d_in[48];

    char* wsb = (char*)d_ws;
    float* XC = (float*)(wsb + BOFF_XC);
    float* SM = (float*)(wsb + BOFF_SMALL);
    float* TS = SM + F_TS;
    float* AD1 = SM + F_AD1;
    float* AD11 = SM + F_AD11;
    float* AD2 = SM + F_AD2;
    float* QA = SM + F_QA;
    float* C1 = SM + F_C1;
    float* H2 = SM + F_H2;
    float* G1 = SM + F_G1;
    float* MB = SM + F_MB;
    float* TRE = SM + F_TRE;
    float* TIM = SM + F_TIM;
    int*   TIX = (int*)(SM + F_TIX);
    float* TRIG = SM + F_TRIG;
    int* DF = (int*)(wsb + BOFF_FLAG);
    char* WR = wsb + BOFF_WREG;
    float* WTQ  = (float*)(WR + WR_Q);
    float* WTKV = (float*)(WR + WR_KV);
    float* WAGO = (float*)(WR + WR_AGO);
    float* WPRJ = (float*)(WR + WR_PRJ);
    bf16*  W1B  = (bf16*)(WR + WR_W1);
    bf16*  W2B  = (bf16*)(WR + WR_W2);
    char* AC = wsb + BOFF_ACT;
    float* N1F  = (float*)(AC + AC_N1);     // also ENCF
    float* QBUF = (float*)(AC + AC_QBUF);
    float* KVB  = (float*)(AC + AC_KV);
    bf16*  KA   = (bf16*)(AC + AC_KA);
    bf16*  VA   = (bf16*)(AC + AC_VA);
    float* ATTF = (float*)(AC + AC_ATT);
    float* Y2F  = (float*)(AC + AC_Y2);
    float* P    = (float*)(AC + AC_P);
    float* RE   = (float*)(AC + AC_RE);
    float* IM   = (float*)(AC + AC_IM);
    bf16*  N1B  = (bf16*)(AC + AC_N1B);
    bf16*  HID  = (bf16*)(AC + AC_HID);

    const int M_BT = kB * kT;                      // 4096
    const long bsKA = (long)kB * kT * kHS;

    // 0) dtype detection (precedes all d_in consumers)
    k_detect<<<1, 256, 0, stream>>>((const unsigned short*)x_in, DF);

    // phase-1 weight transposes (fp32)
    k_wtf<<<dim3(1024/32, 1024/32), 256, 0, stream>>>(a1_qkv_w, WTQ, 1024, 3072, 0, DF);
    k_wtf<<<dim3(2048/32, 1024/32), 256, 0, stream>>>(a1_qkv_w, WTKV, 1024, 3072, 1024, DF);
    k_wtf<<<dim3(1024/32, 1024/32), 256, 0, stream>>>(a1_ago_w, WAGO, 1024, 1024, 0, DF);
    k_wtf<<<dim3(1024/32, 1024/32), 256, 0, stream>>>(a1_proj_w, WPRJ, 1024, 1024, 0, DF);

    // prologue
    k_temb<<<kB, 512, 0, stream>>>(tstep, TS);
    gemm(stream, TS, TAG_F32, kE, 0L, ln1_w, TAG_AUTO, 3 * kE, 0L, AD1, 3 * kE, 0L,
         kB, 3 * kE, kE, ln1_b, TAG_AUTO, 0, 0, nullptr, 0, 1, 1, DF);
    gemm(stream, TS, TAG_F32, kE, 0L, ln11_w, TAG_AUTO, 3 * kE, 0L, AD11, 3 * kE, 0L,
         kB, 3 * kE, kE, ln11_b, TAG_AUTO, 0, 0, nullptr, 0, 1, 1, DF);
    gemm(stream, TS, TAG_F32, kE, 0L, ln2_w, TAG_AUTO, 3 * kE, 0L, AD2, 3 * kE, 0L,
         kB, 3 * kE, kE, ln2_b, TAG_AUTO, 0, 0, nullptr, 0, 1, 1, DF);
    k_castin<<<(kB * kT * kE) / 1024, 256, 0, stream>>>(x_in, XC, DF);
    k_trig<<<(kNFREQ * kT + 255) / 256, 256, 0, stream>>>(TRIG);

    // ---- attention block 1 (self), fp32 end-to-end via split MFMA ----
    k_adalnf<<<M_BT, 256, 0, stream>>>(XC, AD1, N1F);
    mgemm32(stream, N1F, kE, WTQ, QBUF, kE, M_BT, kE, kE,
            a1_qkv_b, TAG_AUTO, 0L, nullptr, 0, 1, DF);
    mgemm32(stream, N1F, kE, WTKV, KVB, 2 * kE, M_BT, 2 * kE, kE,
            a1_qkv_b, TAG_AUTO, (long)kE, nullptr, 0, 1, DF);
    gemm(stream, a1_agents, TAG_AUTO, kHS, 0L, a1_agq_w, TAG_AUTO, kHS, 0L, QA, kHS, 0L,
         kH * kA, kHS, kHS, a1_agq_b, TAG_AUTO, 0, 0, nullptr, 0, 1, 1, DF);
    gemm(stream, KVB, TAG_F32, 2 * kE, 64L, a1_agk_w, TAG_AUTO, kHS, 0L, KA, kHS, bsKA,
         M_BT, kHS, kHS, a1_agk_b, TAG_AUTO, 0, 0, nullptr, 0, 1, kH, DF);
    gemm(stream, KVB + kE, TAG_F32, 2 * kE, 64L, a1_agv_w, TAG_AUTO, kHS, 0L, VA, kHS, bsKA,
         M_BT, kHS, kHS, a1_agv_b, TAG_AUTO, 0, 0, nullptr, 0, 1, kH, DF);
    k_agatt1<<<kB * kH * kA, 256, 0, stream>>>(QA, KA, VA, C1);
    k_agatt2f<<<kB * kH * (kT / 16), 256, 0, stream>>>(QBUF, kE, C1, ATTF);
    mgemm32(stream, ATTF, kE, WAGO, Y2F, kE, M_BT, kE, kE,
            a1_ago_b, TAG_AUTO, 0L, nullptr, 0, 1, DF);
    mgemm32(stream, Y2F, kE, WPRJ, XC, kE, M_BT, kE, kE,
            a1_proj_b, TAG_AUTO, 0L, AD1 + 2 * kE, 3 * kE, kT, DF);

    // phase-2 weight transposes (WREG safely reusable after prj1)
    k_wtf<<<dim3(1024/32, 1024/32), 256, 0, stream>>>(a2_q_w, WTQ, 1024, 1024, 0, DF);
    k_wtf<<<dim3(2048/32, 1024/32), 256, 0, stream>>>(a2_kv_w, WTKV, 1024, 2048, 0, DF);
    k_wtf<<<dim3(1024/32, 1024/32), 256, 0, stream>>>(a2_ago_w, WAGO, 1024, 1024, 0, DF);
    k_wtf<<<dim3(1024/32, 1024/32), 256, 0, stream>>>(a2_proj_w, WPRJ, 1024, 1024, 0, DF);

    // ---- attention block 2 (cross) ----
    k_castin<<<(kB * kT * kE) / 1024, 256, 0, stream>>>(enc, N1F, DF);   // ENCF in N1F slot
    mgemm32(stream, N1F, kE, WTKV, KVB, 2 * kE, M_BT, 2 * kE, kE,
            a2_kv_b, TAG_AUTO, 0L, nullptr, 0, 1, DF);
    k_adalnf<<<M_BT, 256, 0, stream>>>(XC, AD11, N1F);                    // overwrites ENCF (dead)
    mgemm32(stream, N1F, kE, WTQ, QBUF, kE, M_BT, kE, kE,
            a2_q_b, TAG_AUTO, 0L, nullptr, 0, 1, DF);
    gemm(stream, a2_agents, TAG_AUTO, kHS, 0L, a2_agq_w, TAG_AUTO, kHS, 0L, QA, kHS, 0L,
         kH * kA, kHS, kHS, a2_agq_b, TAG_AUTO, 0, 0, nullptr, 0, 1, 1, DF);
    gemm(stream, KVB, TAG_F32, 2 * kE, 64L, a2_agk_w, TAG_AUTO, kHS, 0L, KA, kHS, bsKA,
         M_BT, kHS, kHS, a2_agk_b, TAG_AUTO, 0, 0, nullptr, 0, 1, kH, DF);
    gemm(stream, KVB + kE, TAG_F32, 2 * kE, 64L, a2_agv_w, TAG_AUTO, kHS, 0L, VA, kHS, bsKA,
         M_BT, kHS, kHS, a2_agv_b, TAG_AUTO, 0, 0, nullptr, 0, 1, kH, DF);
    k_agatt1<<<kB * kH * kA, 256, 0, stream>>>(QA, KA, VA, C1);
    k_agatt2f<<<kB * kH * (kT / 16), 256, 0, stream>>>(QBUF, kE, C1, ATTF);
    mgemm32(stream, ATTF, kE, WAGO, Y2F, kE, M_BT, kE, kE,
            a2_ago_b, TAG_AUTO, 0L, nullptr, 0, 1, DF);
    mgemm32(stream, Y2F, kE, WPRJ, XC, kE, M_BT, kE, kE,
            a2_proj_b, TAG_AUTO, 0L, AD11 + 2 * kE, 3 * kE, kT, DF);

    // ---- phase 3: p = einsum('bce,oc->boe') + DFT + trend (all fp32 VALU) ----
    gemm(stream, pr_w, TAG_AUTO, kT, 0L, XC, TAG_F32, kE, (long)kT * kE,
         P, kE, (long)kT2 * kE, kT2, kE, kT,
         pr_b, TAG_AUTO, 1, 0, nullptr, 0, 1, kB, DF);
    gemm(stream, TRIG, TAG_F32, kT, 0L, P + (long)kT * kE, TAG_F32, kE, (long)kT2 * kE,
         RE, kE, (long)kNFREQ * kE, kNFREQ, kE, kT,
         nullptr, 0, 0, 0, nullptr, 0, 1, kB, DF);
    gemm(stream, TRIG + (long)kNFREQ * kT, TAG_F32, kT, 0L, P + (long)kT * kE, TAG_F32, kE, (long)kT2 * kE,
         IM, kE, (long)kNFREQ * kE, kNFREQ, kE, kT,
         nullptr, 0, 0, 0, nullptr, 0, 1, kB, DF);
    k_topk<<<(kB * kE) / 16, 256, 0, stream>>>(RE, IM, TRE, TIM, TIX);
    k_season<<<(kB * kT * kE) / 256, 256, 0, stream>>>(TRE, TIM, TIX, TRIG, d_out, O3, DF);
    k_conv1<<<dim3(kB * 3, 8), 256, 0, stream>>>(P, tr_c1_w, tr_c1_b, G1, DF);
    k_conv2<<<kB * kNF, 256, 0, stream>>>(G1, tr_c2_w, tr_c2_b, H2, DF);
    k_trend<<<(kB * kT * kNF) / 256, 256, 0, stream>>>(H2, d_out, O2, DF);

    // ---- phase 4: MLP (post-P; plain bf16 MFMA -- proven on outputs 0/1) ----
    k_wt<<<dim3(4096/32, 1024/32), 256, 0, stream>>>(mlp_w1, W1B, 1024, 4096, DF);
    k_wt<<<dim3(1024/32, 4096/32), 256, 0, stream>>>(mlp_w2, W2B, 4096, 1024, DF);
    k_adaln<<<M_BT, 256, 0, stream>>>(XC, AD2, N1B);
    mgemm(stream, N1B, kE, W1B, HID, kMLP, M_BT, kMLP, kE,
          mlp_b1, TAG_AUTO, 1 /*gelu*/, nullptr, 0, 1, DF);
    mgemm(stream, HID, kMLP, W2B, XC, kE, M_BT, kE, kMLP,
          mlp_b2, TAG_AUTO, 0, AD2 + 2 * kE, 3 * kE, kT, DF);

    // ---- finals ----
    k_mean<<<(kB * kE) / 256, 256, 0, stream>>>(XC, MB);
    k_out0<<<(kB * kT * kE) / 256, 256, 0, stream>>>(XC, MB, d_out, O0, DF);
    k_out1<<<(kB * kNF + 255) / 256, 256, 0, stream>>>(MB, lin_w, lin_b, d_out, O1, DF);
}

// Round 5
// 2229.554 us; speedup vs baseline: 1.4347x; 1.0666x over previous
//
#include <hip/hip_runtime.h>
#include <hip/hip_bf16.h>

using bf16 = __hip_bfloat16;
typedef __attribute__((ext_vector_type(8))) short short8;     // 8 bf16 (4 VGPRs)
typedef __attribute__((ext_vector_type(4))) float floatx4;    // MFMA acc

// Problem constants
constexpr int kB = 8, kT = 512, kE = 1024, kH = 16, kA = 64, kNF = 64, kHS = 64;
constexpr int kMLP = 4096, kT2 = 1024, kNFREQ = 255, kKTOP = 5;

constexpr int TAG_F32 = 0, TAG_BF16 = 1, TAG_AUTO = 2;

// ---------------- workspace arena (BYTE offsets) ----------------------------
// XC 16.78M | SMALL 4.36M | FLAG 64 | WREG 20.97M (phase-reused weight xposes)
// | ACT 67.11M (phase-reused activations).  Total 109.2 MB < 117.6 MB proven.
constexpr long BOFF_XC    = 0;                          // fp32 (B,T,E)
constexpr long BOFF_SMALL = 16777216;                   // 4,360,192 B
constexpr long BOFF_FLAG  = 21137408;                   // 64 B
constexpr long BOFF_WREG  = 21137472;                   // 20,971,520 B
constexpr long BOFF_ACT   = 42108992;                   // 67,108,864 B
constexpr long WS_NEED    = BOFF_ACT + 67108864;        // 109,217,856 B

// WREG slots (bytes from BOFF_WREG)
constexpr long WR_Q   = 0;          // fp32 1024x1024 (4,194,304)
constexpr long WR_KV  = 4194304;    // fp32 2048x1024 (8,388,608)
constexpr long WR_AGO = 12582912;   // fp32 1024x1024
constexpr long WR_PRJ = 16777216;   // fp32 1024x1024
constexpr long WR_W1  = 0;          // bf16 4096x1024 (8,388,608)  [phase 4]
constexpr long WR_W2  = 8388608;    // bf16 1024x4096 (8,388,608)  [phase 4]

// ACT slots (bytes from BOFF_ACT)
constexpr long AC_N1   = 0;         // fp32 (B,T,E) 16.78M   (also ENCF / P lo-half / N1b+HID)
constexpr long AC_QBUF = 16777216;  // fp32 (B,T,E) 16.78M
constexpr long AC_KV   = 33554432;  // fp32 (B,T,2E) 33.55M
constexpr long AC_KA   = 0;         // bf16 (H,B,T,HS) 8.39M  (over N1, after N1 dead)
constexpr long AC_VA   = 8388608;   // bf16 (H,B,T,HS) 8.39M
constexpr long AC_ATT  = 33554432;  // fp32 (B,T,E) 16.78M    (over KV, after KV dead)
constexpr long AC_Y2   = 50331648;  // fp32 (B,T,E) 16.78M
constexpr long AC_P    = 0;         // fp32 (B,2T,E) 33.55M   [phase 3]
constexpr long AC_RE   = 33554432;  // fp32 (B,255,E) 8,355,840
constexpr long AC_IM   = 41910272;  // fp32 (B,255,E) 8,355,840
constexpr long AC_N1B  = 0;         // bf16 (B,T,E) 8.39M     [phase 4]
constexpr long AC_HID  = 8388608;   // bf16 (B,T,MLP) 33.55M  [phase 4]

// small-region float offsets (relative to BOFF_SMALL)
constexpr long F_TS = 0, F_AD1 = 8192, F_AD11 = 32768, F_AD2 = 57344, F_QA = 81920,
               F_C1 = 147456, F_H2 = 671744, F_G1 = 673280, F_MB = 697856,
               F_TRE = 706048, F_TIM = 747008, F_TIX = 787968, F_TRIG = 828928;

// output regions (element offsets)
constexpr long O0 = 0, O1 = 4194304, O2 = 4194816, O3 = 4456960;

// ---------------- helpers ---------------------------------------------------
__device__ inline float bf2f(bf16 h) {
    unsigned short u = *(unsigned short*)&h;
    return __uint_as_float((unsigned)u << 16);
}
__device__ inline unsigned short bfbits(bf16 b) { return *(unsigned short*)&b; }
__device__ inline float gelu_f(float x) {
    return 0.5f * x * (1.0f + erff(x * 0.7071067811865476f));
}
__device__ inline float4 load4f(const float* p) { return *(const float4*)p; }
__device__ inline float4 load4bf(const bf16* p) {
    ushort4 u = *(const ushort4*)p;
    float4 r;
    r.x = __uint_as_float((unsigned)u.x << 16);
    r.y = __uint_as_float((unsigned)u.y << 16);
    r.z = __uint_as_float((unsigned)u.z << 16);
    r.w = __uint_as_float((unsigned)u.w << 16);
    return r;
}
__device__ inline float4 load4auto(const void* p, long idx, bool isF32) {
    if (isF32) return load4f((const float*)p + idx);
    return load4bf((const bf16*)p + idx);
}
__device__ inline float ld1auto(const void* p, long idx, bool isF32) {
    if (isF32) return ((const float*)p)[idx];
    return bf2f(((const bf16*)p)[idx]);
}
__device__ inline void st1auto(void* p, long idx, bool isF32, float v) {
    if (isF32) ((float*)p)[idx] = v;
    else       ((bf16*)p)[idx] = __float2bfloat16(v);
}
__device__ inline float ldc1(const float* p) { return *p; }
__device__ inline float ldc1(const bf16* p) { return bf2f(*p); }
__device__ inline void stc1(float* p, float v) { *p = v; }
__device__ inline void stc1(bf16* p, float v) { *p = __float2bfloat16(v); }

__device__ inline void blockReduce2(float& a, float& b, float* sm) {
    #pragma unroll
    for (int m = 32; m > 0; m >>= 1) { a += __shfl_down(a, m); b += __shfl_down(b, m); }
    int w = threadIdx.x >> 6;
    if ((threadIdx.x & 63) == 0) { sm[w] = a; sm[4 + w] = b; }
    __syncthreads();
    a = sm[0] + sm[1] + sm[2] + sm[3];
    b = sm[4] + sm[5] + sm[6] + sm[7];
    __syncthreads();
}

// ---------------- dtype detector --------------------------------------------
__global__ void k_detect(const unsigned short* __restrict__ xraw, int* __restrict__ flag) {
    int tid = threadIdx.x;
    unsigned short h = xraw[2 * tid];
    float v = __uint_as_float((unsigned)h << 16);
    float av = fabsf(v);
    if (!(av == av)) av = 1e30f;
    __shared__ float red[4];
    for (int m = 32; m > 0; m >>= 1) av = fmaxf(av, __shfl_down(av, m));
    if ((tid & 63) == 0) red[tid >> 6] = av;
    __syncthreads();
    if (tid == 0) {
        float mx = fmaxf(fmaxf(red[0], red[1]), fmaxf(red[2], red[3]));
        flag[0] = (mx < 1e3f) ? 0 : 1;             // 0 = bf16, 1 = fp32
    }
}

// ---------------- small kernels ---------------------------------------------
__global__ void k_temb(const int* __restrict__ ts, float* __restrict__ out) {
    int b = blockIdx.x, i = threadIdx.x;           // 512 threads
    float t = (float)ts[b];
    const float rate = (float)(-9.210340371976184 / 511.0);
    float f = expf(rate * (float)i);
    float arg = t * f;
    float sv = sinf(arg), cv = cosf(arg);
    out[(long)b * kE + i]        = sv / (1.f + expf(-sv));
    out[(long)b * kE + 512 + i]  = cv / (1.f + expf(-cv));
}

__global__ void k_castin(const void* __restrict__ in, float* __restrict__ out,
                         const int* __restrict__ DF) {
    bool f = DF[0] != 0;
    long i = ((long)blockIdx.x * 256 + threadIdx.x) * 4;
    float4 v = load4auto(in, i, f);
    *(float4*)(out + i) = v;
}

// fp32 weight transpose: W[K][Ntot] (auto dtype), cols [c0, c0+Nout) -> WT[Nout][K] fp32
__global__ __launch_bounds__(256) void k_wtf(const void* __restrict__ W, float* __restrict__ WT,
                                             int K, int Ntot, int c0,
                                             const int* __restrict__ DF) {
    bool f = DF[0] != 0;
    __shared__ float tile[32][33];
    int n0 = blockIdx.x * 32, k0 = blockIdx.y * 32;
    int tx = threadIdx.x & 31, ty = threadIdx.x >> 5;
    #pragma unroll
    for (int i = 0; i < 4; i++) {
        int k = ty + i * 8;
        tile[k][tx] = ld1auto(W, (long)(k0 + k) * Ntot + c0 + n0 + tx, f);
    }
    __syncthreads();
    #pragma unroll
    for (int i = 0; i < 4; i++) {
        int n = ty + i * 8;
        WT[(long)(n0 + n) * K + k0 + tx] = tile[tx][n];
    }
}

// bf16 weight transpose (for MLP): W[K][N] -> WT[N][K] bf16
__global__ __launch_bounds__(256) void k_wt(const void* __restrict__ W, bf16* __restrict__ WT,
                                            int K, int N, const int* __restrict__ DF) {
    bool f = DF[0] != 0;
    __shared__ float tile[32][33];
    int n0 = blockIdx.x * 32, k0 = blockIdx.y * 32;
    int tx = threadIdx.x & 31, ty = threadIdx.x >> 5;
    #pragma unroll
    for (int i = 0; i < 4; i++) {
        int k = ty + i * 8;
        tile[k][tx] = ld1auto(W, (long)(k0 + k) * N + n0 + tx, f);
    }
    __syncthreads();
    #pragma unroll
    for (int i = 0; i < 4; i++) {
        int n = ty + i * 8;
        WT[(long)(n0 + n) * K + k0 + tx] = __float2bfloat16(tile[tx][n]);
    }
}

// adaLN -> fp32 out (phases 1,2)
__global__ __launch_bounds__(256) void k_adalnf(const float* __restrict__ X,
                                                const float* __restrict__ AD,
                                                float* __restrict__ N) {
    int row = blockIdx.x;
    int b = row / kT;
    const float* xr = X + (long)row * kE;
    int tid = threadIdx.x;
    float4 xv = *(const float4*)(xr + tid * 4);
    float s  = xv.x + xv.y + xv.z + xv.w;
    float sq = xv.x * xv.x + xv.y * xv.y + xv.z * xv.z + xv.w * xv.w;
    __shared__ float sm[8];
    blockReduce2(s, sq, sm);
    float mu  = s * (1.f / kE);
    float var = sq * (1.f / kE) - mu * mu;
    float rstd = rsqrtf(fmaxf(var, 0.f) + 1e-5f);
    const float* ad = AD + (long)b * 3 * kE;
    float* nr = N + (long)row * kE;
    float xs[4] = {xv.x, xv.y, xv.z, xv.w};
    #pragma unroll
    for (int j = 0; j < 4; j++) {
        int e = tid * 4 + j;
        float xn = (xs[j] - mu) * rstd;
        nr[e] = xn * (1.f + ad[kE + e]) + ad[e];
    }
}

// adaLN -> bf16 out (phase 4 / MLP)
__global__ __launch_bounds__(256) void k_adaln(const float* __restrict__ X,
                                               const float* __restrict__ AD,
                                               bf16* __restrict__ N) {
    int row = blockIdx.x;
    int b = row / kT;
    const float* xr = X + (long)row * kE;
    int tid = threadIdx.x;
    float4 xv = *(const float4*)(xr + tid * 4);
    float s  = xv.x + xv.y + xv.z + xv.w;
    float sq = xv.x * xv.x + xv.y * xv.y + xv.z * xv.z + xv.w * xv.w;
    __shared__ float sm[8];
    blockReduce2(s, sq, sm);
    float mu  = s * (1.f / kE);
    float var = sq * (1.f / kE) - mu * mu;
    float rstd = rsqrtf(fmaxf(var, 0.f) + 1e-5f);
    const float* ad = AD + (long)b * 3 * kE;
    bf16* nr = N + (long)row * kE;
    float xs[4] = {xv.x, xv.y, xv.z, xv.w};
    #pragma unroll
    for (int j = 0; j < 4; j++) {
        int e = tid * 4 + j;
        float xn = (xs[j] - mu) * rstd;
        nr[e] = __float2bfloat16(xn * (1.f + ad[kE + e]) + ad[e]);
    }
}

// ---------------- split-precision MFMA GEMM (fp32-accurate) -----------------
// C = A(fp32 MxK) @ WT(fp32 NxK)^T via hi/lo bf16 split: Ah*Bh + Ah*Bl + Al*Bh.
// Relative error ~8e-6 (vs 2e-3 plain bf16). M,N mult of 128, K mult of 32.
template <typename TC>
__global__ __launch_bounds__(256) void k_mfma32(
    const float* __restrict__ A, int lda,
    const float* __restrict__ WT,
    TC* __restrict__ C, int ldc,
    int M, int N, int K,
    const void* __restrict__ bias, int bTag, long biasOff,
    const float* __restrict__ alpha, int alphaStride, int rowsPerB,
    const int* __restrict__ DF) {
    constexpr int BK = 32, PAD = 8;                 // 40 elem (80 B) row stride
    __shared__ bf16 Ah[128][BK + PAD], Al[128][BK + PAD];
    __shared__ bf16 Bh[128][BK + PAD], Bl[128][BK + PAD];
    int tid = threadIdx.x;
    int wave = tid >> 6, lane = tid & 63;
    int bm = blockIdx.y * 128, bn = blockIdx.x * 128;
    int wm = (wave >> 1) * 64, wn = (wave & 1) * 64;
    int lm = lane & 15, quad = lane >> 4;
    floatx4 acc[4][4] = {};
    int sRow = tid >> 1, sCol = (tid & 1) * 16;      // 16 fp32 per thread per tile
    const float* ag = A  + (long)(bm + sRow) * lda + sCol;
    const float* bg = WT + (long)(bn + sRow) * K   + sCol;
    for (int k0 = 0; k0 < K; k0 += BK) {
        #pragma unroll
        for (int i = 0; i < 4; i++) {
            float4 v = *(const float4*)(ag + k0 + i * 4);
            bf16 h0 = __float2bfloat16(v.x), h1 = __float2bfloat16(v.y);
            bf16 h2 = __float2bfloat16(v.z), h3 = __float2bfloat16(v.w);
            bf16 l0 = __float2bfloat16(v.x - bf2f(h0));
            bf16 l1 = __float2bfloat16(v.y - bf2f(h1));
            bf16 l2 = __float2bfloat16(v.z - bf2f(h2));
            bf16 l3 = __float2bfloat16(v.w - bf2f(h3));
            ushort4 hv = {bfbits(h0), bfbits(h1), bfbits(h2), bfbits(h3)};
            ushort4 lv = {bfbits(l0), bfbits(l1), bfbits(l2), bfbits(l3)};
            *(ushort4*)&Ah[sRow][sCol + i * 4] = hv;
            *(ushort4*)&Al[sRow][sCol + i * 4] = lv;
        }
        #pragma unroll
        for (int i = 0; i < 4; i++) {
            float4 v = *(const float4*)(bg + k0 + i * 4);
            bf16 h0 = __float2bfloat16(v.x), h1 = __float2bfloat16(v.y);
            bf16 h2 = __float2bfloat16(v.z), h3 = __float2bfloat16(v.w);
            bf16 l0 = __float2bfloat16(v.x - bf2f(h0));
            bf16 l1 = __float2bfloat16(v.y - bf2f(h1));
            bf16 l2 = __float2bfloat16(v.z - bf2f(h2));
            bf16 l3 = __float2bfloat16(v.w - bf2f(h3));
            ushort4 hv = {bfbits(h0), bfbits(h1), bfbits(h2), bfbits(h3)};
            ushort4 lv = {bfbits(l0), bfbits(l1), bfbits(l2), bfbits(l3)};
            *(ushort4*)&Bh[sRow][sCol + i * 4] = hv;
            *(ushort4*)&Bl[sRow][sCol + i * 4] = lv;
        }
        __syncthreads();
        short8 ahf[4], alf[4], bhf[4], blf[4];
        #pragma unroll
        for (int mi = 0; mi < 4; mi++) {
            ahf[mi] = *(const short8*)&Ah[wm + mi * 16 + lm][quad * 8];
            alf[mi] = *(const short8*)&Al[wm + mi * 16 + lm][quad * 8];
        }
        #pragma unroll
        for (int ni = 0; ni < 4; ni++) {
            bhf[ni] = *(const short8*)&Bh[wn + ni * 16 + lm][quad * 8];
            blf[ni] = *(const short8*)&Bl[wn + ni * 16 + lm][quad * 8];
        }
        #pragma unroll
        for (int mi = 0; mi < 4; mi++)
            #pragma unroll
            for (int ni = 0; ni < 4; ni++) {
                acc[mi][ni] = __builtin_amdgcn_mfma_f32_16x16x32_bf16(ahf[mi], bhf[ni], acc[mi][ni], 0, 0, 0);
                acc[mi][ni] = __builtin_amdgcn_mfma_f32_16x16x32_bf16(ahf[mi], blf[ni], acc[mi][ni], 0, 0, 0);
                acc[mi][ni] = __builtin_amdgcn_mfma_f32_16x16x32_bf16(alf[mi], bhf[ni], acc[mi][ni], 0, 0, 0);
            }
        __syncthreads();
    }
    bool f32f = DF[0] != 0;
    bool bF = (bTag == TAG_F32) || (bTag == TAG_AUTO && f32f);
    #pragma unroll
    for (int ni = 0; ni < 4; ni++) {
        int col = bn + wn + ni * 16 + lm;
        float cb = bias ? ld1auto(bias, biasOff + col, bF) : 0.f;
        #pragma unroll
        for (int mi = 0; mi < 4; mi++) {
            #pragma unroll
            for (int reg = 0; reg < 4; reg++) {
                int row = bm + wm + mi * 16 + quad * 4 + reg;
                float v = acc[mi][ni][reg] + cb;
                TC* cp = C + (long)row * ldc + col;
                if (alpha) {
                    const float* al = alpha + (long)(row / rowsPerB) * alphaStride + col;
                    v = ldc1(cp) + al[0] * v;
                }
                stc1(cp, v);
            }
        }
    }
}

template <typename TC>
static void mgemm32(hipStream_t s, const float* A, int lda, const float* WT,
                    TC* C, int ldc, int M, int N, int K,
                    const void* bias, int bTag, long biasOff,
                    const float* alpha, int alphaStride, int rowsPerB, const int* DF) {
    dim3 g(N / 128, M / 128);
    k_mfma32<TC><<<g, 256, 0, s>>>(A, lda, WT, C, ldc, M, N, K,
                                   bias, bTag, biasOff, alpha, alphaStride, rowsPerB, DF);
}

// ---------------- plain bf16 MFMA GEMM (MLP only; post-season-critical) -----
template <typename TC>
__global__ __launch_bounds__(256) void k_mfma(
    const bf16* __restrict__ A, int lda,
    const bf16* __restrict__ WT,
    TC* __restrict__ C, int ldc,
    int M, int N, int K,
    const void* __restrict__ bias, int bTag, int act,
    const float* __restrict__ alpha, int alphaStride, int rowsPerB,
    const int* __restrict__ DF) {
    constexpr int BK = 64, PAD = 8;
    __shared__ bf16 As[128][BK + PAD];
    __shared__ bf16 Bs[128][BK + PAD];
    int tid = threadIdx.x;
    int wave = tid >> 6, lane = tid & 63;
    int bm = blockIdx.y * 128, bn = blockIdx.x * 128;
    int wm = (wave >> 1) * 64, wn = (wave & 1) * 64;
    int lm = lane & 15, quad = lane >> 4;
    floatx4 acc[4][4] = {};
    int sRow = tid >> 1, sCol = (tid & 1) * 32;
    const bf16* ag = A  + (long)(bm + sRow) * lda + sCol;
    const bf16* bg = WT + (long)(bn + sRow) * K   + sCol;
    for (int k0 = 0; k0 < K; k0 += BK) {
        #pragma unroll
        for (int i = 0; i < 4; i++)
            *(float4*)&As[sRow][sCol + i * 8] = *(const float4*)(ag + k0 + i * 8);
        #pragma unroll
        for (int i = 0; i < 4; i++)
            *(float4*)&Bs[sRow][sCol + i * 8] = *(const float4*)(bg + k0 + i * 8);
        __syncthreads();
        #pragma unroll
        for (int kk = 0; kk < BK; kk += 32) {
            short8 af[4], bf[4];
            #pragma unroll
            for (int mi = 0; mi < 4; mi++)
                af[mi] = *(const short8*)&As[wm + mi * 16 + lm][kk + quad * 8];
            #pragma unroll
            for (int ni = 0; ni < 4; ni++)
                bf[ni] = *(const short8*)&Bs[wn + ni * 16 + lm][kk + quad * 8];
            #pragma unroll
            for (int mi = 0; mi < 4; mi++)
                #pragma unroll
                for (int ni = 0; ni < 4; ni++)
                    acc[mi][ni] = __builtin_amdgcn_mfma_f32_16x16x32_bf16(
                        af[mi], bf[ni], acc[mi][ni], 0, 0, 0);
        }
        __syncthreads();
    }
    bool f32f = DF[0] != 0;
    bool bF = (bTag == TAG_F32) || (bTag == TAG_AUTO && f32f);
    #pragma unroll
    for (int ni = 0; ni < 4; ni++) {
        int col = bn + wn + ni * 16 + lm;
        float cb = bias ? ld1auto(bias, col, bF) : 0.f;
        #pragma unroll
        for (int mi = 0; mi < 4; mi++) {
            #pragma unroll
            for (int reg = 0; reg < 4; reg++) {
                int row = bm + wm + mi * 16 + quad * 4 + reg;
                float v = acc[mi][ni][reg] + cb;
                TC* cp = C + (long)row * ldc + col;
                if (alpha) {
                    const float* al = alpha + (long)(row / rowsPerB) * alphaStride + col;
                    v = ldc1(cp) + al[0] * v;
                } else if (act == 1) {
                    v = gelu_f(v);
                }
                stc1(cp, v);
            }
        }
    }
}

template <typename TC>
static void mgemm(hipStream_t s, const bf16* A, int lda, const bf16* WT,
                  TC* C, int ldc, int M, int N, int K,
                  const void* bias, int bTag, int act,
                  const float* alpha, int alphaStride, int rowsPerB, const int* DF) {
    dim3 g(N / 128, M / 128);
    k_mfma<TC><<<g, 256, 0, s>>>(A, lda, WT, C, ldc, M, N, K,
                                 bias, bTag, act, alpha, alphaStride, rowsPerB, DF);
}

// ---------------- generic tiled fp32-VALU GEMM ------------------------------
template <typename TC>
__global__ __launch_bounds__(256) void k_gemm(
    const void* __restrict__ Ab, int aTag, int lda, long bsA,
    const void* __restrict__ Wb, int wTag, int ldw, long bsW,
    TC* __restrict__ Cb, int ldc, long bsC,
    int M, int N, int K,
    const void* __restrict__ bias, int bTag, int biasRow, int act,
    const float* __restrict__ alpha, int alphaStride, int rowsPerB,
    const int* __restrict__ DF) {
    __shared__ float As[16][68];
    __shared__ float Bs[16][68];
    bool f32f = DF[0] != 0;
    bool aF = (aTag == TAG_F32) || (aTag == TAG_AUTO && f32f);
    bool wF = (wTag == TAG_F32) || (wTag == TAG_AUTO && f32f);
    bool bF = (bTag == TAG_F32) || (bTag == TAG_AUTO && f32f);
    TC* Cbase = Cb + (long)blockIdx.z * bsC;
    long aBase = (long)blockIdx.z * bsA;
    long wBase = (long)blockIdx.z * bsW;
    int tid = threadIdx.x;
    int bm = blockIdx.y, bn = blockIdx.x;
    int tx = tid & 15, ty = tid >> 4;
    int arow = tid >> 2, acol = (tid & 3) * 4;
    int wrow = tid >> 4, wcol = (tid & 15) * 4;
    int gArow = bm * 64 + arow;
    bool aValid = gArow < M;
    float acc[4][4] = {};
    for (int kk = 0; kk < K; kk += 16) {
        float4 av = {0.f, 0.f, 0.f, 0.f};
        if (aValid) av = load4auto(Ab, aBase + (long)gArow * lda + kk + acol, aF);
        As[acol + 0][arow] = av.x;
        As[acol + 1][arow] = av.y;
        As[acol + 2][arow] = av.z;
        As[acol + 3][arow] = av.w;
        float4 wv = load4auto(Wb, wBase + (long)(kk + wrow) * ldw + bn * 64 + wcol, wF);
        *(float4*)&Bs[wrow][wcol] = wv;
        __syncthreads();
        #pragma unroll
        for (int k = 0; k < 16; k++) {
            float4 a4 = *(const float4*)&As[k][ty * 4];
            float4 b4 = *(const float4*)&Bs[k][tx * 4];
            acc[0][0] += a4.x * b4.x; acc[0][1] += a4.x * b4.y; acc[0][2] += a4.x * b4.z; acc[0][3] += a4.x * b4.w;
            acc[1][0] += a4.y * b4.x; acc[1][1] += a4.y * b4.y; acc[1][2] += a4.y * b4.z; acc[1][3] += a4.y * b4.w;
            acc[2][0] += a4.z * b4.x; acc[2][1] += a4.z * b4.y; acc[2][2] += a4.z * b4.z; acc[2][3] += a4.z * b4.w;
            acc[3][0] += a4.w * b4.x; acc[3][1] += a4.w * b4.y; acc[3][2] += a4.w * b4.z; acc[3][3] += a4.w * b4.w;
        }
        __syncthreads();
    }
    int gcol = bn * 64 + tx * 4;
    float cb[4] = {0.f, 0.f, 0.f, 0.f};
    if (bias && !biasRow) {
        #pragma unroll
        for (int j = 0; j < 4; j++) cb[j] = ld1auto(bias, gcol + j, bF);
    }
    #pragma unroll
    for (int i = 0; i < 4; i++) {
        int grow = bm * 64 + ty * 4 + i;
        if (grow >= M) continue;
        float rb = (bias && biasRow) ? ld1auto(bias, grow, bF) : 0.f;
        TC* crow = Cbase + (long)grow * ldc + gcol;
        const float* al = nullptr;
        if (alpha) al = alpha + (long)(grow / rowsPerB) * alphaStride + gcol;
        #pragma unroll
        for (int j = 0; j < 4; j++) {
            float v = acc[i][j] + cb[j] + rb;
            if (alpha)         v = ldc1(crow + j) + al[j] * v;
            else if (act == 1) v = gelu_f(v);
            stc1(crow + j, v);
        }
    }
}

template <typename TC>
static void gemm(hipStream_t s, const void* A, int aTag, int lda, long bsA,
                 const void* W, int wTag, int ldw, long bsW,
                 TC* C, int ldc, long bsC, int M, int N, int K,
                 const void* bias, int bTag, int biasRow, int act,
                 const float* alpha, int alphaStride, int rowsPerB, int batch,
                 const int* DF) {
    dim3 g(N / 64, (M + 63) / 64, batch);
    k_gemm<TC><<<g, 256, 0, s>>>(A, aTag, lda, bsA, W, wTag, ldw, bsW, C, ldc, bsC,
                                 M, N, K, bias, bTag, biasRow, act,
                                 alpha, alphaStride, rowsPerB, DF);
}

// ---------------- agent attention stage 1 -----------------------------------
// 4-agents-per-block + vectorized PV rewrite.
// Old: 1 agent/block (8192 blocks), scalar 2B V loads, 128-iter dependent
// FMA chain -> 140 us @ VALUBusy 27% / HBM 6% (latency-bound, 4x overfetch).
// New: 2048 blocks; K/V bytes read exactly once per block (4x less traffic
// and 4x fewer loads/FLOP); PV uses float4 loads feeding 16 FMAs each with
// 32-long chains x4-agent ILP; 16-way LDS tree reduce.
__global__ __launch_bounds__(256) void k_agatt1(const float* __restrict__ qa,
                                                const bf16* __restrict__ ka,
                                                const bf16* __restrict__ va,
                                                float* __restrict__ c1) {
    constexpr int AQ = 4;
    int blk = blockIdx.x;
    int aq = blk % (kA / AQ);
    int h = (blk / (kA / AQ)) % kH;
    int b = blk / ((kA / AQ) * kH);
    int ag0 = aq * AQ;
    __shared__ float qs[AQ][kHS];
    __shared__ float probs[AQ][kT];
    __shared__ float red[16][AQ * 68];
    __shared__ float sred[32];
    int tid = threadIdx.x;
    {
        int ag = tid >> 6, d = tid & 63;
        qs[ag][d] = qa[((long)h * kA + ag0 + ag) * kHS + d];
    }
    __syncthreads();
    const bf16* kab = ka + ((long)h * kB + b) * kT * kHS;
    float sc[2][AQ];
    #pragma unroll
    for (int rep = 0; rep < 2; rep++) {
        const bf16* kr = kab + (long)(tid + rep * 256) * kHS;
        float a0 = 0.f, a1 = 0.f, a2 = 0.f, a3 = 0.f;
        #pragma unroll
        for (int d = 0; d < kHS; d += 4) {
            float4 k4 = load4bf(kr + d);
            float4 q0 = *(const float4*)&qs[0][d];
            float4 q1 = *(const float4*)&qs[1][d];
            float4 q2 = *(const float4*)&qs[2][d];
            float4 q3 = *(const float4*)&qs[3][d];
            a0 += k4.x * q0.x + k4.y * q0.y + k4.z * q0.z + k4.w * q0.w;
            a1 += k4.x * q1.x + k4.y * q1.y + k4.z * q1.z + k4.w * q1.w;
            a2 += k4.x * q2.x + k4.y * q2.y + k4.z * q2.z + k4.w * q2.w;
            a3 += k4.x * q3.x + k4.y * q3.y + k4.z * q3.z + k4.w * q3.w;
        }
        sc[rep][0] = a0 * 0.125f; sc[rep][1] = a1 * 0.125f;
        sc[rep][2] = a2 * 0.125f; sc[rep][3] = a3 * 0.125f;
    }
    int w = tid >> 6;
    float mx[AQ], ss[AQ];
    #pragma unroll
    for (int ag = 0; ag < AQ; ag++) mx[ag] = fmaxf(sc[0][ag], sc[1][ag]);
    #pragma unroll
    for (int m = 32; m > 0; m >>= 1)
        #pragma unroll
        for (int ag = 0; ag < AQ; ag++) mx[ag] = fmaxf(mx[ag], __shfl_down(mx[ag], m));
    if ((tid & 63) == 0)
        #pragma unroll
        for (int ag = 0; ag < AQ; ag++) sred[w * 4 + ag] = mx[ag];
    __syncthreads();
    #pragma unroll
    for (int ag = 0; ag < AQ; ag++)
        mx[ag] = fmaxf(fmaxf(sred[ag], sred[4 + ag]), fmaxf(sred[8 + ag], sred[12 + ag]));
    float e0[AQ], e1[AQ];
    #pragma unroll
    for (int ag = 0; ag < AQ; ag++) {
        e0[ag] = expf(sc[0][ag] - mx[ag]);
        e1[ag] = expf(sc[1][ag] - mx[ag]);
        ss[ag] = e0[ag] + e1[ag];
    }
    #pragma unroll
    for (int m = 32; m > 0; m >>= 1)
        #pragma unroll
        for (int ag = 0; ag < AQ; ag++) ss[ag] += __shfl_down(ss[ag], m);
    if ((tid & 63) == 0)
        #pragma unroll
        for (int ag = 0; ag < AQ; ag++) sred[16 + w * 4 + ag] = ss[ag];
    __syncthreads();
    #pragma unroll
    for (int ag = 0; ag < AQ; ag++) {
        float tot = sred[16 + ag] + sred[20 + ag] + sred[24 + ag] + sred[28 + ag];
        float rs = 1.f / tot;
        probs[ag][tid] = e0[ag] * rs;
        probs[ag][tid + 256] = e1[ag] * rs;
    }
    __syncthreads();
    // PV: dg = d-quad 0..15 (4 d's), nc = n-chunk 0..15 (32 n's)
    int dg = tid & 15, nc = tid >> 4;
    const bf16* vab = va + ((long)h * kB + b) * kT * kHS;
    float4 acc[AQ] = {};
    for (int s = 0; s < 32; s++) {
        int n = nc * 32 + s;
        float4 v = load4bf(vab + (long)n * kHS + dg * 4);
        #pragma unroll
        for (int ag = 0; ag < AQ; ag++) {
            float p = probs[ag][n];
            acc[ag].x += p * v.x; acc[ag].y += p * v.y;
            acc[ag].z += p * v.z; acc[ag].w += p * v.w;
        }
    }
    #pragma unroll
    for (int ag = 0; ag < AQ; ag++)
        *(float4*)&red[nc][ag * 68 + dg * 4] = acc[ag];
    __syncthreads();
    {
        int ag = tid >> 6, d = tid & 63;
        float s = 0.f;
        #pragma unroll
        for (int n2 = 0; n2 < 16; n2++) s += red[n2][ag * 68 + d];
        c1[(((long)b * kH + h) * kA + ag0 + ag) * kHS + d] = s;
    }
}

// ---------------- agent attention stage 2 (fp32 in/out) ----------------------
__global__ __launch_bounds__(256) void k_agatt2f(const float* __restrict__ qsrc, int ldq,
                                                 const float* __restrict__ c1,
                                                 float* __restrict__ out) {
    int blk = blockIdx.x;
    int nt = blk % (kT / 16);
    int h = (blk / (kT / 16)) % kH;
    int b = blk / ((kT / 16) * kH);
    __shared__ float c1s[kA][kHS + 1];
    __shared__ float qs[16][kHS + 1];
    __shared__ float ps[16][kA + 1];
    int tid = threadIdx.x;
    const float* c1b = c1 + ((long)b * kH + h) * kA * kHS;
    for (int i = tid; i < kA * kHS; i += 256) c1s[i >> 6][i & 63] = c1b[i];
    int n0 = nt * 16;
    {
        int r = tid >> 4, d = (tid & 15) * 4;
        float4 q4 = load4f(qsrc + (long)(b * kT + n0 + r) * ldq + h * kHS + d);
        qs[r][d] = q4.x; qs[r][d + 1] = q4.y; qs[r][d + 2] = q4.z; qs[r][d + 3] = q4.w;
    }
    __syncthreads();
    int r = tid >> 4, c = tid & 15;
    float sc[4];
    #pragma unroll
    for (int j = 0; j < 4; j++) {
        int a = c * 4 + j;
        float acc = 0.f;
        for (int d = 0; d < kHS; d++) acc += qs[r][d] * c1s[a][d];
        sc[j] = acc * 0.125f;
    }
    float mx = fmaxf(fmaxf(sc[0], sc[1]), fmaxf(sc[2], sc[3]));
    for (int m = 1; m < 16; m <<= 1) mx = fmaxf(mx, __shfl_xor(mx, m));
    float e[4], ss = 0.f;
    #pragma unroll
    for (int j = 0; j < 4; j++) { e[j] = expf(sc[j] - mx); ss += e[j]; }
    for (int m = 1; m < 16; m <<= 1) ss += __shfl_xor(ss, m);
    float rs = 1.f / ss;
    #pragma unroll
    for (int j = 0; j < 4; j++) ps[r][c * 4 + j] = e[j] * rs;
    __syncthreads();
    float o0 = 0.f, o1 = 0.f, o2 = 0.f, o3 = 0.f;
    int d0 = c * 4;
    for (int a = 0; a < kA; a++) {
        float p = ps[r][a];
        o0 += p * c1s[a][d0 + 0];
        o1 += p * c1s[a][d0 + 1];
        o2 += p * c1s[a][d0 + 2];
        o3 += p * c1s[a][d0 + 3];
    }
    float* orow = out + (long)(b * kT + n0 + r) * kE + h * kHS + d0;
    orow[0] = o0; orow[1] = o1; orow[2] = o2; orow[3] = o3;
}

// ---------------- DFT tables --------------------------------------------------
__global__ void k_trig(float* __restrict__ trig) {
    int id = blockIdx.x * 256 + threadIdx.x;
    if (id >= kNFREQ * kT) return;
    int t = id & 511;
    int f = (id >> 9) + 1;
    int m = (f * t) & 511;
    double ang = (double)m * (2.0 * 3.14159265358979323846 / 512.0);
    trig[id] = (float)cos(ang);
    trig[kNFREQ * kT + id] = (float)(-sin(ang));
}

// ---------------- top-5 |X_f|^2 per (b,e) column ------------------------------
// f-parallel rewrite: 16 threads per column each scan a 16-frequency chunk
// keeping a private top-5; partials merge via LDS.  Tie-break (v==, lower f
// wins) reproduces jax.lax.top_k stable semantics independent of merge order.
// Old: 32 blocks, serial 255-iter scan -> 207 us @ 1.4% occupancy.
__global__ __launch_bounds__(256) void k_topk(const float* __restrict__ RE, const float* __restrict__ IM,
                                              float* __restrict__ tre, float* __restrict__ tim,
                                              int* __restrict__ tix) {
    int tid = threadIdx.x;
    int c = tid & 15;                       // column within block
    int j = tid >> 4;                       // f-group 0..15
    int colId = blockIdx.x * 16 + c;        // 0..8191
    int b = colId >> 10, e = colId & 1023;
    const float* rp = RE + (long)b * kNFREQ * kE + e;
    const float* ip = IM + (long)b * kNFREQ * kE + e;
    float bv[kKTOP] = {-1e30f, -1e30f, -1e30f, -1e30f, -1e30f};
    int bi[kKTOP] = {1 << 30, 1 << 30, 1 << 30, 1 << 30, 1 << 30};
    #pragma unroll
    for (int s = 0; s < 16; s++) {
        int fq = j * 16 + s;
        if (fq >= kNFREQ) break;
        float re = rp[(long)fq * kE], im = ip[(long)fq * kE];
        float m2 = re * re + im * im;
        if (m2 > bv[kKTOP - 1] || (m2 == bv[kKTOP - 1] && fq < bi[kKTOP - 1])) {
            int p = kKTOP - 1;
            while (p > 0 && (m2 > bv[p - 1] || (m2 == bv[p - 1] && fq < bi[p - 1]))) {
                bv[p] = bv[p - 1]; bi[p] = bi[p - 1]; p--;
            }
            bv[p] = m2; bi[p] = fq;
        }
    }
    __shared__ float sv[16][16][kKTOP];
    __shared__ int   si[16][16][kKTOP];
    #pragma unroll
    for (int q = 0; q < kKTOP; q++) { sv[c][j][q] = bv[q]; si[c][j][q] = bi[q]; }
    __syncthreads();
    if (j == 0) {
        for (int jj = 1; jj < 16; jj++) {
            #pragma unroll
            for (int q = 0; q < kKTOP; q++) {
                float v = sv[c][jj][q];
                int fq = si[c][jj][q];
                if (v > bv[kKTOP - 1] || (v == bv[kKTOP - 1] && fq < bi[kKTOP - 1])) {
                    int p = kKTOP - 1;
                    while (p > 0 && (v > bv[p - 1] || (v == bv[p - 1] && fq < bi[p - 1]))) {
                        bv[p] = bv[p - 1]; bi[p] = bi[p - 1]; p--;
                    }
                    bv[p] = v; bi[p] = fq;
                }
            }
        }
        #pragma unroll
        for (int q = 0; q < kKTOP; q++) {
            int fq = bi[q];
            tre[(long)colId * kKTOP + q] = rp[(long)fq * kE];
            tim[(long)colId * kKTOP + q] = ip[(long)fq * kE];
            tix[(long)colId * kKTOP + q] = fq;
        }
    }
}

__global__ void k_season(const float* __restrict__ tre, const float* __restrict__ tim,
                         const int* __restrict__ tix, const float* __restrict__ trig,
                         void* __restrict__ out, long obase, const int* __restrict__ DF) {
    bool f32o = DF[0] != 0;
    long id = (long)blockIdx.x * 256 + threadIdx.x;
    int e = id & 1023;
    long bt = id >> 10;
    int t = (int)(bt & 511);
    int b = (int)(bt >> 9);
    long be = (long)b * kE + e;
    float acc = 0.f;
    #pragma unroll
    for (int j = 0; j < kKTOP; j++) {
        int f = tix[be * kKTOP + j];
        acc += tre[be * kKTOP + j] * trig[(long)f * kT + t]
             + tim[be * kKTOP + j] * trig[(long)kNFREQ * kT + (long)f * kT + t];
    }
    st1auto(out, obase + id, f32o, 2.f * acc);
}

// ---------------- trend branch ------------------------------------------------
// conv1 re-parallelized: grid = (b,o) x 8 l-tiles = 192 blocks.  Weight slab
// w[o,:,:] (6 KB) staged in LDS once; each thread owns one l of a 128-wide
// tile and half the i-range; 2-way LDS reduce.  Old: 96 blocks, 512-iter
// serial loop with per-iter scalar weight loads -> 224 us @ 4.2% occupancy.
__global__ __launch_bounds__(256) void k_conv1(const float* __restrict__ P,
                                               const void* __restrict__ w,
                                               const void* __restrict__ bias,
                                               float* __restrict__ G,
                                               const int* __restrict__ DF) {
    bool f = DF[0] != 0;
    int bo = blockIdx.x;                 // 0..23 -> (b,o)
    int lt = blockIdx.y;                 // 0..7  -> 128-l tile
    int o = bo % 3, b = bo / 3;
    int tid = threadIdx.x;
    __shared__ float ws[512][3];         // 6 KB weight slab for this o
    for (int idx = tid; idx < 512 * 3; idx += 256)
        ws[idx / 3][idx % 3] = ld1auto(w, (long)o * 512 * 3 + idx, f);
    __syncthreads();
    int l = lt * 128 + (tid & 127);
    int ih = (tid >> 7) * 256;           // 0 or 256
    const float* xb = P + (long)b * kT2 * kE;
    float acc = 0.f;
    for (int ii = 0; ii < 256; ii++) {
        int i = ih + ii;
        const float* xr = xb + (long)i * kE + l;
        float xm = (l > 0)    ? xr[-1] : 0.f;
        float xc = xr[0];
        float xp = (l < 1023) ? xr[1]  : 0.f;
        acc += xm * ws[i][0] + xc * ws[i][1] + xp * ws[i][2];
    }
    __shared__ float red[128];
    if (tid >= 128) red[tid - 128] = acc;
    __syncthreads();
    if (tid < 128) {
        float tot = acc + red[tid] + ld1auto(bias, o, f);
        G[((long)b * 3 + o) * 1024 + l] = gelu_f(tot);
    }
}

// conv2 re-parallelized: one workgroup per (b,n) output pair (512 blocks),
// 256 threads stride over i, 3 pp-partials in registers, block-reduce.
// Old version: 6 blocks, serial 3072-iter scalar loop -> 489 us @ 0.3% occupancy.
__global__ __launch_bounds__(256) void k_conv2(const float* __restrict__ G,
                                               const void* __restrict__ w,
                                               const void* __restrict__ bias,
                                               float* __restrict__ H2,
                                               const int* __restrict__ DF) {
    bool f = DF[0] != 0;
    int n = blockIdx.x % kNF;
    int b = blockIdx.x / kNF;
    int tid = threadIdx.x;
    const float* Gb = G + (long)b * 3 * 1024;
    // valid (pp, k -> l = pp + k - 1) combos:
    // pp=0: g[0]*w[1] + g[1]*w[2]
    // pp=1: g[0]*w[0] + g[1]*w[1] + g[2]*w[2]
    // pp=2: g[1]*w[0] + g[2]*w[1]
    float a0 = 0.f, a1 = 0.f, a2 = 0.f;
    for (int i = tid; i < 1024; i += 256) {
        float g0 = Gb[i], g1 = Gb[1024 + i], g2 = Gb[2048 + i];
        long wo = ((long)n * 1024 + i) * 3;
        float w0 = ld1auto(w, wo + 0, f);
        float w1 = ld1auto(w, wo + 1, f);
        float w2 = ld1auto(w, wo + 2, f);
        a0 += g0 * w1 + g1 * w2;
        a1 += g0 * w0 + g1 * w1 + g2 * w2;
        a2 += g1 * w0 + g2 * w1;
    }
    __shared__ float sm[12];
    #pragma unroll
    for (int m = 32; m > 0; m >>= 1) {
        a0 += __shfl_down(a0, m);
        a1 += __shfl_down(a1, m);
        a2 += __shfl_down(a2, m);
    }
    int wv = tid >> 6;
    if ((tid & 63) == 0) { sm[wv] = a0; sm[4 + wv] = a1; sm[8 + wv] = a2; }
    __syncthreads();
    if (tid == 0) {
        float cb = ld1auto(bias, n, f);
        float* hp = H2 + ((long)b * kNF + n) * 3;
        hp[0] = cb + sm[0] + sm[1] + sm[2] + sm[3];
        hp[1] = cb + sm[4] + sm[5] + sm[6] + sm[7];
        hp[2] = cb + sm[8] + sm[9] + sm[10] + sm[11];
    }
}

__global__ void k_trend(const float* __restrict__ H2, void* __restrict__ out, long obase,
                        const int* __restrict__ DF) {
    bool f32o = DF[0] != 0;
    int id = blockIdx.x * 256 + threadIdx.x;
    int n = id % kNF;
    int t = (id / kNF) % kT;
    int b = id / (kNF * kT);
    float lin = (float)(t + 1) / 513.0f;
    const float* h = H2 + ((long)b * kNF + n) * 3;
    float l2 = lin * lin;
    st1auto(out, obase + id, f32o, h[0] * lin + h[1] * l2 + h[2] * l2 * lin);
}

// ---------------- finals -------------------------------------------------------
__global__ void k_mean(const float* __restrict__ X, float* __restrict__ m) {
    int id = blockIdx.x * 256 + threadIdx.x;
    int b = id >> 10, e = id & 1023;
    const float* p = X + (long)b * kT * kE + e;
    float s = 0.f;
    for (int t = 0; t < kT; t++) s += p[(long)t * kE];
    m[id] = s * (1.f / kT);
}

__global__ void k_out0(const float* __restrict__ X, const float* __restrict__ m,
                       void* __restrict__ out, long obase, const int* __restrict__ DF) {
    bool f32o = DF[0] != 0;
    long id = (long)blockIdx.x * 256 + threadIdx.x;
    int e = id & 1023;
    int b = (int)(id >> 19);
    st1auto(out, obase + id, f32o, X[id] - m[b * kE + e]);
}

__global__ void k_out1(const float* __restrict__ m, const void* __restrict__ w,
                       const void* __restrict__ bias, void* __restrict__ out, long obase,
                       const int* __restrict__ DF) {
    bool f = DF[0] != 0;
    int id = blockIdx.x * 256 + threadIdx.x;
    if (id >= kB * kNF) return;
    int b = id / kNF, n = id % kNF;
    float acc = ld1auto(bias, n, f);
    for (int e = 0; e < kE; e++) acc += m[b * kE + e] * ld1auto(w, (long)e * kNF + n, f);
    st1auto(out, obase + id, f, acc);
}

// ---------------- launch -------------------------------------------------------
extern "C" void kernel_launch(void* const* d_in, const int* in_sizes, int n_in,
                              void* d_out, int out_size, void* d_ws, size_t ws_size,
                              hipStream_t stream) {
    (void)in_sizes; (void)n_in; (void)out_size; (void)ws_size;
    const void* x_in = d_in[0];
    const void* enc  = d_in[1];
    const int* tstep = (const int*)d_in[2];
    const void *ln1_w = d_in[3],  *ln1_b = d_in[4],  *ln11_w = d_in[5], *ln11_b = d_in[6];
    const void *ln2_w = d_in[7],  *ln2_b = d_in[8];
    const void *a1_qkv_w = d_in[9], *a1_qkv_b = d_in[10];
    const void *a1_agq_w = d_in[11], *a1_agq_b = d_in[12];
    const void *a1_agk_w = d_in[13], *a1_agk_b = d_in[14];
    const void *a1_agv_w = d_in[15], *a1_agv_b = d_in[16];
    const void *a1_ago_w = d_in[17], *a1_ago_b = d_in[18];
    const void *a1_agents = d_in[19];
    const void *a1_proj_w = d_in[20], *a1_proj_b = d_in[21];
    const void *a2_q_w = d_in[22], *a2_q_b = d_in[23];
    const void *a2_kv_w = d_in[24], *a2_kv_b = d_in[25];
    const void *a2_agq_w = d_in[26], *a2_agq_b = d_in[27];
    const void *a2_agk_w = d_in[28], *a2_agk_b = d_in[29];
    const void *a2_agv_w = d_in[30], *a2_agv_b = d_in[31];
    const void *a2_ago_w = d_in[32], *a2_ago_b = d_in[33];
    const void *a2_agents = d_in[34];
    const void *a2_proj_w = d_in[35], *a2_proj_b = d_in[36];
    const void *tr_c1_w = d_in[37], *tr_c1_b = d_in[38];
    const void *tr_c2_w = d_in[39], *tr_c2_b = d_in[40];
    const void *mlp_w1 = d_in[41], *mlp_b1 = d_in[42];
    const void *mlp_w2 = d_in[43], *mlp_b2 = d_in[44];
    const void *pr_w = d_in[45], *pr_b = d_in[46];
    const void *lin_w = d_in[47], *lin_b = d_in[48];

    char* wsb = (char*)d_ws;
    float* XC = (float*)(wsb + BOFF_XC);
    float* SM = (float*)(wsb + BOFF_SMALL);
    float* TS = SM + F_TS;
    float* AD1 = SM + F_AD1;
    float* AD11 = SM + F_AD11;
    float* AD2 = SM + F_AD2;
    float* QA = SM + F_QA;
    float* C1 = SM + F_C1;
    float* H2 = SM + F_H2;
    float* G1 = SM + F_G1;
    float* MB = SM + F_MB;
    float* TRE = SM + F_TRE;
    float* TIM = SM + F_TIM;
    int*   TIX = (int*)(SM + F_TIX);
    float* TRIG = SM + F_TRIG;
    int* DF = (int*)(wsb + BOFF_FLAG);
    char* WR = wsb + BOFF_WREG;
    float* WTQ  = (float*)(WR + WR_Q);
    float* WTKV = (float*)(WR + WR_KV);
    float* WAGO = (float*)(WR + WR_AGO);
    float* WPRJ = (float*)(WR + WR_PRJ);
    bf16*  W1B  = (bf16*)(WR + WR_W1);
    bf16*  W2B  = (bf16*)(WR + WR_W2);
    char* AC = wsb + BOFF_ACT;
    float* N1F  = (float*)(AC + AC_N1);     // also ENCF
    float* QBUF = (float*)(AC + AC_QBUF);
    float* KVB  = (float*)(AC + AC_KV);
    bf16*  KA   = (bf16*)(AC + AC_KA);
    bf16*  VA   = (bf16*)(AC + AC_VA);
    float* ATTF = (float*)(AC + AC_ATT);
    float* Y2F  = (float*)(AC + AC_Y2);
    float* P    = (float*)(AC + AC_P);
    float* RE   = (float*)(AC + AC_RE);
    float* IM   = (float*)(AC + AC_IM);
    bf16*  N1B  = (bf16*)(AC + AC_N1B);
    bf16*  HID  = (bf16*)(AC + AC_HID);

    const int M_BT = kB * kT;                      // 4096
    const long bsKA = (long)kB * kT * kHS;

    // 0) dtype detection (precedes all d_in consumers)
    k_detect<<<1, 256, 0, stream>>>((const unsigned short*)x_in, DF);

    // phase-1 weight transposes (fp32)
    k_wtf<<<dim3(1024/32, 1024/32), 256, 0, stream>>>(a1_qkv_w, WTQ, 1024, 3072, 0, DF);
    k_wtf<<<dim3(2048/32, 1024/32), 256, 0, stream>>>(a1_qkv_w, WTKV, 1024, 3072, 1024, DF);
    k_wtf<<<dim3(1024/32, 1024/32), 256, 0, stream>>>(a1_ago_w, WAGO, 1024, 1024, 0, DF);
    k_wtf<<<dim3(1024/32, 1024/32), 256, 0, stream>>>(a1_proj_w, WPRJ, 1024, 1024, 0, DF);

    // prologue
    k_temb<<<kB, 512, 0, stream>>>(tstep, TS);
    gemm(stream, TS, TAG_F32, kE, 0L, ln1_w, TAG_AUTO, 3 * kE, 0L, AD1, 3 * kE, 0L,
         kB, 3 * kE, kE, ln1_b, TAG_AUTO, 0, 0, nullptr, 0, 1, 1, DF);
    gemm(stream, TS, TAG_F32, kE, 0L, ln11_w, TAG_AUTO, 3 * kE, 0L, AD11, 3 * kE, 0L,
         kB, 3 * kE, kE, ln11_b, TAG_AUTO, 0, 0, nullptr, 0, 1, 1, DF);
    gemm(stream, TS, TAG_F32, kE, 0L, ln2_w, TAG_AUTO, 3 * kE, 0L, AD2, 3 * kE, 0L,
         kB, 3 * kE, kE, ln2_b, TAG_AUTO, 0, 0, nullptr, 0, 1, 1, DF);
    k_castin<<<(kB * kT * kE) / 1024, 256, 0, stream>>>(x_in, XC, DF);
    k_trig<<<(kNFREQ * kT + 255) / 256, 256, 0, stream>>>(TRIG);

    // ---- attention block 1 (self), fp32 end-to-end via split MFMA ----
    k_adalnf<<<M_BT, 256, 0, stream>>>(XC, AD1, N1F);
    mgemm32(stream, N1F, kE, WTQ, QBUF, kE, M_BT, kE, kE,
            a1_qkv_b, TAG_AUTO, 0L, nullptr, 0, 1, DF);
    mgemm32(stream, N1F, kE, WTKV, KVB, 2 * kE, M_BT, 2 * kE, kE,
            a1_qkv_b, TAG_AUTO, (long)kE, nullptr, 0, 1, DF);
    gemm(stream, a1_agents, TAG_AUTO, kHS, 0L, a1_agq_w, TAG_AUTO, kHS, 0L, QA, kHS, 0L,
         kH * kA, kHS, kHS, a1_agq_b, TAG_AUTO, 0, 0, nullptr, 0, 1, 1, DF);
    gemm(stream, KVB, TAG_F32, 2 * kE, 64L, a1_agk_w, TAG_AUTO, kHS, 0L, KA, kHS, bsKA,
         M_BT, kHS, kHS, a1_agk_b, TAG_AUTO, 0, 0, nullptr, 0, 1, kH, DF);
    gemm(stream, KVB + kE, TAG_F32, 2 * kE, 64L, a1_agv_w, TAG_AUTO, kHS, 0L, VA, kHS, bsKA,
         M_BT, kHS, kHS, a1_agv_b, TAG_AUTO, 0, 0, nullptr, 0, 1, kH, DF);
    k_agatt1<<<kB * kH * (kA / 4), 256, 0, stream>>>(QA, KA, VA, C1);
    k_agatt2f<<<kB * kH * (kT / 16), 256, 0, stream>>>(QBUF, kE, C1, ATTF);
    mgemm32(stream, ATTF, kE, WAGO, Y2F, kE, M_BT, kE, kE,
            a1_ago_b, TAG_AUTO, 0L, nullptr, 0, 1, DF);
    mgemm32(stream, Y2F, kE, WPRJ, XC, kE, M_BT, kE, kE,
            a1_proj_b, TAG_AUTO, 0L, AD1 + 2 * kE, 3 * kE, kT, DF);

    // phase-2 weight transposes (WREG safely reusable after prj1)
    k_wtf<<<dim3(1024/32, 1024/32), 256, 0, stream>>>(a2_q_w, WTQ, 1024, 1024, 0, DF);
    k_wtf<<<dim3(2048/32, 1024/32), 256, 0, stream>>>(a2_kv_w, WTKV, 1024, 2048, 0, DF);
    k_wtf<<<dim3(1024/32, 1024/32), 256, 0, stream>>>(a2_ago_w, WAGO, 1024, 1024, 0, DF);
    k_wtf<<<dim3(1024/32, 1024/32), 256, 0, stream>>>(a2_proj_w, WPRJ, 1024, 1024, 0, DF);

    // ---- attention block 2 (cross) ----
    k_castin<<<(kB * kT * kE) / 1024, 256, 0, stream>>>(enc, N1F, DF);   // ENCF in N1F slot
    mgemm32(stream, N1F, kE, WTKV, KVB, 2 * kE, M_BT, 2 * kE, kE,
            a2_kv_b, TAG_AUTO, 0L, nullptr, 0, 1, DF);
    k_adalnf<<<M_BT, 256, 0, stream>>>(XC, AD11, N1F);                    // overwrites ENCF (dead)
    mgemm32(stream, N1F, kE, WTQ, QBUF, kE, M_BT, kE, kE,
            a2_q_b, TAG_AUTO, 0L, nullptr, 0, 1, DF);
    gemm(stream, a2_agents, TAG_AUTO, kHS, 0L, a2_agq_w, TAG_AUTO, kHS, 0L, QA, kHS, 0L,
         kH * kA, kHS, kHS, a2_agq_b, TAG_AUTO, 0, 0, nullptr, 0, 1, 1, DF);
    gemm(stream, KVB, TAG_F32, 2 * kE, 64L, a2_agk_w, TAG_AUTO, kHS, 0L, KA, kHS, bsKA,
         M_BT, kHS, kHS, a2_agk_b, TAG_AUTO, 0, 0, nullptr, 0, 1, kH, DF);
    gemm(stream, KVB + kE, TAG_F32, 2 * kE, 64L, a2_agv_w, TAG_AUTO, kHS, 0L, VA, kHS, bsKA,
         M_BT, kHS, kHS, a2_agv_b, TAG_AUTO, 0, 0, nullptr, 0, 1, kH, DF);
    k_agatt1<<<kB * kH * (kA / 4), 256, 0, stream>>>(QA, KA, VA, C1);
    k_agatt2f<<<kB * kH * (kT / 16), 256, 0, stream>>>(QBUF, kE, C1, ATTF);
    mgemm32(stream, ATTF, kE, WAGO, Y2F, kE, M_BT, kE, kE,
            a2_ago_b, TAG_AUTO, 0L, nullptr, 0, 1, DF);
    mgemm32(stream, Y2F, kE, WPRJ, XC, kE, M_BT, kE, kE,
            a2_proj_b, TAG_AUTO, 0L, AD11 + 2 * kE, 3 * kE, kT, DF);

    // ---- phase 3: p = einsum('bce,oc->boe') + DFT + trend (all fp32 VALU) ----
    gemm(stream, pr_w, TAG_AUTO, kT, 0L, XC, TAG_F32, kE, (long)kT * kE,
         P, kE, (long)kT2 * kE, kT2, kE, kT,
         pr_b, TAG_AUTO, 1, 0, nullptr, 0, 1, kB, DF);
    gemm(stream, TRIG, TAG_F32, kT, 0L, P + (long)kT * kE, TAG_F32, kE, (long)kT2 * kE,
         RE, kE, (long)kNFREQ * kE, kNFREQ, kE, kT,
         nullptr, 0, 0, 0, nullptr, 0, 1, kB, DF);
    gemm(stream, TRIG + (long)kNFREQ * kT, TAG_F32, kT, 0L, P + (long)kT * kE, TAG_F32, kE, (long)kT2 * kE,
         IM, kE, (long)kNFREQ * kE, kNFREQ, kE, kT,
         nullptr, 0, 0, 0, nullptr, 0, 1, kB, DF);
    k_topk<<<(kB * kE) / 16, 256, 0, stream>>>(RE, IM, TRE, TIM, TIX);
    k_season<<<(kB * kT * kE) / 256, 256, 0, stream>>>(TRE, TIM, TIX, TRIG, d_out, O3, DF);
    k_conv1<<<dim3(kB * 3, 8), 256, 0, stream>>>(P, tr_c1_w, tr_c1_b, G1, DF);
    k_conv2<<<kB * kNF, 256, 0, stream>>>(G1, tr_c2_w, tr_c2_b, H2, DF);
    k_trend<<<(kB * kT * kNF) / 256, 256, 0, stream>>>(H2, d_out, O2, DF);

    // ---- phase 4: MLP (post-P; plain bf16 MFMA -- proven on outputs 0/1) ----
    k_wt<<<dim3(4096/32, 1024/32), 256, 0, stream>>>(mlp_w1, W1B, 1024, 4096, DF);
    k_wt<<<dim3(1024/32, 4096/32), 256, 0, stream>>>(mlp_w2, W2B, 4096, 1024, DF);
    k_adaln<<<M_BT, 256, 0, stream>>>(XC, AD2, N1B);
    mgemm(stream, N1B, kE, W1B, HID, kMLP, M_BT, kMLP, kE,
          mlp_b1, TAG_AUTO, 1 /*gelu*/, nullptr, 0, 1, DF);
    mgemm(stream, HID, kMLP, W2B, XC, kE, M_BT, kE, kMLP,
          mlp_b2, TAG_AUTO, 0, AD2 + 2 * kE, 3 * kE, kT, DF);

    // ---- finals ----
    k_mean<<<(kB * kE) / 256, 256, 0, stream>>>(XC, MB);
    k_out0<<<(kB * kT * kE) / 256, 256, 0, stream>>>(XC, MB, d_out, O0, DF);
    k_out1<<<(kB * kNF + 255) / 256, 256, 0, stream>>>(MB, lin_w, lin_b, d_out, O1, DF);
}

// Round 6
// 2188.832 us; speedup vs baseline: 1.4614x; 1.0186x over previous
//
#include <hip/hip_runtime.h>
#include <hip/hip_bf16.h>

using bf16 = __hip_bfloat16;
typedef __attribute__((ext_vector_type(8))) short short8;     // 8 bf16 (4 VGPRs)
typedef __attribute__((ext_vector_type(4))) float floatx4;    // MFMA acc

// Problem constants
constexpr int kB = 8, kT = 512, kE = 1024, kH = 16, kA = 64, kNF = 64, kHS = 64;
constexpr int kMLP = 4096, kT2 = 1024, kNFREQ = 255, kKTOP = 5;

constexpr int TAG_F32 = 0, TAG_BF16 = 1, TAG_AUTO = 2;

// ---------------- workspace arena (BYTE offsets) ----------------------------
// XC 16.78M | SMALL 4.36M | FLAG 64 | WREG 20.97M (phase-reused weight xposes)
// | ACT 67.11M (phase-reused activations).  Total 109.2 MB < 117.6 MB proven.
constexpr long BOFF_XC    = 0;                          // fp32 (B,T,E)
constexpr long BOFF_SMALL = 16777216;                   // 4,360,192 B
constexpr long BOFF_FLAG  = 21137408;                   // 64 B
constexpr long BOFF_WREG  = 21137472;                   // 20,971,520 B
constexpr long BOFF_ACT   = 42108992;                   // 67,108,864 B
constexpr long WS_NEED    = BOFF_ACT + 67108864;        // 109,217,856 B

// WREG slots (bytes from BOFF_WREG)
constexpr long WR_Q   = 0;          // fp32 1024x1024 (4,194,304)
constexpr long WR_KV  = 4194304;    // fp32 2048x1024 (8,388,608)
constexpr long WR_AGO = 12582912;   // fp32 1024x1024
constexpr long WR_PRJ = 16777216;   // fp32 1024x1024
constexpr long WR_W1  = 0;          // bf16 4096x1024 (8,388,608)  [phase 4]
constexpr long WR_W2  = 8388608;    // bf16 1024x4096 (8,388,608)  [phase 4]

// ACT slots (bytes from BOFF_ACT)
constexpr long AC_N1   = 0;         // fp32 (B,T,E) 16.78M   (also ENCF / P lo-half / N1b+HID)
constexpr long AC_QBUF = 16777216;  // fp32 (B,T,E) 16.78M
constexpr long AC_KV   = 33554432;  // fp32 (B,T,2E) 33.55M
constexpr long AC_KA   = 0;         // bf16 (H,B,T,HS) 8.39M  (over N1, after N1 dead)
constexpr long AC_VA   = 8388608;   // bf16 (H,B,T,HS) 8.39M
constexpr long AC_ATT  = 33554432;  // fp32 (B,T,E) 16.78M    (over KV, after KV dead)
constexpr long AC_Y2   = 50331648;  // fp32 (B,T,E) 16.78M
constexpr long AC_P    = 0;         // fp32 (B,2T,E) 33.55M   [phase 3]
constexpr long AC_RE   = 33554432;  // fp32 (B,255,E) 8,355,840
constexpr long AC_IM   = 41910272;  // fp32 (B,255,E) 8,355,840
constexpr long AC_N1B  = 0;         // bf16 (B,T,E) 8.39M     [phase 4]
constexpr long AC_HID  = 8388608;   // bf16 (B,T,MLP) 33.55M  [phase 4]

// small-region float offsets (relative to BOFF_SMALL)
constexpr long F_TS = 0, F_AD1 = 8192, F_AD11 = 32768, F_AD2 = 57344, F_QA = 81920,
               F_C1 = 147456, F_H2 = 671744, F_G1 = 673280, F_MB = 697856,
               F_TRE = 706048, F_TIM = 747008, F_TIX = 787968, F_TRIG = 828928;

// output regions (element offsets)
constexpr long O0 = 0, O1 = 4194304, O2 = 4194816, O3 = 4456960;

// ---------------- helpers ---------------------------------------------------
__device__ inline float bf2f(bf16 h) {
    unsigned short u = *(unsigned short*)&h;
    return __uint_as_float((unsigned)u << 16);
}
__device__ inline unsigned short bfbits(bf16 b) { return *(unsigned short*)&b; }
__device__ inline float gelu_f(float x) {
    return 0.5f * x * (1.0f + erff(x * 0.7071067811865476f));
}
__device__ inline float4 load4f(const float* p) { return *(const float4*)p; }
__device__ inline float4 load4bf(const bf16* p) {
    ushort4 u = *(const ushort4*)p;
    float4 r;
    r.x = __uint_as_float((unsigned)u.x << 16);
    r.y = __uint_as_float((unsigned)u.y << 16);
    r.z = __uint_as_float((unsigned)u.z << 16);
    r.w = __uint_as_float((unsigned)u.w << 16);
    return r;
}
__device__ inline float4 load4auto(const void* p, long idx, bool isF32) {
    if (isF32) return load4f((const float*)p + idx);
    return load4bf((const bf16*)p + idx);
}
__device__ inline float ld1auto(const void* p, long idx, bool isF32) {
    if (isF32) return ((const float*)p)[idx];
    return bf2f(((const bf16*)p)[idx]);
}
__device__ inline void st1auto(void* p, long idx, bool isF32, float v) {
    if (isF32) ((float*)p)[idx] = v;
    else       ((bf16*)p)[idx] = __float2bfloat16(v);
}
__device__ inline float ldc1(const float* p) { return *p; }
__device__ inline float ldc1(const bf16* p) { return bf2f(*p); }
__device__ inline void stc1(float* p, float v) { *p = v; }
__device__ inline void stc1(bf16* p, float v) { *p = __float2bfloat16(v); }

__device__ inline void blockReduce2(float& a, float& b, float* sm) {
    #pragma unroll
    for (int m = 32; m > 0; m >>= 1) { a += __shfl_down(a, m); b += __shfl_down(b, m); }
    int w = threadIdx.x >> 6;
    if ((threadIdx.x & 63) == 0) { sm[w] = a; sm[4 + w] = b; }
    __syncthreads();
    a = sm[0] + sm[1] + sm[2] + sm[3];
    b = sm[4] + sm[5] + sm[6] + sm[7];
    __syncthreads();
}

// ---------------- dtype detector --------------------------------------------
__global__ void k_detect(const unsigned short* __restrict__ xraw, int* __restrict__ flag) {
    int tid = threadIdx.x;
    unsigned short h = xraw[2 * tid];
    float v = __uint_as_float((unsigned)h << 16);
    float av = fabsf(v);
    if (!(av == av)) av = 1e30f;
    __shared__ float red[4];
    for (int m = 32; m > 0; m >>= 1) av = fmaxf(av, __shfl_down(av, m));
    if ((tid & 63) == 0) red[tid >> 6] = av;
    __syncthreads();
    if (tid == 0) {
        float mx = fmaxf(fmaxf(red[0], red[1]), fmaxf(red[2], red[3]));
        flag[0] = (mx < 1e3f) ? 0 : 1;             // 0 = bf16, 1 = fp32
    }
}

// ---------------- small kernels ---------------------------------------------
__global__ void k_temb(const int* __restrict__ ts, float* __restrict__ out) {
    int b = blockIdx.x, i = threadIdx.x;           // 512 threads
    float t = (float)ts[b];
    const float rate = (float)(-9.210340371976184 / 511.0);
    float f = expf(rate * (float)i);
    float arg = t * f;
    float sv = sinf(arg), cv = cosf(arg);
    out[(long)b * kE + i]        = sv / (1.f + expf(-sv));
    out[(long)b * kE + 512 + i]  = cv / (1.f + expf(-cv));
}

__global__ void k_castin(const void* __restrict__ in, float* __restrict__ out,
                         const int* __restrict__ DF) {
    bool f = DF[0] != 0;
    long i = ((long)blockIdx.x * 256 + threadIdx.x) * 4;
    float4 v = load4auto(in, i, f);
    *(float4*)(out + i) = v;
}

// fp32 weight transpose: W[K][Ntot] (auto dtype), cols [c0, c0+Nout) -> WT[Nout][K] fp32
__global__ __launch_bounds__(256) void k_wtf(const void* __restrict__ W, float* __restrict__ WT,
                                             int K, int Ntot, int c0,
                                             const int* __restrict__ DF) {
    bool f = DF[0] != 0;
    __shared__ float tile[32][33];
    int n0 = blockIdx.x * 32, k0 = blockIdx.y * 32;
    int tx = threadIdx.x & 31, ty = threadIdx.x >> 5;
    #pragma unroll
    for (int i = 0; i < 4; i++) {
        int k = ty + i * 8;
        tile[k][tx] = ld1auto(W, (long)(k0 + k) * Ntot + c0 + n0 + tx, f);
    }
    __syncthreads();
    #pragma unroll
    for (int i = 0; i < 4; i++) {
        int n = ty + i * 8;
        WT[(long)(n0 + n) * K + k0 + tx] = tile[tx][n];
    }
}

// bf16 weight transpose (for MLP): W[K][N] -> WT[N][K] bf16
__global__ __launch_bounds__(256) void k_wt(const void* __restrict__ W, bf16* __restrict__ WT,
                                            int K, int N, const int* __restrict__ DF) {
    bool f = DF[0] != 0;
    __shared__ float tile[32][33];
    int n0 = blockIdx.x * 32, k0 = blockIdx.y * 32;
    int tx = threadIdx.x & 31, ty = threadIdx.x >> 5;
    #pragma unroll
    for (int i = 0; i < 4; i++) {
        int k = ty + i * 8;
        tile[k][tx] = ld1auto(W, (long)(k0 + k) * N + n0 + tx, f);
    }
    __syncthreads();
    #pragma unroll
    for (int i = 0; i < 4; i++) {
        int n = ty + i * 8;
        WT[(long)(n0 + n) * K + k0 + tx] = __float2bfloat16(tile[tx][n]);
    }
}

// adaLN -> fp32 out (phases 1,2)
__global__ __launch_bounds__(256) void k_adalnf(const float* __restrict__ X,
                                                const float* __restrict__ AD,
                                                float* __restrict__ N) {
    int row = blockIdx.x;
    int b = row / kT;
    const float* xr = X + (long)row * kE;
    int tid = threadIdx.x;
    float4 xv = *(const float4*)(xr + tid * 4);
    float s  = xv.x + xv.y + xv.z + xv.w;
    float sq = xv.x * xv.x + xv.y * xv.y + xv.z * xv.z + xv.w * xv.w;
    __shared__ float sm[8];
    blockReduce2(s, sq, sm);
    float mu  = s * (1.f / kE);
    float var = sq * (1.f / kE) - mu * mu;
    float rstd = rsqrtf(fmaxf(var, 0.f) + 1e-5f);
    const float* ad = AD + (long)b * 3 * kE;
    float* nr = N + (long)row * kE;
    float xs[4] = {xv.x, xv.y, xv.z, xv.w};
    #pragma unroll
    for (int j = 0; j < 4; j++) {
        int e = tid * 4 + j;
        float xn = (xs[j] - mu) * rstd;
        nr[e] = xn * (1.f + ad[kE + e]) + ad[e];
    }
}

// adaLN -> bf16 out (phase 4 / MLP)
__global__ __launch_bounds__(256) void k_adaln(const float* __restrict__ X,
                                               const float* __restrict__ AD,
                                               bf16* __restrict__ N) {
    int row = blockIdx.x;
    int b = row / kT;
    const float* xr = X + (long)row * kE;
    int tid = threadIdx.x;
    float4 xv = *(const float4*)(xr + tid * 4);
    float s  = xv.x + xv.y + xv.z + xv.w;
    float sq = xv.x * xv.x + xv.y * xv.y + xv.z * xv.z + xv.w * xv.w;
    __shared__ float sm[8];
    blockReduce2(s, sq, sm);
    float mu  = s * (1.f / kE);
    float var = sq * (1.f / kE) - mu * mu;
    float rstd = rsqrtf(fmaxf(var, 0.f) + 1e-5f);
    const float* ad = AD + (long)b * 3 * kE;
    bf16* nr = N + (long)row * kE;
    float xs[4] = {xv.x, xv.y, xv.z, xv.w};
    #pragma unroll
    for (int j = 0; j < 4; j++) {
        int e = tid * 4 + j;
        float xn = (xs[j] - mu) * rstd;
        nr[e] = __float2bfloat16(xn * (1.f + ad[kE + e]) + ad[e]);
    }
}

// ---------------- split-precision MFMA GEMM (fp32-accurate) -----------------
// C = A(fp32 MxK) @ WT(fp32 NxK)^T via hi/lo bf16 split: Ah*Bh + Ah*Bl + Al*Bh.
// Relative error ~8e-6 (vs 2e-3 plain bf16). M,N mult of 128, K mult of 32.
template <typename TC>
__global__ __launch_bounds__(256) void k_mfma32(
    const float* __restrict__ A, int lda,
    const float* __restrict__ WT,
    TC* __restrict__ C, int ldc,
    int M, int N, int K,
    const void* __restrict__ bias, int bTag, long biasOff,
    const float* __restrict__ alpha, int alphaStride, int rowsPerB,
    const int* __restrict__ DF) {
    constexpr int BK = 32, PAD = 8;                 // 40 elem (80 B) row stride
    __shared__ bf16 Ah[128][BK + PAD], Al[128][BK + PAD];
    __shared__ bf16 Bh[128][BK + PAD], Bl[128][BK + PAD];
    int tid = threadIdx.x;
    int wave = tid >> 6, lane = tid & 63;
    int bm = blockIdx.y * 128, bn = blockIdx.x * 128;
    int wm = (wave >> 1) * 64, wn = (wave & 1) * 64;
    int lm = lane & 15, quad = lane >> 4;
    floatx4 acc[4][4] = {};
    int sRow = tid >> 1, sCol = (tid & 1) * 16;      // 16 fp32 per thread per tile
    const float* ag = A  + (long)(bm + sRow) * lda + sCol;
    const float* bg = WT + (long)(bn + sRow) * K   + sCol;
    for (int k0 = 0; k0 < K; k0 += BK) {
        #pragma unroll
        for (int i = 0; i < 4; i++) {
            float4 v = *(const float4*)(ag + k0 + i * 4);
            bf16 h0 = __float2bfloat16(v.x), h1 = __float2bfloat16(v.y);
            bf16 h2 = __float2bfloat16(v.z), h3 = __float2bfloat16(v.w);
            bf16 l0 = __float2bfloat16(v.x - bf2f(h0));
            bf16 l1 = __float2bfloat16(v.y - bf2f(h1));
            bf16 l2 = __float2bfloat16(v.z - bf2f(h2));
            bf16 l3 = __float2bfloat16(v.w - bf2f(h3));
            ushort4 hv = {bfbits(h0), bfbits(h1), bfbits(h2), bfbits(h3)};
            ushort4 lv = {bfbits(l0), bfbits(l1), bfbits(l2), bfbits(l3)};
            *(ushort4*)&Ah[sRow][sCol + i * 4] = hv;
            *(ushort4*)&Al[sRow][sCol + i * 4] = lv;
        }
        #pragma unroll
        for (int i = 0; i < 4; i++) {
            float4 v = *(const float4*)(bg + k0 + i * 4);
            bf16 h0 = __float2bfloat16(v.x), h1 = __float2bfloat16(v.y);
            bf16 h2 = __float2bfloat16(v.z), h3 = __float2bfloat16(v.w);
            bf16 l0 = __float2bfloat16(v.x - bf2f(h0));
            bf16 l1 = __float2bfloat16(v.y - bf2f(h1));
            bf16 l2 = __float2bfloat16(v.z - bf2f(h2));
            bf16 l3 = __float2bfloat16(v.w - bf2f(h3));
            ushort4 hv = {bfbits(h0), bfbits(h1), bfbits(h2), bfbits(h3)};
            ushort4 lv = {bfbits(l0), bfbits(l1), bfbits(l2), bfbits(l3)};
            *(ushort4*)&Bh[sRow][sCol + i * 4] = hv;
            *(ushort4*)&Bl[sRow][sCol + i * 4] = lv;
        }
        __syncthreads();
        short8 ahf[4], alf[4], bhf[4], blf[4];
        #pragma unroll
        for (int mi = 0; mi < 4; mi++) {
            ahf[mi] = *(const short8*)&Ah[wm + mi * 16 + lm][quad * 8];
            alf[mi] = *(const short8*)&Al[wm + mi * 16 + lm][quad * 8];
        }
        #pragma unroll
        for (int ni = 0; ni < 4; ni++) {
            bhf[ni] = *(const short8*)&Bh[wn + ni * 16 + lm][quad * 8];
            blf[ni] = *(const short8*)&Bl[wn + ni * 16 + lm][quad * 8];
        }
        #pragma unroll
        for (int mi = 0; mi < 4; mi++)
            #pragma unroll
            for (int ni = 0; ni < 4; ni++) {
                acc[mi][ni] = __builtin_amdgcn_mfma_f32_16x16x32_bf16(ahf[mi], bhf[ni], acc[mi][ni], 0, 0, 0);
                acc[mi][ni] = __builtin_amdgcn_mfma_f32_16x16x32_bf16(ahf[mi], blf[ni], acc[mi][ni], 0, 0, 0);
                acc[mi][ni] = __builtin_amdgcn_mfma_f32_16x16x32_bf16(alf[mi], bhf[ni], acc[mi][ni], 0, 0, 0);
            }
        __syncthreads();
    }
    bool f32f = DF[0] != 0;
    bool bF = (bTag == TAG_F32) || (bTag == TAG_AUTO && f32f);
    #pragma unroll
    for (int ni = 0; ni < 4; ni++) {
        int col = bn + wn + ni * 16 + lm;
        float cb = bias ? ld1auto(bias, biasOff + col, bF) : 0.f;
        #pragma unroll
        for (int mi = 0; mi < 4; mi++) {
            #pragma unroll
            for (int reg = 0; reg < 4; reg++) {
                int row = bm + wm + mi * 16 + quad * 4 + reg;
                float v = acc[mi][ni][reg] + cb;
                TC* cp = C + (long)row * ldc + col;
                if (alpha) {
                    const float* al = alpha + (long)(row / rowsPerB) * alphaStride + col;
                    v = ldc1(cp) + al[0] * v;
                }
                stc1(cp, v);
            }
        }
    }
}

template <typename TC>
static void mgemm32(hipStream_t s, const float* A, int lda, const float* WT,
                    TC* C, int ldc, int M, int N, int K,
                    const void* bias, int bTag, long biasOff,
                    const float* alpha, int alphaStride, int rowsPerB, const int* DF) {
    dim3 g(N / 128, M / 128);
    k_mfma32<TC><<<g, 256, 0, s>>>(A, lda, WT, C, ldc, M, N, K,
                                   bias, bTag, biasOff, alpha, alphaStride, rowsPerB, DF);
}

// ---------------- plain bf16 MFMA GEMM (MLP only; post-season-critical) -----
template <typename TC>
__global__ __launch_bounds__(256) void k_mfma(
    const bf16* __restrict__ A, int lda,
    const bf16* __restrict__ WT,
    TC* __restrict__ C, int ldc,
    int M, int N, int K,
    const void* __restrict__ bias, int bTag, int act,
    const float* __restrict__ alpha, int alphaStride, int rowsPerB,
    const int* __restrict__ DF) {
    constexpr int BK = 64, PAD = 8;
    __shared__ bf16 As[128][BK + PAD];
    __shared__ bf16 Bs[128][BK + PAD];
    int tid = threadIdx.x;
    int wave = tid >> 6, lane = tid & 63;
    int bm = blockIdx.y * 128, bn = blockIdx.x * 128;
    int wm = (wave >> 1) * 64, wn = (wave & 1) * 64;
    int lm = lane & 15, quad = lane >> 4;
    floatx4 acc[4][4] = {};
    int sRow = tid >> 1, sCol = (tid & 1) * 32;
    const bf16* ag = A  + (long)(bm + sRow) * lda + sCol;
    const bf16* bg = WT + (long)(bn + sRow) * K   + sCol;
    for (int k0 = 0; k0 < K; k0 += BK) {
        #pragma unroll
        for (int i = 0; i < 4; i++)
            *(float4*)&As[sRow][sCol + i * 8] = *(const float4*)(ag + k0 + i * 8);
        #pragma unroll
        for (int i = 0; i < 4; i++)
            *(float4*)&Bs[sRow][sCol + i * 8] = *(const float4*)(bg + k0 + i * 8);
        __syncthreads();
        #pragma unroll
        for (int kk = 0; kk < BK; kk += 32) {
            short8 af[4], bf[4];
            #pragma unroll
            for (int mi = 0; mi < 4; mi++)
                af[mi] = *(const short8*)&As[wm + mi * 16 + lm][kk + quad * 8];
            #pragma unroll
            for (int ni = 0; ni < 4; ni++)
                bf[ni] = *(const short8*)&Bs[wn + ni * 16 + lm][kk + quad * 8];
            #pragma unroll
            for (int mi = 0; mi < 4; mi++)
                #pragma unroll
                for (int ni = 0; ni < 4; ni++)
                    acc[mi][ni] = __builtin_amdgcn_mfma_f32_16x16x32_bf16(
                        af[mi], bf[ni], acc[mi][ni], 0, 0, 0);
        }
        __syncthreads();
    }
    bool f32f = DF[0] != 0;
    bool bF = (bTag == TAG_F32) || (bTag == TAG_AUTO && f32f);
    #pragma unroll
    for (int ni = 0; ni < 4; ni++) {
        int col = bn + wn + ni * 16 + lm;
        float cb = bias ? ld1auto(bias, col, bF) : 0.f;
        #pragma unroll
        for (int mi = 0; mi < 4; mi++) {
            #pragma unroll
            for (int reg = 0; reg < 4; reg++) {
                int row = bm + wm + mi * 16 + quad * 4 + reg;
                float v = acc[mi][ni][reg] + cb;
                TC* cp = C + (long)row * ldc + col;
                if (alpha) {
                    const float* al = alpha + (long)(row / rowsPerB) * alphaStride + col;
                    v = ldc1(cp) + al[0] * v;
                } else if (act == 1) {
                    v = gelu_f(v);
                }
                stc1(cp, v);
            }
        }
    }
}

template <typename TC>
static void mgemm(hipStream_t s, const bf16* A, int lda, const bf16* WT,
                  TC* C, int ldc, int M, int N, int K,
                  const void* bias, int bTag, int act,
                  const float* alpha, int alphaStride, int rowsPerB, const int* DF) {
    dim3 g(N / 128, M / 128);
    k_mfma<TC><<<g, 256, 0, s>>>(A, lda, WT, C, ldc, M, N, K,
                                 bias, bTag, act, alpha, alphaStride, rowsPerB, DF);
}

// ---------------- generic tiled fp32-VALU GEMM ------------------------------
// Register-prefetch double-buffered: tile k+1's global loads are issued
// right after the store barrier, so HBM/L2 latency hides under the 16x16
// FMA block.  Old: loads sat on the barrier-to-barrier critical path ->
// P gemm 136 us @ VALUBusy 57%.
template <typename TC>
__global__ __launch_bounds__(256) void k_gemm(
    const void* __restrict__ Ab, int aTag, int lda, long bsA,
    const void* __restrict__ Wb, int wTag, int ldw, long bsW,
    TC* __restrict__ Cb, int ldc, long bsC,
    int M, int N, int K,
    const void* __restrict__ bias, int bTag, int biasRow, int act,
    const float* __restrict__ alpha, int alphaStride, int rowsPerB,
    const int* __restrict__ DF) {
    __shared__ float As[16][68];
    __shared__ float Bs[16][68];
    bool f32f = DF[0] != 0;
    bool aF = (aTag == TAG_F32) || (aTag == TAG_AUTO && f32f);
    bool wF = (wTag == TAG_F32) || (wTag == TAG_AUTO && f32f);
    bool bF = (bTag == TAG_F32) || (bTag == TAG_AUTO && f32f);
    TC* Cbase = Cb + (long)blockIdx.z * bsC;
    long aBase = (long)blockIdx.z * bsA;
    long wBase = (long)blockIdx.z * bsW;
    int tid = threadIdx.x;
    int bm = blockIdx.y, bn = blockIdx.x;
    int tx = tid & 15, ty = tid >> 4;
    int arow = tid >> 2, acol = (tid & 3) * 4;
    int wrow = tid >> 4, wcol = (tid & 15) * 4;
    int gArow = bm * 64 + arow;
    bool aValid = gArow < M;
    float acc[4][4] = {};
    float4 av = {0.f, 0.f, 0.f, 0.f};
    if (aValid) av = load4auto(Ab, aBase + (long)gArow * lda + acol, aF);
    float4 wv = load4auto(Wb, wBase + (long)wrow * ldw + bn * 64 + wcol, wF);
    for (int kk = 0; kk < K; kk += 16) {
        As[acol + 0][arow] = av.x;
        As[acol + 1][arow] = av.y;
        As[acol + 2][arow] = av.z;
        As[acol + 3][arow] = av.w;
        *(float4*)&Bs[wrow][wcol] = wv;
        __syncthreads();
        if (kk + 16 < K) {           // prefetch next tile (overlaps FMA below)
            if (aValid) av = load4auto(Ab, aBase + (long)gArow * lda + kk + 16 + acol, aF);
            wv = load4auto(Wb, wBase + (long)(kk + 16 + wrow) * ldw + bn * 64 + wcol, wF);
        }
        #pragma unroll
        for (int k = 0; k < 16; k++) {
            float4 a4 = *(const float4*)&As[k][ty * 4];
            float4 b4 = *(const float4*)&Bs[k][tx * 4];
            acc[0][0] += a4.x * b4.x; acc[0][1] += a4.x * b4.y; acc[0][2] += a4.x * b4.z; acc[0][3] += a4.x * b4.w;
            acc[1][0] += a4.y * b4.x; acc[1][1] += a4.y * b4.y; acc[1][2] += a4.y * b4.z; acc[1][3] += a4.y * b4.w;
            acc[2][0] += a4.z * b4.x; acc[2][1] += a4.z * b4.y; acc[2][2] += a4.z * b4.z; acc[2][3] += a4.z * b4.w;
            acc[3][0] += a4.w * b4.x; acc[3][1] += a4.w * b4.y; acc[3][2] += a4.w * b4.z; acc[3][3] += a4.w * b4.w;
        }
        __syncthreads();
    }
    int gcol = bn * 64 + tx * 4;
    float cb[4] = {0.f, 0.f, 0.f, 0.f};
    if (bias && !biasRow) {
        #pragma unroll
        for (int j = 0; j < 4; j++) cb[j] = ld1auto(bias, gcol + j, bF);
    }
    #pragma unroll
    for (int i = 0; i < 4; i++) {
        int grow = bm * 64 + ty * 4 + i;
        if (grow >= M) continue;
        float rb = (bias && biasRow) ? ld1auto(bias, grow, bF) : 0.f;
        TC* crow = Cbase + (long)grow * ldc + gcol;
        const float* al = nullptr;
        if (alpha) al = alpha + (long)(grow / rowsPerB) * alphaStride + gcol;
        #pragma unroll
        for (int j = 0; j < 4; j++) {
            float v = acc[i][j] + cb[j] + rb;
            if (alpha)         v = ldc1(crow + j) + al[j] * v;
            else if (act == 1) v = gelu_f(v);
            stc1(crow + j, v);
        }
    }
}

template <typename TC>
static void gemm(hipStream_t s, const void* A, int aTag, int lda, long bsA,
                 const void* W, int wTag, int ldw, long bsW,
                 TC* C, int ldc, long bsC, int M, int N, int K,
                 const void* bias, int bTag, int biasRow, int act,
                 const float* alpha, int alphaStride, int rowsPerB, int batch,
                 const int* DF) {
    dim3 g(N / 64, (M + 63) / 64, batch);
    k_gemm<TC><<<g, 256, 0, s>>>(A, aTag, lda, bsA, W, wTag, ldw, bsW, C, ldc, bsC,
                                 M, N, K, bias, bTag, biasRow, act,
                                 alpha, alphaStride, rowsPerB, DF);
}

// ---------------- agent attention stage 1 -----------------------------------
// 4-agents-per-block + vectorized PV rewrite.
// Old: 1 agent/block (8192 blocks), scalar 2B V loads, 128-iter dependent
// FMA chain -> 140 us @ VALUBusy 27% / HBM 6% (latency-bound, 4x overfetch).
// New: 2048 blocks; K/V bytes read exactly once per block (4x less traffic
// and 4x fewer loads/FLOP); PV uses float4 loads feeding 16 FMAs each with
// 32-long chains x4-agent ILP; 16-way LDS tree reduce.
__global__ __launch_bounds__(256) void k_agatt1(const float* __restrict__ qa,
                                                const bf16* __restrict__ ka,
                                                const bf16* __restrict__ va,
                                                float* __restrict__ c1) {
    constexpr int AQ = 4;
    int blk = blockIdx.x;
    int aq = blk % (kA / AQ);
    int h = (blk / (kA / AQ)) % kH;
    int b = blk / ((kA / AQ) * kH);
    int ag0 = aq * AQ;
    __shared__ float qs[AQ][kHS];
    __shared__ float probs[AQ][kT];
    __shared__ float red[16][AQ * 68];
    __shared__ float sred[32];
    int tid = threadIdx.x;
    {
        int ag = tid >> 6, d = tid & 63;
        qs[ag][d] = qa[((long)h * kA + ag0 + ag) * kHS + d];
    }
    __syncthreads();
    const bf16* kab = ka + ((long)h * kB + b) * kT * kHS;
    float sc[2][AQ];
    #pragma unroll
    for (int rep = 0; rep < 2; rep++) {
        const bf16* kr = kab + (long)(tid + rep * 256) * kHS;
        float a0 = 0.f, a1 = 0.f, a2 = 0.f, a3 = 0.f;
        #pragma unroll
        for (int d = 0; d < kHS; d += 4) {
            float4 k4 = load4bf(kr + d);
            float4 q0 = *(const float4*)&qs[0][d];
            float4 q1 = *(const float4*)&qs[1][d];
            float4 q2 = *(const float4*)&qs[2][d];
            float4 q3 = *(const float4*)&qs[3][d];
            a0 += k4.x * q0.x + k4.y * q0.y + k4.z * q0.z + k4.w * q0.w;
            a1 += k4.x * q1.x + k4.y * q1.y + k4.z * q1.z + k4.w * q1.w;
            a2 += k4.x * q2.x + k4.y * q2.y + k4.z * q2.z + k4.w * q2.w;
            a3 += k4.x * q3.x + k4.y * q3.y + k4.z * q3.z + k4.w * q3.w;
        }
        sc[rep][0] = a0 * 0.125f; sc[rep][1] = a1 * 0.125f;
        sc[rep][2] = a2 * 0.125f; sc[rep][3] = a3 * 0.125f;
    }
    int w = tid >> 6;
    float mx[AQ], ss[AQ];
    #pragma unroll
    for (int ag = 0; ag < AQ; ag++) mx[ag] = fmaxf(sc[0][ag], sc[1][ag]);
    #pragma unroll
    for (int m = 32; m > 0; m >>= 1)
        #pragma unroll
        for (int ag = 0; ag < AQ; ag++) mx[ag] = fmaxf(mx[ag], __shfl_down(mx[ag], m));
    if ((tid & 63) == 0)
        #pragma unroll
        for (int ag = 0; ag < AQ; ag++) sred[w * 4 + ag] = mx[ag];
    __syncthreads();
    #pragma unroll
    for (int ag = 0; ag < AQ; ag++)
        mx[ag] = fmaxf(fmaxf(sred[ag], sred[4 + ag]), fmaxf(sred[8 + ag], sred[12 + ag]));
    float e0[AQ], e1[AQ];
    #pragma unroll
    for (int ag = 0; ag < AQ; ag++) {
        e0[ag] = expf(sc[0][ag] - mx[ag]);
        e1[ag] = expf(sc[1][ag] - mx[ag]);
        ss[ag] = e0[ag] + e1[ag];
    }
    #pragma unroll
    for (int m = 32; m > 0; m >>= 1)
        #pragma unroll
        for (int ag = 0; ag < AQ; ag++) ss[ag] += __shfl_down(ss[ag], m);
    if ((tid & 63) == 0)
        #pragma unroll
        for (int ag = 0; ag < AQ; ag++) sred[16 + w * 4 + ag] = ss[ag];
    __syncthreads();
    #pragma unroll
    for (int ag = 0; ag < AQ; ag++) {
        float tot = sred[16 + ag] + sred[20 + ag] + sred[24 + ag] + sred[28 + ag];
        float rs = 1.f / tot;
        probs[ag][tid] = e0[ag] * rs;
        probs[ag][tid + 256] = e1[ag] * rs;
    }
    __syncthreads();
    // PV: dg = d-quad 0..15 (4 d's), nc = n-chunk 0..15 (32 n's)
    int dg = tid & 15, nc = tid >> 4;
    const bf16* vab = va + ((long)h * kB + b) * kT * kHS;
    float4 acc[AQ] = {};
    for (int s = 0; s < 32; s++) {
        int n = nc * 32 + s;
        float4 v = load4bf(vab + (long)n * kHS + dg * 4);
        #pragma unroll
        for (int ag = 0; ag < AQ; ag++) {
            float p = probs[ag][n];
            acc[ag].x += p * v.x; acc[ag].y += p * v.y;
            acc[ag].z += p * v.z; acc[ag].w += p * v.w;
        }
    }
    #pragma unroll
    for (int ag = 0; ag < AQ; ag++)
        *(float4*)&red[nc][ag * 68 + dg * 4] = acc[ag];
    __syncthreads();
    {
        int ag = tid >> 6, d = tid & 63;
        float s = 0.f;
        #pragma unroll
        for (int n2 = 0; n2 < 16; n2++) s += red[n2][ag * 68 + d];
        c1[(((long)b * kH + h) * kA + ag0 + ag) * kHS + d] = s;
    }
}

// ---------------- agent attention stage 2 (fp32 in/out) ----------------------
__global__ __launch_bounds__(256) void k_agatt2f(const float* __restrict__ qsrc, int ldq,
                                                 const float* __restrict__ c1,
                                                 float* __restrict__ out) {
    int blk = blockIdx.x;
    int nt = blk % (kT / 16);
    int h = (blk / (kT / 16)) % kH;
    int b = blk / ((kT / 16) * kH);
    __shared__ float c1s[kA][kHS + 1];
    __shared__ float qs[16][kHS + 1];
    __shared__ float ps[16][kA + 1];
    int tid = threadIdx.x;
    const float* c1b = c1 + ((long)b * kH + h) * kA * kHS;
    for (int i = tid; i < kA * kHS; i += 256) c1s[i >> 6][i & 63] = c1b[i];
    int n0 = nt * 16;
    {
        int r = tid >> 4, d = (tid & 15) * 4;
        float4 q4 = load4f(qsrc + (long)(b * kT + n0 + r) * ldq + h * kHS + d);
        qs[r][d] = q4.x; qs[r][d + 1] = q4.y; qs[r][d + 2] = q4.z; qs[r][d + 3] = q4.w;
    }
    __syncthreads();
    int r = tid >> 4, c = tid & 15;
    float sc[4];
    #pragma unroll
    for (int j = 0; j < 4; j++) {
        int a = c * 4 + j;
        float acc = 0.f;
        for (int d = 0; d < kHS; d++) acc += qs[r][d] * c1s[a][d];
        sc[j] = acc * 0.125f;
    }
    float mx = fmaxf(fmaxf(sc[0], sc[1]), fmaxf(sc[2], sc[3]));
    for (int m = 1; m < 16; m <<= 1) mx = fmaxf(mx, __shfl_xor(mx, m));
    float e[4], ss = 0.f;
    #pragma unroll
    for (int j = 0; j < 4; j++) { e[j] = expf(sc[j] - mx); ss += e[j]; }
    for (int m = 1; m < 16; m <<= 1) ss += __shfl_xor(ss, m);
    float rs = 1.f / ss;
    #pragma unroll
    for (int j = 0; j < 4; j++) ps[r][c * 4 + j] = e[j] * rs;
    __syncthreads();
    float o0 = 0.f, o1 = 0.f, o2 = 0.f, o3 = 0.f;
    int d0 = c * 4;
    for (int a = 0; a < kA; a++) {
        float p = ps[r][a];
        o0 += p * c1s[a][d0 + 0];
        o1 += p * c1s[a][d0 + 1];
        o2 += p * c1s[a][d0 + 2];
        o3 += p * c1s[a][d0 + 3];
    }
    float* orow = out + (long)(b * kT + n0 + r) * kE + h * kHS + d0;
    orow[0] = o0; orow[1] = o1; orow[2] = o2; orow[3] = o3;
}

// ---------------- DFT tables --------------------------------------------------
__global__ void k_trig(float* __restrict__ trig) {
    int id = blockIdx.x * 256 + threadIdx.x;
    if (id >= kNFREQ * kT) return;
    int t = id & 511;
    int f = (id >> 9) + 1;
    int m = (f * t) & 511;
    double ang = (double)m * (2.0 * 3.14159265358979323846 / 512.0);
    trig[id] = (float)cos(ang);
    trig[kNFREQ * kT + id] = (float)(-sin(ang));
}

// ---------------- top-5 |X_f|^2 per (b,e) column ------------------------------
// f-parallel rewrite: 16 threads per column each scan a 16-frequency chunk
// keeping a private top-5; partials merge via LDS.  Tie-break (v==, lower f
// wins) reproduces jax.lax.top_k stable semantics independent of merge order.
// Old: 32 blocks, serial 255-iter scan -> 207 us @ 1.4% occupancy.
__global__ __launch_bounds__(256) void k_topk(const float* __restrict__ RE, const float* __restrict__ IM,
                                              float* __restrict__ tre, float* __restrict__ tim,
                                              int* __restrict__ tix) {
    int tid = threadIdx.x;
    int c = tid & 15;                       // column within block
    int j = tid >> 4;                       // f-group 0..15
    int colId = blockIdx.x * 16 + c;        // 0..8191
    int b = colId >> 10, e = colId & 1023;
    const float* rp = RE + (long)b * kNFREQ * kE + e;
    const float* ip = IM + (long)b * kNFREQ * kE + e;
    float bv[kKTOP] = {-1e30f, -1e30f, -1e30f, -1e30f, -1e30f};
    int bi[kKTOP] = {1 << 30, 1 << 30, 1 << 30, 1 << 30, 1 << 30};
    #pragma unroll
    for (int s = 0; s < 16; s++) {
        int fq = j * 16 + s;
        if (fq >= kNFREQ) break;
        float re = rp[(long)fq * kE], im = ip[(long)fq * kE];
        float m2 = re * re + im * im;
        if (m2 > bv[kKTOP - 1] || (m2 == bv[kKTOP - 1] && fq < bi[kKTOP - 1])) {
            int p = kKTOP - 1;
            while (p > 0 && (m2 > bv[p - 1] || (m2 == bv[p - 1] && fq < bi[p - 1]))) {
                bv[p] = bv[p - 1]; bi[p] = bi[p - 1]; p--;
            }
            bv[p] = m2; bi[p] = fq;
        }
    }
    __shared__ float sv[16][16][kKTOP];
    __shared__ int   si[16][16][kKTOP];
    #pragma unroll
    for (int q = 0; q < kKTOP; q++) { sv[c][j][q] = bv[q]; si[c][j][q] = bi[q]; }
    __syncthreads();
    if (j == 0) {
        for (int jj = 1; jj < 16; jj++) {
            #pragma unroll
            for (int q = 0; q < kKTOP; q++) {
                float v = sv[c][jj][q];
                int fq = si[c][jj][q];
                if (v > bv[kKTOP - 1] || (v == bv[kKTOP - 1] && fq < bi[kKTOP - 1])) {
                    int p = kKTOP - 1;
                    while (p > 0 && (v > bv[p - 1] || (v == bv[p - 1] && fq < bi[p - 1]))) {
                        bv[p] = bv[p - 1]; bi[p] = bi[p - 1]; p--;
                    }
                    bv[p] = v; bi[p] = fq;
                }
            }
        }
        #pragma unroll
        for (int q = 0; q < kKTOP; q++) {
            int fq = bi[q];
            tre[(long)colId * kKTOP + q] = rp[(long)fq * kE];
            tim[(long)colId * kKTOP + q] = ip[(long)fq * kE];
            tix[(long)colId * kKTOP + q] = fq;
        }
    }
}

__global__ void k_season(const float* __restrict__ tre, const float* __restrict__ tim,
                         const int* __restrict__ tix, const float* __restrict__ trig,
                         void* __restrict__ out, long obase, const int* __restrict__ DF) {
    bool f32o = DF[0] != 0;
    long id = (long)blockIdx.x * 256 + threadIdx.x;
    int e = id & 1023;
    long bt = id >> 10;
    int t = (int)(bt & 511);
    int b = (int)(bt >> 9);
    long be = (long)b * kE + e;
    float acc = 0.f;
    #pragma unroll
    for (int j = 0; j < kKTOP; j++) {
        int f = tix[be * kKTOP + j];
        acc += tre[be * kKTOP + j] * trig[(long)f * kT + t]
             + tim[be * kKTOP + j] * trig[(long)kNFREQ * kT + (long)f * kT + t];
    }
    st1auto(out, obase + id, f32o, 2.f * acc);
}

// ---------------- trend branch ------------------------------------------------
// conv1 re-parallelized: grid = (b,o) x 8 l-tiles = 192 blocks.  Weight slab
// w[o,:,:] (6 KB) staged in LDS once; each thread owns one l of a 128-wide
// tile and half the i-range; 2-way LDS reduce.  Old: 96 blocks, 512-iter
// serial loop with per-iter scalar weight loads -> 224 us @ 4.2% occupancy.
__global__ __launch_bounds__(256) void k_conv1(const float* __restrict__ P,
                                               const void* __restrict__ w,
                                               const void* __restrict__ bias,
                                               float* __restrict__ G,
                                               const int* __restrict__ DF) {
    bool f = DF[0] != 0;
    int bo = blockIdx.x;                 // 0..23 -> (b,o)
    int lt = blockIdx.y;                 // 0..7  -> 128-l tile
    int o = bo % 3, b = bo / 3;
    int tid = threadIdx.x;
    __shared__ float ws[512][3];         // 6 KB weight slab for this o
    for (int idx = tid; idx < 512 * 3; idx += 256)
        ws[idx / 3][idx % 3] = ld1auto(w, (long)o * 512 * 3 + idx, f);
    __syncthreads();
    int l = lt * 128 + (tid & 127);
    int ih = (tid >> 7) * 256;           // 0 or 256
    const float* xb = P + (long)b * kT2 * kE;
    float acc = 0.f;
    for (int ii = 0; ii < 256; ii++) {
        int i = ih + ii;
        const float* xr = xb + (long)i * kE + l;
        float xm = (l > 0)    ? xr[-1] : 0.f;
        float xc = xr[0];
        float xp = (l < 1023) ? xr[1]  : 0.f;
        acc += xm * ws[i][0] + xc * ws[i][1] + xp * ws[i][2];
    }
    __shared__ float red[128];
    if (tid >= 128) red[tid - 128] = acc;
    __syncthreads();
    if (tid < 128) {
        float tot = acc + red[tid] + ld1auto(bias, o, f);
        G[((long)b * 3 + o) * 1024 + l] = gelu_f(tot);
    }
}

// conv2 re-parallelized: one workgroup per (b,n) output pair (512 blocks),
// 256 threads stride over i, 3 pp-partials in registers, block-reduce.
// Old version: 6 blocks, serial 3072-iter scalar loop -> 489 us @ 0.3% occupancy.
__global__ __launch_bounds__(256) void k_conv2(const float* __restrict__ G,
                                               const void* __restrict__ w,
                                               const void* __restrict__ bias,
                                               float* __restrict__ H2,
                                               const int* __restrict__ DF) {
    bool f = DF[0] != 0;
    int n = blockIdx.x % kNF;
    int b = blockIdx.x / kNF;
    int tid = threadIdx.x;
    const float* Gb = G + (long)b * 3 * 1024;
    // valid (pp, k -> l = pp + k - 1) combos:
    // pp=0: g[0]*w[1] + g[1]*w[2]
    // pp=1: g[0]*w[0] + g[1]*w[1] + g[2]*w[2]
    // pp=2: g[1]*w[0] + g[2]*w[1]
    float a0 = 0.f, a1 = 0.f, a2 = 0.f;
    for (int i = tid; i < 1024; i += 256) {
        float g0 = Gb[i], g1 = Gb[1024 + i], g2 = Gb[2048 + i];
        long wo = ((long)n * 1024 + i) * 3;
        float w0 = ld1auto(w, wo + 0, f);
        float w1 = ld1auto(w, wo + 1, f);
        float w2 = ld1auto(w, wo + 2, f);
        a0 += g0 * w1 + g1 * w2;
        a1 += g0 * w0 + g1 * w1 + g2 * w2;
        a2 += g1 * w0 + g2 * w1;
    }
    __shared__ float sm[12];
    #pragma unroll
    for (int m = 32; m > 0; m >>= 1) {
        a0 += __shfl_down(a0, m);
        a1 += __shfl_down(a1, m);
        a2 += __shfl_down(a2, m);
    }
    int wv = tid >> 6;
    if ((tid & 63) == 0) { sm[wv] = a0; sm[4 + wv] = a1; sm[8 + wv] = a2; }
    __syncthreads();
    if (tid == 0) {
        float cb = ld1auto(bias, n, f);
        float* hp = H2 + ((long)b * kNF + n) * 3;
        hp[0] = cb + sm[0] + sm[1] + sm[2] + sm[3];
        hp[1] = cb + sm[4] + sm[5] + sm[6] + sm[7];
        hp[2] = cb + sm[8] + sm[9] + sm[10] + sm[11];
    }
}

__global__ void k_trend(const float* __restrict__ H2, void* __restrict__ out, long obase,
                        const int* __restrict__ DF) {
    bool f32o = DF[0] != 0;
    int id = blockIdx.x * 256 + threadIdx.x;
    int n = id % kNF;
    int t = (id / kNF) % kT;
    int b = id / (kNF * kT);
    float lin = (float)(t + 1) / 513.0f;
    const float* h = H2 + ((long)b * kNF + n) * 3;
    float l2 = lin * lin;
    st1auto(out, obase + id, f32o, h[0] * lin + h[1] * l2 + h[2] * l2 * lin);
}

// ---------------- finals -------------------------------------------------------
__global__ void k_mean(const float* __restrict__ X, float* __restrict__ m) {
    int id = blockIdx.x * 256 + threadIdx.x;
    int b = id >> 10, e = id & 1023;
    const float* p = X + (long)b * kT * kE + e;
    float s = 0.f;
    for (int t = 0; t < kT; t++) s += p[(long)t * kE];
    m[id] = s * (1.f / kT);
}

__global__ void k_out0(const float* __restrict__ X, const float* __restrict__ m,
                       void* __restrict__ out, long obase, const int* __restrict__ DF) {
    bool f32o = DF[0] != 0;
    long id = (long)blockIdx.x * 256 + threadIdx.x;
    int e = id & 1023;
    int b = (int)(id >> 19);
    st1auto(out, obase + id, f32o, X[id] - m[b * kE + e]);
}

__global__ void k_out1(const float* __restrict__ m, const void* __restrict__ w,
                       const void* __restrict__ bias, void* __restrict__ out, long obase,
                       const int* __restrict__ DF) {
    bool f = DF[0] != 0;
    int id = blockIdx.x * 256 + threadIdx.x;
    if (id >= kB * kNF) return;
    int b = id / kNF, n = id % kNF;
    float acc = ld1auto(bias, n, f);
    for (int e = 0; e < kE; e++) acc += m[b * kE + e] * ld1auto(w, (long)e * kNF + n, f);
    st1auto(out, obase + id, f, acc);
}

// ---------------- launch -------------------------------------------------------
extern "C" void kernel_launch(void* const* d_in, const int* in_sizes, int n_in,
                              void* d_out, int out_size, void* d_ws, size_t ws_size,
                              hipStream_t stream) {
    (void)in_sizes; (void)n_in; (void)out_size; (void)ws_size;
    const void* x_in = d_in[0];
    const void* enc  = d_in[1];
    const int* tstep = (const int*)d_in[2];
    const void *ln1_w = d_in[3],  *ln1_b = d_in[4],  *ln11_w = d_in[5], *ln11_b = d_in[6];
    const void *ln2_w = d_in[7],  *ln2_b = d_in[8];
    const void *a1_qkv_w = d_in[9], *a1_qkv_b = d_in[10];
    const void *a1_agq_w = d_in[11], *a1_agq_b = d_in[12];
    const void *a1_agk_w = d_in[13], *a1_agk_b = d_in[14];
    const void *a1_agv_w = d_in[15], *a1_agv_b = d_in[16];
    const void *a1_ago_w = d_in[17], *a1_ago_b = d_in[18];
    const void *a1_agents = d_in[19];
    const void *a1_proj_w = d_in[20], *a1_proj_b = d_in[21];
    const void *a2_q_w = d_in[22], *a2_q_b = d_in[23];
    const void *a2_kv_w = d_in[24], *a2_kv_b = d_in[25];
    const void *a2_agq_w = d_in[26], *a2_agq_b = d_in[27];
    const void *a2_agk_w = d_in[28], *a2_agk_b = d_in[29];
    const void *a2_agv_w = d_in[30], *a2_agv_b = d_in[31];
    const void *a2_ago_w = d_in[32], *a2_ago_b = d_in[33];
    const void *a2_agents = d_in[34];
    const void *a2_proj_w = d_in[35], *a2_proj_b = d_in[36];
    const void *tr_c1_w = d_in[37], *tr_c1_b = d_in[38];
    const void *tr_c2_w = d_in[39], *tr_c2_b = d_in[40];
    const void *mlp_w1 = d_in[41], *mlp_b1 = d_in[42];
    const void *mlp_w2 = d_in[43], *mlp_b2 = d_in[44];
    const void *pr_w = d_in[45], *pr_b = d_in[46];
    const void *lin_w = d_in[47], *lin_b = d_in[48];

    char* wsb = (char*)d_ws;
    float* XC = (float*)(wsb + BOFF_XC);
    float* SM = (float*)(wsb + BOFF_SMALL);
    float* TS = SM + F_TS;
    float* AD1 = SM + F_AD1;
    float* AD11 = SM + F_AD11;
    float* AD2 = SM + F_AD2;
    float* QA = SM + F_QA;
    float* C1 = SM + F_C1;
    float* H2 = SM + F_H2;
    float* G1 = SM + F_G1;
    float* MB = SM + F_MB;
    float* TRE = SM + F_TRE;
    float* TIM = SM + F_TIM;
    int*   TIX = (int*)(SM + F_TIX);
    float* TRIG = SM + F_TRIG;
    int* DF = (int*)(wsb + BOFF_FLAG);
    char* WR = wsb + BOFF_WREG;
    float* WTQ  = (float*)(WR + WR_Q);
    float* WTKV = (float*)(WR + WR_KV);
    float* WAGO = (float*)(WR + WR_AGO);
    float* WPRJ = (float*)(WR + WR_PRJ);
    bf16*  W1B  = (bf16*)(WR + WR_W1);
    bf16*  W2B  = (bf16*)(WR + WR_W2);
    char* AC = wsb + BOFF_ACT;
    float* N1F  = (float*)(AC + AC_N1);     // also ENCF
    float* QBUF = (float*)(AC + AC_QBUF);
    float* KVB  = (float*)(AC + AC_KV);
    bf16*  KA   = (bf16*)(AC + AC_KA);
    bf16*  VA   = (bf16*)(AC + AC_VA);
    float* ATTF = (float*)(AC + AC_ATT);
    float* Y2F  = (float*)(AC + AC_Y2);
    float* P    = (float*)(AC + AC_P);
    float* RE   = (float*)(AC + AC_RE);
    float* IM   = (float*)(AC + AC_IM);
    bf16*  N1B  = (bf16*)(AC + AC_N1B);
    bf16*  HID  = (bf16*)(AC + AC_HID);

    const int M_BT = kB * kT;                      // 4096
    const long bsKA = (long)kB * kT * kHS;

    // 0) dtype detection (precedes all d_in consumers)
    k_detect<<<1, 256, 0, stream>>>((const unsigned short*)x_in, DF);

    // phase-1 weight transposes (fp32)
    k_wtf<<<dim3(1024/32, 1024/32), 256, 0, stream>>>(a1_qkv_w, WTQ, 1024, 3072, 0, DF);
    k_wtf<<<dim3(2048/32, 1024/32), 256, 0, stream>>>(a1_qkv_w, WTKV, 1024, 3072, 1024, DF);
    k_wtf<<<dim3(1024/32, 1024/32), 256, 0, stream>>>(a1_ago_w, WAGO, 1024, 1024, 0, DF);
    k_wtf<<<dim3(1024/32, 1024/32), 256, 0, stream>>>(a1_proj_w, WPRJ, 1024, 1024, 0, DF);

    // prologue
    k_temb<<<kB, 512, 0, stream>>>(tstep, TS);
    gemm(stream, TS, TAG_F32, kE, 0L, ln1_w, TAG_AUTO, 3 * kE, 0L, AD1, 3 * kE, 0L,
         kB, 3 * kE, kE, ln1_b, TAG_AUTO, 0, 0, nullptr, 0, 1, 1, DF);
    gemm(stream, TS, TAG_F32, kE, 0L, ln11_w, TAG_AUTO, 3 * kE, 0L, AD11, 3 * kE, 0L,
         kB, 3 * kE, kE, ln11_b, TAG_AUTO, 0, 0, nullptr, 0, 1, 1, DF);
    gemm(stream, TS, TAG_F32, kE, 0L, ln2_w, TAG_AUTO, 3 * kE, 0L, AD2, 3 * kE, 0L,
         kB, 3 * kE, kE, ln2_b, TAG_AUTO, 0, 0, nullptr, 0, 1, 1, DF);
    k_castin<<<(kB * kT * kE) / 1024, 256, 0, stream>>>(x_in, XC, DF);
    k_trig<<<(kNFREQ * kT + 255) / 256, 256, 0, stream>>>(TRIG);

    // ---- attention block 1 (self), fp32 end-to-end via split MFMA ----
    k_adalnf<<<M_BT, 256, 0, stream>>>(XC, AD1, N1F);
    mgemm32(stream, N1F, kE, WTQ, QBUF, kE, M_BT, kE, kE,
            a1_qkv_b, TAG_AUTO, 0L, nullptr, 0, 1, DF);
    mgemm32(stream, N1F, kE, WTKV, KVB, 2 * kE, M_BT, 2 * kE, kE,
            a1_qkv_b, TAG_AUTO, (long)kE, nullptr, 0, 1, DF);
    gemm(stream, a1_agents, TAG_AUTO, kHS, 0L, a1_agq_w, TAG_AUTO, kHS, 0L, QA, kHS, 0L,
         kH * kA, kHS, kHS, a1_agq_b, TAG_AUTO, 0, 0, nullptr, 0, 1, 1, DF);
    gemm(stream, KVB, TAG_F32, 2 * kE, 64L, a1_agk_w, TAG_AUTO, kHS, 0L, KA, kHS, bsKA,
         M_BT, kHS, kHS, a1_agk_b, TAG_AUTO, 0, 0, nullptr, 0, 1, kH, DF);
    gemm(stream, KVB + kE, TAG_F32, 2 * kE, 64L, a1_agv_w, TAG_AUTO, kHS, 0L, VA, kHS, bsKA,
         M_BT, kHS, kHS, a1_agv_b, TAG_AUTO, 0, 0, nullptr, 0, 1, kH, DF);
    k_agatt1<<<kB * kH * (kA / 4), 256, 0, stream>>>(QA, KA, VA, C1);
    k_agatt2f<<<kB * kH * (kT / 16), 256, 0, stream>>>(QBUF, kE, C1, ATTF);
    mgemm32(stream, ATTF, kE, WAGO, Y2F, kE, M_BT, kE, kE,
            a1_ago_b, TAG_AUTO, 0L, nullptr, 0, 1, DF);
    mgemm32(stream, Y2F, kE, WPRJ, XC, kE, M_BT, kE, kE,
            a1_proj_b, TAG_AUTO, 0L, AD1 + 2 * kE, 3 * kE, kT, DF);

    // phase-2 weight transposes (WREG safely reusable after prj1)
    k_wtf<<<dim3(1024/32, 1024/32), 256, 0, stream>>>(a2_q_w, WTQ, 1024, 1024, 0, DF);
    k_wtf<<<dim3(2048/32, 1024/32), 256, 0, stream>>>(a2_kv_w, WTKV, 1024, 2048, 0, DF);
    k_wtf<<<dim3(1024/32, 1024/32), 256, 0, stream>>>(a2_ago_w, WAGO, 1024, 1024, 0, DF);
    k_wtf<<<dim3(1024/32, 1024/32), 256, 0, stream>>>(a2_proj_w, WPRJ, 1024, 1024, 0, DF);

    // ---- attention block 2 (cross) ----
    k_castin<<<(kB * kT * kE) / 1024, 256, 0, stream>>>(enc, N1F, DF);   // ENCF in N1F slot
    mgemm32(stream, N1F, kE, WTKV, KVB, 2 * kE, M_BT, 2 * kE, kE,
            a2_kv_b, TAG_AUTO, 0L, nullptr, 0, 1, DF);
    k_adalnf<<<M_BT, 256, 0, stream>>>(XC, AD11, N1F);                    // overwrites ENCF (dead)
    mgemm32(stream, N1F, kE, WTQ, QBUF, kE, M_BT, kE, kE,
            a2_q_b, TAG_AUTO, 0L, nullptr, 0, 1, DF);
    gemm(stream, a2_agents, TAG_AUTO, kHS, 0L, a2_agq_w, TAG_AUTO, kHS, 0L, QA, kHS, 0L,
         kH * kA, kHS, kHS, a2_agq_b, TAG_AUTO, 0, 0, nullptr, 0, 1, 1, DF);
    gemm(stream, KVB, TAG_F32, 2 * kE, 64L, a2_agk_w, TAG_AUTO, kHS, 0L, KA, kHS, bsKA,
         M_BT, kHS, kHS, a2_agk_b, TAG_AUTO, 0, 0, nullptr, 0, 1, kH, DF);
    gemm(stream, KVB + kE, TAG_F32, 2 * kE, 64L, a2_agv_w, TAG_AUTO, kHS, 0L, VA, kHS, bsKA,
         M_BT, kHS, kHS, a2_agv_b, TAG_AUTO, 0, 0, nullptr, 0, 1, kH, DF);
    k_agatt1<<<kB * kH * (kA / 4), 256, 0, stream>>>(QA, KA, VA, C1);
    k_agatt2f<<<kB * kH * (kT / 16), 256, 0, stream>>>(QBUF, kE, C1, ATTF);
    mgemm32(stream, ATTF, kE, WAGO, Y2F, kE, M_BT, kE, kE,
            a2_ago_b, TAG_AUTO, 0L, nullptr, 0, 1, DF);
    mgemm32(stream, Y2F, kE, WPRJ, XC, kE, M_BT, kE, kE,
            a2_proj_b, TAG_AUTO, 0L, AD11 + 2 * kE, 3 * kE, kT, DF);

    // ---- phase 3: p = einsum('bce,oc->boe') + DFT + trend (all fp32 VALU) ----
    gemm(stream, pr_w, TAG_AUTO, kT, 0L, XC, TAG_F32, kE, (long)kT * kE,
         P, kE, (long)kT2 * kE, kT2, kE, kT,
         pr_b, TAG_AUTO, 1, 0, nullptr, 0, 1, kB, DF);
    gemm(stream, TRIG, TAG_F32, kT, 0L, P + (long)kT * kE, TAG_F32, kE, (long)kT2 * kE,
         RE, kE, (long)kNFREQ * kE, kNFREQ, kE, kT,
         nullptr, 0, 0, 0, nullptr, 0, 1, kB, DF);
    gemm(stream, TRIG + (long)kNFREQ * kT, TAG_F32, kT, 0L, P + (long)kT * kE, TAG_F32, kE, (long)kT2 * kE,
         IM, kE, (long)kNFREQ * kE, kNFREQ, kE, kT,
         nullptr, 0, 0, 0, nullptr, 0, 1, kB, DF);
    k_topk<<<(kB * kE) / 16, 256, 0, stream>>>(RE, IM, TRE, TIM, TIX);
    k_season<<<(kB * kT * kE) / 256, 256, 0, stream>>>(TRE, TIM, TIX, TRIG, d_out, O3, DF);
    k_conv1<<<dim3(kB * 3, 8), 256, 0, stream>>>(P, tr_c1_w, tr_c1_b, G1, DF);
    k_conv2<<<kB * kNF, 256, 0, stream>>>(G1, tr_c2_w, tr_c2_b, H2, DF);
    k_trend<<<(kB * kT * kNF) / 256, 256, 0, stream>>>(H2, d_out, O2, DF);

    // ---- phase 4: MLP (post-P; plain bf16 MFMA -- proven on outputs 0/1) ----
    k_wt<<<dim3(4096/32, 1024/32), 256, 0, stream>>>(mlp_w1, W1B, 1024, 4096, DF);
    k_wt<<<dim3(1024/32, 4096/32), 256, 0, stream>>>(mlp_w2, W2B, 4096, 1024, DF);
    k_adaln<<<M_BT, 256, 0, stream>>>(XC, AD2, N1B);
    mgemm(stream, N1B, kE, W1B, HID, kMLP, M_BT, kMLP, kE,
          mlp_b1, TAG_AUTO, 1 /*gelu*/, nullptr, 0, 1, DF);
    mgemm(stream, HID, kMLP, W2B, XC, kE, M_BT, kE, kMLP,
          mlp_b2, TAG_AUTO, 0, AD2 + 2 * kE, 3 * kE, kT, DF);

    // ---- finals ----
    k_mean<<<(kB * kE) / 256, 256, 0, stream>>>(XC, MB);
    k_out0<<<(kB * kT * kE) / 256, 256, 0, stream>>>(XC, MB, d_out, O0, DF);
    k_out1<<<(kB * kNF + 255) / 256, 256, 0, stream>>>(MB, lin_w, lin_b, d_out, O1, DF);
}

// Round 7
// 2007.532 us; speedup vs baseline: 1.5934x; 1.0903x over previous
//
#include <hip/hip_runtime.h>
#include <hip/hip_bf16.h>

using bf16 = __hip_bfloat16;
typedef __attribute__((ext_vector_type(8))) short short8;     // 8 bf16 (4 VGPRs)
typedef __attribute__((ext_vector_type(4))) float floatx4;    // MFMA acc

// Problem constants
constexpr int kB = 8, kT = 512, kE = 1024, kH = 16, kA = 64, kNF = 64, kHS = 64;
constexpr int kMLP = 4096, kT2 = 1024, kNFREQ = 255, kKTOP = 5;

constexpr int TAG_F32 = 0, TAG_BF16 = 1, TAG_AUTO = 2;

// ---------------- workspace arena (BYTE offsets) ----------------------------
// XC 16.78M | SMALL 4.36M | FLAG 64 | WREG 20.97M (phase-reused weight xposes)
// | ACT 67.11M (phase-reused activations).  Total 109.2 MB < 117.6 MB proven.
constexpr long BOFF_XC    = 0;                          // fp32 (B,T,E)
constexpr long BOFF_SMALL = 16777216;                   // 4,360,192 B
constexpr long BOFF_FLAG  = 21137408;                   // 64 B
constexpr long BOFF_WREG  = 21137472;                   // 20,971,520 B
constexpr long BOFF_ACT   = 42108992;                   // 67,108,864 B
constexpr long WS_NEED    = BOFF_ACT + 67108864;        // 109,217,856 B

// WREG slots (bytes from BOFF_WREG)
constexpr long WR_Q   = 0;          // fp32 1024x1024 (4,194,304)
constexpr long WR_KV  = 4194304;    // fp32 2048x1024 (8,388,608)
constexpr long WR_AGO = 12582912;   // fp32 1024x1024
constexpr long WR_PRJ = 16777216;   // fp32 1024x1024
constexpr long WR_W1  = 0;          // bf16 4096x1024 (8,388,608)  [phase 4]
constexpr long WR_W2  = 8388608;    // bf16 1024x4096 (8,388,608)  [phase 4]

// ACT slots (bytes from BOFF_ACT)
constexpr long AC_N1   = 0;         // fp32 (B,T,E) 16.78M   (also ENCF / P lo-half / N1b+HID)
constexpr long AC_QBUF = 16777216;  // fp32 (B,T,E) 16.78M
constexpr long AC_KV   = 33554432;  // fp32 (B,T,2E) 33.55M
constexpr long AC_KA   = 0;         // bf16 (H,B,T,HS) 8.39M  (over N1, after N1 dead)
constexpr long AC_VA   = 8388608;   // bf16 (H,B,T,HS) 8.39M
constexpr long AC_ATT  = 33554432;  // fp32 (B,T,E) 16.78M    (over KV, after KV dead)
constexpr long AC_Y2   = 50331648;  // fp32 (B,T,E) 16.78M
constexpr long AC_P    = 0;         // fp32 (B,2T,E) 33.55M   [phase 3]
constexpr long AC_RE   = 33554432;  // fp32 (B,255,E) 8,355,840
constexpr long AC_IM   = 41910272;  // fp32 (B,255,E) 8,355,840
constexpr long AC_N1B  = 0;         // bf16 (B,T,E) 8.39M     [phase 4]
constexpr long AC_HID  = 8388608;   // bf16 (B,T,MLP) 33.55M  [phase 4]

// small-region float offsets (relative to BOFF_SMALL)
constexpr long F_TS = 0, F_AD1 = 8192, F_AD11 = 32768, F_AD2 = 57344, F_QA = 81920,
               F_C1 = 147456, F_H2 = 671744, F_G1 = 673280, F_MB = 697856,
               F_TRE = 706048, F_TIM = 747008, F_TIX = 787968, F_TRIG = 828928;

// output regions (element offsets)
constexpr long O0 = 0, O1 = 4194304, O2 = 4194816, O3 = 4456960;

// ---------------- helpers ---------------------------------------------------
__device__ inline float bf2f(bf16 h) {
    unsigned short u = *(unsigned short*)&h;
    return __uint_as_float((unsigned)u << 16);
}
__device__ inline unsigned short bfbits(bf16 b) { return *(unsigned short*)&b; }
__device__ inline float gelu_f(float x) {
    return 0.5f * x * (1.0f + erff(x * 0.7071067811865476f));
}
__device__ inline float4 load4f(const float* p) { return *(const float4*)p; }
__device__ inline float4 load4bf(const bf16* p) {
    ushort4 u = *(const ushort4*)p;
    float4 r;
    r.x = __uint_as_float((unsigned)u.x << 16);
    r.y = __uint_as_float((unsigned)u.y << 16);
    r.z = __uint_as_float((unsigned)u.z << 16);
    r.w = __uint_as_float((unsigned)u.w << 16);
    return r;
}
__device__ inline float4 load4auto(const void* p, long idx, bool isF32) {
    if (isF32) return load4f((const float*)p + idx);
    return load4bf((const bf16*)p + idx);
}
__device__ inline float ld1auto(const void* p, long idx, bool isF32) {
    if (isF32) return ((const float*)p)[idx];
    return bf2f(((const bf16*)p)[idx]);
}
__device__ inline void st1auto(void* p, long idx, bool isF32, float v) {
    if (isF32) ((float*)p)[idx] = v;
    else       ((bf16*)p)[idx] = __float2bfloat16(v);
}
__device__ inline float ldc1(const float* p) { return *p; }
__device__ inline float ldc1(const bf16* p) { return bf2f(*p); }
__device__ inline void stc1(float* p, float v) { *p = v; }
__device__ inline void stc1(bf16* p, float v) { *p = __float2bfloat16(v); }

__device__ inline void blockReduce2(float& a, float& b, float* sm) {
    #pragma unroll
    for (int m = 32; m > 0; m >>= 1) { a += __shfl_down(a, m); b += __shfl_down(b, m); }
    int w = threadIdx.x >> 6;
    if ((threadIdx.x & 63) == 0) { sm[w] = a; sm[4 + w] = b; }
    __syncthreads();
    a = sm[0] + sm[1] + sm[2] + sm[3];
    b = sm[4] + sm[5] + sm[6] + sm[7];
    __syncthreads();
}

// ---------------- dtype detector --------------------------------------------
__global__ void k_detect(const unsigned short* __restrict__ xraw, int* __restrict__ flag) {
    int tid = threadIdx.x;
    unsigned short h = xraw[2 * tid];
    float v = __uint_as_float((unsigned)h << 16);
    float av = fabsf(v);
    if (!(av == av)) av = 1e30f;
    __shared__ float red[4];
    for (int m = 32; m > 0; m >>= 1) av = fmaxf(av, __shfl_down(av, m));
    if ((tid & 63) == 0) red[tid >> 6] = av;
    __syncthreads();
    if (tid == 0) {
        float mx = fmaxf(fmaxf(red[0], red[1]), fmaxf(red[2], red[3]));
        flag[0] = (mx < 1e3f) ? 0 : 1;             // 0 = bf16, 1 = fp32
    }
}

// ---------------- small kernels ---------------------------------------------
__global__ void k_temb(const int* __restrict__ ts, float* __restrict__ out) {
    int b = blockIdx.x, i = threadIdx.x;           // 512 threads
    float t = (float)ts[b];
    const float rate = (float)(-9.210340371976184 / 511.0);
    float f = expf(rate * (float)i);
    float arg = t * f;
    float sv = sinf(arg), cv = cosf(arg);
    out[(long)b * kE + i]        = sv / (1.f + expf(-sv));
    out[(long)b * kE + 512 + i]  = cv / (1.f + expf(-cv));
}

__global__ void k_castin(const void* __restrict__ in, float* __restrict__ out,
                         const int* __restrict__ DF) {
    bool f = DF[0] != 0;
    long i = ((long)blockIdx.x * 256 + threadIdx.x) * 4;
    float4 v = load4auto(in, i, f);
    *(float4*)(out + i) = v;
}

// fp32 weight transpose: W[K][Ntot] (auto dtype), cols [c0, c0+Nout) -> WT[Nout][K] fp32
__global__ __launch_bounds__(256) void k_wtf(const void* __restrict__ W, float* __restrict__ WT,
                                             int K, int Ntot, int c0,
                                             const int* __restrict__ DF) {
    bool f = DF[0] != 0;
    __shared__ float tile[32][33];
    int n0 = blockIdx.x * 32, k0 = blockIdx.y * 32;
    int tx = threadIdx.x & 31, ty = threadIdx.x >> 5;
    #pragma unroll
    for (int i = 0; i < 4; i++) {
        int k = ty + i * 8;
        tile[k][tx] = ld1auto(W, (long)(k0 + k) * Ntot + c0 + n0 + tx, f);
    }
    __syncthreads();
    #pragma unroll
    for (int i = 0; i < 4; i++) {
        int n = ty + i * 8;
        WT[(long)(n0 + n) * K + k0 + tx] = tile[tx][n];
    }
}

// bf16 weight transpose (for MLP): W[K][N] -> WT[N][K] bf16
__global__ __launch_bounds__(256) void k_wt(const void* __restrict__ W, bf16* __restrict__ WT,
                                            int K, int N, const int* __restrict__ DF) {
    bool f = DF[0] != 0;
    __shared__ float tile[32][33];
    int n0 = blockIdx.x * 32, k0 = blockIdx.y * 32;
    int tx = threadIdx.x & 31, ty = threadIdx.x >> 5;
    #pragma unroll
    for (int i = 0; i < 4; i++) {
        int k = ty + i * 8;
        tile[k][tx] = ld1auto(W, (long)(k0 + k) * N + n0 + tx, f);
    }
    __syncthreads();
    #pragma unroll
    for (int i = 0; i < 4; i++) {
        int n = ty + i * 8;
        WT[(long)(n0 + n) * K + k0 + tx] = __float2bfloat16(tile[tx][n]);
    }
}

// adaLN -> fp32 out (phases 1,2)
__global__ __launch_bounds__(256) void k_adalnf(const float* __restrict__ X,
                                                const float* __restrict__ AD,
                                                float* __restrict__ N) {
    int row = blockIdx.x;
    int b = row / kT;
    const float* xr = X + (long)row * kE;
    int tid = threadIdx.x;
    float4 xv = *(const float4*)(xr + tid * 4);
    float s  = xv.x + xv.y + xv.z + xv.w;
    float sq = xv.x * xv.x + xv.y * xv.y + xv.z * xv.z + xv.w * xv.w;
    __shared__ float sm[8];
    blockReduce2(s, sq, sm);
    float mu  = s * (1.f / kE);
    float var = sq * (1.f / kE) - mu * mu;
    float rstd = rsqrtf(fmaxf(var, 0.f) + 1e-5f);
    const float* ad = AD + (long)b * 3 * kE;
    float* nr = N + (long)row * kE;
    float xs[4] = {xv.x, xv.y, xv.z, xv.w};
    #pragma unroll
    for (int j = 0; j < 4; j++) {
        int e = tid * 4 + j;
        float xn = (xs[j] - mu) * rstd;
        nr[e] = xn * (1.f + ad[kE + e]) + ad[e];
    }
}

// adaLN -> bf16 out (phase 4 / MLP)
__global__ __launch_bounds__(256) void k_adaln(const float* __restrict__ X,
                                               const float* __restrict__ AD,
                                               bf16* __restrict__ N) {
    int row = blockIdx.x;
    int b = row / kT;
    const float* xr = X + (long)row * kE;
    int tid = threadIdx.x;
    float4 xv = *(const float4*)(xr + tid * 4);
    float s  = xv.x + xv.y + xv.z + xv.w;
    float sq = xv.x * xv.x + xv.y * xv.y + xv.z * xv.z + xv.w * xv.w;
    __shared__ float sm[8];
    blockReduce2(s, sq, sm);
    float mu  = s * (1.f / kE);
    float var = sq * (1.f / kE) - mu * mu;
    float rstd = rsqrtf(fmaxf(var, 0.f) + 1e-5f);
    const float* ad = AD + (long)b * 3 * kE;
    bf16* nr = N + (long)row * kE;
    float xs[4] = {xv.x, xv.y, xv.z, xv.w};
    #pragma unroll
    for (int j = 0; j < 4; j++) {
        int e = tid * 4 + j;
        float xn = (xs[j] - mu) * rstd;
        nr[e] = __float2bfloat16(xn * (1.f + ad[kE + e]) + ad[e]);
    }
}

// ---------------- split-precision MFMA GEMM (fp32-accurate) -----------------
// C = A(fp32 MxK) @ WT(fp32 NxK)^T via hi/lo bf16 split: Ah*Bh + Ah*Bl + Al*Bh.
// Relative error ~8e-6 (vs 2e-3 plain bf16). M,N mult of 128, K mult of 32.
template <typename TC>
__global__ __launch_bounds__(256) void k_mfma32(
    const float* __restrict__ A, int lda,
    const float* __restrict__ WT,
    TC* __restrict__ C, int ldc,
    int M, int N, int K,
    const void* __restrict__ bias, int bTag, long biasOff,
    const float* __restrict__ alpha, int alphaStride, int rowsPerB,
    const int* __restrict__ DF) {
    constexpr int BK = 32, PAD = 8;                 // 40 elem (80 B) row stride
    __shared__ bf16 Ah[128][BK + PAD], Al[128][BK + PAD];
    __shared__ bf16 Bh[128][BK + PAD], Bl[128][BK + PAD];
    int tid = threadIdx.x;
    int wave = tid >> 6, lane = tid & 63;
    int bm = blockIdx.y * 128, bn = blockIdx.x * 128;
    int wm = (wave >> 1) * 64, wn = (wave & 1) * 64;
    int lm = lane & 15, quad = lane >> 4;
    floatx4 acc[4][4] = {};
    int sRow = tid >> 1, sCol = (tid & 1) * 16;      // 16 fp32 per thread per tile
    const float* ag = A  + (long)(bm + sRow) * lda + sCol;
    const float* bg = WT + (long)(bn + sRow) * K   + sCol;
    for (int k0 = 0; k0 < K; k0 += BK) {
        #pragma unroll
        for (int i = 0; i < 4; i++) {
            float4 v = *(const float4*)(ag + k0 + i * 4);
            bf16 h0 = __float2bfloat16(v.x), h1 = __float2bfloat16(v.y);
            bf16 h2 = __float2bfloat16(v.z), h3 = __float2bfloat16(v.w);
            bf16 l0 = __float2bfloat16(v.x - bf2f(h0));
            bf16 l1 = __float2bfloat16(v.y - bf2f(h1));
            bf16 l2 = __float2bfloat16(v.z - bf2f(h2));
            bf16 l3 = __float2bfloat16(v.w - bf2f(h3));
            ushort4 hv = {bfbits(h0), bfbits(h1), bfbits(h2), bfbits(h3)};
            ushort4 lv = {bfbits(l0), bfbits(l1), bfbits(l2), bfbits(l3)};
            *(ushort4*)&Ah[sRow][sCol + i * 4] = hv;
            *(ushort4*)&Al[sRow][sCol + i * 4] = lv;
        }
        #pragma unroll
        for (int i = 0; i < 4; i++) {
            float4 v = *(const float4*)(bg + k0 + i * 4);
            bf16 h0 = __float2bfloat16(v.x), h1 = __float2bfloat16(v.y);
            bf16 h2 = __float2bfloat16(v.z), h3 = __float2bfloat16(v.w);
            bf16 l0 = __float2bfloat16(v.x - bf2f(h0));
            bf16 l1 = __float2bfloat16(v.y - bf2f(h1));
            bf16 l2 = __float2bfloat16(v.z - bf2f(h2));
            bf16 l3 = __float2bfloat16(v.w - bf2f(h3));
            ushort4 hv = {bfbits(h0), bfbits(h1), bfbits(h2), bfbits(h3)};
            ushort4 lv = {bfbits(l0), bfbits(l1), bfbits(l2), bfbits(l3)};
            *(ushort4*)&Bh[sRow][sCol + i * 4] = hv;
            *(ushort4*)&Bl[sRow][sCol + i * 4] = lv;
        }
        __syncthreads();
        short8 ahf[4], alf[4], bhf[4], blf[4];
        #pragma unroll
        for (int mi = 0; mi < 4; mi++) {
            ahf[mi] = *(const short8*)&Ah[wm + mi * 16 + lm][quad * 8];
            alf[mi] = *(const short8*)&Al[wm + mi * 16 + lm][quad * 8];
        }
        #pragma unroll
        for (int ni = 0; ni < 4; ni++) {
            bhf[ni] = *(const short8*)&Bh[wn + ni * 16 + lm][quad * 8];
            blf[ni] = *(const short8*)&Bl[wn + ni * 16 + lm][quad * 8];
        }
        #pragma unroll
        for (int mi = 0; mi < 4; mi++)
            #pragma unroll
            for (int ni = 0; ni < 4; ni++) {
                acc[mi][ni] = __builtin_amdgcn_mfma_f32_16x16x32_bf16(ahf[mi], bhf[ni], acc[mi][ni], 0, 0, 0);
                acc[mi][ni] = __builtin_amdgcn_mfma_f32_16x16x32_bf16(ahf[mi], blf[ni], acc[mi][ni], 0, 0, 0);
                acc[mi][ni] = __builtin_amdgcn_mfma_f32_16x16x32_bf16(alf[mi], bhf[ni], acc[mi][ni], 0, 0, 0);
            }
        __syncthreads();
    }
    bool f32f = DF[0] != 0;
    bool bF = (bTag == TAG_F32) || (bTag == TAG_AUTO && f32f);
    #pragma unroll
    for (int ni = 0; ni < 4; ni++) {
        int col = bn + wn + ni * 16 + lm;
        float cb = bias ? ld1auto(bias, biasOff + col, bF) : 0.f;
        #pragma unroll
        for (int mi = 0; mi < 4; mi++) {
            #pragma unroll
            for (int reg = 0; reg < 4; reg++) {
                int row = bm + wm + mi * 16 + quad * 4 + reg;
                float v = acc[mi][ni][reg] + cb;
                TC* cp = C + (long)row * ldc + col;
                if (alpha) {
                    const float* al = alpha + (long)(row / rowsPerB) * alphaStride + col;
                    v = ldc1(cp) + al[0] * v;
                }
                stc1(cp, v);
            }
        }
    }
}

template <typename TC>
static void mgemm32(hipStream_t s, const float* A, int lda, const float* WT,
                    TC* C, int ldc, int M, int N, int K,
                    const void* bias, int bTag, long biasOff,
                    const float* alpha, int alphaStride, int rowsPerB, const int* DF) {
    dim3 g(N / 128, M / 128);
    k_mfma32<TC><<<g, 256, 0, s>>>(A, lda, WT, C, ldc, M, N, K,
                                   bias, bTag, biasOff, alpha, alphaStride, rowsPerB, DF);
}

// ---------------- plain bf16 MFMA GEMM (MLP only; post-season-critical) -----
template <typename TC>
__global__ __launch_bounds__(256) void k_mfma(
    const bf16* __restrict__ A, int lda,
    const bf16* __restrict__ WT,
    TC* __restrict__ C, int ldc,
    int M, int N, int K,
    const void* __restrict__ bias, int bTag, int act,
    const float* __restrict__ alpha, int alphaStride, int rowsPerB,
    const int* __restrict__ DF) {
    constexpr int BK = 64, PAD = 8;
    __shared__ bf16 As[128][BK + PAD];
    __shared__ bf16 Bs[128][BK + PAD];
    int tid = threadIdx.x;
    int wave = tid >> 6, lane = tid & 63;
    int bm = blockIdx.y * 128, bn = blockIdx.x * 128;
    int wm = (wave >> 1) * 64, wn = (wave & 1) * 64;
    int lm = lane & 15, quad = lane >> 4;
    floatx4 acc[4][4] = {};
    int sRow = tid >> 1, sCol = (tid & 1) * 32;
    const bf16* ag = A  + (long)(bm + sRow) * lda + sCol;
    const bf16* bg = WT + (long)(bn + sRow) * K   + sCol;
    for (int k0 = 0; k0 < K; k0 += BK) {
        #pragma unroll
        for (int i = 0; i < 4; i++)
            *(float4*)&As[sRow][sCol + i * 8] = *(const float4*)(ag + k0 + i * 8);
        #pragma unroll
        for (int i = 0; i < 4; i++)
            *(float4*)&Bs[sRow][sCol + i * 8] = *(const float4*)(bg + k0 + i * 8);
        __syncthreads();
        #pragma unroll
        for (int kk = 0; kk < BK; kk += 32) {
            short8 af[4], bf[4];
            #pragma unroll
            for (int mi = 0; mi < 4; mi++)
                af[mi] = *(const short8*)&As[wm + mi * 16 + lm][kk + quad * 8];
            #pragma unroll
            for (int ni = 0; ni < 4; ni++)
                bf[ni] = *(const short8*)&Bs[wn + ni * 16 + lm][kk + quad * 8];
            #pragma unroll
            for (int mi = 0; mi < 4; mi++)
                #pragma unroll
                for (int ni = 0; ni < 4; ni++)
                    acc[mi][ni] = __builtin_amdgcn_mfma_f32_16x16x32_bf16(
                        af[mi], bf[ni], acc[mi][ni], 0, 0, 0);
        }
        __syncthreads();
    }
    bool f32f = DF[0] != 0;
    bool bF = (bTag == TAG_F32) || (bTag == TAG_AUTO && f32f);
    #pragma unroll
    for (int ni = 0; ni < 4; ni++) {
        int col = bn + wn + ni * 16 + lm;
        float cb = bias ? ld1auto(bias, col, bF) : 0.f;
        #pragma unroll
        for (int mi = 0; mi < 4; mi++) {
            #pragma unroll
            for (int reg = 0; reg < 4; reg++) {
                int row = bm + wm + mi * 16 + quad * 4 + reg;
                float v = acc[mi][ni][reg] + cb;
                TC* cp = C + (long)row * ldc + col;
                if (alpha) {
                    const float* al = alpha + (long)(row / rowsPerB) * alphaStride + col;
                    v = ldc1(cp) + al[0] * v;
                } else if (act == 1) {
                    v = gelu_f(v);
                }
                stc1(cp, v);
            }
        }
    }
}

template <typename TC>
static void mgemm(hipStream_t s, const bf16* A, int lda, const bf16* WT,
                  TC* C, int ldc, int M, int N, int K,
                  const void* bias, int bTag, int act,
                  const float* alpha, int alphaStride, int rowsPerB, const int* DF) {
    dim3 g(N / 128, M / 128);
    k_mfma<TC><<<g, 256, 0, s>>>(A, lda, WT, C, ldc, M, N, K,
                                 bias, bTag, act, alpha, alphaStride, rowsPerB, DF);
}

// ---------------- generic tiled fp32-VALU GEMM ------------------------------
// Register-prefetch double-buffered: tile k+1's global loads are issued
// right after the store barrier, so HBM/L2 latency hides under the 16x16
// FMA block.  Old: loads sat on the barrier-to-barrier critical path ->
// P gemm 136 us @ VALUBusy 57%.
template <typename TC>
__global__ __launch_bounds__(256) void k_gemm(
    const void* __restrict__ Ab, int aTag, int lda, long bsA,
    const void* __restrict__ Wb, int wTag, int ldw, long bsW,
    TC* __restrict__ Cb, int ldc, long bsC,
    int M, int N, int K,
    const void* __restrict__ bias, int bTag, int biasRow, int act,
    const float* __restrict__ alpha, int alphaStride, int rowsPerB,
    const int* __restrict__ DF) {
    __shared__ float As[16][68];
    __shared__ float Bs[16][68];
    bool f32f = DF[0] != 0;
    bool aF = (aTag == TAG_F32) || (aTag == TAG_AUTO && f32f);
    bool wF = (wTag == TAG_F32) || (wTag == TAG_AUTO && f32f);
    bool bF = (bTag == TAG_F32) || (bTag == TAG_AUTO && f32f);
    TC* Cbase = Cb + (long)blockIdx.z * bsC;
    long aBase = (long)blockIdx.z * bsA;
    long wBase = (long)blockIdx.z * bsW;
    int tid = threadIdx.x;
    int bm = blockIdx.y, bn = blockIdx.x;
    int tx = tid & 15, ty = tid >> 4;
    int arow = tid >> 2, acol = (tid & 3) * 4;
    int wrow = tid >> 4, wcol = (tid & 15) * 4;
    int gArow = bm * 64 + arow;
    bool aValid = gArow < M;
    float acc[4][4] = {};
    float4 av = {0.f, 0.f, 0.f, 0.f};
    if (aValid) av = load4auto(Ab, aBase + (long)gArow * lda + acol, aF);
    float4 wv = load4auto(Wb, wBase + (long)wrow * ldw + bn * 64 + wcol, wF);
    for (int kk = 0; kk < K; kk += 16) {
        As[acol + 0][arow] = av.x;
        As[acol + 1][arow] = av.y;
        As[acol + 2][arow] = av.z;
        As[acol + 3][arow] = av.w;
        *(float4*)&Bs[wrow][wcol] = wv;
        __syncthreads();
        if (kk + 16 < K) {           // prefetch next tile (overlaps FMA below)
            if (aValid) av = load4auto(Ab, aBase + (long)gArow * lda + kk + 16 + acol, aF);
            wv = load4auto(Wb, wBase + (long)(kk + 16 + wrow) * ldw + bn * 64 + wcol, wF);
        }
        #pragma unroll
        for (int k = 0; k < 16; k++) {
            float4 a4 = *(const float4*)&As[k][ty * 4];
            float4 b4 = *(const float4*)&Bs[k][tx * 4];
            acc[0][0] += a4.x * b4.x; acc[0][1] += a4.x * b4.y; acc[0][2] += a4.x * b4.z; acc[0][3] += a4.x * b4.w;
            acc[1][0] += a4.y * b4.x; acc[1][1] += a4.y * b4.y; acc[1][2] += a4.y * b4.z; acc[1][3] += a4.y * b4.w;
            acc[2][0] += a4.z * b4.x; acc[2][1] += a4.z * b4.y; acc[2][2] += a4.z * b4.z; acc[2][3] += a4.z * b4.w;
            acc[3][0] += a4.w * b4.x; acc[3][1] += a4.w * b4.y; acc[3][2] += a4.w * b4.z; acc[3][3] += a4.w * b4.w;
        }
        __syncthreads();
    }
    int gcol = bn * 64 + tx * 4;
    float cb[4] = {0.f, 0.f, 0.f, 0.f};
    if (bias && !biasRow) {
        #pragma unroll
        for (int j = 0; j < 4; j++) cb[j] = ld1auto(bias, gcol + j, bF);
    }
    #pragma unroll
    for (int i = 0; i < 4; i++) {
        int grow = bm * 64 + ty * 4 + i;
        if (grow >= M) continue;
        float rb = (bias && biasRow) ? ld1auto(bias, grow, bF) : 0.f;
        TC* crow = Cbase + (long)grow * ldc + gcol;
        const float* al = nullptr;
        if (alpha) al = alpha + (long)(grow / rowsPerB) * alphaStride + gcol;
        #pragma unroll
        for (int j = 0; j < 4; j++) {
            float v = acc[i][j] + cb[j] + rb;
            if (alpha)         v = ldc1(crow + j) + al[j] * v;
            else if (act == 1) v = gelu_f(v);
            stc1(crow + j, v);
        }
    }
}

template <typename TC>
static void gemm(hipStream_t s, const void* A, int aTag, int lda, long bsA,
                 const void* W, int wTag, int ldw, long bsW,
                 TC* C, int ldc, long bsC, int M, int N, int K,
                 const void* bias, int bTag, int biasRow, int act,
                 const float* alpha, int alphaStride, int rowsPerB, int batch,
                 const int* DF) {
    dim3 g(N / 64, (M + 63) / 64, batch);
    k_gemm<TC><<<g, 256, 0, s>>>(A, aTag, lda, bsA, W, wTag, ldw, bsW, C, ldc, bsC,
                                 M, N, K, bias, bTag, biasRow, act,
                                 alpha, alphaStride, rowsPerB, DF);
}

// ---------------- agent attention stage 1 -----------------------------------
// 4-agents-per-block + vectorized PV rewrite.
// Old: 1 agent/block (8192 blocks), scalar 2B V loads, 128-iter dependent
// FMA chain -> 140 us @ VALUBusy 27% / HBM 6% (latency-bound, 4x overfetch).
// New: 2048 blocks; K/V bytes read exactly once per block (4x less traffic
// and 4x fewer loads/FLOP); PV uses float4 loads feeding 16 FMAs each with
// 32-long chains x4-agent ILP; 16-way LDS tree reduce.
__global__ __launch_bounds__(256) void k_agatt1(const float* __restrict__ qa,
                                                const bf16* __restrict__ ka,
                                                const bf16* __restrict__ va,
                                                float* __restrict__ c1) {
    constexpr int AQ = 4;
    int blk = blockIdx.x;
    int aq = blk % (kA / AQ);
    int h = (blk / (kA / AQ)) % kH;
    int b = blk / ((kA / AQ) * kH);
    int ag0 = aq * AQ;
    __shared__ float qs[AQ][kHS];
    __shared__ float probs[AQ][kT];
    __shared__ float red[16][AQ * 68];
    __shared__ float sred[32];
    int tid = threadIdx.x;
    {
        int ag = tid >> 6, d = tid & 63;
        qs[ag][d] = qa[((long)h * kA + ag0 + ag) * kHS + d];
    }
    __syncthreads();
    const bf16* kab = ka + ((long)h * kB + b) * kT * kHS;
    float sc[2][AQ];
    #pragma unroll
    for (int rep = 0; rep < 2; rep++) {
        const bf16* kr = kab + (long)(tid + rep * 256) * kHS;
        float a0 = 0.f, a1 = 0.f, a2 = 0.f, a3 = 0.f;
        #pragma unroll
        for (int d = 0; d < kHS; d += 4) {
            float4 k4 = load4bf(kr + d);
            float4 q0 = *(const float4*)&qs[0][d];
            float4 q1 = *(const float4*)&qs[1][d];
            float4 q2 = *(const float4*)&qs[2][d];
            float4 q3 = *(const float4*)&qs[3][d];
            a0 += k4.x * q0.x + k4.y * q0.y + k4.z * q0.z + k4.w * q0.w;
            a1 += k4.x * q1.x + k4.y * q1.y + k4.z * q1.z + k4.w * q1.w;
            a2 += k4.x * q2.x + k4.y * q2.y + k4.z * q2.z + k4.w * q2.w;
            a3 += k4.x * q3.x + k4.y * q3.y + k4.z * q3.z + k4.w * q3.w;
        }
        sc[rep][0] = a0 * 0.125f; sc[rep][1] = a1 * 0.125f;
        sc[rep][2] = a2 * 0.125f; sc[rep][3] = a3 * 0.125f;
    }
    int w = tid >> 6;
    float mx[AQ], ss[AQ];
    #pragma unroll
    for (int ag = 0; ag < AQ; ag++) mx[ag] = fmaxf(sc[0][ag], sc[1][ag]);
    #pragma unroll
    for (int m = 32; m > 0; m >>= 1)
        #pragma unroll
        for (int ag = 0; ag < AQ; ag++) mx[ag] = fmaxf(mx[ag], __shfl_down(mx[ag], m));
    if ((tid & 63) == 0)
        #pragma unroll
        for (int ag = 0; ag < AQ; ag++) sred[w * 4 + ag] = mx[ag];
    __syncthreads();
    #pragma unroll
    for (int ag = 0; ag < AQ; ag++)
        mx[ag] = fmaxf(fmaxf(sred[ag], sred[4 + ag]), fmaxf(sred[8 + ag], sred[12 + ag]));
    float e0[AQ], e1[AQ];
    #pragma unroll
    for (int ag = 0; ag < AQ; ag++) {
        e0[ag] = expf(sc[0][ag] - mx[ag]);
        e1[ag] = expf(sc[1][ag] - mx[ag]);
        ss[ag] = e0[ag] + e1[ag];
    }
    #pragma unroll
    for (int m = 32; m > 0; m >>= 1)
        #pragma unroll
        for (int ag = 0; ag < AQ; ag++) ss[ag] += __shfl_down(ss[ag], m);
    if ((tid & 63) == 0)
        #pragma unroll
        for (int ag = 0; ag < AQ; ag++) sred[16 + w * 4 + ag] = ss[ag];
    __syncthreads();
    #pragma unroll
    for (int ag = 0; ag < AQ; ag++) {
        float tot = sred[16 + ag] + sred[20 + ag] + sred[24 + ag] + sred[28 + ag];
        float rs = 1.f / tot;
        probs[ag][tid] = e0[ag] * rs;
        probs[ag][tid + 256] = e1[ag] * rs;
    }
    __syncthreads();
    // PV: dg = d-quad 0..15 (4 d's), nc = n-chunk 0..15 (32 n's)
    int dg = tid & 15, nc = tid >> 4;
    const bf16* vab = va + ((long)h * kB + b) * kT * kHS;
    float4 acc[AQ] = {};
    for (int s = 0; s < 32; s++) {
        int n = nc * 32 + s;
        float4 v = load4bf(vab + (long)n * kHS + dg * 4);
        #pragma unroll
        for (int ag = 0; ag < AQ; ag++) {
            float p = probs[ag][n];
            acc[ag].x += p * v.x; acc[ag].y += p * v.y;
            acc[ag].z += p * v.z; acc[ag].w += p * v.w;
        }
    }
    #pragma unroll
    for (int ag = 0; ag < AQ; ag++)
        *(float4*)&red[nc][ag * 68 + dg * 4] = acc[ag];
    __syncthreads();
    {
        int ag = tid >> 6, d = tid & 63;
        float s = 0.f;
        #pragma unroll
        for (int n2 = 0; n2 < 16; n2++) s += red[n2][ag * 68 + d];
        c1[(((long)b * kH + h) * kA + ag0 + ag) * kHS + d] = s;
    }
}

// ---------------- agent attention stage 2 (fp32 in/out) ----------------------
__global__ __launch_bounds__(256) void k_agatt2f(const float* __restrict__ qsrc, int ldq,
                                                 const float* __restrict__ c1,
                                                 float* __restrict__ out) {
    int blk = blockIdx.x;
    int nt = blk % (kT / 16);
    int h = (blk / (kT / 16)) % kH;
    int b = blk / ((kT / 16) * kH);
    __shared__ float c1s[kA][kHS + 1];
    __shared__ float qs[16][kHS + 1];
    __shared__ float ps[16][kA + 1];
    int tid = threadIdx.x;
    const float* c1b = c1 + ((long)b * kH + h) * kA * kHS;
    for (int i = tid; i < kA * kHS; i += 256) c1s[i >> 6][i & 63] = c1b[i];
    int n0 = nt * 16;
    {
        int r = tid >> 4, d = (tid & 15) * 4;
        float4 q4 = load4f(qsrc + (long)(b * kT + n0 + r) * ldq + h * kHS + d);
        qs[r][d] = q4.x; qs[r][d + 1] = q4.y; qs[r][d + 2] = q4.z; qs[r][d + 3] = q4.w;
    }
    __syncthreads();
    int r = tid >> 4, c = tid & 15;
    float sc[4];
    #pragma unroll
    for (int j = 0; j < 4; j++) {
        int a = c * 4 + j;
        float acc = 0.f;
        for (int d = 0; d < kHS; d++) acc += qs[r][d] * c1s[a][d];
        sc[j] = acc * 0.125f;
    }
    float mx = fmaxf(fmaxf(sc[0], sc[1]), fmaxf(sc[2], sc[3]));
    for (int m = 1; m < 16; m <<= 1) mx = fmaxf(mx, __shfl_xor(mx, m));
    float e[4], ss = 0.f;
    #pragma unroll
    for (int j = 0; j < 4; j++) { e[j] = expf(sc[j] - mx); ss += e[j]; }
    for (int m = 1; m < 16; m <<= 1) ss += __shfl_xor(ss, m);
    float rs = 1.f / ss;
    #pragma unroll
    for (int j = 0; j < 4; j++) ps[r][c * 4 + j] = e[j] * rs;
    __syncthreads();
    float o0 = 0.f, o1 = 0.f, o2 = 0.f, o3 = 0.f;
    int d0 = c * 4;
    for (int a = 0; a < kA; a++) {
        float p = ps[r][a];
        o0 += p * c1s[a][d0 + 0];
        o1 += p * c1s[a][d0 + 1];
        o2 += p * c1s[a][d0 + 2];
        o3 += p * c1s[a][d0 + 3];
    }
    float* orow = out + (long)(b * kT + n0 + r) * kE + h * kHS + d0;
    orow[0] = o0; orow[1] = o1; orow[2] = o2; orow[3] = o3;
}

// ---------------- DFT tables --------------------------------------------------
__global__ void k_trig(float* __restrict__ trig) {
    int id = blockIdx.x * 256 + threadIdx.x;
    if (id >= kNFREQ * kT) return;
    int t = id & 511;
    int f = (id >> 9) + 1;
    int m = (f * t) & 511;
    double ang = (double)m * (2.0 * 3.14159265358979323846 / 512.0);
    trig[id] = (float)cos(ang);
    trig[kNFREQ * kT + id] = (float)(-sin(ang));
}

// ---------------- top-5 |X_f|^2 per (b,e) column ------------------------------
// f-parallel rewrite: 16 threads per column each scan a 16-frequency chunk
// keeping a private top-5; partials merge via LDS.  Tie-break (v==, lower f
// wins) reproduces jax.lax.top_k stable semantics independent of merge order.
// Old: 32 blocks, serial 255-iter scan -> 207 us @ 1.4% occupancy.
__global__ __launch_bounds__(256) void k_topk(const float* __restrict__ RE, const float* __restrict__ IM,
                                              float* __restrict__ tre, float* __restrict__ tim,
                                              int* __restrict__ tix) {
    int tid = threadIdx.x;
    int c = tid & 15;                       // column within block
    int j = tid >> 4;                       // f-group 0..15
    int colId = blockIdx.x * 16 + c;        // 0..8191
    int b = colId >> 10, e = colId & 1023;
    const float* rp = RE + (long)b * kNFREQ * kE + e;
    const float* ip = IM + (long)b * kNFREQ * kE + e;
    float bv[kKTOP] = {-1e30f, -1e30f, -1e30f, -1e30f, -1e30f};
    int bi[kKTOP] = {1 << 30, 1 << 30, 1 << 30, 1 << 30, 1 << 30};
    #pragma unroll
    for (int s = 0; s < 16; s++) {
        int fq = j * 16 + s;
        if (fq >= kNFREQ) break;
        float re = rp[(long)fq * kE], im = ip[(long)fq * kE];
        float m2 = re * re + im * im;
        if (m2 > bv[kKTOP - 1] || (m2 == bv[kKTOP - 1] && fq < bi[kKTOP - 1])) {
            int p = kKTOP - 1;
            while (p > 0 && (m2 > bv[p - 1] || (m2 == bv[p - 1] && fq < bi[p - 1]))) {
                bv[p] = bv[p - 1]; bi[p] = bi[p - 1]; p--;
            }
            bv[p] = m2; bi[p] = fq;
        }
    }
    __shared__ float sv[16][16][kKTOP];
    __shared__ int   si[16][16][kKTOP];
    #pragma unroll
    for (int q = 0; q < kKTOP; q++) { sv[c][j][q] = bv[q]; si[c][j][q] = bi[q]; }
    __syncthreads();
    if (j == 0) {
        for (int jj = 1; jj < 16; jj++) {
            #pragma unroll
            for (int q = 0; q < kKTOP; q++) {
                float v = sv[c][jj][q];
                int fq = si[c][jj][q];
                if (v > bv[kKTOP - 1] || (v == bv[kKTOP - 1] && fq < bi[kKTOP - 1])) {
                    int p = kKTOP - 1;
                    while (p > 0 && (v > bv[p - 1] || (v == bv[p - 1] && fq < bi[p - 1]))) {
                        bv[p] = bv[p - 1]; bi[p] = bi[p - 1]; p--;
                    }
                    bv[p] = v; bi[p] = fq;
                }
            }
        }
        #pragma unroll
        for (int q = 0; q < kKTOP; q++) {
            int fq = bi[q];
            tre[(long)colId * kKTOP + q] = rp[(long)fq * kE];
            tim[(long)colId * kKTOP + q] = ip[(long)fq * kE];
            tix[(long)colId * kKTOP + q] = fq;
        }
    }
}

__global__ void k_season(const float* __restrict__ tre, const float* __restrict__ tim,
                         const int* __restrict__ tix, const float* __restrict__ trig,
                         void* __restrict__ out, long obase, const int* __restrict__ DF) {
    bool f32o = DF[0] != 0;
    long id = (long)blockIdx.x * 256 + threadIdx.x;
    int e = id & 1023;
    long bt = id >> 10;
    int t = (int)(bt & 511);
    int b = (int)(bt >> 9);
    long be = (long)b * kE + e;
    float acc = 0.f;
    #pragma unroll
    for (int j = 0; j < kKTOP; j++) {
        int f = tix[be * kKTOP + j];
        acc += tre[be * kKTOP + j] * trig[(long)f * kT + t]
             + tim[be * kKTOP + j] * trig[(long)kNFREQ * kT + (long)f * kT + t];
    }
    st1auto(out, obase + id, f32o, 2.f * acc);
}

// ---------------- trend branch ------------------------------------------------
// conv1 re-parallelized: grid = (b,o) x 8 l-tiles = 192 blocks.  Weight slab
// w[o,:,:] (6 KB) staged in LDS once; each thread owns one l of a 128-wide
// tile and half the i-range; 2-way LDS reduce.  Old: 96 blocks, 512-iter
// serial loop with per-iter scalar weight loads -> 224 us @ 4.2% occupancy.
__global__ __launch_bounds__(256) void k_conv1(const float* __restrict__ P,
                                               const void* __restrict__ w,
                                               const void* __restrict__ bias,
                                               float* __restrict__ G,
                                               const int* __restrict__ DF) {
    bool f = DF[0] != 0;
    int bo = blockIdx.x;                 // 0..23 -> (b,o)
    int lt = blockIdx.y;                 // 0..7  -> 128-l tile
    int o = bo % 3, b = bo / 3;
    int tid = threadIdx.x;
    __shared__ float ws[512][3];         // 6 KB weight slab for this o
    for (int idx = tid; idx < 512 * 3; idx += 256)
        ws[idx / 3][idx % 3] = ld1auto(w, (long)o * 512 * 3 + idx, f);
    __syncthreads();
    int l = lt * 128 + (tid & 127);
    int ih = (tid >> 7) * 256;           // 0 or 256
    const float* xb = P + (long)b * kT2 * kE;
    float acc = 0.f;
    for (int ii = 0; ii < 256; ii++) {
        int i = ih + ii;
        const float* xr = xb + (long)i * kE + l;
        float xm = (l > 0)    ? xr[-1] : 0.f;
        float xc = xr[0];
        float xp = (l < 1023) ? xr[1]  : 0.f;
        acc += xm * ws[i][0] + xc * ws[i][1] + xp * ws[i][2];
    }
    __shared__ float red[128];
    if (tid >= 128) red[tid - 128] = acc;
    __syncthreads();
    if (tid < 128) {
        float tot = acc + red[tid] + ld1auto(bias, o, f);
        G[((long)b * 3 + o) * 1024 + l] = gelu_f(tot);
    }
}

// conv2 re-parallelized: one workgroup per (b,n) output pair (512 blocks),
// 256 threads stride over i, 3 pp-partials in registers, block-reduce.
// Old version: 6 blocks, serial 3072-iter scalar loop -> 489 us @ 0.3% occupancy.
__global__ __launch_bounds__(256) void k_conv2(const float* __restrict__ G,
                                               const void* __restrict__ w,
                                               const void* __restrict__ bias,
                                               float* __restrict__ H2,
                                               const int* __restrict__ DF) {
    bool f = DF[0] != 0;
    int n = blockIdx.x % kNF;
    int b = blockIdx.x / kNF;
    int tid = threadIdx.x;
    const float* Gb = G + (long)b * 3 * 1024;
    // valid (pp, k -> l = pp + k - 1) combos:
    // pp=0: g[0]*w[1] + g[1]*w[2]
    // pp=1: g[0]*w[0] + g[1]*w[1] + g[2]*w[2]
    // pp=2: g[1]*w[0] + g[2]*w[1]
    float a0 = 0.f, a1 = 0.f, a2 = 0.f;
    for (int i = tid; i < 1024; i += 256) {
        float g0 = Gb[i], g1 = Gb[1024 + i], g2 = Gb[2048 + i];
        long wo = ((long)n * 1024 + i) * 3;
        float w0 = ld1auto(w, wo + 0, f);
        float w1 = ld1auto(w, wo + 1, f);
        float w2 = ld1auto(w, wo + 2, f);
        a0 += g0 * w1 + g1 * w2;
        a1 += g0 * w0 + g1 * w1 + g2 * w2;
        a2 += g1 * w0 + g2 * w1;
    }
    __shared__ float sm[12];
    #pragma unroll
    for (int m = 32; m > 0; m >>= 1) {
        a0 += __shfl_down(a0, m);
        a1 += __shfl_down(a1, m);
        a2 += __shfl_down(a2, m);
    }
    int wv = tid >> 6;
    if ((tid & 63) == 0) { sm[wv] = a0; sm[4 + wv] = a1; sm[8 + wv] = a2; }
    __syncthreads();
    if (tid == 0) {
        float cb = ld1auto(bias, n, f);
        float* hp = H2 + ((long)b * kNF + n) * 3;
        hp[0] = cb + sm[0] + sm[1] + sm[2] + sm[3];
        hp[1] = cb + sm[4] + sm[5] + sm[6] + sm[7];
        hp[2] = cb + sm[8] + sm[9] + sm[10] + sm[11];
    }
}

__global__ void k_trend(const float* __restrict__ H2, void* __restrict__ out, long obase,
                        const int* __restrict__ DF) {
    bool f32o = DF[0] != 0;
    int id = blockIdx.x * 256 + threadIdx.x;
    int n = id % kNF;
    int t = (id / kNF) % kT;
    int b = id / (kNF * kT);
    float lin = (float)(t + 1) / 513.0f;
    const float* h = H2 + ((long)b * kNF + n) * 3;
    float l2 = lin * lin;
    st1auto(out, obase + id, f32o, h[0] * lin + h[1] * l2 + h[2] * l2 * lin);
}

// ---------------- finals -------------------------------------------------------
__global__ void k_mean(const float* __restrict__ X, float* __restrict__ m) {
    int id = blockIdx.x * 256 + threadIdx.x;
    int b = id >> 10, e = id & 1023;
    const float* p = X + (long)b * kT * kE + e;
    float s = 0.f;
    for (int t = 0; t < kT; t++) s += p[(long)t * kE];
    m[id] = s * (1.f / kT);
}

__global__ void k_out0(const float* __restrict__ X, const float* __restrict__ m,
                       void* __restrict__ out, long obase, const int* __restrict__ DF) {
    bool f32o = DF[0] != 0;
    long id = (long)blockIdx.x * 256 + threadIdx.x;
    int e = id & 1023;
    int b = (int)(id >> 19);
    st1auto(out, obase + id, f32o, X[id] - m[b * kE + e]);
}

// out1 re-parallelized: one block per batch b (8 blocks); thread = (n, e-slice).
// Coalesced-in-n w loads, 4-way LDS reduce.  Old: 2 blocks, 1024 serial
// column-strided scalar loads per thread -> 125 us @ 0.09% occupancy.
__global__ __launch_bounds__(256) void k_out1(const float* __restrict__ m,
                                              const void* __restrict__ w,
                                              const void* __restrict__ bias,
                                              void* __restrict__ out, long obase,
                                              const int* __restrict__ DF) {
    bool f = DF[0] != 0;
    int b = blockIdx.x;                  // 0..7
    int tid = threadIdx.x;
    int n = tid & 63, es = tid >> 6;     // 4 e-slices of 256
    const float* mb = m + (long)b * kE;
    float acc = 0.f;
    for (int e = es * 256; e < es * 256 + 256; e++)
        acc += mb[e] * ld1auto(w, (long)e * kNF + n, f);
    __shared__ float sm[4][64];
    sm[es][n] = acc;
    __syncthreads();
    if (tid < 64) {
        float tot = sm[0][tid] + sm[1][tid] + sm[2][tid] + sm[3][tid]
                  + ld1auto(bias, tid, f);
        st1auto(out, obase + (long)b * kNF + tid, f, tot);
    }
}

// ---------------- launch -------------------------------------------------------
extern "C" void kernel_launch(void* const* d_in, const int* in_sizes, int n_in,
                              void* d_out, int out_size, void* d_ws, size_t ws_size,
                              hipStream_t stream) {
    (void)in_sizes; (void)n_in; (void)out_size; (void)ws_size;
    const void* x_in = d_in[0];
    const void* enc  = d_in[1];
    const int* tstep = (const int*)d_in[2];
    const void *ln1_w = d_in[3],  *ln1_b = d_in[4],  *ln11_w = d_in[5], *ln11_b = d_in[6];
    const void *ln2_w = d_in[7],  *ln2_b = d_in[8];
    const void *a1_qkv_w = d_in[9], *a1_qkv_b = d_in[10];
    const void *a1_agq_w = d_in[11], *a1_agq_b = d_in[12];
    const void *a1_agk_w = d_in[13], *a1_agk_b = d_in[14];
    const void *a1_agv_w = d_in[15], *a1_agv_b = d_in[16];
    const void *a1_ago_w = d_in[17], *a1_ago_b = d_in[18];
    const void *a1_agents = d_in[19];
    const void *a1_proj_w = d_in[20], *a1_proj_b = d_in[21];
    const void *a2_q_w = d_in[22], *a2_q_b = d_in[23];
    const void *a2_kv_w = d_in[24], *a2_kv_b = d_in[25];
    const void *a2_agq_w = d_in[26], *a2_agq_b = d_in[27];
    const void *a2_agk_w = d_in[28], *a2_agk_b = d_in[29];
    const void *a2_agv_w = d_in[30], *a2_agv_b = d_in[31];
    const void *a2_ago_w = d_in[32], *a2_ago_b = d_in[33];
    const void *a2_agents = d_in[34];
    const void *a2_proj_w = d_in[35], *a2_proj_b = d_in[36];
    const void *tr_c1_w = d_in[37], *tr_c1_b = d_in[38];
    const void *tr_c2_w = d_in[39], *tr_c2_b = d_in[40];
    const void *mlp_w1 = d_in[41], *mlp_b1 = d_in[42];
    const void *mlp_w2 = d_in[43], *mlp_b2 = d_in[44];
    const void *pr_w = d_in[45], *pr_b = d_in[46];
    const void *lin_w = d_in[47], *lin_b = d_in[48];

    char* wsb = (char*)d_ws;
    float* XC = (float*)(wsb + BOFF_XC);
    float* SM = (float*)(wsb + BOFF_SMALL);
    float* TS = SM + F_TS;
    float* AD1 = SM + F_AD1;
    float* AD11 = SM + F_AD11;
    float* AD2 = SM + F_AD2;
    float* QA = SM + F_QA;
    float* C1 = SM + F_C1;
    float* H2 = SM + F_H2;
    float* G1 = SM + F_G1;
    float* MB = SM + F_MB;
    float* TRE = SM + F_TRE;
    float* TIM = SM + F_TIM;
    int*   TIX = (int*)(SM + F_TIX);
    float* TRIG = SM + F_TRIG;
    int* DF = (int*)(wsb + BOFF_FLAG);
    char* WR = wsb + BOFF_WREG;
    float* WTQ  = (float*)(WR + WR_Q);
    float* WTKV = (float*)(WR + WR_KV);
    float* WAGO = (float*)(WR + WR_AGO);
    float* WPRJ = (float*)(WR + WR_PRJ);
    bf16*  W1B  = (bf16*)(WR + WR_W1);
    bf16*  W2B  = (bf16*)(WR + WR_W2);
    char* AC = wsb + BOFF_ACT;
    float* N1F  = (float*)(AC + AC_N1);     // also ENCF
    float* QBUF = (float*)(AC + AC_QBUF);
    float* KVB  = (float*)(AC + AC_KV);
    bf16*  KA   = (bf16*)(AC + AC_KA);
    bf16*  VA   = (bf16*)(AC + AC_VA);
    float* ATTF = (float*)(AC + AC_ATT);
    float* Y2F  = (float*)(AC + AC_Y2);
    float* P    = (float*)(AC + AC_P);
    float* RE   = (float*)(AC + AC_RE);
    float* IM   = (float*)(AC + AC_IM);
    bf16*  N1B  = (bf16*)(AC + AC_N1B);
    bf16*  HID  = (bf16*)(AC + AC_HID);

    const int M_BT = kB * kT;                      // 4096
    const long bsKA = (long)kB * kT * kHS;

    // 0) dtype detection (precedes all d_in consumers)
    k_detect<<<1, 256, 0, stream>>>((const unsigned short*)x_in, DF);

    // phase-1 weight transposes (fp32)
    k_wtf<<<dim3(1024/32, 1024/32), 256, 0, stream>>>(a1_qkv_w, WTQ, 1024, 3072, 0, DF);
    k_wtf<<<dim3(2048/32, 1024/32), 256, 0, stream>>>(a1_qkv_w, WTKV, 1024, 3072, 1024, DF);
    k_wtf<<<dim3(1024/32, 1024/32), 256, 0, stream>>>(a1_ago_w, WAGO, 1024, 1024, 0, DF);
    k_wtf<<<dim3(1024/32, 1024/32), 256, 0, stream>>>(a1_proj_w, WPRJ, 1024, 1024, 0, DF);

    // prologue
    k_temb<<<kB, 512, 0, stream>>>(tstep, TS);
    gemm(stream, TS, TAG_F32, kE, 0L, ln1_w, TAG_AUTO, 3 * kE, 0L, AD1, 3 * kE, 0L,
         kB, 3 * kE, kE, ln1_b, TAG_AUTO, 0, 0, nullptr, 0, 1, 1, DF);
    gemm(stream, TS, TAG_F32, kE, 0L, ln11_w, TAG_AUTO, 3 * kE, 0L, AD11, 3 * kE, 0L,
         kB, 3 * kE, kE, ln11_b, TAG_AUTO, 0, 0, nullptr, 0, 1, 1, DF);
    gemm(stream, TS, TAG_F32, kE, 0L, ln2_w, TAG_AUTO, 3 * kE, 0L, AD2, 3 * kE, 0L,
         kB, 3 * kE, kE, ln2_b, TAG_AUTO, 0, 0, nullptr, 0, 1, 1, DF);
    k_castin<<<(kB * kT * kE) / 1024, 256, 0, stream>>>(x_in, XC, DF);
    k_trig<<<(kNFREQ * kT + 255) / 256, 256, 0, stream>>>(TRIG);

    // ---- attention block 1 (self), fp32 end-to-end via split MFMA ----
    k_adalnf<<<M_BT, 256, 0, stream>>>(XC, AD1, N1F);
    mgemm32(stream, N1F, kE, WTQ, QBUF, kE, M_BT, kE, kE,
            a1_qkv_b, TAG_AUTO, 0L, nullptr, 0, 1, DF);
    mgemm32(stream, N1F, kE, WTKV, KVB, 2 * kE, M_BT, 2 * kE, kE,
            a1_qkv_b, TAG_AUTO, (long)kE, nullptr, 0, 1, DF);
    gemm(stream, a1_agents, TAG_AUTO, kHS, 0L, a1_agq_w, TAG_AUTO, kHS, 0L, QA, kHS, 0L,
         kH * kA, kHS, kHS, a1_agq_b, TAG_AUTO, 0, 0, nullptr, 0, 1, 1, DF);
    gemm(stream, KVB, TAG_F32, 2 * kE, 64L, a1_agk_w, TAG_AUTO, kHS, 0L, KA, kHS, bsKA,
         M_BT, kHS, kHS, a1_agk_b, TAG_AUTO, 0, 0, nullptr, 0, 1, kH, DF);
    gemm(stream, KVB + kE, TAG_F32, 2 * kE, 64L, a1_agv_w, TAG_AUTO, kHS, 0L, VA, kHS, bsKA,
         M_BT, kHS, kHS, a1_agv_b, TAG_AUTO, 0, 0, nullptr, 0, 1, kH, DF);
    k_agatt1<<<kB * kH * (kA / 4), 256, 0, stream>>>(QA, KA, VA, C1);
    k_agatt2f<<<kB * kH * (kT / 16), 256, 0, stream>>>(QBUF, kE, C1, ATTF);
    mgemm32(stream, ATTF, kE, WAGO, Y2F, kE, M_BT, kE, kE,
            a1_ago_b, TAG_AUTO, 0L, nullptr, 0, 1, DF);
    mgemm32(stream, Y2F, kE, WPRJ, XC, kE, M_BT, kE, kE,
            a1_proj_b, TAG_AUTO, 0L, AD1 + 2 * kE, 3 * kE, kT, DF);

    // phase-2 weight transposes (WREG safely reusable after prj1)
    k_wtf<<<dim3(1024/32, 1024/32), 256, 0, stream>>>(a2_q_w, WTQ, 1024, 1024, 0, DF);
    k_wtf<<<dim3(2048/32, 1024/32), 256, 0, stream>>>(a2_kv_w, WTKV, 1024, 2048, 0, DF);
    k_wtf<<<dim3(1024/32, 1024/32), 256, 0, stream>>>(a2_ago_w, WAGO, 1024, 1024, 0, DF);
    k_wtf<<<dim3(1024/32, 1024/32), 256, 0, stream>>>(a2_proj_w, WPRJ, 1024, 1024, 0, DF);

    // ---- attention block 2 (cross) ----
    k_castin<<<(kB * kT * kE) / 1024, 256, 0, stream>>>(enc, N1F, DF);   // ENCF in N1F slot
    mgemm32(stream, N1F, kE, WTKV, KVB, 2 * kE, M_BT, 2 * kE, kE,
            a2_kv_b, TAG_AUTO, 0L, nullptr, 0, 1, DF);
    k_adalnf<<<M_BT, 256, 0, stream>>>(XC, AD11, N1F);                    // overwrites ENCF (dead)
    mgemm32(stream, N1F, kE, WTQ, QBUF, kE, M_BT, kE, kE,
            a2_q_b, TAG_AUTO, 0L, nullptr, 0, 1, DF);
    gemm(stream, a2_agents, TAG_AUTO, kHS, 0L, a2_agq_w, TAG_AUTO, kHS, 0L, QA, kHS, 0L,
         kH * kA, kHS, kHS, a2_agq_b, TAG_AUTO, 0, 0, nullptr, 0, 1, 1, DF);
    gemm(stream, KVB, TAG_F32, 2 * kE, 64L, a2_agk_w, TAG_AUTO, kHS, 0L, KA, kHS, bsKA,
         M_BT, kHS, kHS, a2_agk_b, TAG_AUTO, 0, 0, nullptr, 0, 1, kH, DF);
    gemm(stream, KVB + kE, TAG_F32, 2 * kE, 64L, a2_agv_w, TAG_AUTO, kHS, 0L, VA, kHS, bsKA,
         M_BT, kHS, kHS, a2_agv_b, TAG_AUTO, 0, 0, nullptr, 0, 1, kH, DF);
    k_agatt1<<<kB * kH * (kA / 4), 256, 0, stream>>>(QA, KA, VA, C1);
    k_agatt2f<<<kB * kH * (kT / 16), 256, 0, stream>>>(QBUF, kE, C1, ATTF);
    mgemm32(stream, ATTF, kE, WAGO, Y2F, kE, M_BT, kE, kE,
            a2_ago_b, TAG_AUTO, 0L, nullptr, 0, 1, DF);
    mgemm32(stream, Y2F, kE, WPRJ, XC, kE, M_BT, kE, kE,
            a2_proj_b, TAG_AUTO, 0L, AD11 + 2 * kE, 3 * kE, kT, DF);

    // ---- phase 3: p = einsum('bce,oc->boe') + DFT + trend (all fp32 VALU) ----
    gemm(stream, pr_w, TAG_AUTO, kT, 0L, XC, TAG_F32, kE, (long)kT * kE,
         P, kE, (long)kT2 * kE, kT2, kE, kT,
         pr_b, TAG_AUTO, 1, 0, nullptr, 0, 1, kB, DF);
    gemm(stream, TRIG, TAG_F32, kT, 0L, P + (long)kT * kE, TAG_F32, kE, (long)kT2 * kE,
         RE, kE, (long)kNFREQ * kE, kNFREQ, kE, kT,
         nullptr, 0, 0, 0, nullptr, 0, 1, kB, DF);
    gemm(stream, TRIG + (long)kNFREQ * kT, TAG_F32, kT, 0L, P + (long)kT * kE, TAG_F32, kE, (long)kT2 * kE,
         IM, kE, (long)kNFREQ * kE, kNFREQ, kE, kT,
         nullptr, 0, 0, 0, nullptr, 0, 1, kB, DF);
    k_topk<<<(kB * kE) / 16, 256, 0, stream>>>(RE, IM, TRE, TIM, TIX);
    k_season<<<(kB * kT * kE) / 256, 256, 0, stream>>>(TRE, TIM, TIX, TRIG, d_out, O3, DF);
    k_conv1<<<dim3(kB * 3, 8), 256, 0, stream>>>(P, tr_c1_w, tr_c1_b, G1, DF);
    k_conv2<<<kB * kNF, 256, 0, stream>>>(G1, tr_c2_w, tr_c2_b, H2, DF);
    k_trend<<<(kB * kT * kNF) / 256, 256, 0, stream>>>(H2, d_out, O2, DF);

    // ---- phase 4: MLP (post-P; plain bf16 MFMA -- proven on outputs 0/1) ----
    k_wt<<<dim3(4096/32, 1024/32), 256, 0, stream>>>(mlp_w1, W1B, 1024, 4096, DF);
    k_wt<<<dim3(1024/32, 4096/32), 256, 0, stream>>>(mlp_w2, W2B, 4096, 1024, DF);
    k_adaln<<<M_BT, 256, 0, stream>>>(XC, AD2, N1B);
    mgemm(stream, N1B, kE, W1B, HID, kMLP, M_BT, kMLP, kE,
          mlp_b1, TAG_AUTO, 1 /*gelu*/, nullptr, 0, 1, DF);
    mgemm(stream, HID, kMLP, W2B, XC, kE, M_BT, kE, kMLP,
          mlp_b2, TAG_AUTO, 0, AD2 + 2 * kE, 3 * kE, kT, DF);

    // ---- finals ----
    k_mean<<<(kB * kE) / 256, 256, 0, stream>>>(XC, MB);
    k_out0<<<(kB * kT * kE) / 256, 256, 0, stream>>>(XC, MB, d_out, O0, DF);
    k_out1<<<kB, 256, 0, stream>>>(MB, lin_w, lin_b, d_out, O1, DF);
}

// Round 8
// 2002.171 us; speedup vs baseline: 1.5976x; 1.0027x over previous
//
#include <hip/hip_runtime.h>
#include <hip/hip_bf16.h>

using bf16 = __hip_bfloat16;
typedef __attribute__((ext_vector_type(8))) short short8;     // 8 bf16 (4 VGPRs)
typedef __attribute__((ext_vector_type(4))) float floatx4;    // MFMA acc

// Problem constants
constexpr int kB = 8, kT = 512, kE = 1024, kH = 16, kA = 64, kNF = 64, kHS = 64;
constexpr int kMLP = 4096, kT2 = 1024, kNFREQ = 255, kKTOP = 5;

constexpr int TAG_F32 = 0, TAG_BF16 = 1, TAG_AUTO = 2;

// ---------------- workspace arena (BYTE offsets) ----------------------------
// XC 16.78M | SMALL 4.36M | FLAG 64 | WREG 20.97M (phase-reused weight xposes)
// | ACT 67.11M (phase-reused activations).  Total 109.2 MB < 117.6 MB proven.
constexpr long BOFF_XC    = 0;                          // fp32 (B,T,E)
constexpr long BOFF_SMALL = 16777216;                   // 4,360,192 B
constexpr long BOFF_FLAG  = 21137408;                   // 64 B
constexpr long BOFF_WREG  = 21137472;                   // 20,971,520 B
constexpr long BOFF_ACT   = 42108992;                   // 67,108,864 B
constexpr long WS_NEED    = BOFF_ACT + 67108864;        // 109,217,856 B

// WREG slots (bytes from BOFF_WREG)
constexpr long WR_Q   = 0;          // fp32 1024x1024 (4,194,304)
constexpr long WR_KV  = 4194304;    // fp32 2048x1024 (8,388,608)
constexpr long WR_AGO = 12582912;   // fp32 1024x1024
constexpr long WR_PRJ = 16777216;   // fp32 1024x1024
constexpr long WR_W1  = 0;          // bf16 4096x1024 (8,388,608)  [phase 4]
constexpr long WR_W2  = 8388608;    // bf16 1024x4096 (8,388,608)  [phase 4]
constexpr long WR_PRW = 0;          // fp32 1024x512 (2,097,152)   [phase 3]
constexpr long WR_XCT = 2097152;    // fp32 8x1024x512 (16,777,216)[phase 3]

// ACT slots (bytes from BOFF_ACT)
constexpr long AC_N1   = 0;         // fp32 (B,T,E) 16.78M   (also ENCF / P lo-half / N1b+HID)
constexpr long AC_QBUF = 16777216;  // fp32 (B,T,E) 16.78M
constexpr long AC_KV   = 33554432;  // fp32 (B,T,2E) 33.55M
constexpr long AC_KA   = 0;         // bf16 (H,B,T,HS) 8.39M  (over N1, after N1 dead)
constexpr long AC_VA   = 8388608;   // bf16 (H,B,T,HS) 8.39M
constexpr long AC_ATT  = 33554432;  // fp32 (B,T,E) 16.78M    (over KV, after KV dead)
constexpr long AC_Y2   = 50331648;  // fp32 (B,T,E) 16.78M
constexpr long AC_P    = 0;         // fp32 (B,2T,E) 33.55M   [phase 3]
constexpr long AC_RE   = 33554432;  // fp32 (B,255,E) 8,355,840
constexpr long AC_IM   = 41910272;  // fp32 (B,255,E) 8,355,840
constexpr long AC_N1B  = 0;         // bf16 (B,T,E) 8.39M     [phase 4]
constexpr long AC_HID  = 8388608;   // bf16 (B,T,MLP) 33.55M  [phase 4]

// small-region float offsets (relative to BOFF_SMALL)
constexpr long F_TS = 0, F_AD1 = 8192, F_AD11 = 32768, F_AD2 = 57344, F_QA = 81920,
               F_C1 = 147456, F_H2 = 671744, F_G1 = 673280, F_MB = 697856,
               F_TRE = 706048, F_TIM = 747008, F_TIX = 787968, F_TRIG = 828928;

// output regions (element offsets)
constexpr long O0 = 0, O1 = 4194304, O2 = 4194816, O3 = 4456960;

// ---------------- helpers ---------------------------------------------------
__device__ inline float bf2f(bf16 h) {
    unsigned short u = *(unsigned short*)&h;
    return __uint_as_float((unsigned)u << 16);
}
__device__ inline unsigned short bfbits(bf16 b) { return *(unsigned short*)&b; }
__device__ inline float gelu_f(float x) {
    return 0.5f * x * (1.0f + erff(x * 0.7071067811865476f));
}
__device__ inline float4 load4f(const float* p) { return *(const float4*)p; }
__device__ inline float4 load4bf(const bf16* p) {
    ushort4 u = *(const ushort4*)p;
    float4 r;
    r.x = __uint_as_float((unsigned)u.x << 16);
    r.y = __uint_as_float((unsigned)u.y << 16);
    r.z = __uint_as_float((unsigned)u.z << 16);
    r.w = __uint_as_float((unsigned)u.w << 16);
    return r;
}
__device__ inline float4 load4auto(const void* p, long idx, bool isF32) {
    if (isF32) return load4f((const float*)p + idx);
    return load4bf((const bf16*)p + idx);
}
__device__ inline float ld1auto(const void* p, long idx, bool isF32) {
    if (isF32) return ((const float*)p)[idx];
    return bf2f(((const bf16*)p)[idx]);
}
__device__ inline void st1auto(void* p, long idx, bool isF32, float v) {
    if (isF32) ((float*)p)[idx] = v;
    else       ((bf16*)p)[idx] = __float2bfloat16(v);
}
__device__ inline float ldc1(const float* p) { return *p; }
__device__ inline float ldc1(const bf16* p) { return bf2f(*p); }
__device__ inline void stc1(float* p, float v) { *p = v; }
__device__ inline void stc1(bf16* p, float v) { *p = __float2bfloat16(v); }

__device__ inline void blockReduce2(float& a, float& b, float* sm) {
    #pragma unroll
    for (int m = 32; m > 0; m >>= 1) { a += __shfl_down(a, m); b += __shfl_down(b, m); }
    int w = threadIdx.x >> 6;
    if ((threadIdx.x & 63) == 0) { sm[w] = a; sm[4 + w] = b; }
    __syncthreads();
    a = sm[0] + sm[1] + sm[2] + sm[3];
    b = sm[4] + sm[5] + sm[6] + sm[7];
    __syncthreads();
}

// ---------------- dtype detector --------------------------------------------
__global__ void k_detect(const unsigned short* __restrict__ xraw, int* __restrict__ flag) {
    int tid = threadIdx.x;
    unsigned short h = xraw[2 * tid];
    float v = __uint_as_float((unsigned)h << 16);
    float av = fabsf(v);
    if (!(av == av)) av = 1e30f;
    __shared__ float red[4];
    for (int m = 32; m > 0; m >>= 1) av = fmaxf(av, __shfl_down(av, m));
    if ((tid & 63) == 0) red[tid >> 6] = av;
    __syncthreads();
    if (tid == 0) {
        float mx = fmaxf(fmaxf(red[0], red[1]), fmaxf(red[2], red[3]));
        flag[0] = (mx < 1e3f) ? 0 : 1;             // 0 = bf16, 1 = fp32
    }
}

// ---------------- small kernels ---------------------------------------------
__global__ void k_temb(const int* __restrict__ ts, float* __restrict__ out) {
    int b = blockIdx.x, i = threadIdx.x;           // 512 threads
    float t = (float)ts[b];
    const float rate = (float)(-9.210340371976184 / 511.0);
    float f = expf(rate * (float)i);
    float arg = t * f;
    float sv = sinf(arg), cv = cosf(arg);
    out[(long)b * kE + i]        = sv / (1.f + expf(-sv));
    out[(long)b * kE + 512 + i]  = cv / (1.f + expf(-cv));
}

__global__ void k_castin(const void* __restrict__ in, float* __restrict__ out,
                         const int* __restrict__ DF) {
    bool f = DF[0] != 0;
    long i = ((long)blockIdx.x * 256 + threadIdx.x) * 4;
    float4 v = load4auto(in, i, f);
    *(float4*)(out + i) = v;
}

// fp32 weight transpose: W[K][Ntot] (auto dtype), cols [c0, c0+Nout) -> WT[Nout][K] fp32
__global__ __launch_bounds__(256) void k_wtf(const void* __restrict__ W, float* __restrict__ WT,
                                             int K, int Ntot, int c0,
                                             const int* __restrict__ DF) {
    bool f = DF[0] != 0;
    __shared__ float tile[32][33];
    int n0 = blockIdx.x * 32, k0 = blockIdx.y * 32;
    int tx = threadIdx.x & 31, ty = threadIdx.x >> 5;
    #pragma unroll
    for (int i = 0; i < 4; i++) {
        int k = ty + i * 8;
        tile[k][tx] = ld1auto(W, (long)(k0 + k) * Ntot + c0 + n0 + tx, f);
    }
    __syncthreads();
    #pragma unroll
    for (int i = 0; i < 4; i++) {
        int n = ty + i * 8;
        WT[(long)(n0 + n) * K + k0 + tx] = tile[tx][n];
    }
}

// batched pure-fp32 transpose: X[b][c][e] (c=kT, e=kE) -> XT[b][e][c]   [phase 3]
__global__ __launch_bounds__(256) void k_xt(const float* __restrict__ X, float* __restrict__ XT) {
    __shared__ float tile[32][33];
    int b = blockIdx.z;
    int e0 = blockIdx.x * 32, c0 = blockIdx.y * 32;
    int tx = threadIdx.x & 31, ty = threadIdx.x >> 5;
    const float* Xb = X + (long)b * kT * kE;
    float* XTb = XT + (long)b * kE * kT;
    #pragma unroll
    for (int i = 0; i < 4; i++) {
        int c = ty + i * 8;
        tile[c][tx] = Xb[(long)(c0 + c) * kE + e0 + tx];
    }
    __syncthreads();
    #pragma unroll
    for (int i = 0; i < 4; i++) {
        int e = ty + i * 8;
        XTb[(long)(e0 + e) * kT + c0 + tx] = tile[tx][e];
    }
}

// bf16 weight transpose (for MLP): W[K][N] -> WT[N][K] bf16
__global__ __launch_bounds__(256) void k_wt(const void* __restrict__ W, bf16* __restrict__ WT,
                                            int K, int N, const int* __restrict__ DF) {
    bool f = DF[0] != 0;
    __shared__ float tile[32][33];
    int n0 = blockIdx.x * 32, k0 = blockIdx.y * 32;
    int tx = threadIdx.x & 31, ty = threadIdx.x >> 5;
    #pragma unroll
    for (int i = 0; i < 4; i++) {
        int k = ty + i * 8;
        tile[k][tx] = ld1auto(W, (long)(k0 + k) * N + n0 + tx, f);
    }
    __syncthreads();
    #pragma unroll
    for (int i = 0; i < 4; i++) {
        int n = ty + i * 8;
        WT[(long)(n0 + n) * K + k0 + tx] = __float2bfloat16(tile[tx][n]);
    }
}

// adaLN -> fp32 out (phases 1,2)
__global__ __launch_bounds__(256) void k_adalnf(const float* __restrict__ X,
                                                const float* __restrict__ AD,
                                                float* __restrict__ N) {
    int row = blockIdx.x;
    int b = row / kT;
    const float* xr = X + (long)row * kE;
    int tid = threadIdx.x;
    float4 xv = *(const float4*)(xr + tid * 4);
    float s  = xv.x + xv.y + xv.z + xv.w;
    float sq = xv.x * xv.x + xv.y * xv.y + xv.z * xv.z + xv.w * xv.w;
    __shared__ float sm[8];
    blockReduce2(s, sq, sm);
    float mu  = s * (1.f / kE);
    float var = sq * (1.f / kE) - mu * mu;
    float rstd = rsqrtf(fmaxf(var, 0.f) + 1e-5f);
    const float* ad = AD + (long)b * 3 * kE;
    float* nr = N + (long)row * kE;
    float xs[4] = {xv.x, xv.y, xv.z, xv.w};
    #pragma unroll
    for (int j = 0; j < 4; j++) {
        int e = tid * 4 + j;
        float xn = (xs[j] - mu) * rstd;
        nr[e] = xn * (1.f + ad[kE + e]) + ad[e];
    }
}

// adaLN -> bf16 out (phase 4 / MLP)
__global__ __launch_bounds__(256) void k_adaln(const float* __restrict__ X,
                                               const float* __restrict__ AD,
                                               bf16* __restrict__ N) {
    int row = blockIdx.x;
    int b = row / kT;
    const float* xr = X + (long)row * kE;
    int tid = threadIdx.x;
    float4 xv = *(const float4*)(xr + tid * 4);
    float s  = xv.x + xv.y + xv.z + xv.w;
    float sq = xv.x * xv.x + xv.y * xv.y + xv.z * xv.z + xv.w * xv.w;
    __shared__ float sm[8];
    blockReduce2(s, sq, sm);
    float mu  = s * (1.f / kE);
    float var = sq * (1.f / kE) - mu * mu;
    float rstd = rsqrtf(fmaxf(var, 0.f) + 1e-5f);
    const float* ad = AD + (long)b * 3 * kE;
    bf16* nr = N + (long)row * kE;
    float xs[4] = {xv.x, xv.y, xv.z, xv.w};
    #pragma unroll
    for (int j = 0; j < 4; j++) {
        int e = tid * 4 + j;
        float xn = (xs[j] - mu) * rstd;
        nr[e] = __float2bfloat16(xn * (1.f + ad[kE + e]) + ad[e]);
    }
}

// ---------------- split-precision MFMA GEMM (fp32-accurate) -----------------
// C = A(fp32 MxK) @ WT(fp32 NxK)^T via hi/lo bf16 split: Ah*Bh + Ah*Bl + Al*Bh.
// Relative error ~8e-6 (vs 2e-3 plain bf16). M,N mult of 128, K mult of 32.
// Batched via blockIdx.z strides (bsA/bsW/bsC); biasRow=1 -> per-row bias.
template <typename TC>
__global__ __launch_bounds__(256) void k_mfma32(
    const float* __restrict__ A, int lda,
    const float* __restrict__ WT,
    TC* __restrict__ C, int ldc,
    int M, int N, int K,
    const void* __restrict__ bias, int bTag, long biasOff, int biasRow,
    const float* __restrict__ alpha, int alphaStride, int rowsPerB,
    long bsA, long bsW, long bsC,
    const int* __restrict__ DF) {
    constexpr int BK = 32, PAD = 8;                 // 40 elem (80 B) row stride
    __shared__ bf16 Ah[128][BK + PAD], Al[128][BK + PAD];
    __shared__ bf16 Bh[128][BK + PAD], Bl[128][BK + PAD];
    int tid = threadIdx.x;
    int wave = tid >> 6, lane = tid & 63;
    int bm = blockIdx.y * 128, bn = blockIdx.x * 128;
    int wm = (wave >> 1) * 64, wn = (wave & 1) * 64;
    int lm = lane & 15, quad = lane >> 4;
    floatx4 acc[4][4] = {};
    int sRow = tid >> 1, sCol = (tid & 1) * 16;      // 16 fp32 per thread per tile
    const float* ag = A  + (long)blockIdx.z * bsA + (long)(bm + sRow) * lda + sCol;
    const float* bg = WT + (long)blockIdx.z * bsW + (long)(bn + sRow) * K   + sCol;
    TC* Cz = C + (long)blockIdx.z * bsC;
    for (int k0 = 0; k0 < K; k0 += BK) {
        #pragma unroll
        for (int i = 0; i < 4; i++) {
            float4 v = *(const float4*)(ag + k0 + i * 4);
            bf16 h0 = __float2bfloat16(v.x), h1 = __float2bfloat16(v.y);
            bf16 h2 = __float2bfloat16(v.z), h3 = __float2bfloat16(v.w);
            bf16 l0 = __float2bfloat16(v.x - bf2f(h0));
            bf16 l1 = __float2bfloat16(v.y - bf2f(h1));
            bf16 l2 = __float2bfloat16(v.z - bf2f(h2));
            bf16 l3 = __float2bfloat16(v.w - bf2f(h3));
            ushort4 hv = {bfbits(h0), bfbits(h1), bfbits(h2), bfbits(h3)};
            ushort4 lv = {bfbits(l0), bfbits(l1), bfbits(l2), bfbits(l3)};
            *(ushort4*)&Ah[sRow][sCol + i * 4] = hv;
            *(ushort4*)&Al[sRow][sCol + i * 4] = lv;
        }
        #pragma unroll
        for (int i = 0; i < 4; i++) {
            float4 v = *(const float4*)(bg + k0 + i * 4);
            bf16 h0 = __float2bfloat16(v.x), h1 = __float2bfloat16(v.y);
            bf16 h2 = __float2bfloat16(v.z), h3 = __float2bfloat16(v.w);
            bf16 l0 = __float2bfloat16(v.x - bf2f(h0));
            bf16 l1 = __float2bfloat16(v.y - bf2f(h1));
            bf16 l2 = __float2bfloat16(v.z - bf2f(h2));
            bf16 l3 = __float2bfloat16(v.w - bf2f(h3));
            ushort4 hv = {bfbits(h0), bfbits(h1), bfbits(h2), bfbits(h3)};
            ushort4 lv = {bfbits(l0), bfbits(l1), bfbits(l2), bfbits(l3)};
            *(ushort4*)&Bh[sRow][sCol + i * 4] = hv;
            *(ushort4*)&Bl[sRow][sCol + i * 4] = lv;
        }
        __syncthreads();
        short8 ahf[4], alf[4], bhf[4], blf[4];
        #pragma unroll
        for (int mi = 0; mi < 4; mi++) {
            ahf[mi] = *(const short8*)&Ah[wm + mi * 16 + lm][quad * 8];
            alf[mi] = *(const short8*)&Al[wm + mi * 16 + lm][quad * 8];
        }
        #pragma unroll
        for (int ni = 0; ni < 4; ni++) {
            bhf[ni] = *(const short8*)&Bh[wn + ni * 16 + lm][quad * 8];
            blf[ni] = *(const short8*)&Bl[wn + ni * 16 + lm][quad * 8];
        }
        #pragma unroll
        for (int mi = 0; mi < 4; mi++)
            #pragma unroll
            for (int ni = 0; ni < 4; ni++) {
                acc[mi][ni] = __builtin_amdgcn_mfma_f32_16x16x32_bf16(ahf[mi], bhf[ni], acc[mi][ni], 0, 0, 0);
                acc[mi][ni] = __builtin_amdgcn_mfma_f32_16x16x32_bf16(ahf[mi], blf[ni], acc[mi][ni], 0, 0, 0);
                acc[mi][ni] = __builtin_amdgcn_mfma_f32_16x16x32_bf16(alf[mi], bhf[ni], acc[mi][ni], 0, 0, 0);
            }
        __syncthreads();
    }
    bool f32f = DF[0] != 0;
    bool bF = (bTag == TAG_F32) || (bTag == TAG_AUTO && f32f);
    #pragma unroll
    for (int ni = 0; ni < 4; ni++) {
        int col = bn + wn + ni * 16 + lm;
        float cbc = (bias && !biasRow) ? ld1auto(bias, biasOff + col, bF) : 0.f;
        #pragma unroll
        for (int mi = 0; mi < 4; mi++) {
            #pragma unroll
            for (int reg = 0; reg < 4; reg++) {
                int row = bm + wm + mi * 16 + quad * 4 + reg;
                float v = acc[mi][ni][reg] + cbc;
                if (bias && biasRow) v += ld1auto(bias, biasOff + row, bF);
                TC* cp = Cz + (long)row * ldc + col;
                if (alpha) {
                    const float* al = alpha + (long)(row / rowsPerB) * alphaStride + col;
                    v = ldc1(cp) + al[0] * v;
                }
                stc1(cp, v);
            }
        }
    }
}

template <typename TC>
static void mgemm32(hipStream_t s, const float* A, int lda, const float* WT,
                    TC* C, int ldc, int M, int N, int K,
                    const void* bias, int bTag, long biasOff,
                    const float* alpha, int alphaStride, int rowsPerB, const int* DF,
                    int biasRow = 0, long bsA = 0, long bsW = 0, long bsC = 0,
                    int batch = 1) {
    dim3 g(N / 128, M / 128, batch);
    k_mfma32<TC><<<g, 256, 0, s>>>(A, lda, WT, C, ldc, M, N, K,
                                   bias, bTag, biasOff, biasRow,
                                   alpha, alphaStride, rowsPerB,
                                   bsA, bsW, bsC, DF);
}

// ---------------- plain bf16 MFMA GEMM (MLP only; post-season-critical) -----
template <typename TC>
__global__ __launch_bounds__(256) void k_mfma(
    const bf16* __restrict__ A, int lda,
    const bf16* __restrict__ WT,
    TC* __restrict__ C, int ldc,
    int M, int N, int K,
    const void* __restrict__ bias, int bTag, int act,
    const float* __restrict__ alpha, int alphaStride, int rowsPerB,
    const int* __restrict__ DF) {
    constexpr int BK = 64, PAD = 8;
    __shared__ bf16 As[128][BK + PAD];
    __shared__ bf16 Bs[128][BK + PAD];
    int tid = threadIdx.x;
    int wave = tid >> 6, lane = tid & 63;
    int bm = blockIdx.y * 128, bn = blockIdx.x * 128;
    int wm = (wave >> 1) * 64, wn = (wave & 1) * 64;
    int lm = lane & 15, quad = lane >> 4;
    floatx4 acc[4][4] = {};
    int sRow = tid >> 1, sCol = (tid & 1) * 32;
    const bf16* ag = A  + (long)(bm + sRow) * lda + sCol;
    const bf16* bg = WT + (long)(bn + sRow) * K   + sCol;
    for (int k0 = 0; k0 < K; k0 += BK) {
        #pragma unroll
        for (int i = 0; i < 4; i++)
            *(float4*)&As[sRow][sCol + i * 8] = *(const float4*)(ag + k0 + i * 8);
        #pragma unroll
        for (int i = 0; i < 4; i++)
            *(float4*)&Bs[sRow][sCol + i * 8] = *(const float4*)(bg + k0 + i * 8);
        __syncthreads();
        #pragma unroll
        for (int kk = 0; kk < BK; kk += 32) {
            short8 af[4], bf[4];
            #pragma unroll
            for (int mi = 0; mi < 4; mi++)
                af[mi] = *(const short8*)&As[wm + mi * 16 + lm][kk + quad * 8];
            #pragma unroll
            for (int ni = 0; ni < 4; ni++)
                bf[ni] = *(const short8*)&Bs[wn + ni * 16 + lm][kk + quad * 8];
            #pragma unroll
            for (int mi = 0; mi < 4; mi++)
                #pragma unroll
                for (int ni = 0; ni < 4; ni++)
                    acc[mi][ni] = __builtin_amdgcn_mfma_f32_16x16x32_bf16(
                        af[mi], bf[ni], acc[mi][ni], 0, 0, 0);
        }
        __syncthreads();
    }
    bool f32f = DF[0] != 0;
    bool bF = (bTag == TAG_F32) || (bTag == TAG_AUTO && f32f);
    #pragma unroll
    for (int ni = 0; ni < 4; ni++) {
        int col = bn + wn + ni * 16 + lm;
        float cb = bias ? ld1auto(bias, col, bF) : 0.f;
        #pragma unroll
        for (int mi = 0; mi < 4; mi++) {
            #pragma unroll
            for (int reg = 0; reg < 4; reg++) {
                int row = bm + wm + mi * 16 + quad * 4 + reg;
                float v = acc[mi][ni][reg] + cb;
                TC* cp = C + (long)row * ldc + col;
                if (alpha) {
                    const float* al = alpha + (long)(row / rowsPerB) * alphaStride + col;
                    v = ldc1(cp) + al[0] * v;
                } else if (act == 1) {
                    v = gelu_f(v);
                }
                stc1(cp, v);
            }
        }
    }
}

template <typename TC>
static void mgemm(hipStream_t s, const bf16* A, int lda, const bf16* WT,
                  TC* C, int ldc, int M, int N, int K,
                  const void* bias, int bTag, int act,
                  const float* alpha, int alphaStride, int rowsPerB, const int* DF) {
    dim3 g(N / 128, M / 128);
    k_mfma<TC><<<g, 256, 0, s>>>(A, lda, WT, C, ldc, M, N, K,
                                 bias, bTag, act, alpha, alphaStride, rowsPerB, DF);
}

// ---------------- generic tiled fp32-VALU GEMM ------------------------------
// Register-prefetch double-buffered: tile k+1's global loads are issued
// right after the store barrier, so HBM/L2 latency hides under the 16x16
// FMA block.
template <typename TC>
__global__ __launch_bounds__(256) void k_gemm(
    const void* __restrict__ Ab, int aTag, int lda, long bsA,
    const void* __restrict__ Wb, int wTag, int ldw, long bsW,
    TC* __restrict__ Cb, int ldc, long bsC,
    int M, int N, int K,
    const void* __restrict__ bias, int bTag, int biasRow, int act,
    const float* __restrict__ alpha, int alphaStride, int rowsPerB,
    const int* __restrict__ DF) {
    __shared__ float As[16][68];
    __shared__ float Bs[16][68];
    bool f32f = DF[0] != 0;
    bool aF = (aTag == TAG_F32) || (aTag == TAG_AUTO && f32f);
    bool wF = (wTag == TAG_F32) || (wTag == TAG_AUTO && f32f);
    bool bF = (bTag == TAG_F32) || (bTag == TAG_AUTO && f32f);
    TC* Cbase = Cb + (long)blockIdx.z * bsC;
    long aBase = (long)blockIdx.z * bsA;
    long wBase = (long)blockIdx.z * bsW;
    int tid = threadIdx.x;
    int bm = blockIdx.y, bn = blockIdx.x;
    int tx = tid & 15, ty = tid >> 4;
    int arow = tid >> 2, acol = (tid & 3) * 4;
    int wrow = tid >> 4, wcol = (tid & 15) * 4;
    int gArow = bm * 64 + arow;
    bool aValid = gArow < M;
    float acc[4][4] = {};
    float4 av = {0.f, 0.f, 0.f, 0.f};
    if (aValid) av = load4auto(Ab, aBase + (long)gArow * lda + acol, aF);
    float4 wv = load4auto(Wb, wBase + (long)wrow * ldw + bn * 64 + wcol, wF);
    for (int kk = 0; kk < K; kk += 16) {
        As[acol + 0][arow] = av.x;
        As[acol + 1][arow] = av.y;
        As[acol + 2][arow] = av.z;
        As[acol + 3][arow] = av.w;
        *(float4*)&Bs[wrow][wcol] = wv;
        __syncthreads();
        if (kk + 16 < K) {           // prefetch next tile (overlaps FMA below)
            if (aValid) av = load4auto(Ab, aBase + (long)gArow * lda + kk + 16 + acol, aF);
            wv = load4auto(Wb, wBase + (long)(kk + 16 + wrow) * ldw + bn * 64 + wcol, wF);
        }
        #pragma unroll
        for (int k = 0; k < 16; k++) {
            float4 a4 = *(const float4*)&As[k][ty * 4];
            float4 b4 = *(const float4*)&Bs[k][tx * 4];
            acc[0][0] += a4.x * b4.x; acc[0][1] += a4.x * b4.y; acc[0][2] += a4.x * b4.z; acc[0][3] += a4.x * b4.w;
            acc[1][0] += a4.y * b4.x; acc[1][1] += a4.y * b4.y; acc[1][2] += a4.y * b4.z; acc[1][3] += a4.y * b4.w;
            acc[2][0] += a4.z * b4.x; acc[2][1] += a4.z * b4.y; acc[2][2] += a4.z * b4.z; acc[2][3] += a4.z * b4.w;
            acc[3][0] += a4.w * b4.x; acc[3][1] += a4.w * b4.y; acc[3][2] += a4.w * b4.z; acc[3][3] += a4.w * b4.w;
        }
        __syncthreads();
    }
    int gcol = bn * 64 + tx * 4;
    float cb[4] = {0.f, 0.f, 0.f, 0.f};
    if (bias && !biasRow) {
        #pragma unroll
        for (int j = 0; j < 4; j++) cb[j] = ld1auto(bias, gcol + j, bF);
    }
    #pragma unroll
    for (int i = 0; i < 4; i++) {
        int grow = bm * 64 + ty * 4 + i;
        if (grow >= M) continue;
        float rb = (bias && biasRow) ? ld1auto(bias, grow, bF) : 0.f;
        TC* crow = Cbase + (long)grow * ldc + gcol;
        const float* al = nullptr;
        if (alpha) al = alpha + (long)(grow / rowsPerB) * alphaStride + gcol;
        #pragma unroll
        for (int j = 0; j < 4; j++) {
            float v = acc[i][j] + cb[j] + rb;
            if (alpha)         v = ldc1(crow + j) + al[j] * v;
            else if (act == 1) v = gelu_f(v);
            stc1(crow + j, v);
        }
    }
}

template <typename TC>
static void gemm(hipStream_t s, const void* A, int aTag, int lda, long bsA,
                 const void* W, int wTag, int ldw, long bsW,
                 TC* C, int ldc, long bsC, int M, int N, int K,
                 const void* bias, int bTag, int biasRow, int act,
                 const float* alpha, int alphaStride, int rowsPerB, int batch,
                 const int* DF) {
    dim3 g(N / 64, (M + 63) / 64, batch);
    k_gemm<TC><<<g, 256, 0, s>>>(A, aTag, lda, bsA, W, wTag, ldw, bsW, C, ldc, bsC,
                                 M, N, K, bias, bTag, biasRow, act,
                                 alpha, alphaStride, rowsPerB, DF);
}

// ---------------- agent attention stage 1 -----------------------------------
// 4-agents-per-block + vectorized PV rewrite.
__global__ __launch_bounds__(256) void k_agatt1(const float* __restrict__ qa,
                                                const bf16* __restrict__ ka,
                                                const bf16* __restrict__ va,
                                                float* __restrict__ c1) {
    constexpr int AQ = 4;
    int blk = blockIdx.x;
    int aq = blk % (kA / AQ);
    int h = (blk / (kA / AQ)) % kH;
    int b = blk / ((kA / AQ) * kH);
    int ag0 = aq * AQ;
    __shared__ float qs[AQ][kHS];
    __shared__ float probs[AQ][kT];
    __shared__ float red[16][AQ * 68];
    __shared__ float sred[32];
    int tid = threadIdx.x;
    {
        int ag = tid >> 6, d = tid & 63;
        qs[ag][d] = qa[((long)h * kA + ag0 + ag) * kHS + d];
    }
    __syncthreads();
    const bf16* kab = ka + ((long)h * kB + b) * kT * kHS;
    float sc[2][AQ];
    #pragma unroll
    for (int rep = 0; rep < 2; rep++) {
        const bf16* kr = kab + (long)(tid + rep * 256) * kHS;
        float a0 = 0.f, a1 = 0.f, a2 = 0.f, a3 = 0.f;
        #pragma unroll
        for (int d = 0; d < kHS; d += 4) {
            float4 k4 = load4bf(kr + d);
            float4 q0 = *(const float4*)&qs[0][d];
            float4 q1 = *(const float4*)&qs[1][d];
            float4 q2 = *(const float4*)&qs[2][d];
            float4 q3 = *(const float4*)&qs[3][d];
            a0 += k4.x * q0.x + k4.y * q0.y + k4.z * q0.z + k4.w * q0.w;
            a1 += k4.x * q1.x + k4.y * q1.y + k4.z * q1.z + k4.w * q1.w;
            a2 += k4.x * q2.x + k4.y * q2.y + k4.z * q2.z + k4.w * q2.w;
            a3 += k4.x * q3.x + k4.y * q3.y + k4.z * q3.z + k4.w * q3.w;
        }
        sc[rep][0] = a0 * 0.125f; sc[rep][1] = a1 * 0.125f;
        sc[rep][2] = a2 * 0.125f; sc[rep][3] = a3 * 0.125f;
    }
    int w = tid >> 6;
    float mx[AQ], ss[AQ];
    #pragma unroll
    for (int ag = 0; ag < AQ; ag++) mx[ag] = fmaxf(sc[0][ag], sc[1][ag]);
    #pragma unroll
    for (int m = 32; m > 0; m >>= 1)
        #pragma unroll
        for (int ag = 0; ag < AQ; ag++) mx[ag] = fmaxf(mx[ag], __shfl_down(mx[ag], m));
    if ((tid & 63) == 0)
        #pragma unroll
        for (int ag = 0; ag < AQ; ag++) sred[w * 4 + ag] = mx[ag];
    __syncthreads();
    #pragma unroll
    for (int ag = 0; ag < AQ; ag++)
        mx[ag] = fmaxf(fmaxf(sred[ag], sred[4 + ag]), fmaxf(sred[8 + ag], sred[12 + ag]));
    float e0[AQ], e1[AQ];
    #pragma unroll
    for (int ag = 0; ag < AQ; ag++) {
        e0[ag] = expf(sc[0][ag] - mx[ag]);
        e1[ag] = expf(sc[1][ag] - mx[ag]);
        ss[ag] = e0[ag] + e1[ag];
    }
    #pragma unroll
    for (int m = 32; m > 0; m >>= 1)
        #pragma unroll
        for (int ag = 0; ag < AQ; ag++) ss[ag] += __shfl_down(ss[ag], m);
    if ((tid & 63) == 0)
        #pragma unroll
        for (int ag = 0; ag < AQ; ag++) sred[16 + w * 4 + ag] = ss[ag];
    __syncthreads();
    #pragma unroll
    for (int ag = 0; ag < AQ; ag++) {
        float tot = sred[16 + ag] + sred[20 + ag] + sred[24 + ag] + sred[28 + ag];
        float rs = 1.f / tot;
        probs[ag][tid] = e0[ag] * rs;
        probs[ag][tid + 256] = e1[ag] * rs;
    }
    __syncthreads();
    // PV: dg = d-quad 0..15 (4 d's), nc = n-chunk 0..15 (32 n's)
    int dg = tid & 15, nc = tid >> 4;
    const bf16* vab = va + ((long)h * kB + b) * kT * kHS;
    float4 acc[AQ] = {};
    for (int s = 0; s < 32; s++) {
        int n = nc * 32 + s;
        float4 v = load4bf(vab + (long)n * kHS + dg * 4);
        #pragma unroll
        for (int ag = 0; ag < AQ; ag++) {
            float p = probs[ag][n];
            acc[ag].x += p * v.x; acc[ag].y += p * v.y;
            acc[ag].z += p * v.z; acc[ag].w += p * v.w;
        }
    }
    #pragma unroll
    for (int ag = 0; ag < AQ; ag++)
        *(float4*)&red[nc][ag * 68 + dg * 4] = acc[ag];
    __syncthreads();
    {
        int ag = tid >> 6, d = tid & 63;
        float s = 0.f;
        #pragma unroll
        for (int n2 = 0; n2 < 16; n2++) s += red[n2][ag * 68 + d];
        c1[(((long)b * kH + h) * kA + ag0 + ag) * kHS + d] = s;
    }
}

// ---------------- agent attention stage 2 (fp32 in/out) ----------------------
__global__ __launch_bounds__(256) void k_agatt2f(const float* __restrict__ qsrc, int ldq,
                                                 const float* __restrict__ c1,
                                                 float* __restrict__ out) {
    int blk = blockIdx.x;
    int nt = blk % (kT / 16);
    int h = (blk / (kT / 16)) % kH;
    int b = blk / ((kT / 16) * kH);
    __shared__ float c1s[kA][kHS + 1];
    __shared__ float qs[16][kHS + 1];
    __shared__ float ps[16][kA + 1];
    int tid = threadIdx.x;
    const float* c1b = c1 + ((long)b * kH + h) * kA * kHS;
    for (int i = tid; i < kA * kHS; i += 256) c1s[i >> 6][i & 63] = c1b[i];
    int n0 = nt * 16;
    {
        int r = tid >> 4, d = (tid & 15) * 4;
        float4 q4 = load4f(qsrc + (long)(b * kT + n0 + r) * ldq + h * kHS + d);
        qs[r][d] = q4.x; qs[r][d + 1] = q4.y; qs[r][d + 2] = q4.z; qs[r][d + 3] = q4.w;
    }
    __syncthreads();
    int r = tid >> 4, c = tid & 15;
    float sc[4];
    #pragma unroll
    for (int j = 0; j < 4; j++) {
        int a = c * 4 + j;
        float acc = 0.f;
        for (int d = 0; d < kHS; d++) acc += qs[r][d] * c1s[a][d];
        sc[j] = acc * 0.125f;
    }
    float mx = fmaxf(fmaxf(sc[0], sc[1]), fmaxf(sc[2], sc[3]));
    for (int m = 1; m < 16; m <<= 1) mx = fmaxf(mx, __shfl_xor(mx, m));
    float e[4], ss = 0.f;
    #pragma unroll
    for (int j = 0; j < 4; j++) { e[j] = expf(sc[j] - mx); ss += e[j]; }
    for (int m = 1; m < 16; m <<= 1) ss += __shfl_xor(ss, m);
    float rs = 1.f / ss;
    #pragma unroll
    for (int j = 0; j < 4; j++) ps[r][c * 4 + j] = e[j] * rs;
    __syncthreads();
    float o0 = 0.f, o1 = 0.f, o2 = 0.f, o3 = 0.f;
    int d0 = c * 4;
    for (int a = 0; a < kA; a++) {
        float p = ps[r][a];
        o0 += p * c1s[a][d0 + 0];
        o1 += p * c1s[a][d0 + 1];
        o2 += p * c1s[a][d0 + 2];
        o3 += p * c1s[a][d0 + 3];
    }
    float* orow = out + (long)(b * kT + n0 + r) * kE + h * kHS + d0;
    orow[0] = o0; orow[1] = o1; orow[2] = o2; orow[3] = o3;
}

// ---------------- DFT tables --------------------------------------------------
__global__ void k_trig(float* __restrict__ trig) {
    int id = blockIdx.x * 256 + threadIdx.x;
    if (id >= kNFREQ * kT) return;
    int t = id & 511;
    int f = (id >> 9) + 1;
    int m = (f * t) & 511;
    double ang = (double)m * (2.0 * 3.14159265358979323846 / 512.0);
    trig[id] = (float)cos(ang);
    trig[kNFREQ * kT + id] = (float)(-sin(ang));
}

// ---------------- top-5 |X_f|^2 per (b,e) column ------------------------------
// f-parallel: 16 threads per column, private top-5, LDS merge; stable tie-break.
__global__ __launch_bounds__(256) void k_topk(const float* __restrict__ RE, const float* __restrict__ IM,
                                              float* __restrict__ tre, float* __restrict__ tim,
                                              int* __restrict__ tix) {
    int tid = threadIdx.x;
    int c = tid & 15;                       // column within block
    int j = tid >> 4;                       // f-group 0..15
    int colId = blockIdx.x * 16 + c;        // 0..8191
    int b = colId >> 10, e = colId & 1023;
    const float* rp = RE + (long)b * kNFREQ * kE + e;
    const float* ip = IM + (long)b * kNFREQ * kE + e;
    float bv[kKTOP] = {-1e30f, -1e30f, -1e30f, -1e30f, -1e30f};
    int bi[kKTOP] = {1 << 30, 1 << 30, 1 << 30, 1 << 30, 1 << 30};
    #pragma unroll
    for (int s = 0; s < 16; s++) {
        int fq = j * 16 + s;
        if (fq >= kNFREQ) break;
        float re = rp[(long)fq * kE], im = ip[(long)fq * kE];
        float m2 = re * re + im * im;
        if (m2 > bv[kKTOP - 1] || (m2 == bv[kKTOP - 1] && fq < bi[kKTOP - 1])) {
            int p = kKTOP - 1;
            while (p > 0 && (m2 > bv[p - 1] || (m2 == bv[p - 1] && fq < bi[p - 1]))) {
                bv[p] = bv[p - 1]; bi[p] = bi[p - 1]; p--;
            }
            bv[p] = m2; bi[p] = fq;
        }
    }
    __shared__ float sv[16][16][kKTOP];
    __shared__ int   si[16][16][kKTOP];
    #pragma unroll
    for (int q = 0; q < kKTOP; q++) { sv[c][j][q] = bv[q]; si[c][j][q] = bi[q]; }
    __syncthreads();
    if (j == 0) {
        for (int jj = 1; jj < 16; jj++) {
            #pragma unroll
            for (int q = 0; q < kKTOP; q++) {
                float v = sv[c][jj][q];
                int fq = si[c][jj][q];
                if (v > bv[kKTOP - 1] || (v == bv[kKTOP - 1] && fq < bi[kKTOP - 1])) {
                    int p = kKTOP - 1;
                    while (p > 0 && (v > bv[p - 1] || (v == bv[p - 1] && fq < bi[p - 1]))) {
                        bv[p] = bv[p - 1]; bi[p] = bi[p - 1]; p--;
                    }
                    bv[p] = v; bi[p] = fq;
                }
            }
        }
        #pragma unroll
        for (int q = 0; q < kKTOP; q++) {
            int fq = bi[q];
            tre[(long)colId * kKTOP + q] = rp[(long)fq * kE];
            tim[(long)colId * kKTOP + q] = ip[(long)fq * kE];
            tix[(long)colId * kKTOP + q] = fq;
        }
    }
}

__global__ void k_season(const float* __restrict__ tre, const float* __restrict__ tim,
                         const int* __restrict__ tix, const float* __restrict__ trig,
                         void* __restrict__ out, long obase, const int* __restrict__ DF) {
    bool f32o = DF[0] != 0;
    long id = (long)blockIdx.x * 256 + threadIdx.x;
    int e = id & 1023;
    long bt = id >> 10;
    int t = (int)(bt & 511);
    int b = (int)(bt >> 9);
    long be = (long)b * kE + e;
    float acc = 0.f;
    #pragma unroll
    for (int j = 0; j < kKTOP; j++) {
        int f = tix[be * kKTOP + j];
        acc += tre[be * kKTOP + j] * trig[(long)f * kT + t]
             + tim[be * kKTOP + j] * trig[(long)kNFREQ * kT + (long)f * kT + t];
    }
    st1auto(out, obase + id, f32o, 2.f * acc);
}

// ---------------- trend branch ------------------------------------------------
__global__ __launch_bounds__(256) void k_conv1(const float* __restrict__ P,
                                               const void* __restrict__ w,
                                               const void* __restrict__ bias,
                                               float* __restrict__ G,
                                               const int* __restrict__ DF) {
    bool f = DF[0] != 0;
    int bo = blockIdx.x;                 // 0..23 -> (b,o)
    int lt = blockIdx.y;                 // 0..7  -> 128-l tile
    int o = bo % 3, b = bo / 3;
    int tid = threadIdx.x;
    __shared__ float ws[512][3];         // 6 KB weight slab for this o
    for (int idx = tid; idx < 512 * 3; idx += 256)
        ws[idx / 3][idx % 3] = ld1auto(w, (long)o * 512 * 3 + idx, f);
    __syncthreads();
    int l = lt * 128 + (tid & 127);
    int ih = (tid >> 7) * 256;           // 0 or 256
    const float* xb = P + (long)b * kT2 * kE;
    float acc = 0.f;
    for (int ii = 0; ii < 256; ii++) {
        int i = ih + ii;
        const float* xr = xb + (long)i * kE + l;
        float xm = (l > 0)    ? xr[-1] : 0.f;
        float xc = xr[0];
        float xp = (l < 1023) ? xr[1]  : 0.f;
        acc += xm * ws[i][0] + xc * ws[i][1] + xp * ws[i][2];
    }
    __shared__ float red[128];
    if (tid >= 128) red[tid - 128] = acc;
    __syncthreads();
    if (tid < 128) {
        float tot = acc + red[tid] + ld1auto(bias, o, f);
        G[((long)b * 3 + o) * 1024 + l] = gelu_f(tot);
    }
}

__global__ __launch_bounds__(256) void k_conv2(const float* __restrict__ G,
                                               const void* __restrict__ w,
                                               const void* __restrict__ bias,
                                               float* __restrict__ H2,
                                               const int* __restrict__ DF) {
    bool f = DF[0] != 0;
    int n = blockIdx.x % kNF;
    int b = blockIdx.x / kNF;
    int tid = threadIdx.x;
    const float* Gb = G + (long)b * 3 * 1024;
    float a0 = 0.f, a1 = 0.f, a2 = 0.f;
    for (int i = tid; i < 1024; i += 256) {
        float g0 = Gb[i], g1 = Gb[1024 + i], g2 = Gb[2048 + i];
        long wo = ((long)n * 1024 + i) * 3;
        float w0 = ld1auto(w, wo + 0, f);
        float w1 = ld1auto(w, wo + 1, f);
        float w2 = ld1auto(w, wo + 2, f);
        a0 += g0 * w1 + g1 * w2;
        a1 += g0 * w0 + g1 * w1 + g2 * w2;
        a2 += g1 * w0 + g2 * w1;
    }
    __shared__ float sm[12];
    #pragma unroll
    for (int m = 32; m > 0; m >>= 1) {
        a0 += __shfl_down(a0, m);
        a1 += __shfl_down(a1, m);
        a2 += __shfl_down(a2, m);
    }
    int wv = tid >> 6;
    if ((tid & 63) == 0) { sm[wv] = a0; sm[4 + wv] = a1; sm[8 + wv] = a2; }
    __syncthreads();
    if (tid == 0) {
        float cb = ld1auto(bias, n, f);
        float* hp = H2 + ((long)b * kNF + n) * 3;
        hp[0] = cb + sm[0] + sm[1] + sm[2] + sm[3];
        hp[1] = cb + sm[4] + sm[5] + sm[6] + sm[7];
        hp[2] = cb + sm[8] + sm[9] + sm[10] + sm[11];
    }
}

__global__ void k_trend(const float* __restrict__ H2, void* __restrict__ out, long obase,
                        const int* __restrict__ DF) {
    bool f32o = DF[0] != 0;
    int id = blockIdx.x * 256 + threadIdx.x;
    int n = id % kNF;
    int t = (id / kNF) % kT;
    int b = id / (kNF * kT);
    float lin = (float)(t + 1) / 513.0f;
    const float* h = H2 + ((long)b * kNF + n) * 3;
    float l2 = lin * lin;
    st1auto(out, obase + id, f32o, h[0] * lin + h[1] * l2 + h[2] * l2 * lin);
}

// ---------------- finals -------------------------------------------------------
__global__ void k_mean(const float* __restrict__ X, float* __restrict__ m) {
    int id = blockIdx.x * 256 + threadIdx.x;
    int b = id >> 10, e = id & 1023;
    const float* p = X + (long)b * kT * kE + e;
    float s = 0.f;
    for (int t = 0; t < kT; t++) s += p[(long)t * kE];
    m[id] = s * (1.f / kT);
}

__global__ void k_out0(const float* __restrict__ X, const float* __restrict__ m,
                       void* __restrict__ out, long obase, const int* __restrict__ DF) {
    bool f32o = DF[0] != 0;
    long id = (long)blockIdx.x * 256 + threadIdx.x;
    int e = id & 1023;
    int b = (int)(id >> 19);
    st1auto(out, obase + id, f32o, X[id] - m[b * kE + e]);
}

// out1: one block per batch b; thread = (n, e-slice); coalesced-in-n w loads.
__global__ __launch_bounds__(256) void k_out1(const float* __restrict__ m,
                                              const void* __restrict__ w,
                                              const void* __restrict__ bias,
                                              void* __restrict__ out, long obase,
                                              const int* __restrict__ DF) {
    bool f = DF[0] != 0;
    int b = blockIdx.x;                  // 0..7
    int tid = threadIdx.x;
    int n = tid & 63, es = tid >> 6;     // 4 e-slices of 256
    const float* mb = m + (long)b * kE;
    float acc = 0.f;
    for (int e = es * 256; e < es * 256 + 256; e++)
        acc += mb[e] * ld1auto(w, (long)e * kNF + n, f);
    __shared__ float sm[4][64];
    sm[es][n] = acc;
    __syncthreads();
    if (tid < 64) {
        float tot = sm[0][tid] + sm[1][tid] + sm[2][tid] + sm[3][tid]
                  + ld1auto(bias, tid, f);
        st1auto(out, obase + (long)b * kNF + tid, f, tot);
    }
}

// ---------------- launch -------------------------------------------------------
extern "C" void kernel_launch(void* const* d_in, const int* in_sizes, int n_in,
                              void* d_out, int out_size, void* d_ws, size_t ws_size,
                              hipStream_t stream) {
    (void)in_sizes; (void)n_in; (void)out_size; (void)ws_size;
    const void* x_in = d_in[0];
    const void* enc  = d_in[1];
    const int* tstep = (const int*)d_in[2];
    const void *ln1_w = d_in[3],  *ln1_b = d_in[4],  *ln11_w = d_in[5], *ln11_b = d_in[6];
    const void *ln2_w = d_in[7],  *ln2_b = d_in[8];
    const void *a1_qkv_w = d_in[9], *a1_qkv_b = d_in[10];
    const void *a1_agq_w = d_in[11], *a1_agq_b = d_in[12];
    const void *a1_agk_w = d_in[13], *a1_agk_b = d_in[14];
    const void *a1_agv_w = d_in[15], *a1_agv_b = d_in[16];
    const void *a1_ago_w = d_in[17], *a1_ago_b = d_in[18];
    const void *a1_agents = d_in[19];
    const void *a1_proj_w = d_in[20], *a1_proj_b = d_in[21];
    const void *a2_q_w = d_in[22], *a2_q_b = d_in[23];
    const void *a2_kv_w = d_in[24], *a2_kv_b = d_in[25];
    const void *a2_agq_w = d_in[26], *a2_agq_b = d_in[27];
    const void *a2_agk_w = d_in[28], *a2_agk_b = d_in[29];
    const void *a2_agv_w = d_in[30], *a2_agv_b = d_in[31];
    const void *a2_ago_w = d_in[32], *a2_ago_b = d_in[33];
    const void *a2_agents = d_in[34];
    const void *a2_proj_w = d_in[35], *a2_proj_b = d_in[36];
    const void *tr_c1_w = d_in[37], *tr_c1_b = d_in[38];
    const void *tr_c2_w = d_in[39], *tr_c2_b = d_in[40];
    const void *mlp_w1 = d_in[41], *mlp_b1 = d_in[42];
    const void *mlp_w2 = d_in[43], *mlp_b2 = d_in[44];
    const void *pr_w = d_in[45], *pr_b = d_in[46];
    const void *lin_w = d_in[47], *lin_b = d_in[48];

    char* wsb = (char*)d_ws;
    float* XC = (float*)(wsb + BOFF_XC);
    float* SM = (float*)(wsb + BOFF_SMALL);
    float* TS = SM + F_TS;
    float* AD1 = SM + F_AD1;
    float* AD11 = SM + F_AD11;
    float* AD2 = SM + F_AD2;
    float* QA = SM + F_QA;
    float* C1 = SM + F_C1;
    float* H2 = SM + F_H2;
    float* G1 = SM + F_G1;
    float* MB = SM + F_MB;
    float* TRE = SM + F_TRE;
    float* TIM = SM + F_TIM;
    int*   TIX = (int*)(SM + F_TIX);
    float* TRIG = SM + F_TRIG;
    int* DF = (int*)(wsb + BOFF_FLAG);
    char* WR = wsb + BOFF_WREG;
    float* WTQ  = (float*)(WR + WR_Q);
    float* WTKV = (float*)(WR + WR_KV);
    float* WAGO = (float*)(WR + WR_AGO);
    float* WPRJ = (float*)(WR + WR_PRJ);
    bf16*  W1B  = (bf16*)(WR + WR_W1);
    bf16*  W2B  = (bf16*)(WR + WR_W2);
    float* PRW  = (float*)(WR + WR_PRW);
    float* XCT  = (float*)(WR + WR_XCT);
    char* AC = wsb + BOFF_ACT;
    float* N1F  = (float*)(AC + AC_N1);     // also ENCF
    float* QBUF = (float*)(AC + AC_QBUF);
    float* KVB  = (float*)(AC + AC_KV);
    bf16*  KA   = (bf16*)(AC + AC_KA);
    bf16*  VA   = (bf16*)(AC + AC_VA);
    float* ATTF = (float*)(AC + AC_ATT);
    float* Y2F  = (float*)(AC + AC_Y2);
    float* P    = (float*)(AC + AC_P);
    float* RE   = (float*)(AC + AC_RE);
    float* IM   = (float*)(AC + AC_IM);
    bf16*  N1B  = (bf16*)(AC + AC_N1B);
    bf16*  HID  = (bf16*)(AC + AC_HID);

    const int M_BT = kB * kT;                      // 4096
    const long bsKA = (long)kB * kT * kHS;

    // 0) dtype detection (precedes all d_in consumers)
    k_detect<<<1, 256, 0, stream>>>((const unsigned short*)x_in, DF);

    // phase-1 weight transposes (fp32)
    k_wtf<<<dim3(1024/32, 1024/32), 256, 0, stream>>>(a1_qkv_w, WTQ, 1024, 3072, 0, DF);
    k_wtf<<<dim3(2048/32, 1024/32), 256, 0, stream>>>(a1_qkv_w, WTKV, 1024, 3072, 1024, DF);
    k_wtf<<<dim3(1024/32, 1024/32), 256, 0, stream>>>(a1_ago_w, WAGO, 1024, 1024, 0, DF);
    k_wtf<<<dim3(1024/32, 1024/32), 256, 0, stream>>>(a1_proj_w, WPRJ, 1024, 1024, 0, DF);

    // prologue
    k_temb<<<kB, 512, 0, stream>>>(tstep, TS);
    gemm(stream, TS, TAG_F32, kE, 0L, ln1_w, TAG_AUTO, 3 * kE, 0L, AD1, 3 * kE, 0L,
         kB, 3 * kE, kE, ln1_b, TAG_AUTO, 0, 0, nullptr, 0, 1, 1, DF);
    gemm(stream, TS, TAG_F32, kE, 0L, ln11_w, TAG_AUTO, 3 * kE, 0L, AD11, 3 * kE, 0L,
         kB, 3 * kE, kE, ln11_b, TAG_AUTO, 0, 0, nullptr, 0, 1, 1, DF);
    gemm(stream, TS, TAG_F32, kE, 0L, ln2_w, TAG_AUTO, 3 * kE, 0L, AD2, 3 * kE, 0L,
         kB, 3 * kE, kE, ln2_b, TAG_AUTO, 0, 0, nullptr, 0, 1, 1, DF);
    k_castin<<<(kB * kT * kE) / 1024, 256, 0, stream>>>(x_in, XC, DF);
    k_trig<<<(kNFREQ * kT + 255) / 256, 256, 0, stream>>>(TRIG);

    // ---- attention block 1 (self), fp32 end-to-end via split MFMA ----
    k_adalnf<<<M_BT, 256, 0, stream>>>(XC, AD1, N1F);
    mgemm32(stream, N1F, kE, WTQ, QBUF, kE, M_BT, kE, kE,
            a1_qkv_b, TAG_AUTO, 0L, nullptr, 0, 1, DF);
    mgemm32(stream, N1F, kE, WTKV, KVB, 2 * kE, M_BT, 2 * kE, kE,
            a1_qkv_b, TAG_AUTO, (long)kE, nullptr, 0, 1, DF);
    gemm(stream, a1_agents, TAG_AUTO, kHS, 0L, a1_agq_w, TAG_AUTO, kHS, 0L, QA, kHS, 0L,
         kH * kA, kHS, kHS, a1_agq_b, TAG_AUTO, 0, 0, nullptr, 0, 1, 1, DF);
    gemm(stream, KVB, TAG_F32, 2 * kE, 64L, a1_agk_w, TAG_AUTO, kHS, 0L, KA, kHS, bsKA,
         M_BT, kHS, kHS, a1_agk_b, TAG_AUTO, 0, 0, nullptr, 0, 1, kH, DF);
    gemm(stream, KVB + kE, TAG_F32, 2 * kE, 64L, a1_agv_w, TAG_AUTO, kHS, 0L, VA, kHS, bsKA,
         M_BT, kHS, kHS, a1_agv_b, TAG_AUTO, 0, 0, nullptr, 0, 1, kH, DF);
    k_agatt1<<<kB * kH * (kA / 4), 256, 0, stream>>>(QA, KA, VA, C1);
    k_agatt2f<<<kB * kH * (kT / 16), 256, 0, stream>>>(QBUF, kE, C1, ATTF);
    mgemm32(stream, ATTF, kE, WAGO, Y2F, kE, M_BT, kE, kE,
            a1_ago_b, TAG_AUTO, 0L, nullptr, 0, 1, DF);
    mgemm32(stream, Y2F, kE, WPRJ, XC, kE, M_BT, kE, kE,
            a1_proj_b, TAG_AUTO, 0L, AD1 + 2 * kE, 3 * kE, kT, DF);

    // phase-2 weight transposes (WREG safely reusable after prj1)
    k_wtf<<<dim3(1024/32, 1024/32), 256, 0, stream>>>(a2_q_w, WTQ, 1024, 1024, 0, DF);
    k_wtf<<<dim3(2048/32, 1024/32), 256, 0, stream>>>(a2_kv_w, WTKV, 1024, 2048, 0, DF);
    k_wtf<<<dim3(1024/32, 1024/32), 256, 0, stream>>>(a2_ago_w, WAGO, 1024, 1024, 0, DF);
    k_wtf<<<dim3(1024/32, 1024/32), 256, 0, stream>>>(a2_proj_w, WPRJ, 1024, 1024, 0, DF);

    // ---- attention block 2 (cross) ----
    k_castin<<<(kB * kT * kE) / 1024, 256, 0, stream>>>(enc, N1F, DF);   // ENCF in N1F slot
    mgemm32(stream, N1F, kE, WTKV, KVB, 2 * kE, M_BT, 2 * kE, kE,
            a2_kv_b, TAG_AUTO, 0L, nullptr, 0, 1, DF);
    k_adalnf<<<M_BT, 256, 0, stream>>>(XC, AD11, N1F);                    // overwrites ENCF (dead)
    mgemm32(stream, N1F, kE, WTQ, QBUF, kE, M_BT, kE, kE,
            a2_q_b, TAG_AUTO, 0L, nullptr, 0, 1, DF);
    gemm(stream, a2_agents, TAG_AUTO, kHS, 0L, a2_agq_w, TAG_AUTO, kHS, 0L, QA, kHS, 0L,
         kH * kA, kHS, kHS, a2_agq_b, TAG_AUTO, 0, 0, nullptr, 0, 1, 1, DF);
    gemm(stream, KVB, TAG_F32, 2 * kE, 64L, a2_agk_w, TAG_AUTO, kHS, 0L, KA, kHS, bsKA,
         M_BT, kHS, kHS, a2_agk_b, TAG_AUTO, 0, 0, nullptr, 0, 1, kH, DF);
    gemm(stream, KVB + kE, TAG_F32, 2 * kE, 64L, a2_agv_w, TAG_AUTO, kHS, 0L, VA, kHS, bsKA,
         M_BT, kHS, kHS, a2_agv_b, TAG_AUTO, 0, 0, nullptr, 0, 1, kH, DF);
    k_agatt1<<<kB * kH * (kA / 4), 256, 0, stream>>>(QA, KA, VA, C1);
    k_agatt2f<<<kB * kH * (kT / 16), 256, 0, stream>>>(QBUF, kE, C1, ATTF);
    mgemm32(stream, ATTF, kE, WAGO, Y2F, kE, M_BT, kE, kE,
            a2_ago_b, TAG_AUTO, 0L, nullptr, 0, 1, DF);
    mgemm32(stream, Y2F, kE, WPRJ, XC, kE, M_BT, kE, kE,
            a2_proj_b, TAG_AUTO, 0L, AD11 + 2 * kE, 3 * kE, kT, DF);

    // ---- phase 3: p = einsum('bce,oc->boe') via batched split-MFMA ----
    // PRW = pr_w cast to fp32; XCT = per-batch transpose of XC (both in WREG,
    // phase-2 weights dead).  Old fp32-VALU k_gemm: 126 us @ VALUBusy 60%.
    k_castin<<<(1024 * 512) / 1024, 256, 0, stream>>>(pr_w, PRW, DF);
    k_xt<<<dim3(kE / 32, kT / 32, kB), 256, 0, stream>>>(XC, XCT);
    mgemm32(stream, PRW, kT, XCT, P, kE, kT2, kE, kT,
            pr_b, TAG_AUTO, 0L, nullptr, 0, 1, DF,
            /*biasRow*/1, /*bsA*/0L, /*bsW*/(long)kE * kT, /*bsC*/(long)kT2 * kE,
            /*batch*/kB);
    gemm(stream, TRIG, TAG_F32, kT, 0L, P + (long)kT * kE, TAG_F32, kE, (long)kT2 * kE,
         RE, kE, (long)kNFREQ * kE, kNFREQ, kE, kT,
         nullptr, 0, 0, 0, nullptr, 0, 1, kB, DF);
    gemm(stream, TRIG + (long)kNFREQ * kT, TAG_F32, kT, 0L, P + (long)kT * kE, TAG_F32, kE, (long)kT2 * kE,
         IM, kE, (long)kNFREQ * kE, kNFREQ, kE, kT,
         nullptr, 0, 0, 0, nullptr, 0, 1, kB, DF);
    k_topk<<<(kB * kE) / 16, 256, 0, stream>>>(RE, IM, TRE, TIM, TIX);
    k_season<<<(kB * kT * kE) / 256, 256, 0, stream>>>(TRE, TIM, TIX, TRIG, d_out, O3, DF);
    k_conv1<<<dim3(kB * 3, 8), 256, 0, stream>>>(P, tr_c1_w, tr_c1_b, G1, DF);
    k_conv2<<<kB * kNF, 256, 0, stream>>>(G1, tr_c2_w, tr_c2_b, H2, DF);
    k_trend<<<(kB * kT * kNF) / 256, 256, 0, stream>>>(H2, d_out, O2, DF);

    // ---- phase 4: MLP (post-P; plain bf16 MFMA -- proven on outputs 0/1) ----
    k_wt<<<dim3(4096/32, 1024/32), 256, 0, stream>>>(mlp_w1, W1B, 1024, 4096, DF);
    k_wt<<<dim3(1024/32, 4096/32), 256, 0, stream>>>(mlp_w2, W2B, 4096, 1024, DF);
    k_adaln<<<M_BT, 256, 0, stream>>>(XC, AD2, N1B);
    mgemm(stream, N1B, kE, W1B, HID, kMLP, M_BT, kMLP, kE,
          mlp_b1, TAG_AUTO, 1 /*gelu*/, nullptr, 0, 1, DF);
    mgemm(stream, HID, kMLP, W2B, XC, kE, M_BT, kE, kMLP,
          mlp_b2, TAG_AUTO, 0, AD2 + 2 * kE, 3 * kE, kT, DF);

    // ---- finals ----
    k_mean<<<(kB * kE) / 256, 256, 0, stream>>>(XC, MB);
    k_out0<<<(kB * kT * kE) / 256, 256, 0, stream>>>(XC, MB, d_out, O0, DF);
    k_out1<<<kB, 256, 0, stream>>>(MB, lin_w, lin_b, d_out, O1, DF);
}